// Round 15
// baseline (986.192 us; speedup 1.0000x reference)
//
#include <hip/hip_runtime.h>
#include <math.h>

// ---------------------------------------------------------------------------
// STDF forward, round 15: w_om head conv c8 -> c16 (16 co/thread; proven
// direction for this barrier-free kernel, halves input refetch). Everything
// else byte-identical to round 14 (981us verified; conv3db frozen at its
// issue-bound 331us).
// ---------------------------------------------------------------------------

#define TPB 256

static inline int nblk(long long total) { return (int)((total + TPB - 1) / TPB); }

// ---------------- 3x3 conv2d, stride 1, 4 outputs/thread, block-uniform co --
template <int TB, int RELU, int HAS_RES>
__global__ __launch_bounds__(TB) void conv2d_t4_k(
    const float* __restrict__ in, const float* __restrict__ w,
    const float* __restrict__ bias, const float* __restrict__ res,
    float* __restrict__ out, int B, int Ci, int H, int W, int Co, int BPC) {
    __shared__ float ws_w[32 * 9];
    int co = (blockIdx.x / BPC) % Co;
    int b  = blockIdx.x / (BPC * Co);
    for (int i = threadIdx.x; i < Ci * 9; i += TB)
        ws_w[i] = w[(size_t)co * Ci * 9 + i];
    __syncthreads();
    int nq = W >> 2;
    int r = (blockIdx.x % BPC) * TB + threadIdx.x;
    if (r >= H * nq) return;
    int q = r % nq, ho = r / nq;
    int wb = q * 4;
    float bv = bias[co];
    float a0 = bv, a1 = bv, a2 = bv, a3 = bv;
    const float* ipb = in + (size_t)b * Ci * H * W;
    for (int ci = 0; ci < Ci; ++ci) {
        const float* ip = ipb + (size_t)ci * H * W;
        const float* wc = ws_w + ci * 9;
#pragma unroll
        for (int kh = 0; kh < 3; ++kh) {
            int y = ho - 1 + kh;
            if (y < 0 || y >= H) continue;
            const float* row = ip + (size_t)y * W + wb;
            float4 xv = *(const float4*)row;
            float xm = (wb > 0) ? row[-1] : 0.f;
            float xp = (wb + 4 < W) ? row[4] : 0.f;
            float w0 = wc[kh * 3], w1 = wc[kh * 3 + 1], w2 = wc[kh * 3 + 2];
            a0 += xm   * w0 + xv.x * w1 + xv.y * w2;
            a1 += xv.x * w0 + xv.y * w1 + xv.z * w2;
            a2 += xv.y * w0 + xv.z * w1 + xv.w * w2;
            a3 += xv.z * w0 + xv.w * w1 + xp   * w2;
        }
    }
    size_t o = ((size_t)(b * Co + co) * H + ho) * W + wb;
    if (HAS_RES) {
        float4 rv = *(const float4*)(res + o);
        a0 += rv.x; a1 += rv.y; a2 += rv.z; a3 += rv.w;
    }
    if (RELU) { a0 = fmaxf(a0, 0.f); a1 = fmaxf(a1, 0.f); a2 = fmaxf(a2, 0.f); a3 = fmaxf(a3, 0.f); }
    *(float4*)(out + o) = make_float4(a0, a1, a2, a3);
}

// ------- 3x3 conv2d, stride 1, 4 outputs x 4 co per thread -----------------
template <int RELU, int HAS_RES, int HAS_IN2>
__global__ __launch_bounds__(TPB) void conv2d_c4_k(
    const float* __restrict__ in, const float* __restrict__ in2,
    const float* __restrict__ w, const float* __restrict__ bias,
    const float* __restrict__ res, float* __restrict__ out,
    int B, int Ci, int H, int W, int Co, int COG, int BPC) {
    __shared__ float ws_w[4 * 32 * 9];
    int cog = (blockIdx.x / BPC) % COG;
    int b   = blockIdx.x / (BPC * COG);
    int co0 = cog * 4;
    int nw = Ci * 9;
    for (int i = threadIdx.x; i < 4 * nw; i += TPB) {
        int cr = i / nw; int co = co0 + cr;
        ws_w[i] = (co < Co) ? w[(size_t)co * nw + (i - cr * nw)] : 0.f;
    }
    __syncthreads();
    int nq = W >> 2;
    int r = (blockIdx.x % BPC) * TPB + threadIdx.x;
    if (r >= H * nq) return;
    int q = r % nq, ho = r / nq;
    int wb = q * 4;
    float a[4][4];
#pragma unroll
    for (int cr = 0; cr < 4; ++cr) {
        float bv = (co0 + cr < Co) ? bias[co0 + cr] : 0.f;
        a[cr][0] = bv; a[cr][1] = bv; a[cr][2] = bv; a[cr][3] = bv;
    }
    const float* ipb = in + (size_t)b * Ci * H * W;
    const float* ipb2 = HAS_IN2 ? in2 + (size_t)b * Ci * H * W : nullptr;
    for (int ci = 0; ci < Ci; ++ci) {
        const float* ip = ipb + (size_t)ci * H * W;
        const float* ip2 = HAS_IN2 ? ipb2 + (size_t)ci * H * W : nullptr;
#pragma unroll
        for (int kh = 0; kh < 3; ++kh) {
            int y = ho - 1 + kh;
            if (y < 0 || y >= H) continue;
            const float* row = ip + (size_t)y * W + wb;
            float4 xv = *(const float4*)row;
            float x_[6];
            x_[0] = (wb > 0) ? row[-1] : 0.f;
            x_[5] = (wb + 4 < W) ? row[4] : 0.f;
            if (HAS_IN2) {
                const float* row2 = ip2 + (size_t)y * W + wb;
                float4 x2 = *(const float4*)row2;
                xv.x += x2.x; xv.y += x2.y; xv.z += x2.z; xv.w += x2.w;
                if (wb > 0) x_[0] += row2[-1];
                if (wb + 4 < W) x_[5] += row2[4];
            }
            x_[1] = xv.x; x_[2] = xv.y; x_[3] = xv.z; x_[4] = xv.w;
#pragma unroll
            for (int cr = 0; cr < 4; ++cr) {
                const float* wc = ws_w + cr * nw + ci * 9 + kh * 3;
                float w0 = wc[0], w1 = wc[1], w2 = wc[2];
                a[cr][0] += x_[0] * w0 + x_[1] * w1 + x_[2] * w2;
                a[cr][1] += x_[1] * w0 + x_[2] * w1 + x_[3] * w2;
                a[cr][2] += x_[2] * w0 + x_[3] * w1 + x_[4] * w2;
                a[cr][3] += x_[3] * w0 + x_[4] * w1 + x_[5] * w2;
            }
        }
    }
#pragma unroll
    for (int cr = 0; cr < 4; ++cr) {
        int co = co0 + cr;
        if (co >= Co) break;
        size_t o = ((size_t)(b * Co + co) * H + ho) * W + wb;
        float a0 = a[cr][0], a1 = a[cr][1], a2 = a[cr][2], a3 = a[cr][3];
        if (HAS_RES) {
            float4 rv = *(const float4*)(res + o);
            a0 += rv.x; a1 += rv.y; a2 += rv.z; a3 += rv.w;
        }
        if (RELU) { a0 = fmaxf(a0, 0.f); a1 = fmaxf(a1, 0.f); a2 = fmaxf(a2, 0.f); a3 = fmaxf(a3, 0.f); }
        *(float4*)(out + o) = make_float4(a0, a1, a2, a3);
    }
}

// ------- 3x3 conv2d, stride 1, 4 outputs x 16 co per thread (for w_om) -----
template <int RELU>
__global__ __launch_bounds__(TPB) void conv2d_c16_k(
    const float* __restrict__ in, const float* __restrict__ w,
    const float* __restrict__ bias, float* __restrict__ out,
    int B, int Ci, int H, int W, int Co, int COG, int BPC) {
    __shared__ __align__(16) float4 ws0[32 * 9];
    __shared__ __align__(16) float4 ws1[32 * 9];
    __shared__ __align__(16) float4 ws2[32 * 9];
    __shared__ __align__(16) float4 ws3[32 * 9];
    int cog = (blockIdx.x / BPC) % COG;
    int b   = blockIdx.x / (BPC * COG);
    int co0 = cog * 16;
    int nw = Ci * 9;
    for (int i = threadIdx.x; i < nw; i += TPB) {
#pragma unroll
        for (int gq = 0; gq < 4; ++gq) {
            float4 v;
            int cb = co0 + gq * 4;
            v.x = (cb + 0 < Co) ? w[(size_t)(cb + 0) * nw + i] : 0.f;
            v.y = (cb + 1 < Co) ? w[(size_t)(cb + 1) * nw + i] : 0.f;
            v.z = (cb + 2 < Co) ? w[(size_t)(cb + 2) * nw + i] : 0.f;
            v.w = (cb + 3 < Co) ? w[(size_t)(cb + 3) * nw + i] : 0.f;
            if (gq == 0) ws0[i] = v;
            else if (gq == 1) ws1[i] = v;
            else if (gq == 2) ws2[i] = v;
            else ws3[i] = v;
        }
    }
    __syncthreads();
    int nq = W >> 2;
    int r = (blockIdx.x % BPC) * TPB + threadIdx.x;
    if (r >= H * nq) return;
    int q = r % nq, ho = r / nq;
    int wb = q * 4;
    float a[16][4];
#pragma unroll
    for (int cr = 0; cr < 16; ++cr) {
        float bv = (co0 + cr < Co) ? bias[co0 + cr] : 0.f;
        a[cr][0] = bv; a[cr][1] = bv; a[cr][2] = bv; a[cr][3] = bv;
    }
    const float* ipb = in + (size_t)b * Ci * H * W;
    for (int ci = 0; ci < Ci; ++ci) {
        const float* ip = ipb + (size_t)ci * H * W;
#pragma unroll
        for (int kh = 0; kh < 3; ++kh) {
            int y = ho - 1 + kh;
            if (y < 0 || y >= H) continue;
            const float* row = ip + (size_t)y * W + wb;
            float4 xv = *(const float4*)row;
            float x_[6];
            x_[0] = (wb > 0) ? row[-1] : 0.f;
            x_[1] = xv.x; x_[2] = xv.y; x_[3] = xv.z; x_[4] = xv.w;
            x_[5] = (wb + 4 < W) ? row[4] : 0.f;
#pragma unroll
            for (int kw = 0; kw < 3; ++kw) {
                int wi = ci * 9 + kh * 3 + kw;
                float4 v0 = ws0[wi], v1 = ws1[wi], v2 = ws2[wi], v3 = ws3[wi];
                float x0 = x_[kw], x1 = x_[kw + 1], x2 = x_[kw + 2], x3 = x_[kw + 3];
                a[0][0]  += x0 * v0.x; a[0][1]  += x1 * v0.x; a[0][2]  += x2 * v0.x; a[0][3]  += x3 * v0.x;
                a[1][0]  += x0 * v0.y; a[1][1]  += x1 * v0.y; a[1][2]  += x2 * v0.y; a[1][3]  += x3 * v0.y;
                a[2][0]  += x0 * v0.z; a[2][1]  += x1 * v0.z; a[2][2]  += x2 * v0.z; a[2][3]  += x3 * v0.z;
                a[3][0]  += x0 * v0.w; a[3][1]  += x1 * v0.w; a[3][2]  += x2 * v0.w; a[3][3]  += x3 * v0.w;
                a[4][0]  += x0 * v1.x; a[4][1]  += x1 * v1.x; a[4][2]  += x2 * v1.x; a[4][3]  += x3 * v1.x;
                a[5][0]  += x0 * v1.y; a[5][1]  += x1 * v1.y; a[5][2]  += x2 * v1.y; a[5][3]  += x3 * v1.y;
                a[6][0]  += x0 * v1.z; a[6][1]  += x1 * v1.z; a[6][2]  += x2 * v1.z; a[6][3]  += x3 * v1.z;
                a[7][0]  += x0 * v1.w; a[7][1]  += x1 * v1.w; a[7][2]  += x2 * v1.w; a[7][3]  += x3 * v1.w;
                a[8][0]  += x0 * v2.x; a[8][1]  += x1 * v2.x; a[8][2]  += x2 * v2.x; a[8][3]  += x3 * v2.x;
                a[9][0]  += x0 * v2.y; a[9][1]  += x1 * v2.y; a[9][2]  += x2 * v2.y; a[9][3]  += x3 * v2.y;
                a[10][0] += x0 * v2.z; a[10][1] += x1 * v2.z; a[10][2] += x2 * v2.z; a[10][3] += x3 * v2.z;
                a[11][0] += x0 * v2.w; a[11][1] += x1 * v2.w; a[11][2] += x2 * v2.w; a[11][3] += x3 * v2.w;
                a[12][0] += x0 * v3.x; a[12][1] += x1 * v3.x; a[12][2] += x2 * v3.x; a[12][3] += x3 * v3.x;
                a[13][0] += x0 * v3.y; a[13][1] += x1 * v3.y; a[13][2] += x2 * v3.y; a[13][3] += x3 * v3.y;
                a[14][0] += x0 * v3.z; a[14][1] += x1 * v3.z; a[14][2] += x2 * v3.z; a[14][3] += x3 * v3.z;
                a[15][0] += x0 * v3.w; a[15][1] += x1 * v3.w; a[15][2] += x2 * v3.w; a[15][3] += x3 * v3.w;
            }
        }
    }
#pragma unroll
    for (int cr = 0; cr < 16; ++cr) {
        int co = co0 + cr;
        if (co >= Co) break;
        size_t o = ((size_t)(b * Co + co) * H + ho) * W + wb;
        float a0 = a[cr][0], a1 = a[cr][1], a2 = a[cr][2], a3 = a[cr][3];
        if (RELU) { a0 = fmaxf(a0, 0.f); a1 = fmaxf(a1, 0.f); a2 = fmaxf(a2, 0.f); a3 = fmaxf(a3, 0.f); }
        *(float4*)(out + o) = make_float4(a0, a1, a2, a3);
    }
}

// ------------- 3x3 conv2d over concat of two 32-ch inputs, stride 1, relu ---
template <int TB>
__global__ __launch_bounds__(TB) void conv2d_cat_t4_k(
    const float* __restrict__ in1, const float* __restrict__ in2,
    const float* __restrict__ w, const float* __restrict__ bias,
    float* __restrict__ out, int B, int C1, int C2, int H, int W, int Co, int BPC) {
    __shared__ float ws_w[64 * 9];
    int Ci = C1 + C2;
    int co = (blockIdx.x / BPC) % Co;
    int b  = blockIdx.x / (BPC * Co);
    for (int i = threadIdx.x; i < Ci * 9; i += TB)
        ws_w[i] = w[(size_t)co * Ci * 9 + i];
    __syncthreads();
    int nq = W >> 2;
    int r = (blockIdx.x % BPC) * TB + threadIdx.x;
    if (r >= H * nq) return;
    int q = r % nq, ho = r / nq;
    int wb = q * 4;
    float bv = bias[co];
    float a0 = bv, a1 = bv, a2 = bv, a3 = bv;
    for (int ci = 0; ci < Ci; ++ci) {
        const float* ip = (ci < C1)
            ? in1 + ((size_t)(b * C1 + ci)) * H * W
            : in2 + ((size_t)(b * C2 + (ci - C1))) * H * W;
        const float* wc = ws_w + ci * 9;
#pragma unroll
        for (int kh = 0; kh < 3; ++kh) {
            int y = ho - 1 + kh;
            if (y < 0 || y >= H) continue;
            const float* row = ip + (size_t)y * W + wb;
            float4 xv = *(const float4*)row;
            float xm = (wb > 0) ? row[-1] : 0.f;
            float xp = (wb + 4 < W) ? row[4] : 0.f;
            float w0 = wc[kh * 3], w1 = wc[kh * 3 + 1], w2 = wc[kh * 3 + 2];
            a0 += xm   * w0 + xv.x * w1 + xv.y * w2;
            a1 += xv.x * w0 + xv.y * w1 + xv.z * w2;
            a2 += xv.y * w0 + xv.z * w1 + xv.w * w2;
            a3 += xv.z * w0 + xv.w * w1 + xp   * w2;
        }
    }
    size_t o = ((size_t)(b * Co + co) * H + ho) * W + wb;
    *(float4*)(out + o) = make_float4(fmaxf(a0, 0.f), fmaxf(a1, 0.f), fmaxf(a2, 0.f), fmaxf(a3, 0.f));
}

// ------------- 3x3 conv2d, stride 2, 4 outputs/thread, relu ----------------
template <int TB>
__global__ __launch_bounds__(TB) void conv2d_s2_t4_k(
    const float* __restrict__ in, const float* __restrict__ w,
    const float* __restrict__ bias, float* __restrict__ out,
    int B, int Ci, int Hi, int Wi, int Co, int BPC) {
    __shared__ float ws_w[32 * 9];
    int Ho = Hi >> 1, Wo = Wi >> 1;
    int co = (blockIdx.x / BPC) % Co;
    int b  = blockIdx.x / (BPC * Co);
    for (int i = threadIdx.x; i < Ci * 9; i += TB)
        ws_w[i] = w[(size_t)co * Ci * 9 + i];
    __syncthreads();
    int nq = Wo >> 2;
    int r = (blockIdx.x % BPC) * TB + threadIdx.x;
    if (r >= Ho * nq) return;
    int q = r % nq, ho = r / nq;
    int wb = q * 4;
    float bv = bias[co];
    float a0 = bv, a1 = bv, a2 = bv, a3 = bv;
    const float* ipb = in + (size_t)b * Ci * Hi * Wi;
    for (int ci = 0; ci < Ci; ++ci) {
        const float* ip = ipb + (size_t)ci * Hi * Wi;
        const float* wc = ws_w + ci * 9;
#pragma unroll
        for (int kh = 0; kh < 3; ++kh) {
            int y = 2 * ho - 1 + kh;
            if (y < 0 || y >= Hi) continue;
            const float* row = ip + (size_t)y * Wi;
            float z0 = (2 * wb - 1 >= 0) ? row[2 * wb - 1] : 0.f;
            float4 za = *(const float4*)(row + 2 * wb);
            float4 zb = *(const float4*)(row + 2 * wb + 4);
            float w0 = wc[kh * 3], w1 = wc[kh * 3 + 1], w2 = wc[kh * 3 + 2];
            a0 += z0   * w0 + za.x * w1 + za.y * w2;
            a1 += za.y * w0 + za.z * w1 + za.w * w2;
            a2 += za.w * w0 + zb.x * w1 + zb.y * w2;
            a3 += zb.y * w0 + zb.z * w1 + zb.w * w2;
        }
    }
    size_t o = ((size_t)(b * Co + co) * Ho + ho) * Wo + wb;
    *(float4*)(out + o) = make_float4(fmaxf(a0, 0.f), fmaxf(a1, 0.f), fmaxf(a2, 0.f), fmaxf(a3, 0.f));
}

// ------------- transposed conv 4x4 stride 2, 4 outputs/thread, relu --------
template <int TB>
__global__ __launch_bounds__(TB) void convt2d_t4_k(
    const float* __restrict__ in, const float* __restrict__ wt,
    const float* __restrict__ bias, float* __restrict__ out,
    int B, int C, int Hi, int Wi, int BPC) {
    __shared__ float ws_w[32 * 16];
    int Ho = 2 * Hi, Wo = 2 * Wi;
    int co = (blockIdx.x / BPC) % C;
    int b  = blockIdx.x / (BPC * C);
    for (int i = threadIdx.x; i < C * 16; i += TB) {
        int ci = i >> 4, t = i & 15;
        ws_w[i] = wt[((size_t)ci * C + co) * 16 + t];
    }
    __syncthreads();
    int nq = Wo >> 2;
    int r = (blockIdx.x % BPC) * TB + threadIdx.x;
    if (r >= Ho * nq) return;
    int q = r % nq, ho = r / nq;
    int wb = q * 4;
    int p = ho & 1;
    int iy0 = (ho + p) / 2 - 1;
    int iy1 = iy0 + 1;
    int ix0 = wb / 2 - 1;
    bool vy0 = (iy0 >= 0) && (iy0 < Hi);
    bool vy1 = (iy1 >= 0) && (iy1 < Hi);
    float bv = bias[co];
    float a0 = bv, a1 = bv, a2 = bv, a3 = bv;
    const float* ipb = in + (size_t)b * C * Hi * Wi;
    for (int ci = 0; ci < C; ++ci) {
        const float* ip = ipb + (size_t)ci * Hi * Wi;
        float u0 = 0, u1 = 0, u2 = 0, u3 = 0, v0 = 0, v1 = 0, v2 = 0, v3 = 0;
        if (vy0) {
            const float* rw = ip + (size_t)iy0 * Wi;
            if (ix0 >= 0) u0 = rw[ix0];
            u1 = rw[ix0 + 1]; u2 = rw[ix0 + 2];
            if (ix0 + 3 < Wi) u3 = rw[ix0 + 3];
        }
        if (vy1) {
            const float* rw = ip + (size_t)iy1 * Wi;
            if (ix0 >= 0) v0 = rw[ix0];
            v1 = rw[ix0 + 1]; v2 = rw[ix0 + 2];
            if (ix0 + 3 < Wi) v3 = rw[ix0 + 3];
        }
        const float* wr0 = ws_w + ci * 16 + (3 - p) * 4;
        const float* wr1 = ws_w + ci * 16 + (1 - p) * 4;
        a0 += u0 * wr0[3] + u1 * wr0[1] + v0 * wr1[3] + v1 * wr1[1];
        a1 += u1 * wr0[2] + u2 * wr0[0] + v1 * wr1[2] + v2 * wr1[0];
        a2 += u1 * wr0[3] + u2 * wr0[1] + v1 * wr1[3] + v2 * wr1[1];
        a3 += u2 * wr0[2] + u3 * wr0[0] + v2 * wr1[2] + v3 * wr1[0];
    }
    size_t o = ((size_t)(b * C + co) * Ho + ho) * Wo + wb;
    *(float4*)(out + o) = make_float4(fmaxf(a0, 0.f), fmaxf(a1, 0.f), fmaxf(a2, 0.f), fmaxf(a3, 0.f));
}

// ---- merged prep: wb transpose + wdc transpose + xa border zero -------------
__global__ void prep_k(const float* __restrict__ wb, const float* __restrict__ wdc,
                       float* __restrict__ wt, float* __restrict__ wt2,
                       float* __restrict__ xa_g) {
    int i = blockIdx.x * TPB + threadIdx.x;
    if (i < 27648) {
        int kd = i % 3; int t = i / 3;
        int co = t % 32; t /= 32;
        int j  = t % 9;  int ci = t / 9;
        wt[i] = wb[(size_t)(co * 32 + ci) * 27 + kd * 9 + j];
        return;
    }
    int i2 = i - 27648;
    if (i2 < 4032) {
        int o = i2 & 63, ck = i2 >> 6;
        wt2[i2] = wdc[o * 63 + ck];
        return;
    }
    int i3 = i2 - 4032;
    if (i3 >= 448 * 644) return;
    int pl = i3 / 644, e = i3 % 644;
    int off;
    if (e < 162)      off = e;
    else if (e < 324) off = 161 * 162 + (e - 162);
    else if (e < 484) off = (e - 324 + 1) * 162;
    else              off = (e - 484 + 1) * 162 + 161;
    xa_g[(size_t)pl * 26244 + off] = 0.f;
}

// ---- conv3d_a: x (B,7,H,W) -> relu -> padded xa [B][32][7][162][162] -------
__global__ __launch_bounds__(TPB) void conv3da_k(
    const float* __restrict__ x, const float* __restrict__ wa,
    const float* __restrict__ ba, float* __restrict__ xa_g,
    int B, int H, int W) {
    __shared__ float w27[27];
    int blk = blockIdx.x;
    int t5 = blk % 25; int rest = blk / 25;
    int d = rest % 7; rest /= 7;
    int co = rest % 32; int b = rest / 32;
    if (threadIdx.x < 27) w27[threadIdx.x] = wa[co * 27 + threadIdx.x];
    __syncthreads();
    int r = t5 * TPB + threadIdx.x;
    if (r >= 160 * 40) return;
    int y = r / 40, x0 = (r % 40) * 4;
    float bv = ba[co];
    float a0 = bv, a1 = bv, a2 = bv, a3 = bv;
#pragma unroll
    for (int kd = 0; kd < 3; ++kd) {
        int dz = d + kd - 1;
        if (dz < 0 || dz >= 7) continue;
        const float* pl = x + ((size_t)(b * 7 + dz)) * H * W;
#pragma unroll
        for (int kh = 0; kh < 3; ++kh) {
            int yy = y + kh - 1;
            if (yy < 0 || yy >= H) continue;
            const float* row = pl + (size_t)yy * W + x0;
            float4 xv = *(const float4*)row;
            float xm = (x0 > 0) ? row[-1] : 0.f;
            float xp = (x0 + 4 < W) ? row[4] : 0.f;
            float w0 = w27[kd * 9 + kh * 3], w1 = w27[kd * 9 + kh * 3 + 1], w2 = w27[kd * 9 + kh * 3 + 2];
            a0 += xm   * w0 + xv.x * w1 + xv.y * w2;
            a1 += xv.x * w0 + xv.y * w1 + xv.z * w2;
            a2 += xv.y * w0 + xv.z * w1 + xv.w * w2;
            a3 += xv.z * w0 + xv.w * w1 + xp   * w2;
        }
    }
    size_t base = ((size_t)((b * 32 + co) * 7 + d)) * 26244 + (size_t)(y + 1) * 162 + (x0 + 1);
    xa_g[base + 0] = fmaxf(a0, 0.f);
    xa_g[base + 1] = fmaxf(a1, 0.f);
    xa_g[base + 2] = fmaxf(a2, 0.f);
    xa_g[base + 3] = fmaxf(a3, 0.f);
}

// ---- conv3d_b + relu + mean, streaming xa from global (frozen; verified) ---
__global__ __launch_bounds__(TPB) void conv3db_k(
    const float* __restrict__ xa_g, const float* __restrict__ wt,
    const float* __restrict__ bb, float* __restrict__ out,
    int B, int H, int W) {
    __shared__ float xab[2][840];
    const int PLANE = 26244, CI_S = 183708, B_S = 5878656;
    const int RS = 12, DS = 120;
    int half = blockIdx.x & 1;
    int tile = (blockIdx.x >> 1) % 400;
    int b = blockIdx.x / 800;
    int bx = tile % 20, by = tile / 20;
    int h0 = by * 8, w0 = bx * 8;
    int tid = threadIdx.x;
    int p = tid & 63; int px = p & 7; int py = p >> 3;
    int g = tid >> 6;

    int gu = __builtin_amdgcn_readfirstlane(g);
    const float* wbase = wt + half * 48 + gu * 12;

    int it0 = tid, it1 = tid + 256, it2 = tid + 512;
    bool h2 = (it2 < 700);
    int dd0 = it0 / 100, rm0 = it0 % 100;
    int xo0 = dd0 * PLANE + (h0 + rm0 / 10) * 162 + (w0 + rm0 % 10);
    int lo0 = dd0 * DS + (rm0 / 10) * RS + rm0 % 10;
    int dd1 = it1 / 100, rm1 = it1 % 100;
    int xo1 = dd1 * PLANE + (h0 + rm1 / 10) * 162 + (w0 + rm1 % 10);
    int lo1 = dd1 * DS + (rm1 / 10) * RS + rm1 % 10;
    int xo2 = 0, lo2 = 0;
    if (h2) {
        int dd2 = it2 / 100, rm2 = it2 % 100;
        xo2 = dd2 * PLANE + (h0 + rm2 / 10) * 162 + (w0 + rm2 % 10);
        lo2 = dd2 * DS + (rm2 / 10) * RS + rm2 % 10;
    }

    const float* xbase = xa_g + (size_t)b * B_S;

    float acc[4][7];
#pragma unroll
    for (int r = 0; r < 4; ++r) {
        float bv = bb[half * 16 + g * 4 + r];
#pragma unroll
        for (int d = 0; d < 7; ++d) acc[r][d] = bv;
    }

    {
        float r0 = xbase[xo0], r1 = xbase[xo1], r2 = h2 ? xbase[xo2] : 0.f;
        xab[0][lo0] = r0; xab[0][lo1] = r1; if (h2) xab[0][lo2] = r2;
    }
    __syncthreads();

    for (int ci = 0; ci < 32; ++ci) {
        int cur = ci & 1, nxt = cur ^ 1;
        bool more = (ci + 1 < 32);
        float r0 = 0.f, r1 = 0.f, r2 = 0.f;
        if (more) {
            const float* xs = xbase + (size_t)(ci + 1) * CI_S;
            r0 = xs[xo0]; r1 = xs[xo1]; r2 = h2 ? xs[xo2] : 0.f;
        }
        const float* xab_c = xab[cur];
        const float* wci = wbase + (size_t)ci * 864;
#pragma unroll
        for (int kh = 0; kh < 3; ++kh) {
#pragma unroll
            for (int kw = 0; kw < 3; ++kw) {
                int j = kh * 3 + kw;
                float xav[7];
                const float* xb = xab_c + (py + kh) * RS + (px + kw);
#pragma unroll
                for (int d = 0; d < 7; ++d) xav[d] = xb[d * DS];
                const float4* wp = (const float4*)(wci + j * 96);
                float4 w0 = wp[0], w1 = wp[1], w2 = wp[2];
                float wr[4][3] = {{w0.x, w0.y, w0.z}, {w0.w, w1.x, w1.y},
                                  {w1.z, w1.w, w2.x}, {w2.y, w2.z, w2.w}};
#pragma unroll
                for (int r = 0; r < 4; ++r) {
#pragma unroll
                    for (int d = 1; d < 7; ++d) acc[r][d] += xav[d - 1] * wr[r][0];
#pragma unroll
                    for (int d = 0; d < 7; ++d) acc[r][d] += xav[d] * wr[r][1];
#pragma unroll
                    for (int d = 0; d < 6; ++d) acc[r][d] += xav[d + 1] * wr[r][2];
                }
            }
        }
        if (more) {
            xab[nxt][lo0] = r0; xab[nxt][lo1] = r1; if (h2) xab[nxt][lo2] = r2;
        }
        __syncthreads();
    }

    size_t HW = (size_t)H * W;
#pragma unroll
    for (int r = 0; r < 4; ++r) {
        float s = 0.f;
#pragma unroll
        for (int d = 0; d < 7; ++d) s += fmaxf(acc[r][d], 0.f);
        int co = half * 16 + g * 4 + r;
        out[((size_t)(b * 32 + co)) * HW + (size_t)(h0 + py) * W + (w0 + px)] = s * (1.f / 7.f);
    }
}

// ------------- two-phase modulated deformable conv ---------------------------
__global__ __launch_bounds__(TPB) void deform_conv2_k(
    const float* __restrict__ x, const float* __restrict__ om,
    const float* __restrict__ wt2, const float* __restrict__ bias,
    float* __restrict__ out, int B, int H, int W) {
    __shared__ float smp[63 * 64];
    const int HW = H * W;
    int blk = blockIdx.x;
    int b = blk / (HW / 64);
    int pxbase = (blk % (HW / 64)) * 64;
    int tid = threadIdx.x;
    const float* omb = om + (size_t)b * 189 * HW;
    const float* xb = x + (size_t)b * 7 * HW;

#pragma unroll 4
    for (int k = 0; k < 16; ++k) {
        int it = tid + k * 256;
        if (it >= 4032) break;
        int pxl = it & 63;
        int tap = it >> 6;
        int c = tap / 9, kk = tap % 9;
        int hw = pxbase + pxl;
        int hq = hw / W, wq = hw % W;
        float dy = omb[(size_t)(c * 18 + kk * 2 + 0) * HW + hw];
        float dx = omb[(size_t)(c * 18 + kk * 2 + 1) * HW + hw];
        float mv = omb[(size_t)(126 + c * 9 + kk) * HW + hw];
        float m = 1.f / (1.f + __expf(-mv));
        float py = (float)hq + (float)(kk / 3 - 1) + dy;
        float px = (float)wq + (float)(kk % 3 - 1) + dx;
        float y0f = floorf(py), x0f = floorf(px);
        int y0 = (int)y0f, x0 = (int)x0f;
        float wy1 = py - y0f, wx1 = px - x0f;
        float wy0 = 1.f - wy1, wx0 = 1.f - wx1;
        float v00 = 0.f, v01 = 0.f, v10 = 0.f, v11 = 0.f;
        const float* xc = xb + (size_t)c * HW;
        bool yin0 = (y0 >= 0) & (y0 < H);
        bool yin1 = (y0 + 1 >= 0) & (y0 + 1 < H);
        bool xin0 = (x0 >= 0) & (x0 < W);
        bool xin1 = (x0 + 1 >= 0) & (x0 + 1 < W);
        if (yin0) {
            const float* rr = xc + (size_t)y0 * W;
            if (xin0) v00 = rr[x0];
            if (xin1) v01 = rr[x0 + 1];
        }
        if (yin1) {
            const float* rr = xc + (size_t)(y0 + 1) * W;
            if (xin0) v10 = rr[x0];
            if (xin1) v11 = rr[x0 + 1];
        }
        smp[tap * 64 + pxl] =
            (wy0 * wx0 * v00 + wy0 * wx1 * v01 + wy1 * wx0 * v10 + wy1 * wx1 * v11) * m;
    }
    __syncthreads();

    int pxl = tid & 63;
    int g = tid >> 6;
    int gu = __builtin_amdgcn_readfirstlane(g);
    const float* swb = wt2 + gu * 16;
    const float* bsb = bias + gu * 16;
    float acc[16];
#pragma unroll
    for (int o = 0; o < 16; ++o) acc[o] = 0.f;
    for (int tap = 0; tap < 63; ++tap) {
        float s = smp[tap * 64 + pxl];
        const float* sw = swb + tap * 64;
#pragma unroll
        for (int o = 0; o < 16; ++o) acc[o] += s * sw[o];
    }
    int hw = pxbase + pxl;
    size_t obase = (size_t)b * 64 * HW + (size_t)gu * 16 * HW + hw;
#pragma unroll
    for (int o = 0; o < 16; ++o)
        out[obase + (size_t)o * HW] = fmaxf(acc[o] + bsb[o], 0.f);
}

extern "C" void kernel_launch(void* const* d_in, const int* in_sizes, int n_in,
                              void* d_out, int out_size, void* d_ws, size_t ws_size,
                              hipStream_t stream) {
    (void)in_sizes; (void)n_in; (void)out_size; (void)ws_size;
    const float* inputs = (const float*)d_in[0];
    const float* w_in   = (const float*)d_in[1];  const float* b_in   = (const float*)d_in[2];
    const float* w_dn1a = (const float*)d_in[3];  const float* b_dn1a = (const float*)d_in[4];
    const float* w_dn1b = (const float*)d_in[5];  const float* b_dn1b = (const float*)d_in[6];
    const float* w_up1a = (const float*)d_in[7];  const float* b_up1a = (const float*)d_in[8];
    const float* wt_up1 = (const float*)d_in[9];  const float* bt_up1 = (const float*)d_in[10];
    const float* w_dn2a = (const float*)d_in[11]; const float* b_dn2a = (const float*)d_in[12];
    const float* w_dn2b = (const float*)d_in[13]; const float* b_dn2b = (const float*)d_in[14];
    const float* w_up2a = (const float*)d_in[15]; const float* b_up2a = (const float*)d_in[16];
    const float* wt_up2 = (const float*)d_in[17]; const float* bt_up2 = (const float*)d_in[18];
    const float* w_tra  = (const float*)d_in[19]; const float* b_tra  = (const float*)d_in[20];
    const float* w_trb  = (const float*)d_in[21]; const float* b_trb  = (const float*)d_in[22];
    const float* wt_tr  = (const float*)d_in[23]; const float* bt_tr  = (const float*)d_in[24];
    const float* w_out  = (const float*)d_in[25]; const float* b_out  = (const float*)d_in[26];
    const float* w_tf3a = (const float*)d_in[27]; const float* b_tf3a = (const float*)d_in[28];
    const float* w_tf3b = (const float*)d_in[29]; const float* b_tf3b = (const float*)d_in[30];
    const float* w_tf2  = (const float*)d_in[31]; const float* b_tf2  = (const float*)d_in[32];
    const float* w_om   = (const float*)d_in[33]; const float* b_om   = (const float*)d_in[34];
    const float* w_dc   = (const float*)d_in[35]; const float* b_dc   = (const float*)d_in[36];
    float* out = (float*)d_out;

    const int B = 2, nf = 32, H = 160, W = 160;
    const size_t n160 = (size_t)B * nf * 160 * 160;
    const size_t n80  = (size_t)B * nf * 80 * 80;
    const size_t n40  = (size_t)B * nf * 40 * 40;
    const size_t n20  = (size_t)B * nf * 20 * 20;

    float* ws = (float*)d_ws;
    float* F0    = ws;
    float* TMP80 = F0 + n160;
    float* F1    = TMP80 + n80;
    float* TMP40 = F1 + n80;
    float* F2    = TMP40 + n40;
    float* T20A  = F2 + n40;
    float* T20B  = T20A + n20;
    float* T40   = T20B + n20;
    float* T40B  = T40 + n40;
    float* T80   = T40B + n40;
    float* T80B  = T80 + n80;
    float* T160  = T80B + n80;
    float* TF    = T160 + n160;
    float* XA    = TF + n160;
    float* OM    = XA;                 // ALIAS: OM written after XA is dead
    float* WT    = XA + (size_t)2 * 32 * 7 * 162 * 162;
    float* WT2   = WT + 32 * 9 * 32 * 3;

    const int bpc160 = 25;            // ceil(160*40/256)
    const int bpc80_128 = 13;         // ceil(80*20/128)
    const int bpc40_64  = 7;          // ceil(40*10/64)
    const int bpc20_64  = 2;          // ceil(20*5/64)

    // prep (merged) + conv_a
    prep_k<<<nblk(27648 + 4032 + 448 * 644), TPB, 0, stream>>>(w_tf3b, w_dc, WT, WT2, XA);
    conv3da_k<<<B * 32 * 7 * 25, TPB, 0, stream>>>(inputs, w_tf3a, b_tf3a, XA, B, H, W);

    // --- 2D U-Net branch ---
    conv2d_c4_k<1, 0, 0><<<B * 8 * bpc160, TPB, 0, stream>>>(inputs, nullptr, w_in, b_in, nullptr, F0, B, 7, 160, 160, nf, 8, bpc160);
    conv2d_s2_t4_k<128><<<B * nf * bpc80_128, 128, 0, stream>>>(F0, w_dn1a, b_dn1a, TMP80, B, nf, 160, 160, nf, bpc80_128);
    conv2d_t4_k<128, 1, 0><<<B * nf * bpc80_128, 128, 0, stream>>>(TMP80, w_dn1b, b_dn1b, nullptr, F1, B, nf, 80, 80, nf, bpc80_128);
    conv2d_s2_t4_k<64><<<B * nf * bpc40_64, 64, 0, stream>>>(F1, w_dn2a, b_dn2a, TMP40, B, nf, 80, 80, nf, bpc40_64);
    conv2d_t4_k<64, 1, 0><<<B * nf * bpc40_64, 64, 0, stream>>>(TMP40, w_dn2b, b_dn2b, nullptr, F2, B, nf, 40, 40, nf, bpc40_64);
    conv2d_s2_t4_k<64><<<B * nf * bpc20_64, 64, 0, stream>>>(F2, w_tra, b_tra, T20A, B, nf, 40, 40, nf, bpc20_64);
    conv2d_t4_k<64, 1, 0><<<B * nf * bpc20_64, 64, 0, stream>>>(T20A, w_trb, b_trb, nullptr, T20B, B, nf, 20, 20, nf, bpc20_64);
    convt2d_t4_k<64><<<B * nf * bpc40_64, 64, 0, stream>>>(T20B, wt_tr, bt_tr, T40, B, nf, 20, 20, bpc40_64);
    conv2d_cat_t4_k<64><<<B * nf * bpc40_64, 64, 0, stream>>>(T40, F2, w_up2a, b_up2a, T40B, B, nf, nf, 40, 40, nf, bpc40_64);
    convt2d_t4_k<128><<<B * nf * bpc80_128, 128, 0, stream>>>(T40B, wt_up2, bt_up2, T80, B, nf, 40, 40, bpc80_128);
    conv2d_cat_t4_k<128><<<B * nf * bpc80_128, 128, 0, stream>>>(T80, F1, w_up1a, b_up1a, T80B, B, nf, nf, 80, 80, nf, bpc80_128);
    convt2d_t4_k<256><<<B * nf * bpc160, 256, 0, stream>>>(T80B, wt_up1, bt_up1, T160, B, nf, 80, 80, bpc160);

    // --- conv3d_b + relu + mean (streaming) -> F0 ---
    conv3db_k<<<B * 2 * 400, TPB, 0, stream>>>(XA, WT, b_tf3b, F0, B, H, W);
    // FUSED = relu(conv_tf2(MEAN) + T160)
    conv2d_c4_k<1, 1, 0><<<B * 8 * bpc160, TPB, 0, stream>>>(F0, nullptr, w_tf2, b_tf2, T160, TF, B, nf, 160, 160, nf, 8, bpc160);

    // --- offset/mask head (OM overwrites XA region; XA dead by now) ---
    conv2d_c4_k<1, 0, 0><<<B * 8 * bpc160, TPB, 0, stream>>>(TF, nullptr, w_out, b_out, nullptr, F0, B, nf, 160, 160, nf, 8, bpc160);
    conv2d_c16_k<0><<<B * 12 * bpc160, TPB, 0, stream>>>(F0, w_om, b_om, OM, B, nf, 160, 160, 189, 12, bpc160);

    // --- deformable conv (two-phase) ---
    deform_conv2_k<<<B * (H * W / 64), TPB, 0, stream>>>(inputs, OM, WT2, b_dc, out, B, H, W);
}

// Round 16
// 963.637 us; speedup vs baseline: 1.0234x; 1.0234x over previous
//
#include <hip/hip_runtime.h>
#include <math.h>

// ---------------------------------------------------------------------------
// STDF forward, round 16: revert w_om to c8 (c16 was neutral/worse), add
// convt2d_c4 (4 co/thread) for the 160-level transposed conv (wt_up1) —
// amortizes the 8 input loads/ci over 128 MACs. Rest identical to round 14
// (981us verified).
// ---------------------------------------------------------------------------

#define TPB 256

static inline int nblk(long long total) { return (int)((total + TPB - 1) / TPB); }

// ---------------- 3x3 conv2d, stride 1, 4 outputs/thread, block-uniform co --
template <int TB, int RELU, int HAS_RES>
__global__ __launch_bounds__(TB) void conv2d_t4_k(
    const float* __restrict__ in, const float* __restrict__ w,
    const float* __restrict__ bias, const float* __restrict__ res,
    float* __restrict__ out, int B, int Ci, int H, int W, int Co, int BPC) {
    __shared__ float ws_w[32 * 9];
    int co = (blockIdx.x / BPC) % Co;
    int b  = blockIdx.x / (BPC * Co);
    for (int i = threadIdx.x; i < Ci * 9; i += TB)
        ws_w[i] = w[(size_t)co * Ci * 9 + i];
    __syncthreads();
    int nq = W >> 2;
    int r = (blockIdx.x % BPC) * TB + threadIdx.x;
    if (r >= H * nq) return;
    int q = r % nq, ho = r / nq;
    int wb = q * 4;
    float bv = bias[co];
    float a0 = bv, a1 = bv, a2 = bv, a3 = bv;
    const float* ipb = in + (size_t)b * Ci * H * W;
    for (int ci = 0; ci < Ci; ++ci) {
        const float* ip = ipb + (size_t)ci * H * W;
        const float* wc = ws_w + ci * 9;
#pragma unroll
        for (int kh = 0; kh < 3; ++kh) {
            int y = ho - 1 + kh;
            if (y < 0 || y >= H) continue;
            const float* row = ip + (size_t)y * W + wb;
            float4 xv = *(const float4*)row;
            float xm = (wb > 0) ? row[-1] : 0.f;
            float xp = (wb + 4 < W) ? row[4] : 0.f;
            float w0 = wc[kh * 3], w1 = wc[kh * 3 + 1], w2 = wc[kh * 3 + 2];
            a0 += xm   * w0 + xv.x * w1 + xv.y * w2;
            a1 += xv.x * w0 + xv.y * w1 + xv.z * w2;
            a2 += xv.y * w0 + xv.z * w1 + xv.w * w2;
            a3 += xv.z * w0 + xv.w * w1 + xp   * w2;
        }
    }
    size_t o = ((size_t)(b * Co + co) * H + ho) * W + wb;
    if (HAS_RES) {
        float4 rv = *(const float4*)(res + o);
        a0 += rv.x; a1 += rv.y; a2 += rv.z; a3 += rv.w;
    }
    if (RELU) { a0 = fmaxf(a0, 0.f); a1 = fmaxf(a1, 0.f); a2 = fmaxf(a2, 0.f); a3 = fmaxf(a3, 0.f); }
    *(float4*)(out + o) = make_float4(a0, a1, a2, a3);
}

// ------- 3x3 conv2d, stride 1, 4 outputs x 4 co per thread -----------------
template <int RELU, int HAS_RES, int HAS_IN2>
__global__ __launch_bounds__(TPB) void conv2d_c4_k(
    const float* __restrict__ in, const float* __restrict__ in2,
    const float* __restrict__ w, const float* __restrict__ bias,
    const float* __restrict__ res, float* __restrict__ out,
    int B, int Ci, int H, int W, int Co, int COG, int BPC) {
    __shared__ float ws_w[4 * 32 * 9];
    int cog = (blockIdx.x / BPC) % COG;
    int b   = blockIdx.x / (BPC * COG);
    int co0 = cog * 4;
    int nw = Ci * 9;
    for (int i = threadIdx.x; i < 4 * nw; i += TPB) {
        int cr = i / nw; int co = co0 + cr;
        ws_w[i] = (co < Co) ? w[(size_t)co * nw + (i - cr * nw)] : 0.f;
    }
    __syncthreads();
    int nq = W >> 2;
    int r = (blockIdx.x % BPC) * TPB + threadIdx.x;
    if (r >= H * nq) return;
    int q = r % nq, ho = r / nq;
    int wb = q * 4;
    float a[4][4];
#pragma unroll
    for (int cr = 0; cr < 4; ++cr) {
        float bv = (co0 + cr < Co) ? bias[co0 + cr] : 0.f;
        a[cr][0] = bv; a[cr][1] = bv; a[cr][2] = bv; a[cr][3] = bv;
    }
    const float* ipb = in + (size_t)b * Ci * H * W;
    const float* ipb2 = HAS_IN2 ? in2 + (size_t)b * Ci * H * W : nullptr;
    for (int ci = 0; ci < Ci; ++ci) {
        const float* ip = ipb + (size_t)ci * H * W;
        const float* ip2 = HAS_IN2 ? ipb2 + (size_t)ci * H * W : nullptr;
#pragma unroll
        for (int kh = 0; kh < 3; ++kh) {
            int y = ho - 1 + kh;
            if (y < 0 || y >= H) continue;
            const float* row = ip + (size_t)y * W + wb;
            float4 xv = *(const float4*)row;
            float x_[6];
            x_[0] = (wb > 0) ? row[-1] : 0.f;
            x_[5] = (wb + 4 < W) ? row[4] : 0.f;
            if (HAS_IN2) {
                const float* row2 = ip2 + (size_t)y * W + wb;
                float4 x2 = *(const float4*)row2;
                xv.x += x2.x; xv.y += x2.y; xv.z += x2.z; xv.w += x2.w;
                if (wb > 0) x_[0] += row2[-1];
                if (wb + 4 < W) x_[5] += row2[4];
            }
            x_[1] = xv.x; x_[2] = xv.y; x_[3] = xv.z; x_[4] = xv.w;
#pragma unroll
            for (int cr = 0; cr < 4; ++cr) {
                const float* wc = ws_w + cr * nw + ci * 9 + kh * 3;
                float w0 = wc[0], w1 = wc[1], w2 = wc[2];
                a[cr][0] += x_[0] * w0 + x_[1] * w1 + x_[2] * w2;
                a[cr][1] += x_[1] * w0 + x_[2] * w1 + x_[3] * w2;
                a[cr][2] += x_[2] * w0 + x_[3] * w1 + x_[4] * w2;
                a[cr][3] += x_[3] * w0 + x_[4] * w1 + x_[5] * w2;
            }
        }
    }
#pragma unroll
    for (int cr = 0; cr < 4; ++cr) {
        int co = co0 + cr;
        if (co >= Co) break;
        size_t o = ((size_t)(b * Co + co) * H + ho) * W + wb;
        float a0 = a[cr][0], a1 = a[cr][1], a2 = a[cr][2], a3 = a[cr][3];
        if (HAS_RES) {
            float4 rv = *(const float4*)(res + o);
            a0 += rv.x; a1 += rv.y; a2 += rv.z; a3 += rv.w;
        }
        if (RELU) { a0 = fmaxf(a0, 0.f); a1 = fmaxf(a1, 0.f); a2 = fmaxf(a2, 0.f); a3 = fmaxf(a3, 0.f); }
        *(float4*)(out + o) = make_float4(a0, a1, a2, a3);
    }
}

// ------- 3x3 conv2d, stride 1, 4 outputs x 8 co per thread (for w_om) ------
template <int RELU>
__global__ __launch_bounds__(TPB) void conv2d_c8_k(
    const float* __restrict__ in, const float* __restrict__ w,
    const float* __restrict__ bias, float* __restrict__ out,
    int B, int Ci, int H, int W, int Co, int COG, int BPC) {
    __shared__ __align__(16) float4 wsa[32 * 9];
    __shared__ __align__(16) float4 wsb[32 * 9];
    int cog = (blockIdx.x / BPC) % COG;
    int b   = blockIdx.x / (BPC * COG);
    int co0 = cog * 8;
    int nw = Ci * 9;
    for (int i = threadIdx.x; i < nw; i += TPB) {
        float4 v, u;
        v.x = (co0 + 0 < Co) ? w[(size_t)(co0 + 0) * nw + i] : 0.f;
        v.y = (co0 + 1 < Co) ? w[(size_t)(co0 + 1) * nw + i] : 0.f;
        v.z = (co0 + 2 < Co) ? w[(size_t)(co0 + 2) * nw + i] : 0.f;
        v.w = (co0 + 3 < Co) ? w[(size_t)(co0 + 3) * nw + i] : 0.f;
        u.x = (co0 + 4 < Co) ? w[(size_t)(co0 + 4) * nw + i] : 0.f;
        u.y = (co0 + 5 < Co) ? w[(size_t)(co0 + 5) * nw + i] : 0.f;
        u.z = (co0 + 6 < Co) ? w[(size_t)(co0 + 6) * nw + i] : 0.f;
        u.w = (co0 + 7 < Co) ? w[(size_t)(co0 + 7) * nw + i] : 0.f;
        wsa[i] = v; wsb[i] = u;
    }
    __syncthreads();
    int nq = W >> 2;
    int r = (blockIdx.x % BPC) * TPB + threadIdx.x;
    if (r >= H * nq) return;
    int q = r % nq, ho = r / nq;
    int wb = q * 4;
    float a[8][4];
#pragma unroll
    for (int cr = 0; cr < 8; ++cr) {
        float bv = (co0 + cr < Co) ? bias[co0 + cr] : 0.f;
        a[cr][0] = bv; a[cr][1] = bv; a[cr][2] = bv; a[cr][3] = bv;
    }
    const float* ipb = in + (size_t)b * Ci * H * W;
    for (int ci = 0; ci < Ci; ++ci) {
        const float* ip = ipb + (size_t)ci * H * W;
#pragma unroll
        for (int kh = 0; kh < 3; ++kh) {
            int y = ho - 1 + kh;
            if (y < 0 || y >= H) continue;
            const float* row = ip + (size_t)y * W + wb;
            float4 xv = *(const float4*)row;
            float x_[6];
            x_[0] = (wb > 0) ? row[-1] : 0.f;
            x_[1] = xv.x; x_[2] = xv.y; x_[3] = xv.z; x_[4] = xv.w;
            x_[5] = (wb + 4 < W) ? row[4] : 0.f;
#pragma unroll
            for (int kw = 0; kw < 3; ++kw) {
                float4 wv = wsa[ci * 9 + kh * 3 + kw];
                float4 wu = wsb[ci * 9 + kh * 3 + kw];
                float x0 = x_[kw], x1 = x_[kw + 1], x2 = x_[kw + 2], x3 = x_[kw + 3];
                a[0][0] += x0 * wv.x; a[0][1] += x1 * wv.x; a[0][2] += x2 * wv.x; a[0][3] += x3 * wv.x;
                a[1][0] += x0 * wv.y; a[1][1] += x1 * wv.y; a[1][2] += x2 * wv.y; a[1][3] += x3 * wv.y;
                a[2][0] += x0 * wv.z; a[2][1] += x1 * wv.z; a[2][2] += x2 * wv.z; a[2][3] += x3 * wv.z;
                a[3][0] += x0 * wv.w; a[3][1] += x1 * wv.w; a[3][2] += x2 * wv.w; a[3][3] += x3 * wv.w;
                a[4][0] += x0 * wu.x; a[4][1] += x1 * wu.x; a[4][2] += x2 * wu.x; a[4][3] += x3 * wu.x;
                a[5][0] += x0 * wu.y; a[5][1] += x1 * wu.y; a[5][2] += x2 * wu.y; a[5][3] += x3 * wu.y;
                a[6][0] += x0 * wu.z; a[6][1] += x1 * wu.z; a[6][2] += x2 * wu.z; a[6][3] += x3 * wu.z;
                a[7][0] += x0 * wu.w; a[7][1] += x1 * wu.w; a[7][2] += x2 * wu.w; a[7][3] += x3 * wu.w;
            }
        }
    }
#pragma unroll
    for (int cr = 0; cr < 8; ++cr) {
        int co = co0 + cr;
        if (co >= Co) break;
        size_t o = ((size_t)(b * Co + co) * H + ho) * W + wb;
        float a0 = a[cr][0], a1 = a[cr][1], a2 = a[cr][2], a3 = a[cr][3];
        if (RELU) { a0 = fmaxf(a0, 0.f); a1 = fmaxf(a1, 0.f); a2 = fmaxf(a2, 0.f); a3 = fmaxf(a3, 0.f); }
        *(float4*)(out + o) = make_float4(a0, a1, a2, a3);
    }
}

// ------------- 3x3 conv2d over concat of two 32-ch inputs, stride 1, relu ---
template <int TB>
__global__ __launch_bounds__(TB) void conv2d_cat_t4_k(
    const float* __restrict__ in1, const float* __restrict__ in2,
    const float* __restrict__ w, const float* __restrict__ bias,
    float* __restrict__ out, int B, int C1, int C2, int H, int W, int Co, int BPC) {
    __shared__ float ws_w[64 * 9];
    int Ci = C1 + C2;
    int co = (blockIdx.x / BPC) % Co;
    int b  = blockIdx.x / (BPC * Co);
    for (int i = threadIdx.x; i < Ci * 9; i += TB)
        ws_w[i] = w[(size_t)co * Ci * 9 + i];
    __syncthreads();
    int nq = W >> 2;
    int r = (blockIdx.x % BPC) * TB + threadIdx.x;
    if (r >= H * nq) return;
    int q = r % nq, ho = r / nq;
    int wb = q * 4;
    float bv = bias[co];
    float a0 = bv, a1 = bv, a2 = bv, a3 = bv;
    for (int ci = 0; ci < Ci; ++ci) {
        const float* ip = (ci < C1)
            ? in1 + ((size_t)(b * C1 + ci)) * H * W
            : in2 + ((size_t)(b * C2 + (ci - C1))) * H * W;
        const float* wc = ws_w + ci * 9;
#pragma unroll
        for (int kh = 0; kh < 3; ++kh) {
            int y = ho - 1 + kh;
            if (y < 0 || y >= H) continue;
            const float* row = ip + (size_t)y * W + wb;
            float4 xv = *(const float4*)row;
            float xm = (wb > 0) ? row[-1] : 0.f;
            float xp = (wb + 4 < W) ? row[4] : 0.f;
            float w0 = wc[kh * 3], w1 = wc[kh * 3 + 1], w2 = wc[kh * 3 + 2];
            a0 += xm   * w0 + xv.x * w1 + xv.y * w2;
            a1 += xv.x * w0 + xv.y * w1 + xv.z * w2;
            a2 += xv.y * w0 + xv.z * w1 + xv.w * w2;
            a3 += xv.z * w0 + xv.w * w1 + xp   * w2;
        }
    }
    size_t o = ((size_t)(b * Co + co) * H + ho) * W + wb;
    *(float4*)(out + o) = make_float4(fmaxf(a0, 0.f), fmaxf(a1, 0.f), fmaxf(a2, 0.f), fmaxf(a3, 0.f));
}

// ------------- 3x3 conv2d, stride 2, 4 outputs/thread, relu ----------------
template <int TB>
__global__ __launch_bounds__(TB) void conv2d_s2_t4_k(
    const float* __restrict__ in, const float* __restrict__ w,
    const float* __restrict__ bias, float* __restrict__ out,
    int B, int Ci, int Hi, int Wi, int Co, int BPC) {
    __shared__ float ws_w[32 * 9];
    int Ho = Hi >> 1, Wo = Wi >> 1;
    int co = (blockIdx.x / BPC) % Co;
    int b  = blockIdx.x / (BPC * Co);
    for (int i = threadIdx.x; i < Ci * 9; i += TB)
        ws_w[i] = w[(size_t)co * Ci * 9 + i];
    __syncthreads();
    int nq = Wo >> 2;
    int r = (blockIdx.x % BPC) * TB + threadIdx.x;
    if (r >= Ho * nq) return;
    int q = r % nq, ho = r / nq;
    int wb = q * 4;
    float bv = bias[co];
    float a0 = bv, a1 = bv, a2 = bv, a3 = bv;
    const float* ipb = in + (size_t)b * Ci * Hi * Wi;
    for (int ci = 0; ci < Ci; ++ci) {
        const float* ip = ipb + (size_t)ci * Hi * Wi;
        const float* wc = ws_w + ci * 9;
#pragma unroll
        for (int kh = 0; kh < 3; ++kh) {
            int y = 2 * ho - 1 + kh;
            if (y < 0 || y >= Hi) continue;
            const float* row = ip + (size_t)y * Wi;
            float z0 = (2 * wb - 1 >= 0) ? row[2 * wb - 1] : 0.f;
            float4 za = *(const float4*)(row + 2 * wb);
            float4 zb = *(const float4*)(row + 2 * wb + 4);
            float w0 = wc[kh * 3], w1 = wc[kh * 3 + 1], w2 = wc[kh * 3 + 2];
            a0 += z0   * w0 + za.x * w1 + za.y * w2;
            a1 += za.y * w0 + za.z * w1 + za.w * w2;
            a2 += za.w * w0 + zb.x * w1 + zb.y * w2;
            a3 += zb.y * w0 + zb.z * w1 + zb.w * w2;
        }
    }
    size_t o = ((size_t)(b * Co + co) * Ho + ho) * Wo + wb;
    *(float4*)(out + o) = make_float4(fmaxf(a0, 0.f), fmaxf(a1, 0.f), fmaxf(a2, 0.f), fmaxf(a3, 0.f));
}

// ------------- transposed conv 4x4 stride 2, 4 outputs/thread, relu --------
template <int TB>
__global__ __launch_bounds__(TB) void convt2d_t4_k(
    const float* __restrict__ in, const float* __restrict__ wt,
    const float* __restrict__ bias, float* __restrict__ out,
    int B, int C, int Hi, int Wi, int BPC) {
    __shared__ float ws_w[32 * 16];
    int Ho = 2 * Hi, Wo = 2 * Wi;
    int co = (blockIdx.x / BPC) % C;
    int b  = blockIdx.x / (BPC * C);
    for (int i = threadIdx.x; i < C * 16; i += TB) {
        int ci = i >> 4, t = i & 15;
        ws_w[i] = wt[((size_t)ci * C + co) * 16 + t];
    }
    __syncthreads();
    int nq = Wo >> 2;
    int r = (blockIdx.x % BPC) * TB + threadIdx.x;
    if (r >= Ho * nq) return;
    int q = r % nq, ho = r / nq;
    int wb = q * 4;
    int p = ho & 1;
    int iy0 = (ho + p) / 2 - 1;
    int iy1 = iy0 + 1;
    int ix0 = wb / 2 - 1;
    bool vy0 = (iy0 >= 0) && (iy0 < Hi);
    bool vy1 = (iy1 >= 0) && (iy1 < Hi);
    float bv = bias[co];
    float a0 = bv, a1 = bv, a2 = bv, a3 = bv;
    const float* ipb = in + (size_t)b * C * Hi * Wi;
    for (int ci = 0; ci < C; ++ci) {
        const float* ip = ipb + (size_t)ci * Hi * Wi;
        float u0 = 0, u1 = 0, u2 = 0, u3 = 0, v0 = 0, v1 = 0, v2 = 0, v3 = 0;
        if (vy0) {
            const float* rw = ip + (size_t)iy0 * Wi;
            if (ix0 >= 0) u0 = rw[ix0];
            u1 = rw[ix0 + 1]; u2 = rw[ix0 + 2];
            if (ix0 + 3 < Wi) u3 = rw[ix0 + 3];
        }
        if (vy1) {
            const float* rw = ip + (size_t)iy1 * Wi;
            if (ix0 >= 0) v0 = rw[ix0];
            v1 = rw[ix0 + 1]; v2 = rw[ix0 + 2];
            if (ix0 + 3 < Wi) v3 = rw[ix0 + 3];
        }
        const float* wr0 = ws_w + ci * 16 + (3 - p) * 4;
        const float* wr1 = ws_w + ci * 16 + (1 - p) * 4;
        a0 += u0 * wr0[3] + u1 * wr0[1] + v0 * wr1[3] + v1 * wr1[1];
        a1 += u1 * wr0[2] + u2 * wr0[0] + v1 * wr1[2] + v2 * wr1[0];
        a2 += u1 * wr0[3] + u2 * wr0[1] + v1 * wr1[3] + v2 * wr1[1];
        a3 += u2 * wr0[2] + u3 * wr0[0] + v2 * wr1[2] + v3 * wr1[0];
    }
    size_t o = ((size_t)(b * C + co) * Ho + ho) * Wo + wb;
    *(float4*)(out + o) = make_float4(fmaxf(a0, 0.f), fmaxf(a1, 0.f), fmaxf(a2, 0.f), fmaxf(a3, 0.f));
}

// ------------- transposed conv 4x4 stride 2, 4 outputs x 4 co/thread -------
// grid = B * (C/4) * BPC; 256-thread blocks (160-level only).
__global__ __launch_bounds__(TPB) void convt2d_c4_k(
    const float* __restrict__ in, const float* __restrict__ wt,
    const float* __restrict__ bias, float* __restrict__ out,
    int B, int C, int Hi, int Wi, int BPC) {
    __shared__ float ws_w[4][32 * 16];
    int Ho = 2 * Hi, Wo = 2 * Wi;
    int cog = (blockIdx.x / BPC) % (C / 4);
    int b   = blockIdx.x / (BPC * (C / 4));
    int co0 = cog * 4;
    for (int i = threadIdx.x; i < 4 * C * 16; i += TPB) {
        int cr = i / (C * 16); int j = i % (C * 16);
        int ci = j >> 4, t = j & 15;
        ws_w[cr][j] = wt[((size_t)ci * C + (co0 + cr)) * 16 + t];
    }
    __syncthreads();
    int nq = Wo >> 2;
    int r = (blockIdx.x % BPC) * TPB + threadIdx.x;
    if (r >= Ho * nq) return;
    int q = r % nq, ho = r / nq;
    int wb = q * 4;
    int p = ho & 1;
    int iy0 = (ho + p) / 2 - 1;
    int iy1 = iy0 + 1;
    int ix0 = wb / 2 - 1;
    bool vy0 = (iy0 >= 0) && (iy0 < Hi);
    bool vy1 = (iy1 >= 0) && (iy1 < Hi);
    float a[4][4];
#pragma unroll
    for (int cr = 0; cr < 4; ++cr) {
        float bv = bias[co0 + cr];
        a[cr][0] = bv; a[cr][1] = bv; a[cr][2] = bv; a[cr][3] = bv;
    }
    const float* ipb = in + (size_t)b * C * Hi * Wi;
    for (int ci = 0; ci < C; ++ci) {
        const float* ip = ipb + (size_t)ci * Hi * Wi;
        float u0 = 0, u1 = 0, u2 = 0, u3 = 0, v0 = 0, v1 = 0, v2 = 0, v3 = 0;
        if (vy0) {
            const float* rw = ip + (size_t)iy0 * Wi;
            if (ix0 >= 0) u0 = rw[ix0];
            u1 = rw[ix0 + 1]; u2 = rw[ix0 + 2];
            if (ix0 + 3 < Wi) u3 = rw[ix0 + 3];
        }
        if (vy1) {
            const float* rw = ip + (size_t)iy1 * Wi;
            if (ix0 >= 0) v0 = rw[ix0];
            v1 = rw[ix0 + 1]; v2 = rw[ix0 + 2];
            if (ix0 + 3 < Wi) v3 = rw[ix0 + 3];
        }
#pragma unroll
        for (int cr = 0; cr < 4; ++cr) {
            const float* wr0 = ws_w[cr] + ci * 16 + (3 - p) * 4;
            const float* wr1 = ws_w[cr] + ci * 16 + (1 - p) * 4;
            a[cr][0] += u0 * wr0[3] + u1 * wr0[1] + v0 * wr1[3] + v1 * wr1[1];
            a[cr][1] += u1 * wr0[2] + u2 * wr0[0] + v1 * wr1[2] + v2 * wr1[0];
            a[cr][2] += u1 * wr0[3] + u2 * wr0[1] + v1 * wr1[3] + v2 * wr1[1];
            a[cr][3] += u2 * wr0[2] + u3 * wr0[0] + v2 * wr1[2] + v3 * wr1[0];
        }
    }
#pragma unroll
    for (int cr = 0; cr < 4; ++cr) {
        size_t o = ((size_t)(b * C + co0 + cr) * Ho + ho) * Wo + wb;
        *(float4*)(out + o) = make_float4(fmaxf(a[cr][0], 0.f), fmaxf(a[cr][1], 0.f),
                                          fmaxf(a[cr][2], 0.f), fmaxf(a[cr][3], 0.f));
    }
}

// ---- merged prep: wb transpose + wdc transpose + xa border zero -------------
__global__ void prep_k(const float* __restrict__ wb, const float* __restrict__ wdc,
                       float* __restrict__ wt, float* __restrict__ wt2,
                       float* __restrict__ xa_g) {
    int i = blockIdx.x * TPB + threadIdx.x;
    if (i < 27648) {
        int kd = i % 3; int t = i / 3;
        int co = t % 32; t /= 32;
        int j  = t % 9;  int ci = t / 9;
        wt[i] = wb[(size_t)(co * 32 + ci) * 27 + kd * 9 + j];
        return;
    }
    int i2 = i - 27648;
    if (i2 < 4032) {
        int o = i2 & 63, ck = i2 >> 6;
        wt2[i2] = wdc[o * 63 + ck];
        return;
    }
    int i3 = i2 - 4032;
    if (i3 >= 448 * 644) return;
    int pl = i3 / 644, e = i3 % 644;
    int off;
    if (e < 162)      off = e;
    else if (e < 324) off = 161 * 162 + (e - 162);
    else if (e < 484) off = (e - 324 + 1) * 162;
    else              off = (e - 484 + 1) * 162 + 161;
    xa_g[(size_t)pl * 26244 + off] = 0.f;
}

// ---- conv3d_a: x (B,7,H,W) -> relu -> padded xa [B][32][7][162][162] -------
__global__ __launch_bounds__(TPB) void conv3da_k(
    const float* __restrict__ x, const float* __restrict__ wa,
    const float* __restrict__ ba, float* __restrict__ xa_g,
    int B, int H, int W) {
    __shared__ float w27[27];
    int blk = blockIdx.x;
    int t5 = blk % 25; int rest = blk / 25;
    int d = rest % 7; rest /= 7;
    int co = rest % 32; int b = rest / 32;
    if (threadIdx.x < 27) w27[threadIdx.x] = wa[co * 27 + threadIdx.x];
    __syncthreads();
    int r = t5 * TPB + threadIdx.x;
    if (r >= 160 * 40) return;
    int y = r / 40, x0 = (r % 40) * 4;
    float bv = ba[co];
    float a0 = bv, a1 = bv, a2 = bv, a3 = bv;
#pragma unroll
    for (int kd = 0; kd < 3; ++kd) {
        int dz = d + kd - 1;
        if (dz < 0 || dz >= 7) continue;
        const float* pl = x + ((size_t)(b * 7 + dz)) * H * W;
#pragma unroll
        for (int kh = 0; kh < 3; ++kh) {
            int yy = y + kh - 1;
            if (yy < 0 || yy >= H) continue;
            const float* row = pl + (size_t)yy * W + x0;
            float4 xv = *(const float4*)row;
            float xm = (x0 > 0) ? row[-1] : 0.f;
            float xp = (x0 + 4 < W) ? row[4] : 0.f;
            float w0 = w27[kd * 9 + kh * 3], w1 = w27[kd * 9 + kh * 3 + 1], w2 = w27[kd * 9 + kh * 3 + 2];
            a0 += xm   * w0 + xv.x * w1 + xv.y * w2;
            a1 += xv.x * w0 + xv.y * w1 + xv.z * w2;
            a2 += xv.y * w0 + xv.z * w1 + xv.w * w2;
            a3 += xv.z * w0 + xv.w * w1 + xp   * w2;
        }
    }
    size_t base = ((size_t)((b * 32 + co) * 7 + d)) * 26244 + (size_t)(y + 1) * 162 + (x0 + 1);
    xa_g[base + 0] = fmaxf(a0, 0.f);
    xa_g[base + 1] = fmaxf(a1, 0.f);
    xa_g[base + 2] = fmaxf(a2, 0.f);
    xa_g[base + 3] = fmaxf(a3, 0.f);
}

// ---- conv3d_b + relu + mean, streaming xa from global (frozen; verified) ---
__global__ __launch_bounds__(TPB) void conv3db_k(
    const float* __restrict__ xa_g, const float* __restrict__ wt,
    const float* __restrict__ bb, float* __restrict__ out,
    int B, int H, int W) {
    __shared__ float xab[2][840];
    const int PLANE = 26244, CI_S = 183708, B_S = 5878656;
    const int RS = 12, DS = 120;
    int half = blockIdx.x & 1;
    int tile = (blockIdx.x >> 1) % 400;
    int b = blockIdx.x / 800;
    int bx = tile % 20, by = tile / 20;
    int h0 = by * 8, w0 = bx * 8;
    int tid = threadIdx.x;
    int p = tid & 63; int px = p & 7; int py = p >> 3;
    int g = tid >> 6;

    int gu = __builtin_amdgcn_readfirstlane(g);
    const float* wbase = wt + half * 48 + gu * 12;

    int it0 = tid, it1 = tid + 256, it2 = tid + 512;
    bool h2 = (it2 < 700);
    int dd0 = it0 / 100, rm0 = it0 % 100;
    int xo0 = dd0 * PLANE + (h0 + rm0 / 10) * 162 + (w0 + rm0 % 10);
    int lo0 = dd0 * DS + (rm0 / 10) * RS + rm0 % 10;
    int dd1 = it1 / 100, rm1 = it1 % 100;
    int xo1 = dd1 * PLANE + (h0 + rm1 / 10) * 162 + (w0 + rm1 % 10);
    int lo1 = dd1 * DS + (rm1 / 10) * RS + rm1 % 10;
    int xo2 = 0, lo2 = 0;
    if (h2) {
        int dd2 = it2 / 100, rm2 = it2 % 100;
        xo2 = dd2 * PLANE + (h0 + rm2 / 10) * 162 + (w0 + rm2 % 10);
        lo2 = dd2 * DS + (rm2 / 10) * RS + rm2 % 10;
    }

    const float* xbase = xa_g + (size_t)b * B_S;

    float acc[4][7];
#pragma unroll
    for (int r = 0; r < 4; ++r) {
        float bv = bb[half * 16 + g * 4 + r];
#pragma unroll
        for (int d = 0; d < 7; ++d) acc[r][d] = bv;
    }

    {
        float r0 = xbase[xo0], r1 = xbase[xo1], r2 = h2 ? xbase[xo2] : 0.f;
        xab[0][lo0] = r0; xab[0][lo1] = r1; if (h2) xab[0][lo2] = r2;
    }
    __syncthreads();

    for (int ci = 0; ci < 32; ++ci) {
        int cur = ci & 1, nxt = cur ^ 1;
        bool more = (ci + 1 < 32);
        float r0 = 0.f, r1 = 0.f, r2 = 0.f;
        if (more) {
            const float* xs = xbase + (size_t)(ci + 1) * CI_S;
            r0 = xs[xo0]; r1 = xs[xo1]; r2 = h2 ? xs[xo2] : 0.f;
        }
        const float* xab_c = xab[cur];
        const float* wci = wbase + (size_t)ci * 864;
#pragma unroll
        for (int kh = 0; kh < 3; ++kh) {
#pragma unroll
            for (int kw = 0; kw < 3; ++kw) {
                int j = kh * 3 + kw;
                float xav[7];
                const float* xb = xab_c + (py + kh) * RS + (px + kw);
#pragma unroll
                for (int d = 0; d < 7; ++d) xav[d] = xb[d * DS];
                const float4* wp = (const float4*)(wci + j * 96);
                float4 w0 = wp[0], w1 = wp[1], w2 = wp[2];
                float wr[4][3] = {{w0.x, w0.y, w0.z}, {w0.w, w1.x, w1.y},
                                  {w1.z, w1.w, w2.x}, {w2.y, w2.z, w2.w}};
#pragma unroll
                for (int r = 0; r < 4; ++r) {
#pragma unroll
                    for (int d = 1; d < 7; ++d) acc[r][d] += xav[d - 1] * wr[r][0];
#pragma unroll
                    for (int d = 0; d < 7; ++d) acc[r][d] += xav[d] * wr[r][1];
#pragma unroll
                    for (int d = 0; d < 6; ++d) acc[r][d] += xav[d + 1] * wr[r][2];
                }
            }
        }
        if (more) {
            xab[nxt][lo0] = r0; xab[nxt][lo1] = r1; if (h2) xab[nxt][lo2] = r2;
        }
        __syncthreads();
    }

    size_t HW = (size_t)H * W;
#pragma unroll
    for (int r = 0; r < 4; ++r) {
        float s = 0.f;
#pragma unroll
        for (int d = 0; d < 7; ++d) s += fmaxf(acc[r][d], 0.f);
        int co = half * 16 + g * 4 + r;
        out[((size_t)(b * 32 + co)) * HW + (size_t)(h0 + py) * W + (w0 + px)] = s * (1.f / 7.f);
    }
}

// ------------- two-phase modulated deformable conv ---------------------------
__global__ __launch_bounds__(TPB) void deform_conv2_k(
    const float* __restrict__ x, const float* __restrict__ om,
    const float* __restrict__ wt2, const float* __restrict__ bias,
    float* __restrict__ out, int B, int H, int W) {
    __shared__ float smp[63 * 64];
    const int HW = H * W;
    int blk = blockIdx.x;
    int b = blk / (HW / 64);
    int pxbase = (blk % (HW / 64)) * 64;
    int tid = threadIdx.x;
    const float* omb = om + (size_t)b * 189 * HW;
    const float* xb = x + (size_t)b * 7 * HW;

#pragma unroll 4
    for (int k = 0; k < 16; ++k) {
        int it = tid + k * 256;
        if (it >= 4032) break;
        int pxl = it & 63;
        int tap = it >> 6;
        int c = tap / 9, kk = tap % 9;
        int hw = pxbase + pxl;
        int hq = hw / W, wq = hw % W;
        float dy = omb[(size_t)(c * 18 + kk * 2 + 0) * HW + hw];
        float dx = omb[(size_t)(c * 18 + kk * 2 + 1) * HW + hw];
        float mv = omb[(size_t)(126 + c * 9 + kk) * HW + hw];
        float m = 1.f / (1.f + __expf(-mv));
        float py = (float)hq + (float)(kk / 3 - 1) + dy;
        float px = (float)wq + (float)(kk % 3 - 1) + dx;
        float y0f = floorf(py), x0f = floorf(px);
        int y0 = (int)y0f, x0 = (int)x0f;
        float wy1 = py - y0f, wx1 = px - x0f;
        float wy0 = 1.f - wy1, wx0 = 1.f - wx1;
        float v00 = 0.f, v01 = 0.f, v10 = 0.f, v11 = 0.f;
        const float* xc = xb + (size_t)c * HW;
        bool yin0 = (y0 >= 0) & (y0 < H);
        bool yin1 = (y0 + 1 >= 0) & (y0 + 1 < H);
        bool xin0 = (x0 >= 0) & (x0 < W);
        bool xin1 = (x0 + 1 >= 0) & (x0 + 1 < W);
        if (yin0) {
            const float* rr = xc + (size_t)y0 * W;
            if (xin0) v00 = rr[x0];
            if (xin1) v01 = rr[x0 + 1];
        }
        if (yin1) {
            const float* rr = xc + (size_t)(y0 + 1) * W;
            if (xin0) v10 = rr[x0];
            if (xin1) v11 = rr[x0 + 1];
        }
        smp[tap * 64 + pxl] =
            (wy0 * wx0 * v00 + wy0 * wx1 * v01 + wy1 * wx0 * v10 + wy1 * wx1 * v11) * m;
    }
    __syncthreads();

    int pxl = tid & 63;
    int g = tid >> 6;
    int gu = __builtin_amdgcn_readfirstlane(g);
    const float* swb = wt2 + gu * 16;
    const float* bsb = bias + gu * 16;
    float acc[16];
#pragma unroll
    for (int o = 0; o < 16; ++o) acc[o] = 0.f;
    for (int tap = 0; tap < 63; ++tap) {
        float s = smp[tap * 64 + pxl];
        const float* sw = swb + tap * 64;
#pragma unroll
        for (int o = 0; o < 16; ++o) acc[o] += s * sw[o];
    }
    int hw = pxbase + pxl;
    size_t obase = (size_t)b * 64 * HW + (size_t)gu * 16 * HW + hw;
#pragma unroll
    for (int o = 0; o < 16; ++o)
        out[obase + (size_t)o * HW] = fmaxf(acc[o] + bsb[o], 0.f);
}

extern "C" void kernel_launch(void* const* d_in, const int* in_sizes, int n_in,
                              void* d_out, int out_size, void* d_ws, size_t ws_size,
                              hipStream_t stream) {
    (void)in_sizes; (void)n_in; (void)out_size; (void)ws_size;
    const float* inputs = (const float*)d_in[0];
    const float* w_in   = (const float*)d_in[1];  const float* b_in   = (const float*)d_in[2];
    const float* w_dn1a = (const float*)d_in[3];  const float* b_dn1a = (const float*)d_in[4];
    const float* w_dn1b = (const float*)d_in[5];  const float* b_dn1b = (const float*)d_in[6];
    const float* w_up1a = (const float*)d_in[7];  const float* b_up1a = (const float*)d_in[8];
    const float* wt_up1 = (const float*)d_in[9];  const float* bt_up1 = (const float*)d_in[10];
    const float* w_dn2a = (const float*)d_in[11]; const float* b_dn2a = (const float*)d_in[12];
    const float* w_dn2b = (const float*)d_in[13]; const float* b_dn2b = (const float*)d_in[14];
    const float* w_up2a = (const float*)d_in[15]; const float* b_up2a = (const float*)d_in[16];
    const float* wt_up2 = (const float*)d_in[17]; const float* bt_up2 = (const float*)d_in[18];
    const float* w_tra  = (const float*)d_in[19]; const float* b_tra  = (const float*)d_in[20];
    const float* w_trb  = (const float*)d_in[21]; const float* b_trb  = (const float*)d_in[22];
    const float* wt_tr  = (const float*)d_in[23]; const float* bt_tr  = (const float*)d_in[24];
    const float* w_out  = (const float*)d_in[25]; const float* b_out  = (const float*)d_in[26];
    const float* w_tf3a = (const float*)d_in[27]; const float* b_tf3a = (const float*)d_in[28];
    const float* w_tf3b = (const float*)d_in[29]; const float* b_tf3b = (const float*)d_in[30];
    const float* w_tf2  = (const float*)d_in[31]; const float* b_tf2  = (const float*)d_in[32];
    const float* w_om   = (const float*)d_in[33]; const float* b_om   = (const float*)d_in[34];
    const float* w_dc   = (const float*)d_in[35]; const float* b_dc   = (const float*)d_in[36];
    float* out = (float*)d_out;

    const int B = 2, nf = 32, H = 160, W = 160;
    const size_t n160 = (size_t)B * nf * 160 * 160;
    const size_t n80  = (size_t)B * nf * 80 * 80;
    const size_t n40  = (size_t)B * nf * 40 * 40;
    const size_t n20  = (size_t)B * nf * 20 * 20;

    float* ws = (float*)d_ws;
    float* F0    = ws;
    float* TMP80 = F0 + n160;
    float* F1    = TMP80 + n80;
    float* TMP40 = F1 + n80;
    float* F2    = TMP40 + n40;
    float* T20A  = F2 + n40;
    float* T20B  = T20A + n20;
    float* T40   = T20B + n20;
    float* T40B  = T40 + n40;
    float* T80   = T40B + n40;
    float* T80B  = T80 + n80;
    float* T160  = T80B + n80;
    float* TF    = T160 + n160;
    float* XA    = TF + n160;
    float* OM    = XA;                 // ALIAS: OM written after XA is dead
    float* WT    = XA + (size_t)2 * 32 * 7 * 162 * 162;
    float* WT2   = WT + 32 * 9 * 32 * 3;

    const int bpc160 = 25;            // ceil(160*40/256)
    const int bpc80_128 = 13;         // ceil(80*20/128)
    const int bpc40_64  = 7;          // ceil(40*10/64)
    const int bpc20_64  = 2;          // ceil(20*5/64)

    // prep (merged) + conv_a
    prep_k<<<nblk(27648 + 4032 + 448 * 644), TPB, 0, stream>>>(w_tf3b, w_dc, WT, WT2, XA);
    conv3da_k<<<B * 32 * 7 * 25, TPB, 0, stream>>>(inputs, w_tf3a, b_tf3a, XA, B, H, W);

    // --- 2D U-Net branch ---
    conv2d_c4_k<1, 0, 0><<<B * 8 * bpc160, TPB, 0, stream>>>(inputs, nullptr, w_in, b_in, nullptr, F0, B, 7, 160, 160, nf, 8, bpc160);
    conv2d_s2_t4_k<128><<<B * nf * bpc80_128, 128, 0, stream>>>(F0, w_dn1a, b_dn1a, TMP80, B, nf, 160, 160, nf, bpc80_128);
    conv2d_t4_k<128, 1, 0><<<B * nf * bpc80_128, 128, 0, stream>>>(TMP80, w_dn1b, b_dn1b, nullptr, F1, B, nf, 80, 80, nf, bpc80_128);
    conv2d_s2_t4_k<64><<<B * nf * bpc40_64, 64, 0, stream>>>(F1, w_dn2a, b_dn2a, TMP40, B, nf, 80, 80, nf, bpc40_64);
    conv2d_t4_k<64, 1, 0><<<B * nf * bpc40_64, 64, 0, stream>>>(TMP40, w_dn2b, b_dn2b, nullptr, F2, B, nf, 40, 40, nf, bpc40_64);
    conv2d_s2_t4_k<64><<<B * nf * bpc20_64, 64, 0, stream>>>(F2, w_tra, b_tra, T20A, B, nf, 40, 40, nf, bpc20_64);
    conv2d_t4_k<64, 1, 0><<<B * nf * bpc20_64, 64, 0, stream>>>(T20A, w_trb, b_trb, nullptr, T20B, B, nf, 20, 20, nf, bpc20_64);
    convt2d_t4_k<64><<<B * nf * bpc40_64, 64, 0, stream>>>(T20B, wt_tr, bt_tr, T40, B, nf, 20, 20, bpc40_64);
    conv2d_cat_t4_k<64><<<B * nf * bpc40_64, 64, 0, stream>>>(T40, F2, w_up2a, b_up2a, T40B, B, nf, nf, 40, 40, nf, bpc40_64);
    convt2d_t4_k<128><<<B * nf * bpc80_128, 128, 0, stream>>>(T40B, wt_up2, bt_up2, T80, B, nf, 40, 40, bpc80_128);
    conv2d_cat_t4_k<128><<<B * nf * bpc80_128, 128, 0, stream>>>(T80, F1, w_up1a, b_up1a, T80B, B, nf, nf, 80, 80, nf, bpc80_128);
    convt2d_c4_k<<<B * 8 * bpc160, TPB, 0, stream>>>(T80B, wt_up1, bt_up1, T160, B, nf, 80, 80, bpc160);

    // --- conv3d_b + relu + mean (streaming) -> F0 ---
    conv3db_k<<<B * 2 * 400, TPB, 0, stream>>>(XA, WT, b_tf3b, F0, B, H, W);
    // FUSED = relu(conv_tf2(MEAN) + T160)
    conv2d_c4_k<1, 1, 0><<<B * 8 * bpc160, TPB, 0, stream>>>(F0, nullptr, w_tf2, b_tf2, T160, TF, B, nf, 160, 160, nf, 8, bpc160);

    // --- offset/mask head (OM overwrites XA region; XA dead by now) ---
    conv2d_c4_k<1, 0, 0><<<B * 8 * bpc160, TPB, 0, stream>>>(TF, nullptr, w_out, b_out, nullptr, F0, B, nf, 160, 160, nf, 8, bpc160);
    conv2d_c8_k<0><<<B * 24 * bpc160, TPB, 0, stream>>>(F0, w_om, b_om, OM, B, nf, 160, 160, 189, 24, bpc160);

    // --- deformable conv (two-phase) ---
    deform_conv2_k<<<B * (H * W / 64), TPB, 0, stream>>>(inputs, OM, WT2, b_dc, out, B, H, W);
}

// Round 17
// 730.492 us; speedup vs baseline: 1.3500x; 1.3192x over previous
//
#include <hip/hip_runtime.h>
#include <math.h>

// ---------------------------------------------------------------------------
// STDF forward, round 17: conv3d_b rewritten as bf16 MFMA implicit GEMM
// (M=px, N=32co, K=864). XA(fp32) -> XACL(bf16 channel-last) transpose +
// weight fragment packing in prep. Everything else identical to round 16
// (964us verified). Fallback: revert this kernel trio if it fails.
// ---------------------------------------------------------------------------

#define TPB 256

static inline int nblk(long long total) { return (int)((total + TPB - 1) / TPB); }

typedef short bf16x8 __attribute__((ext_vector_type(8)));
typedef float f32x4 __attribute__((ext_vector_type(4)));

__device__ __forceinline__ unsigned short f2bf(float f) {
    unsigned int u = __float_as_uint(f);
    unsigned int r = u + 0x7FFFu + ((u >> 16) & 1u);   // RNE
    return (unsigned short)(r >> 16);
}

// ---------------- 3x3 conv2d, stride 1, 4 outputs/thread, block-uniform co --
template <int TB, int RELU, int HAS_RES>
__global__ __launch_bounds__(TB) void conv2d_t4_k(
    const float* __restrict__ in, const float* __restrict__ w,
    const float* __restrict__ bias, const float* __restrict__ res,
    float* __restrict__ out, int B, int Ci, int H, int W, int Co, int BPC) {
    __shared__ float ws_w[32 * 9];
    int co = (blockIdx.x / BPC) % Co;
    int b  = blockIdx.x / (BPC * Co);
    for (int i = threadIdx.x; i < Ci * 9; i += TB)
        ws_w[i] = w[(size_t)co * Ci * 9 + i];
    __syncthreads();
    int nq = W >> 2;
    int r = (blockIdx.x % BPC) * TB + threadIdx.x;
    if (r >= H * nq) return;
    int q = r % nq, ho = r / nq;
    int wb = q * 4;
    float bv = bias[co];
    float a0 = bv, a1 = bv, a2 = bv, a3 = bv;
    const float* ipb = in + (size_t)b * Ci * H * W;
    for (int ci = 0; ci < Ci; ++ci) {
        const float* ip = ipb + (size_t)ci * H * W;
        const float* wc = ws_w + ci * 9;
#pragma unroll
        for (int kh = 0; kh < 3; ++kh) {
            int y = ho - 1 + kh;
            if (y < 0 || y >= H) continue;
            const float* row = ip + (size_t)y * W + wb;
            float4 xv = *(const float4*)row;
            float xm = (wb > 0) ? row[-1] : 0.f;
            float xp = (wb + 4 < W) ? row[4] : 0.f;
            float w0 = wc[kh * 3], w1 = wc[kh * 3 + 1], w2 = wc[kh * 3 + 2];
            a0 += xm   * w0 + xv.x * w1 + xv.y * w2;
            a1 += xv.x * w0 + xv.y * w1 + xv.z * w2;
            a2 += xv.y * w0 + xv.z * w1 + xv.w * w2;
            a3 += xv.z * w0 + xv.w * w1 + xp   * w2;
        }
    }
    size_t o = ((size_t)(b * Co + co) * H + ho) * W + wb;
    if (HAS_RES) {
        float4 rv = *(const float4*)(res + o);
        a0 += rv.x; a1 += rv.y; a2 += rv.z; a3 += rv.w;
    }
    if (RELU) { a0 = fmaxf(a0, 0.f); a1 = fmaxf(a1, 0.f); a2 = fmaxf(a2, 0.f); a3 = fmaxf(a3, 0.f); }
    *(float4*)(out + o) = make_float4(a0, a1, a2, a3);
}

// ------- 3x3 conv2d, stride 1, 4 outputs x 4 co per thread -----------------
template <int RELU, int HAS_RES, int HAS_IN2>
__global__ __launch_bounds__(TPB) void conv2d_c4_k(
    const float* __restrict__ in, const float* __restrict__ in2,
    const float* __restrict__ w, const float* __restrict__ bias,
    const float* __restrict__ res, float* __restrict__ out,
    int B, int Ci, int H, int W, int Co, int COG, int BPC) {
    __shared__ float ws_w[4 * 32 * 9];
    int cog = (blockIdx.x / BPC) % COG;
    int b   = blockIdx.x / (BPC * COG);
    int co0 = cog * 4;
    int nw = Ci * 9;
    for (int i = threadIdx.x; i < 4 * nw; i += TPB) {
        int cr = i / nw; int co = co0 + cr;
        ws_w[i] = (co < Co) ? w[(size_t)co * nw + (i - cr * nw)] : 0.f;
    }
    __syncthreads();
    int nq = W >> 2;
    int r = (blockIdx.x % BPC) * TPB + threadIdx.x;
    if (r >= H * nq) return;
    int q = r % nq, ho = r / nq;
    int wb = q * 4;
    float a[4][4];
#pragma unroll
    for (int cr = 0; cr < 4; ++cr) {
        float bv = (co0 + cr < Co) ? bias[co0 + cr] : 0.f;
        a[cr][0] = bv; a[cr][1] = bv; a[cr][2] = bv; a[cr][3] = bv;
    }
    const float* ipb = in + (size_t)b * Ci * H * W;
    const float* ipb2 = HAS_IN2 ? in2 + (size_t)b * Ci * H * W : nullptr;
    for (int ci = 0; ci < Ci; ++ci) {
        const float* ip = ipb + (size_t)ci * H * W;
        const float* ip2 = HAS_IN2 ? ipb2 + (size_t)ci * H * W : nullptr;
#pragma unroll
        for (int kh = 0; kh < 3; ++kh) {
            int y = ho - 1 + kh;
            if (y < 0 || y >= H) continue;
            const float* row = ip + (size_t)y * W + wb;
            float4 xv = *(const float4*)row;
            float x_[6];
            x_[0] = (wb > 0) ? row[-1] : 0.f;
            x_[5] = (wb + 4 < W) ? row[4] : 0.f;
            if (HAS_IN2) {
                const float* row2 = ip2 + (size_t)y * W + wb;
                float4 x2 = *(const float4*)row2;
                xv.x += x2.x; xv.y += x2.y; xv.z += x2.z; xv.w += x2.w;
                if (wb > 0) x_[0] += row2[-1];
                if (wb + 4 < W) x_[5] += row2[4];
            }
            x_[1] = xv.x; x_[2] = xv.y; x_[3] = xv.z; x_[4] = xv.w;
#pragma unroll
            for (int cr = 0; cr < 4; ++cr) {
                const float* wc = ws_w + cr * nw + ci * 9 + kh * 3;
                float w0 = wc[0], w1 = wc[1], w2 = wc[2];
                a[cr][0] += x_[0] * w0 + x_[1] * w1 + x_[2] * w2;
                a[cr][1] += x_[1] * w0 + x_[2] * w1 + x_[3] * w2;
                a[cr][2] += x_[2] * w0 + x_[3] * w1 + x_[4] * w2;
                a[cr][3] += x_[3] * w0 + x_[4] * w1 + x_[5] * w2;
            }
        }
    }
#pragma unroll
    for (int cr = 0; cr < 4; ++cr) {
        int co = co0 + cr;
        if (co >= Co) break;
        size_t o = ((size_t)(b * Co + co) * H + ho) * W + wb;
        float a0 = a[cr][0], a1 = a[cr][1], a2 = a[cr][2], a3 = a[cr][3];
        if (HAS_RES) {
            float4 rv = *(const float4*)(res + o);
            a0 += rv.x; a1 += rv.y; a2 += rv.z; a3 += rv.w;
        }
        if (RELU) { a0 = fmaxf(a0, 0.f); a1 = fmaxf(a1, 0.f); a2 = fmaxf(a2, 0.f); a3 = fmaxf(a3, 0.f); }
        *(float4*)(out + o) = make_float4(a0, a1, a2, a3);
    }
}

// ------- 3x3 conv2d, stride 1, 4 outputs x 8 co per thread (for w_om) ------
template <int RELU>
__global__ __launch_bounds__(TPB) void conv2d_c8_k(
    const float* __restrict__ in, const float* __restrict__ w,
    const float* __restrict__ bias, float* __restrict__ out,
    int B, int Ci, int H, int W, int Co, int COG, int BPC) {
    __shared__ __align__(16) float4 wsa[32 * 9];
    __shared__ __align__(16) float4 wsb[32 * 9];
    int cog = (blockIdx.x / BPC) % COG;
    int b   = blockIdx.x / (BPC * COG);
    int co0 = cog * 8;
    int nw = Ci * 9;
    for (int i = threadIdx.x; i < nw; i += TPB) {
        float4 v, u;
        v.x = (co0 + 0 < Co) ? w[(size_t)(co0 + 0) * nw + i] : 0.f;
        v.y = (co0 + 1 < Co) ? w[(size_t)(co0 + 1) * nw + i] : 0.f;
        v.z = (co0 + 2 < Co) ? w[(size_t)(co0 + 2) * nw + i] : 0.f;
        v.w = (co0 + 3 < Co) ? w[(size_t)(co0 + 3) * nw + i] : 0.f;
        u.x = (co0 + 4 < Co) ? w[(size_t)(co0 + 4) * nw + i] : 0.f;
        u.y = (co0 + 5 < Co) ? w[(size_t)(co0 + 5) * nw + i] : 0.f;
        u.z = (co0 + 6 < Co) ? w[(size_t)(co0 + 6) * nw + i] : 0.f;
        u.w = (co0 + 7 < Co) ? w[(size_t)(co0 + 7) * nw + i] : 0.f;
        wsa[i] = v; wsb[i] = u;
    }
    __syncthreads();
    int nq = W >> 2;
    int r = (blockIdx.x % BPC) * TPB + threadIdx.x;
    if (r >= H * nq) return;
    int q = r % nq, ho = r / nq;
    int wb = q * 4;
    float a[8][4];
#pragma unroll
    for (int cr = 0; cr < 8; ++cr) {
        float bv = (co0 + cr < Co) ? bias[co0 + cr] : 0.f;
        a[cr][0] = bv; a[cr][1] = bv; a[cr][2] = bv; a[cr][3] = bv;
    }
    const float* ipb = in + (size_t)b * Ci * H * W;
    for (int ci = 0; ci < Ci; ++ci) {
        const float* ip = ipb + (size_t)ci * H * W;
#pragma unroll
        for (int kh = 0; kh < 3; ++kh) {
            int y = ho - 1 + kh;
            if (y < 0 || y >= H) continue;
            const float* row = ip + (size_t)y * W + wb;
            float4 xv = *(const float4*)row;
            float x_[6];
            x_[0] = (wb > 0) ? row[-1] : 0.f;
            x_[1] = xv.x; x_[2] = xv.y; x_[3] = xv.z; x_[4] = xv.w;
            x_[5] = (wb + 4 < W) ? row[4] : 0.f;
#pragma unroll
            for (int kw = 0; kw < 3; ++kw) {
                float4 wv = wsa[ci * 9 + kh * 3 + kw];
                float4 wu = wsb[ci * 9 + kh * 3 + kw];
                float x0 = x_[kw], x1 = x_[kw + 1], x2 = x_[kw + 2], x3 = x_[kw + 3];
                a[0][0] += x0 * wv.x; a[0][1] += x1 * wv.x; a[0][2] += x2 * wv.x; a[0][3] += x3 * wv.x;
                a[1][0] += x0 * wv.y; a[1][1] += x1 * wv.y; a[1][2] += x2 * wv.y; a[1][3] += x3 * wv.y;
                a[2][0] += x0 * wv.z; a[2][1] += x1 * wv.z; a[2][2] += x2 * wv.z; a[2][3] += x3 * wv.z;
                a[3][0] += x0 * wv.w; a[3][1] += x1 * wv.w; a[3][2] += x2 * wv.w; a[3][3] += x3 * wv.w;
                a[4][0] += x0 * wu.x; a[4][1] += x1 * wu.x; a[4][2] += x2 * wu.x; a[4][3] += x3 * wu.x;
                a[5][0] += x0 * wu.y; a[5][1] += x1 * wu.y; a[5][2] += x2 * wu.y; a[5][3] += x3 * wu.y;
                a[6][0] += x0 * wu.z; a[6][1] += x1 * wu.z; a[6][2] += x2 * wu.z; a[6][3] += x3 * wu.z;
                a[7][0] += x0 * wu.w; a[7][1] += x1 * wu.w; a[7][2] += x2 * wu.w; a[7][3] += x3 * wu.w;
            }
        }
    }
#pragma unroll
    for (int cr = 0; cr < 8; ++cr) {
        int co = co0 + cr;
        if (co >= Co) break;
        size_t o = ((size_t)(b * Co + co) * H + ho) * W + wb;
        float a0 = a[cr][0], a1 = a[cr][1], a2 = a[cr][2], a3 = a[cr][3];
        if (RELU) { a0 = fmaxf(a0, 0.f); a1 = fmaxf(a1, 0.f); a2 = fmaxf(a2, 0.f); a3 = fmaxf(a3, 0.f); }
        *(float4*)(out + o) = make_float4(a0, a1, a2, a3);
    }
}

// ------------- 3x3 conv2d over concat of two 32-ch inputs, stride 1, relu ---
template <int TB>
__global__ __launch_bounds__(TB) void conv2d_cat_t4_k(
    const float* __restrict__ in1, const float* __restrict__ in2,
    const float* __restrict__ w, const float* __restrict__ bias,
    float* __restrict__ out, int B, int C1, int C2, int H, int W, int Co, int BPC) {
    __shared__ float ws_w[64 * 9];
    int Ci = C1 + C2;
    int co = (blockIdx.x / BPC) % Co;
    int b  = blockIdx.x / (BPC * Co);
    for (int i = threadIdx.x; i < Ci * 9; i += TB)
        ws_w[i] = w[(size_t)co * Ci * 9 + i];
    __syncthreads();
    int nq = W >> 2;
    int r = (blockIdx.x % BPC) * TB + threadIdx.x;
    if (r >= H * nq) return;
    int q = r % nq, ho = r / nq;
    int wb = q * 4;
    float bv = bias[co];
    float a0 = bv, a1 = bv, a2 = bv, a3 = bv;
    for (int ci = 0; ci < Ci; ++ci) {
        const float* ip = (ci < C1)
            ? in1 + ((size_t)(b * C1 + ci)) * H * W
            : in2 + ((size_t)(b * C2 + (ci - C1))) * H * W;
        const float* wc = ws_w + ci * 9;
#pragma unroll
        for (int kh = 0; kh < 3; ++kh) {
            int y = ho - 1 + kh;
            if (y < 0 || y >= H) continue;
            const float* row = ip + (size_t)y * W + wb;
            float4 xv = *(const float4*)row;
            float xm = (wb > 0) ? row[-1] : 0.f;
            float xp = (wb + 4 < W) ? row[4] : 0.f;
            float w0 = wc[kh * 3], w1 = wc[kh * 3 + 1], w2 = wc[kh * 3 + 2];
            a0 += xm   * w0 + xv.x * w1 + xv.y * w2;
            a1 += xv.x * w0 + xv.y * w1 + xv.z * w2;
            a2 += xv.y * w0 + xv.z * w1 + xv.w * w2;
            a3 += xv.z * w0 + xv.w * w1 + xp   * w2;
        }
    }
    size_t o = ((size_t)(b * Co + co) * H + ho) * W + wb;
    *(float4*)(out + o) = make_float4(fmaxf(a0, 0.f), fmaxf(a1, 0.f), fmaxf(a2, 0.f), fmaxf(a3, 0.f));
}

// ------------- 3x3 conv2d, stride 2, 4 outputs/thread, relu ----------------
template <int TB>
__global__ __launch_bounds__(TB) void conv2d_s2_t4_k(
    const float* __restrict__ in, const float* __restrict__ w,
    const float* __restrict__ bias, float* __restrict__ out,
    int B, int Ci, int Hi, int Wi, int Co, int BPC) {
    __shared__ float ws_w[32 * 9];
    int Ho = Hi >> 1, Wo = Wi >> 1;
    int co = (blockIdx.x / BPC) % Co;
    int b  = blockIdx.x / (BPC * Co);
    for (int i = threadIdx.x; i < Ci * 9; i += TB)
        ws_w[i] = w[(size_t)co * Ci * 9 + i];
    __syncthreads();
    int nq = Wo >> 2;
    int r = (blockIdx.x % BPC) * TB + threadIdx.x;
    if (r >= Ho * nq) return;
    int q = r % nq, ho = r / nq;
    int wb = q * 4;
    float bv = bias[co];
    float a0 = bv, a1 = bv, a2 = bv, a3 = bv;
    const float* ipb = in + (size_t)b * Ci * Hi * Wi;
    for (int ci = 0; ci < Ci; ++ci) {
        const float* ip = ipb + (size_t)ci * Hi * Wi;
        const float* wc = ws_w + ci * 9;
#pragma unroll
        for (int kh = 0; kh < 3; ++kh) {
            int y = 2 * ho - 1 + kh;
            if (y < 0 || y >= Hi) continue;
            const float* row = ip + (size_t)y * Wi;
            float z0 = (2 * wb - 1 >= 0) ? row[2 * wb - 1] : 0.f;
            float4 za = *(const float4*)(row + 2 * wb);
            float4 zb = *(const float4*)(row + 2 * wb + 4);
            float w0 = wc[kh * 3], w1 = wc[kh * 3 + 1], w2 = wc[kh * 3 + 2];
            a0 += z0   * w0 + za.x * w1 + za.y * w2;
            a1 += za.y * w0 + za.z * w1 + za.w * w2;
            a2 += za.w * w0 + zb.x * w1 + zb.y * w2;
            a3 += zb.y * w0 + zb.z * w1 + zb.w * w2;
        }
    }
    size_t o = ((size_t)(b * Co + co) * Ho + ho) * Wo + wb;
    *(float4*)(out + o) = make_float4(fmaxf(a0, 0.f), fmaxf(a1, 0.f), fmaxf(a2, 0.f), fmaxf(a3, 0.f));
}

// ------------- transposed conv 4x4 stride 2, 4 outputs/thread, relu --------
template <int TB>
__global__ __launch_bounds__(TB) void convt2d_t4_k(
    const float* __restrict__ in, const float* __restrict__ wt,
    const float* __restrict__ bias, float* __restrict__ out,
    int B, int C, int Hi, int Wi, int BPC) {
    __shared__ float ws_w[32 * 16];
    int Ho = 2 * Hi, Wo = 2 * Wi;
    int co = (blockIdx.x / BPC) % C;
    int b  = blockIdx.x / (BPC * C);
    for (int i = threadIdx.x; i < C * 16; i += TB) {
        int ci = i >> 4, t = i & 15;
        ws_w[i] = wt[((size_t)ci * C + co) * 16 + t];
    }
    __syncthreads();
    int nq = Wo >> 2;
    int r = (blockIdx.x % BPC) * TB + threadIdx.x;
    if (r >= Ho * nq) return;
    int q = r % nq, ho = r / nq;
    int wb = q * 4;
    int p = ho & 1;
    int iy0 = (ho + p) / 2 - 1;
    int iy1 = iy0 + 1;
    int ix0 = wb / 2 - 1;
    bool vy0 = (iy0 >= 0) && (iy0 < Hi);
    bool vy1 = (iy1 >= 0) && (iy1 < Hi);
    float bv = bias[co];
    float a0 = bv, a1 = bv, a2 = bv, a3 = bv;
    const float* ipb = in + (size_t)b * C * Hi * Wi;
    for (int ci = 0; ci < C; ++ci) {
        const float* ip = ipb + (size_t)ci * Hi * Wi;
        float u0 = 0, u1 = 0, u2 = 0, u3 = 0, v0 = 0, v1 = 0, v2 = 0, v3 = 0;
        if (vy0) {
            const float* rw = ip + (size_t)iy0 * Wi;
            if (ix0 >= 0) u0 = rw[ix0];
            u1 = rw[ix0 + 1]; u2 = rw[ix0 + 2];
            if (ix0 + 3 < Wi) u3 = rw[ix0 + 3];
        }
        if (vy1) {
            const float* rw = ip + (size_t)iy1 * Wi;
            if (ix0 >= 0) v0 = rw[ix0];
            v1 = rw[ix0 + 1]; v2 = rw[ix0 + 2];
            if (ix0 + 3 < Wi) v3 = rw[ix0 + 3];
        }
        const float* wr0 = ws_w + ci * 16 + (3 - p) * 4;
        const float* wr1 = ws_w + ci * 16 + (1 - p) * 4;
        a0 += u0 * wr0[3] + u1 * wr0[1] + v0 * wr1[3] + v1 * wr1[1];
        a1 += u1 * wr0[2] + u2 * wr0[0] + v1 * wr1[2] + v2 * wr1[0];
        a2 += u1 * wr0[3] + u2 * wr0[1] + v1 * wr1[3] + v2 * wr1[1];
        a3 += u2 * wr0[2] + u3 * wr0[0] + v2 * wr1[2] + v3 * wr1[0];
    }
    size_t o = ((size_t)(b * C + co) * Ho + ho) * Wo + wb;
    *(float4*)(out + o) = make_float4(fmaxf(a0, 0.f), fmaxf(a1, 0.f), fmaxf(a2, 0.f), fmaxf(a3, 0.f));
}

// ------------- transposed conv 4x4 stride 2, 4 outputs x 4 co/thread -------
__global__ __launch_bounds__(TPB) void convt2d_c4_k(
    const float* __restrict__ in, const float* __restrict__ wt,
    const float* __restrict__ bias, float* __restrict__ out,
    int B, int C, int Hi, int Wi, int BPC) {
    __shared__ float ws_w[4][32 * 16];
    int Ho = 2 * Hi, Wo = 2 * Wi;
    int cog = (blockIdx.x / BPC) % (C / 4);
    int b   = blockIdx.x / (BPC * (C / 4));
    int co0 = cog * 4;
    for (int i = threadIdx.x; i < 4 * C * 16; i += TPB) {
        int cr = i / (C * 16); int j = i % (C * 16);
        int ci = j >> 4, t = j & 15;
        ws_w[cr][j] = wt[((size_t)ci * C + (co0 + cr)) * 16 + t];
    }
    __syncthreads();
    int nq = Wo >> 2;
    int r = (blockIdx.x % BPC) * TPB + threadIdx.x;
    if (r >= Ho * nq) return;
    int q = r % nq, ho = r / nq;
    int wb = q * 4;
    int p = ho & 1;
    int iy0 = (ho + p) / 2 - 1;
    int iy1 = iy0 + 1;
    int ix0 = wb / 2 - 1;
    bool vy0 = (iy0 >= 0) && (iy0 < Hi);
    bool vy1 = (iy1 >= 0) && (iy1 < Hi);
    float a[4][4];
#pragma unroll
    for (int cr = 0; cr < 4; ++cr) {
        float bv = bias[co0 + cr];
        a[cr][0] = bv; a[cr][1] = bv; a[cr][2] = bv; a[cr][3] = bv;
    }
    const float* ipb = in + (size_t)b * C * Hi * Wi;
    for (int ci = 0; ci < C; ++ci) {
        const float* ip = ipb + (size_t)ci * Hi * Wi;
        float u0 = 0, u1 = 0, u2 = 0, u3 = 0, v0 = 0, v1 = 0, v2 = 0, v3 = 0;
        if (vy0) {
            const float* rw = ip + (size_t)iy0 * Wi;
            if (ix0 >= 0) u0 = rw[ix0];
            u1 = rw[ix0 + 1]; u2 = rw[ix0 + 2];
            if (ix0 + 3 < Wi) u3 = rw[ix0 + 3];
        }
        if (vy1) {
            const float* rw = ip + (size_t)iy1 * Wi;
            if (ix0 >= 0) v0 = rw[ix0];
            v1 = rw[ix0 + 1]; v2 = rw[ix0 + 2];
            if (ix0 + 3 < Wi) v3 = rw[ix0 + 3];
        }
#pragma unroll
        for (int cr = 0; cr < 4; ++cr) {
            const float* wr0 = ws_w[cr] + ci * 16 + (3 - p) * 4;
            const float* wr1 = ws_w[cr] + ci * 16 + (1 - p) * 4;
            a[cr][0] += u0 * wr0[3] + u1 * wr0[1] + v0 * wr1[3] + v1 * wr1[1];
            a[cr][1] += u1 * wr0[2] + u2 * wr0[0] + v1 * wr1[2] + v2 * wr1[0];
            a[cr][2] += u1 * wr0[3] + u2 * wr0[1] + v1 * wr1[3] + v2 * wr1[1];
            a[cr][3] += u2 * wr0[2] + u3 * wr0[0] + v2 * wr1[2] + v3 * wr1[0];
        }
    }
#pragma unroll
    for (int cr = 0; cr < 4; ++cr) {
        size_t o = ((size_t)(b * C + co0 + cr) * Ho + ho) * Wo + wb;
        *(float4*)(out + o) = make_float4(fmaxf(a[cr][0], 0.f), fmaxf(a[cr][1], 0.f),
                                          fmaxf(a[cr][2], 0.f), fmaxf(a[cr][3], 0.f));
    }
}

// ---- merged prep: B-fragment pack (bf16) + wdc transpose + xa border zero --
// wbf layout: [tap(27)][coH(2)][lane(64)][j(8)] bf16, B[k=ci][n=co_local]:
// ci = (lane>>4)*8 + j, co = coH*16 + (lane&15).
__global__ void prep_k(const float* __restrict__ wb, const float* __restrict__ wdc,
                       unsigned short* __restrict__ wbf, float* __restrict__ wt2,
                       float* __restrict__ xa_g) {
    int i = blockIdx.x * TPB + threadIdx.x;
    if (i < 27648) {
        int j = i & 7;
        int l = (i >> 3) & 63;
        int coH = (i >> 9) & 1;
        int tap = i >> 10;                    // 0..26 (kd*9 + kh*3 + kw)
        int ci = ((l >> 4) << 3) + j;
        int co = (coH << 4) + (l & 15);
        wbf[i] = f2bf(wb[(size_t)(co * 32 + ci) * 27 + tap]);
        return;
    }
    int i2 = i - 27648;
    if (i2 < 4032) {
        int o = i2 & 63, ck = i2 >> 6;
        wt2[i2] = wdc[o * 63 + ck];
        return;
    }
    int i3 = i2 - 4032;
    if (i3 >= 448 * 644) return;
    int pl = i3 / 644, e = i3 % 644;
    int off;
    if (e < 162)      off = e;
    else if (e < 324) off = 161 * 162 + (e - 162);
    else if (e < 484) off = (e - 324 + 1) * 162;
    else              off = (e - 484 + 1) * 162 + 161;
    xa_g[(size_t)pl * 26244 + off] = 0.f;
}

// ---- conv3d_a: x (B,7,H,W) -> relu -> padded xa [B][32][7][162][162] -------
__global__ __launch_bounds__(TPB) void conv3da_k(
    const float* __restrict__ x, const float* __restrict__ wa,
    const float* __restrict__ ba, float* __restrict__ xa_g,
    int B, int H, int W) {
    __shared__ float w27[27];
    int blk = blockIdx.x;
    int t5 = blk % 25; int rest = blk / 25;
    int d = rest % 7; rest /= 7;
    int co = rest % 32; int b = rest / 32;
    if (threadIdx.x < 27) w27[threadIdx.x] = wa[co * 27 + threadIdx.x];
    __syncthreads();
    int r = t5 * TPB + threadIdx.x;
    if (r >= 160 * 40) return;
    int y = r / 40, x0 = (r % 40) * 4;
    float bv = ba[co];
    float a0 = bv, a1 = bv, a2 = bv, a3 = bv;
#pragma unroll
    for (int kd = 0; kd < 3; ++kd) {
        int dz = d + kd - 1;
        if (dz < 0 || dz >= 7) continue;
        const float* pl = x + ((size_t)(b * 7 + dz)) * H * W;
#pragma unroll
        for (int kh = 0; kh < 3; ++kh) {
            int yy = y + kh - 1;
            if (yy < 0 || yy >= H) continue;
            const float* row = pl + (size_t)yy * W + x0;
            float4 xv = *(const float4*)row;
            float xm = (x0 > 0) ? row[-1] : 0.f;
            float xp = (x0 + 4 < W) ? row[4] : 0.f;
            float w0 = w27[kd * 9 + kh * 3], w1 = w27[kd * 9 + kh * 3 + 1], w2 = w27[kd * 9 + kh * 3 + 2];
            a0 += xm   * w0 + xv.x * w1 + xv.y * w2;
            a1 += xv.x * w0 + xv.y * w1 + xv.z * w2;
            a2 += xv.y * w0 + xv.z * w1 + xv.w * w2;
            a3 += xv.z * w0 + xv.w * w1 + xp   * w2;
        }
    }
    size_t base = ((size_t)((b * 32 + co) * 7 + d)) * 26244 + (size_t)(y + 1) * 162 + (x0 + 1);
    xa_g[base + 0] = fmaxf(a0, 0.f);
    xa_g[base + 1] = fmaxf(a1, 0.f);
    xa_g[base + 2] = fmaxf(a2, 0.f);
    xa_g[base + 3] = fmaxf(a3, 0.f);
}

// ---- XA(fp32, ch-first, padded) -> XACL(bf16, channel-last, padded) --------
// XACL[b][d][y(162)][x(162)][ci(32)] bf16.
__global__ __launch_bounds__(TPB) void xa2cl_k(
    const float* __restrict__ xa, unsigned short* __restrict__ xacl) {
    int idx = blockIdx.x * TPB + threadIdx.x;
    if (idx >= 2 * 7 * 26244) return;
    int pos = idx % 26244;
    int d = (idx / 26244) % 7;
    int b = idx / 183708;
    unsigned int pk[16];
#pragma unroll
    for (int j = 0; j < 16; ++j) {
        float v0 = xa[((size_t)((b * 32 + 2 * j) * 7 + d)) * 26244 + pos];
        float v1 = xa[((size_t)((b * 32 + 2 * j + 1) * 7 + d)) * 26244 + pos];
        pk[j] = (unsigned int)f2bf(v0) | ((unsigned int)f2bf(v1) << 16);
    }
    uint4* dst = (uint4*)(xacl + (size_t)idx * 32);
    dst[0] = make_uint4(pk[0], pk[1], pk[2], pk[3]);
    dst[1] = make_uint4(pk[4], pk[5], pk[6], pk[7]);
    dst[2] = make_uint4(pk[8], pk[9], pk[10], pk[11]);
    dst[3] = make_uint4(pk[12], pk[13], pk[14], pk[15]);
}

// ---- conv3d_b + relu + mean as bf16 MFMA implicit GEMM ---------------------
// grid = B*800 (= 160y x 5 xpairs); block 256 = 4 waves = (2 m-tiles x 2 coH).
// Per wave: M=16px (one x-segment), N=16co, K=864 (27 taps x 32ci), acc 7 d.
__global__ __launch_bounds__(TPB) void conv3db_mfma_k(
    const unsigned short* __restrict__ xacl, const unsigned short* __restrict__ wbf,
    const float* __restrict__ bb, float* __restrict__ out, int B, int H, int W) {
    int blk = blockIdx.x;
    int b = blk / 800;
    int rem = blk % 800;
    int y = rem / 5;
    int xp = rem % 5;
    int tid = threadIdx.x;
    int l = tid & 63;
    int wv = tid >> 6;
    int mt = wv & 1, coH = wv >> 1;
    int x0 = xp * 32 + mt * 16;
    int co = coH * 16 + (l & 15);
    float bv = bb[co];
    f32x4 acc[7];
#pragma unroll
    for (int d = 0; d < 7; ++d) { acc[d][0] = bv; acc[d][1] = bv; acc[d][2] = bv; acc[d][3] = bv; }

    // A-fragment lane base within a (b,dz) plane (ushort units):
    // padded coords: rows y..y+2, cols x0+(l&15)..+2; k-chunk (l>>4)*8.
    int ubase = (y * 162 + x0 + (l & 15)) * 32 + ((l >> 4) << 3);
    const unsigned short* xb = xacl + (size_t)b * 5878656;   // 7*26244*32
    const unsigned short* wbase = wbf + ((size_t)coH * 64 + l) * 8;

#pragma unroll
    for (int kd = 0; kd < 3; ++kd) {
        for (int j2 = 0; j2 < 9; ++j2) {
            int off2 = (j2 / 3) * 5184 + (j2 % 3) * 32;      // (kh*162+kw)*32
            bf16x8 bf = *reinterpret_cast<const bf16x8*>(wbase + (size_t)(kd * 9 + j2) * 1024);
#pragma unroll
            for (int d = 0; d < 7; ++d) {
                int dz = d + kd - 1;
                if (dz < 0 || dz >= 7) continue;             // compile-time folded
                bf16x8 af = *reinterpret_cast<const bf16x8*>(xb + (size_t)dz * 839808 + ubase + off2);
                acc[d] = __builtin_amdgcn_mfma_f32_16x16x32_bf16(af, bf, acc[d], 0, 0, 0);
            }
        }
    }

    // epilogue: D row = (l>>4)*4 + reg (px), col = l&15 (co); relu-mean over d
    int xo = x0 + ((l >> 4) << 2);
    size_t obase = ((size_t)(b * 32 + co)) * 25600 + (size_t)y * 160 + xo;
#pragma unroll
    for (int r = 0; r < 4; ++r) {
        float s = 0.f;
#pragma unroll
        for (int d = 0; d < 7; ++d) s += fmaxf(acc[d][r], 0.f);
        out[obase + r] = s * (1.f / 7.f);
    }
}

// ------------- two-phase modulated deformable conv ---------------------------
__global__ __launch_bounds__(TPB) void deform_conv2_k(
    const float* __restrict__ x, const float* __restrict__ om,
    const float* __restrict__ wt2, const float* __restrict__ bias,
    float* __restrict__ out, int B, int H, int W) {
    __shared__ float smp[63 * 64];
    const int HW = H * W;
    int blk = blockIdx.x;
    int b = blk / (HW / 64);
    int pxbase = (blk % (HW / 64)) * 64;
    int tid = threadIdx.x;
    const float* omb = om + (size_t)b * 189 * HW;
    const float* xb = x + (size_t)b * 7 * HW;

#pragma unroll 4
    for (int k = 0; k < 16; ++k) {
        int it = tid + k * 256;
        if (it >= 4032) break;
        int pxl = it & 63;
        int tap = it >> 6;
        int c = tap / 9, kk = tap % 9;
        int hw = pxbase + pxl;
        int hq = hw / W, wq = hw % W;
        float dy = omb[(size_t)(c * 18 + kk * 2 + 0) * HW + hw];
        float dx = omb[(size_t)(c * 18 + kk * 2 + 1) * HW + hw];
        float mv = omb[(size_t)(126 + c * 9 + kk) * HW + hw];
        float m = 1.f / (1.f + __expf(-mv));
        float py = (float)hq + (float)(kk / 3 - 1) + dy;
        float px = (float)wq + (float)(kk % 3 - 1) + dx;
        float y0f = floorf(py), x0f = floorf(px);
        int y0 = (int)y0f, x0 = (int)x0f;
        float wy1 = py - y0f, wx1 = px - x0f;
        float wy0 = 1.f - wy1, wx0 = 1.f - wx1;
        float v00 = 0.f, v01 = 0.f, v10 = 0.f, v11 = 0.f;
        const float* xc = xb + (size_t)c * HW;
        bool yin0 = (y0 >= 0) & (y0 < H);
        bool yin1 = (y0 + 1 >= 0) & (y0 + 1 < H);
        bool xin0 = (x0 >= 0) & (x0 < W);
        bool xin1 = (x0 + 1 >= 0) & (x0 + 1 < W);
        if (yin0) {
            const float* rr = xc + (size_t)y0 * W;
            if (xin0) v00 = rr[x0];
            if (xin1) v01 = rr[x0 + 1];
        }
        if (yin1) {
            const float* rr = xc + (size_t)(y0 + 1) * W;
            if (xin0) v10 = rr[x0];
            if (xin1) v11 = rr[x0 + 1];
        }
        smp[tap * 64 + pxl] =
            (wy0 * wx0 * v00 + wy0 * wx1 * v01 + wy1 * wx0 * v10 + wy1 * wx1 * v11) * m;
    }
    __syncthreads();

    int pxl = tid & 63;
    int g = tid >> 6;
    int gu = __builtin_amdgcn_readfirstlane(g);
    const float* swb = wt2 + gu * 16;
    const float* bsb = bias + gu * 16;
    float acc[16];
#pragma unroll
    for (int o = 0; o < 16; ++o) acc[o] = 0.f;
    for (int tap = 0; tap < 63; ++tap) {
        float s = smp[tap * 64 + pxl];
        const float* sw = swb + tap * 64;
#pragma unroll
        for (int o = 0; o < 16; ++o) acc[o] += s * sw[o];
    }
    int hw = pxbase + pxl;
    size_t obase = (size_t)b * 64 * HW + (size_t)gu * 16 * HW + hw;
#pragma unroll
    for (int o = 0; o < 16; ++o)
        out[obase + (size_t)o * HW] = fmaxf(acc[o] + bsb[o], 0.f);
}

extern "C" void kernel_launch(void* const* d_in, const int* in_sizes, int n_in,
                              void* d_out, int out_size, void* d_ws, size_t ws_size,
                              hipStream_t stream) {
    (void)in_sizes; (void)n_in; (void)out_size; (void)ws_size;
    const float* inputs = (const float*)d_in[0];
    const float* w_in   = (const float*)d_in[1];  const float* b_in   = (const float*)d_in[2];
    const float* w_dn1a = (const float*)d_in[3];  const float* b_dn1a = (const float*)d_in[4];
    const float* w_dn1b = (const float*)d_in[5];  const float* b_dn1b = (const float*)d_in[6];
    const float* w_up1a = (const float*)d_in[7];  const float* b_up1a = (const float*)d_in[8];
    const float* wt_up1 = (const float*)d_in[9];  const float* bt_up1 = (const float*)d_in[10];
    const float* w_dn2a = (const float*)d_in[11]; const float* b_dn2a = (const float*)d_in[12];
    const float* w_dn2b = (const float*)d_in[13]; const float* b_dn2b = (const float*)d_in[14];
    const float* w_up2a = (const float*)d_in[15]; const float* b_up2a = (const float*)d_in[16];
    const float* wt_up2 = (const float*)d_in[17]; const float* bt_up2 = (const float*)d_in[18];
    const float* w_tra  = (const float*)d_in[19]; const float* b_tra  = (const float*)d_in[20];
    const float* w_trb  = (const float*)d_in[21]; const float* b_trb  = (const float*)d_in[22];
    const float* wt_tr  = (const float*)d_in[23]; const float* bt_tr  = (const float*)d_in[24];
    const float* w_out  = (const float*)d_in[25]; const float* b_out  = (const float*)d_in[26];
    const float* w_tf3a = (const float*)d_in[27]; const float* b_tf3a = (const float*)d_in[28];
    const float* w_tf3b = (const float*)d_in[29]; const float* b_tf3b = (const float*)d_in[30];
    const float* w_tf2  = (const float*)d_in[31]; const float* b_tf2  = (const float*)d_in[32];
    const float* w_om   = (const float*)d_in[33]; const float* b_om   = (const float*)d_in[34];
    const float* w_dc   = (const float*)d_in[35]; const float* b_dc   = (const float*)d_in[36];
    float* out = (float*)d_out;

    const int B = 2, nf = 32, H = 160, W = 160;
    const size_t n160 = (size_t)B * nf * 160 * 160;
    const size_t n80  = (size_t)B * nf * 80 * 80;
    const size_t n40  = (size_t)B * nf * 40 * 40;
    const size_t n20  = (size_t)B * nf * 20 * 20;

    float* ws = (float*)d_ws;
    float* F0    = ws;
    float* TMP80 = F0 + n160;
    float* F1    = TMP80 + n80;
    float* TMP40 = F1 + n80;
    float* F2    = TMP40 + n40;
    float* T20A  = F2 + n40;
    float* T20B  = T20A + n20;
    float* T40   = T20B + n20;
    float* T40B  = T40 + n40;
    float* T80   = T40B + n40;
    float* T80B  = T80 + n80;
    float* T160  = T80B + n80;
    float* TF    = T160 + n160;
    float* XA    = TF + n160;                         // 11,757,312 f (padded fp32)
    float* OM    = XA;                                // ALIAS (disjoint lifetimes)
    float* WT2   = XA + 11757312;                     // 4,032 f
    unsigned short* WBF  = (unsigned short*)(WT2 + 4032);            // 27,648 us
    unsigned short* XACL = (unsigned short*)(WT2 + 4032 + 13824);    // 11,757,312 us

    const int bpc160 = 25;            // ceil(160*40/256)
    const int bpc80_128 = 13;         // ceil(80*20/128)
    const int bpc40_64  = 7;          // ceil(40*10/64)
    const int bpc20_64  = 2;          // ceil(20*5/64)

    // prep (merged) + conv_a (fp32) + transpose to bf16 channel-last
    prep_k<<<nblk(27648 + 4032 + 448 * 644), TPB, 0, stream>>>(w_tf3b, w_dc, WBF, WT2, XA);
    conv3da_k<<<B * 32 * 7 * 25, TPB, 0, stream>>>(inputs, w_tf3a, b_tf3a, XA, B, H, W);
    xa2cl_k<<<nblk(2 * 7 * 26244), TPB, 0, stream>>>(XA, XACL);

    // --- 2D U-Net branch ---
    conv2d_c4_k<1, 0, 0><<<B * 8 * bpc160, TPB, 0, stream>>>(inputs, nullptr, w_in, b_in, nullptr, F0, B, 7, 160, 160, nf, 8, bpc160);
    conv2d_s2_t4_k<128><<<B * nf * bpc80_128, 128, 0, stream>>>(F0, w_dn1a, b_dn1a, TMP80, B, nf, 160, 160, nf, bpc80_128);
    conv2d_t4_k<128, 1, 0><<<B * nf * bpc80_128, 128, 0, stream>>>(TMP80, w_dn1b, b_dn1b, nullptr, F1, B, nf, 80, 80, nf, bpc80_128);
    conv2d_s2_t4_k<64><<<B * nf * bpc40_64, 64, 0, stream>>>(F1, w_dn2a, b_dn2a, TMP40, B, nf, 80, 80, nf, bpc40_64);
    conv2d_t4_k<64, 1, 0><<<B * nf * bpc40_64, 64, 0, stream>>>(TMP40, w_dn2b, b_dn2b, nullptr, F2, B, nf, 40, 40, nf, bpc40_64);
    conv2d_s2_t4_k<64><<<B * nf * bpc20_64, 64, 0, stream>>>(F2, w_tra, b_tra, T20A, B, nf, 40, 40, nf, bpc20_64);
    conv2d_t4_k<64, 1, 0><<<B * nf * bpc20_64, 64, 0, stream>>>(T20A, w_trb, b_trb, nullptr, T20B, B, nf, 20, 20, nf, bpc20_64);
    convt2d_t4_k<64><<<B * nf * bpc40_64, 64, 0, stream>>>(T20B, wt_tr, bt_tr, T40, B, nf, 20, 20, bpc40_64);
    conv2d_cat_t4_k<64><<<B * nf * bpc40_64, 64, 0, stream>>>(T40, F2, w_up2a, b_up2a, T40B, B, nf, nf, 40, 40, nf, bpc40_64);
    convt2d_t4_k<128><<<B * nf * bpc80_128, 128, 0, stream>>>(T40B, wt_up2, bt_up2, T80, B, nf, 40, 40, bpc80_128);
    conv2d_cat_t4_k<128><<<B * nf * bpc80_128, 128, 0, stream>>>(T80, F1, w_up1a, b_up1a, T80B, B, nf, nf, 80, 80, nf, bpc80_128);
    convt2d_c4_k<<<B * 8 * bpc160, TPB, 0, stream>>>(T80B, wt_up1, bt_up1, T160, B, nf, 80, 80, bpc160);

    // --- conv3d_b + relu + mean (bf16 MFMA) -> F0 ---
    conv3db_mfma_k<<<B * 800, TPB, 0, stream>>>(XACL, WBF, b_tf3b, F0, B, H, W);
    // FUSED = relu(conv_tf2(MEAN) + T160)
    conv2d_c4_k<1, 1, 0><<<B * 8 * bpc160, TPB, 0, stream>>>(F0, nullptr, w_tf2, b_tf2, T160, TF, B, nf, 160, 160, nf, 8, bpc160);

    // --- offset/mask head (OM overwrites XA region; XA dead by now) ---
    conv2d_c4_k<1, 0, 0><<<B * 8 * bpc160, TPB, 0, stream>>>(TF, nullptr, w_out, b_out, nullptr, F0, B, nf, 160, 160, nf, 8, bpc160);
    conv2d_c8_k<0><<<B * 24 * bpc160, TPB, 0, stream>>>(F0, w_om, b_om, OM, B, nf, 160, 160, 189, 24, bpc160);

    // --- deformable conv (two-phase) ---
    deform_conv2_k<<<B * (H * W / 64), TPB, 0, stream>>>(inputs, OM, WT2, b_dc, out, B, H, W);
}

// Round 18
// 667.086 us; speedup vs baseline: 1.4784x; 1.0950x over previous
//
#include <hip/hip_runtime.h>
#include <math.h>

// ---------------------------------------------------------------------------
// STDF forward, round 18: w_om head conv converted to bf16 MFMA implicit GEMM
// (pattern proven by round 17's conv3db: 964->730us). OUTC -> OCL(bf16 CL,
// padded) transform + WOMF fragment pack; epilogue writes OM fp32 ch-first.
// Everything else identical to round 17 (730us verified).
// ---------------------------------------------------------------------------

#define TPB 256

static inline int nblk(long long total) { return (int)((total + TPB - 1) / TPB); }

typedef short bf16x8 __attribute__((ext_vector_type(8)));
typedef float f32x4 __attribute__((ext_vector_type(4)));

__device__ __forceinline__ unsigned short f2bf(float f) {
    unsigned int u = __float_as_uint(f);
    unsigned int r = u + 0x7FFFu + ((u >> 16) & 1u);   // RNE
    return (unsigned short)(r >> 16);
}

// ---------------- 3x3 conv2d, stride 1, 4 outputs/thread, block-uniform co --
template <int TB, int RELU, int HAS_RES>
__global__ __launch_bounds__(TB) void conv2d_t4_k(
    const float* __restrict__ in, const float* __restrict__ w,
    const float* __restrict__ bias, const float* __restrict__ res,
    float* __restrict__ out, int B, int Ci, int H, int W, int Co, int BPC) {
    __shared__ float ws_w[32 * 9];
    int co = (blockIdx.x / BPC) % Co;
    int b  = blockIdx.x / (BPC * Co);
    for (int i = threadIdx.x; i < Ci * 9; i += TB)
        ws_w[i] = w[(size_t)co * Ci * 9 + i];
    __syncthreads();
    int nq = W >> 2;
    int r = (blockIdx.x % BPC) * TB + threadIdx.x;
    if (r >= H * nq) return;
    int q = r % nq, ho = r / nq;
    int wb = q * 4;
    float bv = bias[co];
    float a0 = bv, a1 = bv, a2 = bv, a3 = bv;
    const float* ipb = in + (size_t)b * Ci * H * W;
    for (int ci = 0; ci < Ci; ++ci) {
        const float* ip = ipb + (size_t)ci * H * W;
        const float* wc = ws_w + ci * 9;
#pragma unroll
        for (int kh = 0; kh < 3; ++kh) {
            int y = ho - 1 + kh;
            if (y < 0 || y >= H) continue;
            const float* row = ip + (size_t)y * W + wb;
            float4 xv = *(const float4*)row;
            float xm = (wb > 0) ? row[-1] : 0.f;
            float xp = (wb + 4 < W) ? row[4] : 0.f;
            float w0 = wc[kh * 3], w1 = wc[kh * 3 + 1], w2 = wc[kh * 3 + 2];
            a0 += xm   * w0 + xv.x * w1 + xv.y * w2;
            a1 += xv.x * w0 + xv.y * w1 + xv.z * w2;
            a2 += xv.y * w0 + xv.z * w1 + xv.w * w2;
            a3 += xv.z * w0 + xv.w * w1 + xp   * w2;
        }
    }
    size_t o = ((size_t)(b * Co + co) * H + ho) * W + wb;
    if (HAS_RES) {
        float4 rv = *(const float4*)(res + o);
        a0 += rv.x; a1 += rv.y; a2 += rv.z; a3 += rv.w;
    }
    if (RELU) { a0 = fmaxf(a0, 0.f); a1 = fmaxf(a1, 0.f); a2 = fmaxf(a2, 0.f); a3 = fmaxf(a3, 0.f); }
    *(float4*)(out + o) = make_float4(a0, a1, a2, a3);
}

// ------- 3x3 conv2d, stride 1, 4 outputs x 4 co per thread -----------------
template <int RELU, int HAS_RES, int HAS_IN2>
__global__ __launch_bounds__(TPB) void conv2d_c4_k(
    const float* __restrict__ in, const float* __restrict__ in2,
    const float* __restrict__ w, const float* __restrict__ bias,
    const float* __restrict__ res, float* __restrict__ out,
    int B, int Ci, int H, int W, int Co, int COG, int BPC) {
    __shared__ float ws_w[4 * 32 * 9];
    int cog = (blockIdx.x / BPC) % COG;
    int b   = blockIdx.x / (BPC * COG);
    int co0 = cog * 4;
    int nw = Ci * 9;
    for (int i = threadIdx.x; i < 4 * nw; i += TPB) {
        int cr = i / nw; int co = co0 + cr;
        ws_w[i] = (co < Co) ? w[(size_t)co * nw + (i - cr * nw)] : 0.f;
    }
    __syncthreads();
    int nq = W >> 2;
    int r = (blockIdx.x % BPC) * TPB + threadIdx.x;
    if (r >= H * nq) return;
    int q = r % nq, ho = r / nq;
    int wb = q * 4;
    float a[4][4];
#pragma unroll
    for (int cr = 0; cr < 4; ++cr) {
        float bv = (co0 + cr < Co) ? bias[co0 + cr] : 0.f;
        a[cr][0] = bv; a[cr][1] = bv; a[cr][2] = bv; a[cr][3] = bv;
    }
    const float* ipb = in + (size_t)b * Ci * H * W;
    const float* ipb2 = HAS_IN2 ? in2 + (size_t)b * Ci * H * W : nullptr;
    for (int ci = 0; ci < Ci; ++ci) {
        const float* ip = ipb + (size_t)ci * H * W;
        const float* ip2 = HAS_IN2 ? ipb2 + (size_t)ci * H * W : nullptr;
#pragma unroll
        for (int kh = 0; kh < 3; ++kh) {
            int y = ho - 1 + kh;
            if (y < 0 || y >= H) continue;
            const float* row = ip + (size_t)y * W + wb;
            float4 xv = *(const float4*)row;
            float x_[6];
            x_[0] = (wb > 0) ? row[-1] : 0.f;
            x_[5] = (wb + 4 < W) ? row[4] : 0.f;
            if (HAS_IN2) {
                const float* row2 = ip2 + (size_t)y * W + wb;
                float4 x2 = *(const float4*)row2;
                xv.x += x2.x; xv.y += x2.y; xv.z += x2.z; xv.w += x2.w;
                if (wb > 0) x_[0] += row2[-1];
                if (wb + 4 < W) x_[5] += row2[4];
            }
            x_[1] = xv.x; x_[2] = xv.y; x_[3] = xv.z; x_[4] = xv.w;
#pragma unroll
            for (int cr = 0; cr < 4; ++cr) {
                const float* wc = ws_w + cr * nw + ci * 9 + kh * 3;
                float w0 = wc[0], w1 = wc[1], w2 = wc[2];
                a[cr][0] += x_[0] * w0 + x_[1] * w1 + x_[2] * w2;
                a[cr][1] += x_[1] * w0 + x_[2] * w1 + x_[3] * w2;
                a[cr][2] += x_[2] * w0 + x_[3] * w1 + x_[4] * w2;
                a[cr][3] += x_[3] * w0 + x_[4] * w1 + x_[5] * w2;
            }
        }
    }
#pragma unroll
    for (int cr = 0; cr < 4; ++cr) {
        int co = co0 + cr;
        if (co >= Co) break;
        size_t o = ((size_t)(b * Co + co) * H + ho) * W + wb;
        float a0 = a[cr][0], a1 = a[cr][1], a2 = a[cr][2], a3 = a[cr][3];
        if (HAS_RES) {
            float4 rv = *(const float4*)(res + o);
            a0 += rv.x; a1 += rv.y; a2 += rv.z; a3 += rv.w;
        }
        if (RELU) { a0 = fmaxf(a0, 0.f); a1 = fmaxf(a1, 0.f); a2 = fmaxf(a2, 0.f); a3 = fmaxf(a3, 0.f); }
        *(float4*)(out + o) = make_float4(a0, a1, a2, a3);
    }
}

// ------------- 3x3 conv2d over concat of two 32-ch inputs, stride 1, relu ---
template <int TB>
__global__ __launch_bounds__(TB) void conv2d_cat_t4_k(
    const float* __restrict__ in1, const float* __restrict__ in2,
    const float* __restrict__ w, const float* __restrict__ bias,
    float* __restrict__ out, int B, int C1, int C2, int H, int W, int Co, int BPC) {
    __shared__ float ws_w[64 * 9];
    int Ci = C1 + C2;
    int co = (blockIdx.x / BPC) % Co;
    int b  = blockIdx.x / (BPC * Co);
    for (int i = threadIdx.x; i < Ci * 9; i += TB)
        ws_w[i] = w[(size_t)co * Ci * 9 + i];
    __syncthreads();
    int nq = W >> 2;
    int r = (blockIdx.x % BPC) * TB + threadIdx.x;
    if (r >= H * nq) return;
    int q = r % nq, ho = r / nq;
    int wb = q * 4;
    float bv = bias[co];
    float a0 = bv, a1 = bv, a2 = bv, a3 = bv;
    for (int ci = 0; ci < Ci; ++ci) {
        const float* ip = (ci < C1)
            ? in1 + ((size_t)(b * C1 + ci)) * H * W
            : in2 + ((size_t)(b * C2 + (ci - C1))) * H * W;
        const float* wc = ws_w + ci * 9;
#pragma unroll
        for (int kh = 0; kh < 3; ++kh) {
            int y = ho - 1 + kh;
            if (y < 0 || y >= H) continue;
            const float* row = ip + (size_t)y * W + wb;
            float4 xv = *(const float4*)row;
            float xm = (wb > 0) ? row[-1] : 0.f;
            float xp = (wb + 4 < W) ? row[4] : 0.f;
            float w0 = wc[kh * 3], w1 = wc[kh * 3 + 1], w2 = wc[kh * 3 + 2];
            a0 += xm   * w0 + xv.x * w1 + xv.y * w2;
            a1 += xv.x * w0 + xv.y * w1 + xv.z * w2;
            a2 += xv.y * w0 + xv.z * w1 + xv.w * w2;
            a3 += xv.z * w0 + xv.w * w1 + xp   * w2;
        }
    }
    size_t o = ((size_t)(b * Co + co) * H + ho) * W + wb;
    *(float4*)(out + o) = make_float4(fmaxf(a0, 0.f), fmaxf(a1, 0.f), fmaxf(a2, 0.f), fmaxf(a3, 0.f));
}

// ------------- 3x3 conv2d, stride 2, 4 outputs/thread, relu ----------------
template <int TB>
__global__ __launch_bounds__(TB) void conv2d_s2_t4_k(
    const float* __restrict__ in, const float* __restrict__ w,
    const float* __restrict__ bias, float* __restrict__ out,
    int B, int Ci, int Hi, int Wi, int Co, int BPC) {
    __shared__ float ws_w[32 * 9];
    int Ho = Hi >> 1, Wo = Wi >> 1;
    int co = (blockIdx.x / BPC) % Co;
    int b  = blockIdx.x / (BPC * Co);
    for (int i = threadIdx.x; i < Ci * 9; i += TB)
        ws_w[i] = w[(size_t)co * Ci * 9 + i];
    __syncthreads();
    int nq = Wo >> 2;
    int r = (blockIdx.x % BPC) * TB + threadIdx.x;
    if (r >= Ho * nq) return;
    int q = r % nq, ho = r / nq;
    int wb = q * 4;
    float bv = bias[co];
    float a0 = bv, a1 = bv, a2 = bv, a3 = bv;
    const float* ipb = in + (size_t)b * Ci * Hi * Wi;
    for (int ci = 0; ci < Ci; ++ci) {
        const float* ip = ipb + (size_t)ci * Hi * Wi;
        const float* wc = ws_w + ci * 9;
#pragma unroll
        for (int kh = 0; kh < 3; ++kh) {
            int y = 2 * ho - 1 + kh;
            if (y < 0 || y >= Hi) continue;
            const float* row = ip + (size_t)y * Wi;
            float z0 = (2 * wb - 1 >= 0) ? row[2 * wb - 1] : 0.f;
            float4 za = *(const float4*)(row + 2 * wb);
            float4 zb = *(const float4*)(row + 2 * wb + 4);
            float w0 = wc[kh * 3], w1 = wc[kh * 3 + 1], w2 = wc[kh * 3 + 2];
            a0 += z0   * w0 + za.x * w1 + za.y * w2;
            a1 += za.y * w0 + za.z * w1 + za.w * w2;
            a2 += za.w * w0 + zb.x * w1 + zb.y * w2;
            a3 += zb.y * w0 + zb.z * w1 + zb.w * w2;
        }
    }
    size_t o = ((size_t)(b * Co + co) * Ho + ho) * Wo + wb;
    *(float4*)(out + o) = make_float4(fmaxf(a0, 0.f), fmaxf(a1, 0.f), fmaxf(a2, 0.f), fmaxf(a3, 0.f));
}

// ------------- transposed conv 4x4 stride 2, 4 outputs/thread, relu --------
template <int TB>
__global__ __launch_bounds__(TB) void convt2d_t4_k(
    const float* __restrict__ in, const float* __restrict__ wt,
    const float* __restrict__ bias, float* __restrict__ out,
    int B, int C, int Hi, int Wi, int BPC) {
    __shared__ float ws_w[32 * 16];
    int Ho = 2 * Hi, Wo = 2 * Wi;
    int co = (blockIdx.x / BPC) % C;
    int b  = blockIdx.x / (BPC * C);
    for (int i = threadIdx.x; i < C * 16; i += TB) {
        int ci = i >> 4, t = i & 15;
        ws_w[i] = wt[((size_t)ci * C + co) * 16 + t];
    }
    __syncthreads();
    int nq = Wo >> 2;
    int r = (blockIdx.x % BPC) * TB + threadIdx.x;
    if (r >= Ho * nq) return;
    int q = r % nq, ho = r / nq;
    int wb = q * 4;
    int p = ho & 1;
    int iy0 = (ho + p) / 2 - 1;
    int iy1 = iy0 + 1;
    int ix0 = wb / 2 - 1;
    bool vy0 = (iy0 >= 0) && (iy0 < Hi);
    bool vy1 = (iy1 >= 0) && (iy1 < Hi);
    float bv = bias[co];
    float a0 = bv, a1 = bv, a2 = bv, a3 = bv;
    const float* ipb = in + (size_t)b * C * Hi * Wi;
    for (int ci = 0; ci < C; ++ci) {
        const float* ip = ipb + (size_t)ci * Hi * Wi;
        float u0 = 0, u1 = 0, u2 = 0, u3 = 0, v0 = 0, v1 = 0, v2 = 0, v3 = 0;
        if (vy0) {
            const float* rw = ip + (size_t)iy0 * Wi;
            if (ix0 >= 0) u0 = rw[ix0];
            u1 = rw[ix0 + 1]; u2 = rw[ix0 + 2];
            if (ix0 + 3 < Wi) u3 = rw[ix0 + 3];
        }
        if (vy1) {
            const float* rw = ip + (size_t)iy1 * Wi;
            if (ix0 >= 0) v0 = rw[ix0];
            v1 = rw[ix0 + 1]; v2 = rw[ix0 + 2];
            if (ix0 + 3 < Wi) v3 = rw[ix0 + 3];
        }
        const float* wr0 = ws_w + ci * 16 + (3 - p) * 4;
        const float* wr1 = ws_w + ci * 16 + (1 - p) * 4;
        a0 += u0 * wr0[3] + u1 * wr0[1] + v0 * wr1[3] + v1 * wr1[1];
        a1 += u1 * wr0[2] + u2 * wr0[0] + v1 * wr1[2] + v2 * wr1[0];
        a2 += u1 * wr0[3] + u2 * wr0[1] + v1 * wr1[3] + v2 * wr1[1];
        a3 += u2 * wr0[2] + u3 * wr0[0] + v2 * wr1[2] + v3 * wr1[0];
    }
    size_t o = ((size_t)(b * C + co) * Ho + ho) * Wo + wb;
    *(float4*)(out + o) = make_float4(fmaxf(a0, 0.f), fmaxf(a1, 0.f), fmaxf(a2, 0.f), fmaxf(a3, 0.f));
}

// ------------- transposed conv 4x4 stride 2, 4 outputs x 4 co/thread -------
__global__ __launch_bounds__(TPB) void convt2d_c4_k(
    const float* __restrict__ in, const float* __restrict__ wt,
    const float* __restrict__ bias, float* __restrict__ out,
    int B, int C, int Hi, int Wi, int BPC) {
    __shared__ float ws_w[4][32 * 16];
    int Ho = 2 * Hi, Wo = 2 * Wi;
    int cog = (blockIdx.x / BPC) % (C / 4);
    int b   = blockIdx.x / (BPC * (C / 4));
    int co0 = cog * 4;
    for (int i = threadIdx.x; i < 4 * C * 16; i += TPB) {
        int cr = i / (C * 16); int j = i % (C * 16);
        int ci = j >> 4, t = j & 15;
        ws_w[cr][j] = wt[((size_t)ci * C + (co0 + cr)) * 16 + t];
    }
    __syncthreads();
    int nq = Wo >> 2;
    int r = (blockIdx.x % BPC) * TPB + threadIdx.x;
    if (r >= Ho * nq) return;
    int q = r % nq, ho = r / nq;
    int wb = q * 4;
    int p = ho & 1;
    int iy0 = (ho + p) / 2 - 1;
    int iy1 = iy0 + 1;
    int ix0 = wb / 2 - 1;
    bool vy0 = (iy0 >= 0) && (iy0 < Hi);
    bool vy1 = (iy1 >= 0) && (iy1 < Hi);
    float a[4][4];
#pragma unroll
    for (int cr = 0; cr < 4; ++cr) {
        float bv = bias[co0 + cr];
        a[cr][0] = bv; a[cr][1] = bv; a[cr][2] = bv; a[cr][3] = bv;
    }
    const float* ipb = in + (size_t)b * C * Hi * Wi;
    for (int ci = 0; ci < C; ++ci) {
        const float* ip = ipb + (size_t)ci * Hi * Wi;
        float u0 = 0, u1 = 0, u2 = 0, u3 = 0, v0 = 0, v1 = 0, v2 = 0, v3 = 0;
        if (vy0) {
            const float* rw = ip + (size_t)iy0 * Wi;
            if (ix0 >= 0) u0 = rw[ix0];
            u1 = rw[ix0 + 1]; u2 = rw[ix0 + 2];
            if (ix0 + 3 < Wi) u3 = rw[ix0 + 3];
        }
        if (vy1) {
            const float* rw = ip + (size_t)iy1 * Wi;
            if (ix0 >= 0) v0 = rw[ix0];
            v1 = rw[ix0 + 1]; v2 = rw[ix0 + 2];
            if (ix0 + 3 < Wi) v3 = rw[ix0 + 3];
        }
#pragma unroll
        for (int cr = 0; cr < 4; ++cr) {
            const float* wr0 = ws_w[cr] + ci * 16 + (3 - p) * 4;
            const float* wr1 = ws_w[cr] + ci * 16 + (1 - p) * 4;
            a[cr][0] += u0 * wr0[3] + u1 * wr0[1] + v0 * wr1[3] + v1 * wr1[1];
            a[cr][1] += u1 * wr0[2] + u2 * wr0[0] + v1 * wr1[2] + v2 * wr1[0];
            a[cr][2] += u1 * wr0[3] + u2 * wr0[1] + v1 * wr1[3] + v2 * wr1[1];
            a[cr][3] += u2 * wr0[2] + u3 * wr0[0] + v2 * wr1[2] + v3 * wr1[0];
        }
    }
#pragma unroll
    for (int cr = 0; cr < 4; ++cr) {
        size_t o = ((size_t)(b * C + co0 + cr) * Ho + ho) * Wo + wb;
        *(float4*)(out + o) = make_float4(fmaxf(a[cr][0], 0.f), fmaxf(a[cr][1], 0.f),
                                          fmaxf(a[cr][2], 0.f), fmaxf(a[cr][3], 0.f));
    }
}

// ---- merged prep: conv3db B-frags + w_om B-frags + wdc transpose + border --
__global__ void prep_k(const float* __restrict__ wb, const float* __restrict__ wdc,
                       const float* __restrict__ wom,
                       unsigned short* __restrict__ wbf, unsigned short* __restrict__ womf,
                       float* __restrict__ wt2, float* __restrict__ xa_g) {
    int i = blockIdx.x * TPB + threadIdx.x;
    if (i < 27648) {
        int j = i & 7;
        int l = (i >> 3) & 63;
        int coH = (i >> 9) & 1;
        int tap = i >> 10;
        int ci = ((l >> 4) << 3) + j;
        int co = (coH << 4) + (l & 15);
        wbf[i] = f2bf(wb[(size_t)(co * 32 + ci) * 27 + tap]);
        return;
    }
    int i2 = i - 27648;
    if (i2 < 4032) {
        int o = i2 & 63, ck = i2 >> 6;
        wt2[i2] = wdc[o * 63 + ck];
        return;
    }
    int i3 = i2 - 4032;
    if (i3 < 448 * 644) {
        int pl = i3 / 644, e = i3 % 644;
        int off;
        if (e < 162)      off = e;
        else if (e < 324) off = 161 * 162 + (e - 162);
        else if (e < 484) off = (e - 324 + 1) * 162;
        else              off = (e - 484 + 1) * 162 + 161;
        xa_g[(size_t)pl * 26244 + off] = 0.f;
        return;
    }
    int i4 = i3 - 448 * 644;
    if (i4 >= 55296) return;                 // 9 taps x 12 nt x 64 x 8
    int j = i4 & 7;
    int l = (i4 >> 3) & 63;
    int nt = (i4 >> 9) % 12;
    int tap = i4 / 6144;
    int ci = ((l >> 4) << 3) + j;
    int co = nt * 16 + (l & 15);
    womf[i4] = (co < 189) ? f2bf(wom[((size_t)co * 32 + ci) * 9 + tap]) : (unsigned short)0;
}

// ---- conv3d_a: x (B,7,H,W) -> relu -> padded xa [B][32][7][162][162] -------
__global__ __launch_bounds__(TPB) void conv3da_k(
    const float* __restrict__ x, const float* __restrict__ wa,
    const float* __restrict__ ba, float* __restrict__ xa_g,
    int B, int H, int W) {
    __shared__ float w27[27];
    int blk = blockIdx.x;
    int t5 = blk % 25; int rest = blk / 25;
    int d = rest % 7; rest /= 7;
    int co = rest % 32; int b = rest / 32;
    if (threadIdx.x < 27) w27[threadIdx.x] = wa[co * 27 + threadIdx.x];
    __syncthreads();
    int r = t5 * TPB + threadIdx.x;
    if (r >= 160 * 40) return;
    int y = r / 40, x0 = (r % 40) * 4;
    float bv = ba[co];
    float a0 = bv, a1 = bv, a2 = bv, a3 = bv;
#pragma unroll
    for (int kd = 0; kd < 3; ++kd) {
        int dz = d + kd - 1;
        if (dz < 0 || dz >= 7) continue;
        const float* pl = x + ((size_t)(b * 7 + dz)) * H * W;
#pragma unroll
        for (int kh = 0; kh < 3; ++kh) {
            int yy = y + kh - 1;
            if (yy < 0 || yy >= H) continue;
            const float* row = pl + (size_t)yy * W + x0;
            float4 xv = *(const float4*)row;
            float xm = (x0 > 0) ? row[-1] : 0.f;
            float xp = (x0 + 4 < W) ? row[4] : 0.f;
            float w0 = w27[kd * 9 + kh * 3], w1 = w27[kd * 9 + kh * 3 + 1], w2 = w27[kd * 9 + kh * 3 + 2];
            a0 += xm   * w0 + xv.x * w1 + xv.y * w2;
            a1 += xv.x * w0 + xv.y * w1 + xv.z * w2;
            a2 += xv.y * w0 + xv.z * w1 + xv.w * w2;
            a3 += xv.z * w0 + xv.w * w1 + xp   * w2;
        }
    }
    size_t base = ((size_t)((b * 32 + co) * 7 + d)) * 26244 + (size_t)(y + 1) * 162 + (x0 + 1);
    xa_g[base + 0] = fmaxf(a0, 0.f);
    xa_g[base + 1] = fmaxf(a1, 0.f);
    xa_g[base + 2] = fmaxf(a2, 0.f);
    xa_g[base + 3] = fmaxf(a3, 0.f);
}

// ---- XA(fp32, ch-first, padded) -> XACL(bf16, channel-last, padded) --------
__global__ __launch_bounds__(TPB) void xa2cl_k(
    const float* __restrict__ xa, unsigned short* __restrict__ xacl) {
    int idx = blockIdx.x * TPB + threadIdx.x;
    if (idx >= 2 * 7 * 26244) return;
    int pos = idx % 26244;
    int d = (idx / 26244) % 7;
    int b = idx / 183708;
    unsigned int pk[16];
#pragma unroll
    for (int j = 0; j < 16; ++j) {
        float v0 = xa[((size_t)((b * 32 + 2 * j) * 7 + d)) * 26244 + pos];
        float v1 = xa[((size_t)((b * 32 + 2 * j + 1) * 7 + d)) * 26244 + pos];
        pk[j] = (unsigned int)f2bf(v0) | ((unsigned int)f2bf(v1) << 16);
    }
    uint4* dst = (uint4*)(xacl + (size_t)idx * 32);
    dst[0] = make_uint4(pk[0], pk[1], pk[2], pk[3]);
    dst[1] = make_uint4(pk[4], pk[5], pk[6], pk[7]);
    dst[2] = make_uint4(pk[8], pk[9], pk[10], pk[11]);
    dst[3] = make_uint4(pk[12], pk[13], pk[14], pk[15]);
}

// ---- OUTC(fp32 ch-first 160x160x32) -> OCL(bf16 CL, 162x162 padded) --------
__global__ __launch_bounds__(TPB) void o2cl_k(
    const float* __restrict__ o, unsigned short* __restrict__ ocl) {
    int idx = blockIdx.x * TPB + threadIdx.x;
    if (idx >= 2 * 26244) return;
    int pos = idx % 26244;
    int b = idx / 26244;
    int y = pos / 162, x = pos % 162;
    uint4* dst = (uint4*)(ocl + (size_t)idx * 32);
    if (y == 0 || y == 161 || x == 0 || x == 161) {
        uint4 z = make_uint4(0, 0, 0, 0);
        dst[0] = z; dst[1] = z; dst[2] = z; dst[3] = z;
        return;
    }
    unsigned int pk[16];
    const float* src = o + (size_t)b * 32 * 25600 + (size_t)(y - 1) * 160 + (x - 1);
#pragma unroll
    for (int j = 0; j < 16; ++j) {
        float v0 = src[(size_t)(2 * j) * 25600];
        float v1 = src[(size_t)(2 * j + 1) * 25600];
        pk[j] = (unsigned int)f2bf(v0) | ((unsigned int)f2bf(v1) << 16);
    }
    dst[0] = make_uint4(pk[0], pk[1], pk[2], pk[3]);
    dst[1] = make_uint4(pk[4], pk[5], pk[6], pk[7]);
    dst[2] = make_uint4(pk[8], pk[9], pk[10], pk[11]);
    dst[3] = make_uint4(pk[12], pk[13], pk[14], pk[15]);
}

// ---- conv3d_b + relu + mean as bf16 MFMA implicit GEMM (verified r17) ------
__global__ __launch_bounds__(TPB) void conv3db_mfma_k(
    const unsigned short* __restrict__ xacl, const unsigned short* __restrict__ wbf,
    const float* __restrict__ bb, float* __restrict__ out, int B, int H, int W) {
    int blk = blockIdx.x;
    int b = blk / 800;
    int rem = blk % 800;
    int y = rem / 5;
    int xp = rem % 5;
    int tid = threadIdx.x;
    int l = tid & 63;
    int wv = tid >> 6;
    int mt = wv & 1, coH = wv >> 1;
    int x0 = xp * 32 + mt * 16;
    int co = coH * 16 + (l & 15);
    float bv = bb[co];
    f32x4 acc[7];
#pragma unroll
    for (int d = 0; d < 7; ++d) { acc[d][0] = bv; acc[d][1] = bv; acc[d][2] = bv; acc[d][3] = bv; }

    int ubase = (y * 162 + x0 + (l & 15)) * 32 + ((l >> 4) << 3);
    const unsigned short* xb = xacl + (size_t)b * 5878656;
    const unsigned short* wbase = wbf + ((size_t)coH * 64 + l) * 8;

#pragma unroll
    for (int kd = 0; kd < 3; ++kd) {
        for (int j2 = 0; j2 < 9; ++j2) {
            int off2 = (j2 / 3) * 5184 + (j2 % 3) * 32;
            bf16x8 bf = *reinterpret_cast<const bf16x8*>(wbase + (size_t)(kd * 9 + j2) * 1024);
#pragma unroll
            for (int d = 0; d < 7; ++d) {
                int dz = d + kd - 1;
                if (dz < 0 || dz >= 7) continue;
                bf16x8 af = *reinterpret_cast<const bf16x8*>(xb + (size_t)dz * 839808 + ubase + off2);
                acc[d] = __builtin_amdgcn_mfma_f32_16x16x32_bf16(af, bf, acc[d], 0, 0, 0);
            }
        }
    }

    int xo = x0 + ((l >> 4) << 2);
    size_t obase = ((size_t)(b * 32 + co)) * 25600 + (size_t)y * 160 + xo;
#pragma unroll
    for (int r = 0; r < 4; ++r) {
        float s = 0.f;
#pragma unroll
        for (int d = 0; d < 7; ++d) s += fmaxf(acc[d][r], 0.f);
        out[obase + r] = s * (1.f / 7.f);
    }
}

// ---- w_om head as bf16 MFMA implicit GEMM ----------------------------------
// grid = B*1600 (160y x 10 xseg); block = 4 waves; wave owns 3 n-tiles of 16.
// M=16px, K=288 (9 taps x 32ci), N=192 (189 padded).
__global__ __launch_bounds__(TPB) void conv_om_mfma_k(
    const unsigned short* __restrict__ ocl, const unsigned short* __restrict__ womf,
    const float* __restrict__ bias, float* __restrict__ out, int B) {
    int blk = blockIdx.x;
    int b = blk / 1600;
    int rem = blk % 1600;
    int y = rem / 10;
    int xs = rem % 10;
    int tid = threadIdx.x;
    int l = tid & 63;
    int wv = tid >> 6;
    int x0 = xs * 16;
    f32x4 acc[3];
#pragma unroll
    for (int t = 0; t < 3; ++t) {
        int co = (wv * 3 + t) * 16 + (l & 15);
        float bv = (co < 189) ? bias[co] : 0.f;
        acc[t][0] = bv; acc[t][1] = bv; acc[t][2] = bv; acc[t][3] = bv;
    }
    int ubase = (y * 162 + x0 + (l & 15)) * 32 + ((l >> 4) << 3);
    const unsigned short* ob = ocl + (size_t)b * 839808;        // 26244*32
    const unsigned short* wl = womf + (size_t)l * 8;
#pragma unroll
    for (int tap = 0; tap < 9; ++tap) {
        int off = ((tap / 3) * 162 + (tap % 3)) * 32;
        bf16x8 af = *reinterpret_cast<const bf16x8*>(ob + ubase + off);
#pragma unroll
        for (int t = 0; t < 3; ++t) {
            int nt = wv * 3 + t;
            bf16x8 bf = *reinterpret_cast<const bf16x8*>(wl + (size_t)(tap * 12 + nt) * 512);
            acc[t] = __builtin_amdgcn_mfma_f32_16x16x32_bf16(af, bf, acc[t], 0, 0, 0);
        }
    }
    int xo = x0 + ((l >> 4) << 2);
#pragma unroll
    for (int t = 0; t < 3; ++t) {
        int co = (wv * 3 + t) * 16 + (l & 15);
        if (co >= 189) continue;
        size_t obase = ((size_t)(b * 189 + co)) * 25600 + (size_t)y * 160 + xo;
#pragma unroll
        for (int r = 0; r < 4; ++r) out[obase + r] = acc[t][r];
    }
}

// ------------- two-phase modulated deformable conv ---------------------------
__global__ __launch_bounds__(TPB) void deform_conv2_k(
    const float* __restrict__ x, const float* __restrict__ om,
    const float* __restrict__ wt2, const float* __restrict__ bias,
    float* __restrict__ out, int B, int H, int W) {
    __shared__ float smp[63 * 64];
    const int HW = H * W;
    int blk = blockIdx.x;
    int b = blk / (HW / 64);
    int pxbase = (blk % (HW / 64)) * 64;
    int tid = threadIdx.x;
    const float* omb = om + (size_t)b * 189 * HW;
    const float* xb = x + (size_t)b * 7 * HW;

#pragma unroll 4
    for (int k = 0; k < 16; ++k) {
        int it = tid + k * 256;
        if (it >= 4032) break;
        int pxl = it & 63;
        int tap = it >> 6;
        int c = tap / 9, kk = tap % 9;
        int hw = pxbase + pxl;
        int hq = hw / W, wq = hw % W;
        float dy = omb[(size_t)(c * 18 + kk * 2 + 0) * HW + hw];
        float dx = omb[(size_t)(c * 18 + kk * 2 + 1) * HW + hw];
        float mv = omb[(size_t)(126 + c * 9 + kk) * HW + hw];
        float m = 1.f / (1.f + __expf(-mv));
        float py = (float)hq + (float)(kk / 3 - 1) + dy;
        float px = (float)wq + (float)(kk % 3 - 1) + dx;
        float y0f = floorf(py), x0f = floorf(px);
        int y0 = (int)y0f, x0 = (int)x0f;
        float wy1 = py - y0f, wx1 = px - x0f;
        float wy0 = 1.f - wy1, wx0 = 1.f - wx1;
        float v00 = 0.f, v01 = 0.f, v10 = 0.f, v11 = 0.f;
        const float* xc = xb + (size_t)c * HW;
        bool yin0 = (y0 >= 0) & (y0 < H);
        bool yin1 = (y0 + 1 >= 0) & (y0 + 1 < H);
        bool xin0 = (x0 >= 0) & (x0 < W);
        bool xin1 = (x0 + 1 >= 0) & (x0 + 1 < W);
        if (yin0) {
            const float* rr = xc + (size_t)y0 * W;
            if (xin0) v00 = rr[x0];
            if (xin1) v01 = rr[x0 + 1];
        }
        if (yin1) {
            const float* rr = xc + (size_t)(y0 + 1) * W;
            if (xin0) v10 = rr[x0];
            if (xin1) v11 = rr[x0 + 1];
        }
        smp[tap * 64 + pxl] =
            (wy0 * wx0 * v00 + wy0 * wx1 * v01 + wy1 * wx0 * v10 + wy1 * wx1 * v11) * m;
    }
    __syncthreads();

    int pxl = tid & 63;
    int g = tid >> 6;
    int gu = __builtin_amdgcn_readfirstlane(g);
    const float* swb = wt2 + gu * 16;
    const float* bsb = bias + gu * 16;
    float acc[16];
#pragma unroll
    for (int o = 0; o < 16; ++o) acc[o] = 0.f;
    for (int tap = 0; tap < 63; ++tap) {
        float s = smp[tap * 64 + pxl];
        const float* sw = swb + tap * 64;
#pragma unroll
        for (int o = 0; o < 16; ++o) acc[o] += s * sw[o];
    }
    int hw = pxbase + pxl;
    size_t obase = (size_t)b * 64 * HW + (size_t)gu * 16 * HW + hw;
#pragma unroll
    for (int o = 0; o < 16; ++o)
        out[obase + (size_t)o * HW] = fmaxf(acc[o] + bsb[o], 0.f);
}

extern "C" void kernel_launch(void* const* d_in, const int* in_sizes, int n_in,
                              void* d_out, int out_size, void* d_ws, size_t ws_size,
                              hipStream_t stream) {
    (void)in_sizes; (void)n_in; (void)out_size; (void)ws_size;
    const float* inputs = (const float*)d_in[0];
    const float* w_in   = (const float*)d_in[1];  const float* b_in   = (const float*)d_in[2];
    const float* w_dn1a = (const float*)d_in[3];  const float* b_dn1a = (const float*)d_in[4];
    const float* w_dn1b = (const float*)d_in[5];  const float* b_dn1b = (const float*)d_in[6];
    const float* w_up1a = (const float*)d_in[7];  const float* b_up1a = (const float*)d_in[8];
    const float* wt_up1 = (const float*)d_in[9];  const float* bt_up1 = (const float*)d_in[10];
    const float* w_dn2a = (const float*)d_in[11]; const float* b_dn2a = (const float*)d_in[12];
    const float* w_dn2b = (const float*)d_in[13]; const float* b_dn2b = (const float*)d_in[14];
    const float* w_up2a = (const float*)d_in[15]; const float* b_up2a = (const float*)d_in[16];
    const float* wt_up2 = (const float*)d_in[17]; const float* bt_up2 = (const float*)d_in[18];
    const float* w_tra  = (const float*)d_in[19]; const float* b_tra  = (const float*)d_in[20];
    const float* w_trb  = (const float*)d_in[21]; const float* b_trb  = (const float*)d_in[22];
    const float* wt_tr  = (const float*)d_in[23]; const float* bt_tr  = (const float*)d_in[24];
    const float* w_out  = (const float*)d_in[25]; const float* b_out  = (const float*)d_in[26];
    const float* w_tf3a = (const float*)d_in[27]; const float* b_tf3a = (const float*)d_in[28];
    const float* w_tf3b = (const float*)d_in[29]; const float* b_tf3b = (const float*)d_in[30];
    const float* w_tf2  = (const float*)d_in[31]; const float* b_tf2  = (const float*)d_in[32];
    const float* w_om   = (const float*)d_in[33]; const float* b_om   = (const float*)d_in[34];
    const float* w_dc   = (const float*)d_in[35]; const float* b_dc   = (const float*)d_in[36];
    float* out = (float*)d_out;

    const int B = 2, nf = 32, H = 160, W = 160;
    const size_t n160 = (size_t)B * nf * 160 * 160;
    const size_t n80  = (size_t)B * nf * 80 * 80;
    const size_t n40  = (size_t)B * nf * 40 * 40;
    const size_t n20  = (size_t)B * nf * 20 * 20;

    float* ws = (float*)d_ws;
    float* F0    = ws;
    float* TMP80 = F0 + n160;
    float* F1    = TMP80 + n80;
    float* TMP40 = F1 + n80;
    float* F2    = TMP40 + n40;
    float* T20A  = F2 + n40;
    float* T20B  = T20A + n20;
    float* T40   = T20B + n20;
    float* T40B  = T40 + n40;
    float* T80   = T40B + n40;
    float* T80B  = T80 + n80;
    float* T160  = T80B + n80;
    float* TF    = T160 + n160;
    float* XA    = TF + n160;                         // 11,757,312 f (padded fp32)
    float* OM    = XA;                                // ALIAS (disjoint lifetimes)
    float* WT2   = XA + 11757312;                     // 4,032 f
    unsigned short* WBF  = (unsigned short*)(WT2 + 4032);            // 27,648 us
    unsigned short* XACL = (unsigned short*)(WT2 + 4032 + 13824);    // 11,757,312 us
    unsigned short* WOMF = XACL + 11757312;                          // 55,296 us
    unsigned short* OCL  = WOMF + 55296;                             // 1,679,616 us

    const int bpc160 = 25;            // ceil(160*40/256)
    const int bpc80_128 = 13;         // ceil(80*20/128)
    const int bpc40_64  = 7;          // ceil(40*10/64)
    const int bpc20_64  = 2;          // ceil(20*5/64)

    // prep (merged) + conv_a (fp32) + transpose to bf16 channel-last
    prep_k<<<nblk(27648 + 4032 + 448 * 644 + 55296), TPB, 0, stream>>>(
        w_tf3b, w_dc, w_om, WBF, WOMF, WT2, XA);
    conv3da_k<<<B * 32 * 7 * 25, TPB, 0, stream>>>(inputs, w_tf3a, b_tf3a, XA, B, H, W);
    xa2cl_k<<<nblk(2 * 7 * 26244), TPB, 0, stream>>>(XA, XACL);

    // --- 2D U-Net branch ---
    conv2d_c4_k<1, 0, 0><<<B * 8 * bpc160, TPB, 0, stream>>>(inputs, nullptr, w_in, b_in, nullptr, F0, B, 7, 160, 160, nf, 8, bpc160);
    conv2d_s2_t4_k<128><<<B * nf * bpc80_128, 128, 0, stream>>>(F0, w_dn1a, b_dn1a, TMP80, B, nf, 160, 160, nf, bpc80_128);
    conv2d_t4_k<128, 1, 0><<<B * nf * bpc80_128, 128, 0, stream>>>(TMP80, w_dn1b, b_dn1b, nullptr, F1, B, nf, 80, 80, nf, bpc80_128);
    conv2d_s2_t4_k<64><<<B * nf * bpc40_64, 64, 0, stream>>>(F1, w_dn2a, b_dn2a, TMP40, B, nf, 80, 80, nf, bpc40_64);
    conv2d_t4_k<64, 1, 0><<<B * nf * bpc40_64, 64, 0, stream>>>(TMP40, w_dn2b, b_dn2b, nullptr, F2, B, nf, 40, 40, nf, bpc40_64);
    conv2d_s2_t4_k<64><<<B * nf * bpc20_64, 64, 0, stream>>>(F2, w_tra, b_tra, T20A, B, nf, 40, 40, nf, bpc20_64);
    conv2d_t4_k<64, 1, 0><<<B * nf * bpc20_64, 64, 0, stream>>>(T20A, w_trb, b_trb, nullptr, T20B, B, nf, 20, 20, nf, bpc20_64);
    convt2d_t4_k<64><<<B * nf * bpc40_64, 64, 0, stream>>>(T20B, wt_tr, bt_tr, T40, B, nf, 20, 20, bpc40_64);
    conv2d_cat_t4_k<64><<<B * nf * bpc40_64, 64, 0, stream>>>(T40, F2, w_up2a, b_up2a, T40B, B, nf, nf, 40, 40, nf, bpc40_64);
    convt2d_t4_k<128><<<B * nf * bpc80_128, 128, 0, stream>>>(T40B, wt_up2, bt_up2, T80, B, nf, 40, 40, bpc80_128);
    conv2d_cat_t4_k<128><<<B * nf * bpc80_128, 128, 0, stream>>>(T80, F1, w_up1a, b_up1a, T80B, B, nf, nf, 80, 80, nf, bpc80_128);
    convt2d_c4_k<<<B * 8 * bpc160, TPB, 0, stream>>>(T80B, wt_up1, bt_up1, T160, B, nf, 80, 80, bpc160);

    // --- conv3d_b + relu + mean (bf16 MFMA) -> F0 ---
    conv3db_mfma_k<<<B * 800, TPB, 0, stream>>>(XACL, WBF, b_tf3b, F0, B, H, W);
    // FUSED = relu(conv_tf2(MEAN) + T160)
    conv2d_c4_k<1, 1, 0><<<B * 8 * bpc160, TPB, 0, stream>>>(F0, nullptr, w_tf2, b_tf2, T160, TF, B, nf, 160, 160, nf, 8, bpc160);

    // --- offset/mask head: w_out (fp32 c4) -> OUTC; OUTC -> OCL; w_om MFMA ---
    conv2d_c4_k<1, 0, 0><<<B * 8 * bpc160, TPB, 0, stream>>>(TF, nullptr, w_out, b_out, nullptr, F0, B, nf, 160, 160, nf, 8, bpc160);
    o2cl_k<<<nblk(2 * 26244), TPB, 0, stream>>>(F0, OCL);
    conv_om_mfma_k<<<B * 1600, TPB, 0, stream>>>(OCL, WOMF, b_om, OM, B);

    // --- deformable conv (two-phase) ---
    deform_conv2_k<<<B * (H * W / 64), TPB, 0, stream>>>(inputs, OM, WT2, b_dc, out, B, H, W);
}

// Round 19
// 541.126 us; speedup vs baseline: 1.8225x; 1.2328x over previous
//
#include <hip/hip_runtime.h>
#include <math.h>

// ---------------------------------------------------------------------------
// STDF forward, round 19: MFMA template replicated onto tf2, w_out (N=32,
// K=288 — exact w_om shape) and the up1a concat conv (K=576, concat fused
// into the CL transform). o2cl reused 3x. Rest identical to round 18 (667us).
// ---------------------------------------------------------------------------

#define TPB 256

static inline int nblk(long long total) { return (int)((total + TPB - 1) / TPB); }

typedef short bf16x8 __attribute__((ext_vector_type(8)));
typedef float f32x4 __attribute__((ext_vector_type(4)));

__device__ __forceinline__ unsigned short f2bf(float f) {
    unsigned int u = __float_as_uint(f);
    unsigned int r = u + 0x7FFFu + ((u >> 16) & 1u);   // RNE
    return (unsigned short)(r >> 16);
}

// ---------------- 3x3 conv2d, stride 1, 4 outputs/thread, block-uniform co --
template <int TB, int RELU, int HAS_RES>
__global__ __launch_bounds__(TB) void conv2d_t4_k(
    const float* __restrict__ in, const float* __restrict__ w,
    const float* __restrict__ bias, const float* __restrict__ res,
    float* __restrict__ out, int B, int Ci, int H, int W, int Co, int BPC) {
    __shared__ float ws_w[32 * 9];
    int co = (blockIdx.x / BPC) % Co;
    int b  = blockIdx.x / (BPC * Co);
    for (int i = threadIdx.x; i < Ci * 9; i += TB)
        ws_w[i] = w[(size_t)co * Ci * 9 + i];
    __syncthreads();
    int nq = W >> 2;
    int r = (blockIdx.x % BPC) * TB + threadIdx.x;
    if (r >= H * nq) return;
    int q = r % nq, ho = r / nq;
    int wb = q * 4;
    float bv = bias[co];
    float a0 = bv, a1 = bv, a2 = bv, a3 = bv;
    const float* ipb = in + (size_t)b * Ci * H * W;
    for (int ci = 0; ci < Ci; ++ci) {
        const float* ip = ipb + (size_t)ci * H * W;
        const float* wc = ws_w + ci * 9;
#pragma unroll
        for (int kh = 0; kh < 3; ++kh) {
            int y = ho - 1 + kh;
            if (y < 0 || y >= H) continue;
            const float* row = ip + (size_t)y * W + wb;
            float4 xv = *(const float4*)row;
            float xm = (wb > 0) ? row[-1] : 0.f;
            float xp = (wb + 4 < W) ? row[4] : 0.f;
            float w0 = wc[kh * 3], w1 = wc[kh * 3 + 1], w2 = wc[kh * 3 + 2];
            a0 += xm   * w0 + xv.x * w1 + xv.y * w2;
            a1 += xv.x * w0 + xv.y * w1 + xv.z * w2;
            a2 += xv.y * w0 + xv.z * w1 + xv.w * w2;
            a3 += xv.z * w0 + xv.w * w1 + xp   * w2;
        }
    }
    size_t o = ((size_t)(b * Co + co) * H + ho) * W + wb;
    if (HAS_RES) {
        float4 rv = *(const float4*)(res + o);
        a0 += rv.x; a1 += rv.y; a2 += rv.z; a3 += rv.w;
    }
    if (RELU) { a0 = fmaxf(a0, 0.f); a1 = fmaxf(a1, 0.f); a2 = fmaxf(a2, 0.f); a3 = fmaxf(a3, 0.f); }
    *(float4*)(out + o) = make_float4(a0, a1, a2, a3);
}

// ------- 3x3 conv2d, stride 1, 4 outputs x 4 co per thread -----------------
template <int RELU, int HAS_RES, int HAS_IN2>
__global__ __launch_bounds__(TPB) void conv2d_c4_k(
    const float* __restrict__ in, const float* __restrict__ in2,
    const float* __restrict__ w, const float* __restrict__ bias,
    const float* __restrict__ res, float* __restrict__ out,
    int B, int Ci, int H, int W, int Co, int COG, int BPC) {
    __shared__ float ws_w[4 * 32 * 9];
    int cog = (blockIdx.x / BPC) % COG;
    int b   = blockIdx.x / (BPC * COG);
    int co0 = cog * 4;
    int nw = Ci * 9;
    for (int i = threadIdx.x; i < 4 * nw; i += TPB) {
        int cr = i / nw; int co = co0 + cr;
        ws_w[i] = (co < Co) ? w[(size_t)co * nw + (i - cr * nw)] : 0.f;
    }
    __syncthreads();
    int nq = W >> 2;
    int r = (blockIdx.x % BPC) * TPB + threadIdx.x;
    if (r >= H * nq) return;
    int q = r % nq, ho = r / nq;
    int wb = q * 4;
    float a[4][4];
#pragma unroll
    for (int cr = 0; cr < 4; ++cr) {
        float bv = (co0 + cr < Co) ? bias[co0 + cr] : 0.f;
        a[cr][0] = bv; a[cr][1] = bv; a[cr][2] = bv; a[cr][3] = bv;
    }
    const float* ipb = in + (size_t)b * Ci * H * W;
    const float* ipb2 = HAS_IN2 ? in2 + (size_t)b * Ci * H * W : nullptr;
    for (int ci = 0; ci < Ci; ++ci) {
        const float* ip = ipb + (size_t)ci * H * W;
        const float* ip2 = HAS_IN2 ? ipb2 + (size_t)ci * H * W : nullptr;
#pragma unroll
        for (int kh = 0; kh < 3; ++kh) {
            int y = ho - 1 + kh;
            if (y < 0 || y >= H) continue;
            const float* row = ip + (size_t)y * W + wb;
            float4 xv = *(const float4*)row;
            float x_[6];
            x_[0] = (wb > 0) ? row[-1] : 0.f;
            x_[5] = (wb + 4 < W) ? row[4] : 0.f;
            if (HAS_IN2) {
                const float* row2 = ip2 + (size_t)y * W + wb;
                float4 x2 = *(const float4*)row2;
                xv.x += x2.x; xv.y += x2.y; xv.z += x2.z; xv.w += x2.w;
                if (wb > 0) x_[0] += row2[-1];
                if (wb + 4 < W) x_[5] += row2[4];
            }
            x_[1] = xv.x; x_[2] = xv.y; x_[3] = xv.z; x_[4] = xv.w;
#pragma unroll
            for (int cr = 0; cr < 4; ++cr) {
                const float* wc = ws_w + cr * nw + ci * 9 + kh * 3;
                float w0 = wc[0], w1 = wc[1], w2 = wc[2];
                a[cr][0] += x_[0] * w0 + x_[1] * w1 + x_[2] * w2;
                a[cr][1] += x_[1] * w0 + x_[2] * w1 + x_[3] * w2;
                a[cr][2] += x_[2] * w0 + x_[3] * w1 + x_[4] * w2;
                a[cr][3] += x_[3] * w0 + x_[4] * w1 + x_[5] * w2;
            }
        }
    }
#pragma unroll
    for (int cr = 0; cr < 4; ++cr) {
        int co = co0 + cr;
        if (co >= Co) break;
        size_t o = ((size_t)(b * Co + co) * H + ho) * W + wb;
        float a0 = a[cr][0], a1 = a[cr][1], a2 = a[cr][2], a3 = a[cr][3];
        if (HAS_RES) {
            float4 rv = *(const float4*)(res + o);
            a0 += rv.x; a1 += rv.y; a2 += rv.z; a3 += rv.w;
        }
        if (RELU) { a0 = fmaxf(a0, 0.f); a1 = fmaxf(a1, 0.f); a2 = fmaxf(a2, 0.f); a3 = fmaxf(a3, 0.f); }
        *(float4*)(out + o) = make_float4(a0, a1, a2, a3);
    }
}

// ------------- 3x3 conv2d over concat of two 32-ch inputs, stride 1, relu ---
template <int TB>
__global__ __launch_bounds__(TB) void conv2d_cat_t4_k(
    const float* __restrict__ in1, const float* __restrict__ in2,
    const float* __restrict__ w, const float* __restrict__ bias,
    float* __restrict__ out, int B, int C1, int C2, int H, int W, int Co, int BPC) {
    __shared__ float ws_w[64 * 9];
    int Ci = C1 + C2;
    int co = (blockIdx.x / BPC) % Co;
    int b  = blockIdx.x / (BPC * Co);
    for (int i = threadIdx.x; i < Ci * 9; i += TB)
        ws_w[i] = w[(size_t)co * Ci * 9 + i];
    __syncthreads();
    int nq = W >> 2;
    int r = (blockIdx.x % BPC) * TB + threadIdx.x;
    if (r >= H * nq) return;
    int q = r % nq, ho = r / nq;
    int wb = q * 4;
    float bv = bias[co];
    float a0 = bv, a1 = bv, a2 = bv, a3 = bv;
    for (int ci = 0; ci < Ci; ++ci) {
        const float* ip = (ci < C1)
            ? in1 + ((size_t)(b * C1 + ci)) * H * W
            : in2 + ((size_t)(b * C2 + (ci - C1))) * H * W;
        const float* wc = ws_w + ci * 9;
#pragma unroll
        for (int kh = 0; kh < 3; ++kh) {
            int y = ho - 1 + kh;
            if (y < 0 || y >= H) continue;
            const float* row = ip + (size_t)y * W + wb;
            float4 xv = *(const float4*)row;
            float xm = (wb > 0) ? row[-1] : 0.f;
            float xp = (wb + 4 < W) ? row[4] : 0.f;
            float w0 = wc[kh * 3], w1 = wc[kh * 3 + 1], w2 = wc[kh * 3 + 2];
            a0 += xm   * w0 + xv.x * w1 + xv.y * w2;
            a1 += xv.x * w0 + xv.y * w1 + xv.z * w2;
            a2 += xv.y * w0 + xv.z * w1 + xv.w * w2;
            a3 += xv.z * w0 + xv.w * w1 + xp   * w2;
        }
    }
    size_t o = ((size_t)(b * Co + co) * H + ho) * W + wb;
    *(float4*)(out + o) = make_float4(fmaxf(a0, 0.f), fmaxf(a1, 0.f), fmaxf(a2, 0.f), fmaxf(a3, 0.f));
}

// ------------- 3x3 conv2d, stride 2, 4 outputs/thread, relu ----------------
template <int TB>
__global__ __launch_bounds__(TB) void conv2d_s2_t4_k(
    const float* __restrict__ in, const float* __restrict__ w,
    const float* __restrict__ bias, float* __restrict__ out,
    int B, int Ci, int Hi, int Wi, int Co, int BPC) {
    __shared__ float ws_w[32 * 9];
    int Ho = Hi >> 1, Wo = Wi >> 1;
    int co = (blockIdx.x / BPC) % Co;
    int b  = blockIdx.x / (BPC * Co);
    for (int i = threadIdx.x; i < Ci * 9; i += TB)
        ws_w[i] = w[(size_t)co * Ci * 9 + i];
    __syncthreads();
    int nq = Wo >> 2;
    int r = (blockIdx.x % BPC) * TB + threadIdx.x;
    if (r >= Ho * nq) return;
    int q = r % nq, ho = r / nq;
    int wb = q * 4;
    float bv = bias[co];
    float a0 = bv, a1 = bv, a2 = bv, a3 = bv;
    const float* ipb = in + (size_t)b * Ci * Hi * Wi;
    for (int ci = 0; ci < Ci; ++ci) {
        const float* ip = ipb + (size_t)ci * Hi * Wi;
        const float* wc = ws_w + ci * 9;
#pragma unroll
        for (int kh = 0; kh < 3; ++kh) {
            int y = 2 * ho - 1 + kh;
            if (y < 0 || y >= Hi) continue;
            const float* row = ip + (size_t)y * Wi;
            float z0 = (2 * wb - 1 >= 0) ? row[2 * wb - 1] : 0.f;
            float4 za = *(const float4*)(row + 2 * wb);
            float4 zb = *(const float4*)(row + 2 * wb + 4);
            float w0 = wc[kh * 3], w1 = wc[kh * 3 + 1], w2 = wc[kh * 3 + 2];
            a0 += z0   * w0 + za.x * w1 + za.y * w2;
            a1 += za.y * w0 + za.z * w1 + za.w * w2;
            a2 += za.w * w0 + zb.x * w1 + zb.y * w2;
            a3 += zb.y * w0 + zb.z * w1 + zb.w * w2;
        }
    }
    size_t o = ((size_t)(b * Co + co) * Ho + ho) * Wo + wb;
    *(float4*)(out + o) = make_float4(fmaxf(a0, 0.f), fmaxf(a1, 0.f), fmaxf(a2, 0.f), fmaxf(a3, 0.f));
}

// ------------- transposed conv 4x4 stride 2, 4 outputs/thread, relu --------
template <int TB>
__global__ __launch_bounds__(TB) void convt2d_t4_k(
    const float* __restrict__ in, const float* __restrict__ wt,
    const float* __restrict__ bias, float* __restrict__ out,
    int B, int C, int Hi, int Wi, int BPC) {
    __shared__ float ws_w[32 * 16];
    int Ho = 2 * Hi, Wo = 2 * Wi;
    int co = (blockIdx.x / BPC) % C;
    int b  = blockIdx.x / (BPC * C);
    for (int i = threadIdx.x; i < C * 16; i += TB) {
        int ci = i >> 4, t = i & 15;
        ws_w[i] = wt[((size_t)ci * C + co) * 16 + t];
    }
    __syncthreads();
    int nq = Wo >> 2;
    int r = (blockIdx.x % BPC) * TB + threadIdx.x;
    if (r >= Ho * nq) return;
    int q = r % nq, ho = r / nq;
    int wb = q * 4;
    int p = ho & 1;
    int iy0 = (ho + p) / 2 - 1;
    int iy1 = iy0 + 1;
    int ix0 = wb / 2 - 1;
    bool vy0 = (iy0 >= 0) && (iy0 < Hi);
    bool vy1 = (iy1 >= 0) && (iy1 < Hi);
    float bv = bias[co];
    float a0 = bv, a1 = bv, a2 = bv, a3 = bv;
    const float* ipb = in + (size_t)b * C * Hi * Wi;
    for (int ci = 0; ci < C; ++ci) {
        const float* ip = ipb + (size_t)ci * Hi * Wi;
        float u0 = 0, u1 = 0, u2 = 0, u3 = 0, v0 = 0, v1 = 0, v2 = 0, v3 = 0;
        if (vy0) {
            const float* rw = ip + (size_t)iy0 * Wi;
            if (ix0 >= 0) u0 = rw[ix0];
            u1 = rw[ix0 + 1]; u2 = rw[ix0 + 2];
            if (ix0 + 3 < Wi) u3 = rw[ix0 + 3];
        }
        if (vy1) {
            const float* rw = ip + (size_t)iy1 * Wi;
            if (ix0 >= 0) v0 = rw[ix0];
            v1 = rw[ix0 + 1]; v2 = rw[ix0 + 2];
            if (ix0 + 3 < Wi) v3 = rw[ix0 + 3];
        }
        const float* wr0 = ws_w + ci * 16 + (3 - p) * 4;
        const float* wr1 = ws_w + ci * 16 + (1 - p) * 4;
        a0 += u0 * wr0[3] + u1 * wr0[1] + v0 * wr1[3] + v1 * wr1[1];
        a1 += u1 * wr0[2] + u2 * wr0[0] + v1 * wr1[2] + v2 * wr1[0];
        a2 += u1 * wr0[3] + u2 * wr0[1] + v1 * wr1[3] + v2 * wr1[1];
        a3 += u2 * wr0[2] + u3 * wr0[0] + v2 * wr1[2] + v3 * wr1[0];
    }
    size_t o = ((size_t)(b * C + co) * Ho + ho) * Wo + wb;
    *(float4*)(out + o) = make_float4(fmaxf(a0, 0.f), fmaxf(a1, 0.f), fmaxf(a2, 0.f), fmaxf(a3, 0.f));
}

// ------------- transposed conv 4x4 stride 2, 4 outputs x 4 co/thread -------
__global__ __launch_bounds__(TPB) void convt2d_c4_k(
    const float* __restrict__ in, const float* __restrict__ wt,
    const float* __restrict__ bias, float* __restrict__ out,
    int B, int C, int Hi, int Wi, int BPC) {
    __shared__ float ws_w[4][32 * 16];
    int Ho = 2 * Hi, Wo = 2 * Wi;
    int cog = (blockIdx.x / BPC) % (C / 4);
    int b   = blockIdx.x / (BPC * (C / 4));
    int co0 = cog * 4;
    for (int i = threadIdx.x; i < 4 * C * 16; i += TPB) {
        int cr = i / (C * 16); int j = i % (C * 16);
        int ci = j >> 4, t = j & 15;
        ws_w[cr][j] = wt[((size_t)ci * C + (co0 + cr)) * 16 + t];
    }
    __syncthreads();
    int nq = Wo >> 2;
    int r = (blockIdx.x % BPC) * TPB + threadIdx.x;
    if (r >= Ho * nq) return;
    int q = r % nq, ho = r / nq;
    int wb = q * 4;
    int p = ho & 1;
    int iy0 = (ho + p) / 2 - 1;
    int iy1 = iy0 + 1;
    int ix0 = wb / 2 - 1;
    bool vy0 = (iy0 >= 0) && (iy0 < Hi);
    bool vy1 = (iy1 >= 0) && (iy1 < Hi);
    float a[4][4];
#pragma unroll
    for (int cr = 0; cr < 4; ++cr) {
        float bv = bias[co0 + cr];
        a[cr][0] = bv; a[cr][1] = bv; a[cr][2] = bv; a[cr][3] = bv;
    }
    const float* ipb = in + (size_t)b * C * Hi * Wi;
    for (int ci = 0; ci < C; ++ci) {
        const float* ip = ipb + (size_t)ci * Hi * Wi;
        float u0 = 0, u1 = 0, u2 = 0, u3 = 0, v0 = 0, v1 = 0, v2 = 0, v3 = 0;
        if (vy0) {
            const float* rw = ip + (size_t)iy0 * Wi;
            if (ix0 >= 0) u0 = rw[ix0];
            u1 = rw[ix0 + 1]; u2 = rw[ix0 + 2];
            if (ix0 + 3 < Wi) u3 = rw[ix0 + 3];
        }
        if (vy1) {
            const float* rw = ip + (size_t)iy1 * Wi;
            if (ix0 >= 0) v0 = rw[ix0];
            v1 = rw[ix0 + 1]; v2 = rw[ix0 + 2];
            if (ix0 + 3 < Wi) v3 = rw[ix0 + 3];
        }
#pragma unroll
        for (int cr = 0; cr < 4; ++cr) {
            const float* wr0 = ws_w[cr] + ci * 16 + (3 - p) * 4;
            const float* wr1 = ws_w[cr] + ci * 16 + (1 - p) * 4;
            a[cr][0] += u0 * wr0[3] + u1 * wr0[1] + v0 * wr1[3] + v1 * wr1[1];
            a[cr][1] += u1 * wr0[2] + u2 * wr0[0] + v1 * wr1[2] + v2 * wr1[0];
            a[cr][2] += u1 * wr0[3] + u2 * wr0[1] + v1 * wr1[3] + v2 * wr1[1];
            a[cr][3] += u2 * wr0[2] + u3 * wr0[0] + v2 * wr1[2] + v3 * wr1[0];
        }
    }
#pragma unroll
    for (int cr = 0; cr < 4; ++cr) {
        size_t o = ((size_t)(b * C + co0 + cr) * Ho + ho) * Wo + wb;
        *(float4*)(out + o) = make_float4(fmaxf(a[cr][0], 0.f), fmaxf(a[cr][1], 0.f),
                                          fmaxf(a[cr][2], 0.f), fmaxf(a[cr][3], 0.f));
    }
}

// ---- merged prep: all B-fragment packs + wdc transpose + xa border zero ----
__global__ void prep_k(const float* __restrict__ wb, const float* __restrict__ wdc,
                       const float* __restrict__ wom, const float* __restrict__ wtf2,
                       const float* __restrict__ wout, const float* __restrict__ wup1a,
                       unsigned short* __restrict__ wbf, unsigned short* __restrict__ womf,
                       unsigned short* __restrict__ wtf2f, unsigned short* __restrict__ woutf,
                       unsigned short* __restrict__ wup1f,
                       float* __restrict__ wt2, float* __restrict__ xa_g) {
    int i = blockIdx.x * TPB + threadIdx.x;
    if (i < 27648) {                          // conv3db B-frags
        int j = i & 7;
        int l = (i >> 3) & 63;
        int coH = (i >> 9) & 1;
        int tap = i >> 10;
        int ci = ((l >> 4) << 3) + j;
        int co = (coH << 4) + (l & 15);
        wbf[i] = f2bf(wb[(size_t)(co * 32 + ci) * 27 + tap]);
        return;
    }
    int i2 = i - 27648;
    if (i2 < 4032) {                          // deform weight transpose
        int o = i2 & 63, ck = i2 >> 6;
        wt2[i2] = wdc[o * 63 + ck];
        return;
    }
    int i3 = i2 - 4032;
    if (i3 < 448 * 644) {                     // xa border zero
        int pl = i3 / 644, e = i3 % 644;
        int off;
        if (e < 162)      off = e;
        else if (e < 324) off = 161 * 162 + (e - 162);
        else if (e < 484) off = (e - 324 + 1) * 162;
        else              off = (e - 484 + 1) * 162 + 161;
        xa_g[(size_t)pl * 26244 + off] = 0.f;
        return;
    }
    int i4 = i3 - 448 * 644;
    if (i4 < 55296) {                         // w_om B-frags [tap][nt12][l][8]
        int j = i4 & 7;
        int l = (i4 >> 3) & 63;
        int nt = (i4 >> 9) % 12;
        int tap = i4 / 6144;
        int ci = ((l >> 4) << 3) + j;
        int co = nt * 16 + (l & 15);
        womf[i4] = (co < 189) ? f2bf(wom[((size_t)co * 32 + ci) * 9 + tap]) : (unsigned short)0;
        return;
    }
    int i5 = i4 - 55296;
    if (i5 < 9216) {                          // tf2 B-frags [tap][coH][l][8]
        int j = i5 & 7;
        int l = (i5 >> 3) & 63;
        int q = i5 >> 9;
        int coH = q & 1, tap = q >> 1;
        int ci = ((l >> 4) << 3) + j;
        int co = coH * 16 + (l & 15);
        wtf2f[i5] = f2bf(wtf2[((size_t)co * 32 + ci) * 9 + tap]);
        return;
    }
    int i6 = i5 - 9216;
    if (i6 < 9216) {                          // w_out B-frags
        int j = i6 & 7;
        int l = (i6 >> 3) & 63;
        int q = i6 >> 9;
        int coH = q & 1, tap = q >> 1;
        int ci = ((l >> 4) << 3) + j;
        int co = coH * 16 + (l & 15);
        woutf[i6] = f2bf(wout[((size_t)co * 32 + ci) * 9 + tap]);
        return;
    }
    int i7 = i6 - 9216;
    if (i7 >= 18432) return;                  // up1a B-frags [tap][kc][coH][l][8]
    int j = i7 & 7;
    int l = (i7 >> 3) & 63;
    int q = i7 >> 9;                           // 0..35
    int coH = q & 1, kc = (q >> 1) & 1, tap = q >> 2;
    int ci = kc * 32 + ((l >> 4) << 3) + j;
    int co = coH * 16 + (l & 15);
    wup1f[i7] = f2bf(wup1a[((size_t)co * 64 + ci) * 9 + tap]);
}

// ---- conv3d_a: x (B,7,H,W) -> relu -> padded xa [B][32][7][162][162] -------
__global__ __launch_bounds__(TPB) void conv3da_k(
    const float* __restrict__ x, const float* __restrict__ wa,
    const float* __restrict__ ba, float* __restrict__ xa_g,
    int B, int H, int W) {
    __shared__ float w27[27];
    int blk = blockIdx.x;
    int t5 = blk % 25; int rest = blk / 25;
    int d = rest % 7; rest /= 7;
    int co = rest % 32; int b = rest / 32;
    if (threadIdx.x < 27) w27[threadIdx.x] = wa[co * 27 + threadIdx.x];
    __syncthreads();
    int r = t5 * TPB + threadIdx.x;
    if (r >= 160 * 40) return;
    int y = r / 40, x0 = (r % 40) * 4;
    float bv = ba[co];
    float a0 = bv, a1 = bv, a2 = bv, a3 = bv;
#pragma unroll
    for (int kd = 0; kd < 3; ++kd) {
        int dz = d + kd - 1;
        if (dz < 0 || dz >= 7) continue;
        const float* pl = x + ((size_t)(b * 7 + dz)) * H * W;
#pragma unroll
        for (int kh = 0; kh < 3; ++kh) {
            int yy = y + kh - 1;
            if (yy < 0 || yy >= H) continue;
            const float* row = pl + (size_t)yy * W + x0;
            float4 xv = *(const float4*)row;
            float xm = (x0 > 0) ? row[-1] : 0.f;
            float xp = (x0 + 4 < W) ? row[4] : 0.f;
            float w0 = w27[kd * 9 + kh * 3], w1 = w27[kd * 9 + kh * 3 + 1], w2 = w27[kd * 9 + kh * 3 + 2];
            a0 += xm   * w0 + xv.x * w1 + xv.y * w2;
            a1 += xv.x * w0 + xv.y * w1 + xv.z * w2;
            a2 += xv.y * w0 + xv.z * w1 + xv.w * w2;
            a3 += xv.z * w0 + xv.w * w1 + xp   * w2;
        }
    }
    size_t base = ((size_t)((b * 32 + co) * 7 + d)) * 26244 + (size_t)(y + 1) * 162 + (x0 + 1);
    xa_g[base + 0] = fmaxf(a0, 0.f);
    xa_g[base + 1] = fmaxf(a1, 0.f);
    xa_g[base + 2] = fmaxf(a2, 0.f);
    xa_g[base + 3] = fmaxf(a3, 0.f);
}

// ---- XA(fp32, ch-first, padded) -> XACL(bf16, channel-last, padded) --------
__global__ __launch_bounds__(TPB) void xa2cl_k(
    const float* __restrict__ xa, unsigned short* __restrict__ xacl) {
    int idx = blockIdx.x * TPB + threadIdx.x;
    if (idx >= 2 * 7 * 26244) return;
    int pos = idx % 26244;
    int d = (idx / 26244) % 7;
    int b = idx / 183708;
    unsigned int pk[16];
#pragma unroll
    for (int j = 0; j < 16; ++j) {
        float v0 = xa[((size_t)((b * 32 + 2 * j) * 7 + d)) * 26244 + pos];
        float v1 = xa[((size_t)((b * 32 + 2 * j + 1) * 7 + d)) * 26244 + pos];
        pk[j] = (unsigned int)f2bf(v0) | ((unsigned int)f2bf(v1) << 16);
    }
    uint4* dst = (uint4*)(xacl + (size_t)idx * 32);
    dst[0] = make_uint4(pk[0], pk[1], pk[2], pk[3]);
    dst[1] = make_uint4(pk[4], pk[5], pk[6], pk[7]);
    dst[2] = make_uint4(pk[8], pk[9], pk[10], pk[11]);
    dst[3] = make_uint4(pk[12], pk[13], pk[14], pk[15]);
}

// ---- 32ch fp32 ch-first 160x160 -> bf16 CL 162x162 padded ------------------
__global__ __launch_bounds__(TPB) void o2cl_k(
    const float* __restrict__ o, unsigned short* __restrict__ ocl) {
    int idx = blockIdx.x * TPB + threadIdx.x;
    if (idx >= 2 * 26244) return;
    int pos = idx % 26244;
    int b = idx / 26244;
    int y = pos / 162, x = pos % 162;
    uint4* dst = (uint4*)(ocl + (size_t)idx * 32);
    if (y == 0 || y == 161 || x == 0 || x == 161) {
        uint4 z = make_uint4(0, 0, 0, 0);
        dst[0] = z; dst[1] = z; dst[2] = z; dst[3] = z;
        return;
    }
    unsigned int pk[16];
    const float* src = o + (size_t)b * 32 * 25600 + (size_t)(y - 1) * 160 + (x - 1);
#pragma unroll
    for (int j = 0; j < 16; ++j) {
        float v0 = src[(size_t)(2 * j) * 25600];
        float v1 = src[(size_t)(2 * j + 1) * 25600];
        pk[j] = (unsigned int)f2bf(v0) | ((unsigned int)f2bf(v1) << 16);
    }
    dst[0] = make_uint4(pk[0], pk[1], pk[2], pk[3]);
    dst[1] = make_uint4(pk[4], pk[5], pk[6], pk[7]);
    dst[2] = make_uint4(pk[8], pk[9], pk[10], pk[11]);
    dst[3] = make_uint4(pk[12], pk[13], pk[14], pk[15]);
}

// ---- concat(T80, F1) fp32 ch-first 80x80 -> bf16 CL [82][82][64] padded ----
__global__ __launch_bounds__(TPB) void cat2cl_k(
    const float* __restrict__ a, const float* __restrict__ c2,
    unsigned short* __restrict__ dst) {
    int idx = blockIdx.x * TPB + threadIdx.x;
    if (idx >= 2 * 6724) return;
    int pos = idx % 6724;
    int b = idx / 6724;
    int y = pos / 82, x = pos % 82;
    uint4* d = (uint4*)(dst + (size_t)idx * 64);
    if (y == 0 || y == 81 || x == 0 || x == 81) {
        uint4 z = make_uint4(0, 0, 0, 0);
#pragma unroll
        for (int k = 0; k < 8; ++k) d[k] = z;
        return;
    }
    size_t off = (size_t)(y - 1) * 80 + (x - 1);
    const float* sa = a + (size_t)b * 32 * 6400 + off;
    const float* sc = c2 + (size_t)b * 32 * 6400 + off;
    unsigned int pk[32];
#pragma unroll
    for (int j = 0; j < 16; ++j) {
        float v0 = sa[(size_t)(2 * j) * 6400];
        float v1 = sa[(size_t)(2 * j + 1) * 6400];
        pk[j] = (unsigned int)f2bf(v0) | ((unsigned int)f2bf(v1) << 16);
    }
#pragma unroll
    for (int j = 0; j < 16; ++j) {
        float v0 = sc[(size_t)(2 * j) * 6400];
        float v1 = sc[(size_t)(2 * j + 1) * 6400];
        pk[16 + j] = (unsigned int)f2bf(v0) | ((unsigned int)f2bf(v1) << 16);
    }
#pragma unroll
    for (int k = 0; k < 8; ++k)
        d[k] = make_uint4(pk[4 * k], pk[4 * k + 1], pk[4 * k + 2], pk[4 * k + 3]);
}

// ---- conv3d_b + relu + mean as bf16 MFMA implicit GEMM (verified r17) ------
__global__ __launch_bounds__(TPB) void conv3db_mfma_k(
    const unsigned short* __restrict__ xacl, const unsigned short* __restrict__ wbf,
    const float* __restrict__ bb, float* __restrict__ out, int B, int H, int W) {
    int blk = blockIdx.x;
    int b = blk / 800;
    int rem = blk % 800;
    int y = rem / 5;
    int xp = rem % 5;
    int tid = threadIdx.x;
    int l = tid & 63;
    int wv = tid >> 6;
    int mt = wv & 1, coH = wv >> 1;
    int x0 = xp * 32 + mt * 16;
    int co = coH * 16 + (l & 15);
    float bv = bb[co];
    f32x4 acc[7];
#pragma unroll
    for (int d = 0; d < 7; ++d) { acc[d][0] = bv; acc[d][1] = bv; acc[d][2] = bv; acc[d][3] = bv; }

    int ubase = (y * 162 + x0 + (l & 15)) * 32 + ((l >> 4) << 3);
    const unsigned short* xb = xacl + (size_t)b * 5878656;
    const unsigned short* wbase = wbf + ((size_t)coH * 64 + l) * 8;

#pragma unroll
    for (int kd = 0; kd < 3; ++kd) {
        for (int j2 = 0; j2 < 9; ++j2) {
            int off2 = (j2 / 3) * 5184 + (j2 % 3) * 32;
            bf16x8 bf = *reinterpret_cast<const bf16x8*>(wbase + (size_t)(kd * 9 + j2) * 1024);
#pragma unroll
            for (int d = 0; d < 7; ++d) {
                int dz = d + kd - 1;
                if (dz < 0 || dz >= 7) continue;
                bf16x8 af = *reinterpret_cast<const bf16x8*>(xb + (size_t)dz * 839808 + ubase + off2);
                acc[d] = __builtin_amdgcn_mfma_f32_16x16x32_bf16(af, bf, acc[d], 0, 0, 0);
            }
        }
    }

    int xo = x0 + ((l >> 4) << 2);
    size_t obase = ((size_t)(b * 32 + co)) * 25600 + (size_t)y * 160 + xo;
#pragma unroll
    for (int r = 0; r < 4; ++r) {
        float s = 0.f;
#pragma unroll
        for (int d = 0; d < 7; ++d) s += fmaxf(acc[d][r], 0.f);
        out[obase + r] = s * (1.f / 7.f);
    }
}

// ---- N=32 K=288 160-level conv as bf16 MFMA (tf2 / w_out) ------------------
template <int HAS_RES, int RELU>
__global__ __launch_bounds__(TPB) void conv_nf_mfma_k(
    const unsigned short* __restrict__ icl, const unsigned short* __restrict__ wf,
    const float* __restrict__ bias, const float* __restrict__ res,
    float* __restrict__ out, int B) {
    int blk = blockIdx.x;
    int b = blk / 800;
    int rem = blk % 800;
    int y = rem / 5;
    int xp = rem % 5;
    int tid = threadIdx.x;
    int l = tid & 63;
    int wv = tid >> 6;
    int mt = wv & 1, coH = wv >> 1;
    int x0 = xp * 32 + mt * 16;
    int co = coH * 16 + (l & 15);
    float bv = bias[co];
    f32x4 acc;
    acc[0] = bv; acc[1] = bv; acc[2] = bv; acc[3] = bv;
    int ubase = (y * 162 + x0 + (l & 15)) * 32 + ((l >> 4) << 3);
    const unsigned short* ib = icl + (size_t)b * 839808;
    const unsigned short* wl = wf + (size_t)l * 8;
#pragma unroll
    for (int tap = 0; tap < 9; ++tap) {
        int off = ((tap / 3) * 162 + (tap % 3)) * 32;
        bf16x8 af = *reinterpret_cast<const bf16x8*>(ib + ubase + off);
        bf16x8 bf = *reinterpret_cast<const bf16x8*>(wl + (size_t)(tap * 2 + coH) * 512);
        acc = __builtin_amdgcn_mfma_f32_16x16x32_bf16(af, bf, acc, 0, 0, 0);
    }
    int xo = x0 + ((l >> 4) << 2);
    size_t obase = ((size_t)(b * 32 + co)) * 25600 + (size_t)y * 160 + xo;
#pragma unroll
    for (int r = 0; r < 4; ++r) {
        float v = acc[r];
        if (HAS_RES) v += res[obase + r];
        if (RELU) v = fmaxf(v, 0.f);
        out[obase + r] = v;
    }
}

// ---- up1a concat conv as bf16 MFMA: M=80x80, N=32, K=576 -------------------
__global__ __launch_bounds__(TPB) void conv_up1a_mfma_k(
    const unsigned short* __restrict__ catcl, const unsigned short* __restrict__ wf,
    const float* __restrict__ bias, float* __restrict__ out, int B) {
    int blk = blockIdx.x;
    int b = blk / 200;
    int rem = blk % 200;
    int tid = threadIdx.x;
    int l = tid & 63;
    int wv = tid >> 6;
    int mtile = rem * 2 + (wv & 1);          // 0..399
    int coH = wv >> 1;
    int y = mtile / 5, x0 = (mtile % 5) * 16;
    int co = coH * 16 + (l & 15);
    float bv = bias[co];
    f32x4 acc;
    acc[0] = bv; acc[1] = bv; acc[2] = bv; acc[3] = bv;
    int ubase = (y * 82 + x0 + (l & 15)) * 64 + ((l >> 4) << 3);
    const unsigned short* cb = catcl + (size_t)b * 430336;   // 82*82*64
    const unsigned short* wl = wf + (size_t)l * 8;
#pragma unroll
    for (int tap = 0; tap < 9; ++tap) {
        int off = ((tap / 3) * 82 + (tap % 3)) * 64;
#pragma unroll
        for (int kc = 0; kc < 2; ++kc) {
            bf16x8 af = *reinterpret_cast<const bf16x8*>(cb + ubase + off + kc * 32);
            bf16x8 bf = *reinterpret_cast<const bf16x8*>(wl + (size_t)(((tap * 2 + kc) * 2 + coH)) * 512);
            acc = __builtin_amdgcn_mfma_f32_16x16x32_bf16(af, bf, acc, 0, 0, 0);
        }
    }
    int xo = x0 + ((l >> 4) << 2);
    size_t obase = ((size_t)(b * 32 + co)) * 6400 + (size_t)y * 80 + xo;
#pragma unroll
    for (int r = 0; r < 4; ++r)
        out[obase + r] = fmaxf(acc[r], 0.f);
}

// ---- w_om head as bf16 MFMA implicit GEMM (verified r18) -------------------
__global__ __launch_bounds__(TPB) void conv_om_mfma_k(
    const unsigned short* __restrict__ ocl, const unsigned short* __restrict__ womf,
    const float* __restrict__ bias, float* __restrict__ out, int B) {
    int blk = blockIdx.x;
    int b = blk / 1600;
    int rem = blk % 1600;
    int y = rem / 10;
    int xs = rem % 10;
    int tid = threadIdx.x;
    int l = tid & 63;
    int wv = tid >> 6;
    int x0 = xs * 16;
    f32x4 acc[3];
#pragma unroll
    for (int t = 0; t < 3; ++t) {
        int co = (wv * 3 + t) * 16 + (l & 15);
        float bv = (co < 189) ? bias[co] : 0.f;
        acc[t][0] = bv; acc[t][1] = bv; acc[t][2] = bv; acc[t][3] = bv;
    }
    int ubase = (y * 162 + x0 + (l & 15)) * 32 + ((l >> 4) << 3);
    const unsigned short* ob = ocl + (size_t)b * 839808;
    const unsigned short* wl = womf + (size_t)l * 8;
#pragma unroll
    for (int tap = 0; tap < 9; ++tap) {
        int off = ((tap / 3) * 162 + (tap % 3)) * 32;
        bf16x8 af = *reinterpret_cast<const bf16x8*>(ob + ubase + off);
#pragma unroll
        for (int t = 0; t < 3; ++t) {
            int nt = wv * 3 + t;
            bf16x8 bf = *reinterpret_cast<const bf16x8*>(wl + (size_t)(tap * 12 + nt) * 512);
            acc[t] = __builtin_amdgcn_mfma_f32_16x16x32_bf16(af, bf, acc[t], 0, 0, 0);
        }
    }
    int xo = x0 + ((l >> 4) << 2);
#pragma unroll
    for (int t = 0; t < 3; ++t) {
        int co = (wv * 3 + t) * 16 + (l & 15);
        if (co >= 189) continue;
        size_t obase = ((size_t)(b * 189 + co)) * 25600 + (size_t)y * 160 + xo;
#pragma unroll
        for (int r = 0; r < 4; ++r) out[obase + r] = acc[t][r];
    }
}

// ------------- two-phase modulated deformable conv ---------------------------
__global__ __launch_bounds__(TPB) void deform_conv2_k(
    const float* __restrict__ x, const float* __restrict__ om,
    const float* __restrict__ wt2, const float* __restrict__ bias,
    float* __restrict__ out, int B, int H, int W) {
    __shared__ float smp[63 * 64];
    const int HW = H * W;
    int blk = blockIdx.x;
    int b = blk / (HW / 64);
    int pxbase = (blk % (HW / 64)) * 64;
    int tid = threadIdx.x;
    const float* omb = om + (size_t)b * 189 * HW;
    const float* xb = x + (size_t)b * 7 * HW;

#pragma unroll 4
    for (int k = 0; k < 16; ++k) {
        int it = tid + k * 256;
        if (it >= 4032) break;
        int pxl = it & 63;
        int tap = it >> 6;
        int c = tap / 9, kk = tap % 9;
        int hw = pxbase + pxl;
        int hq = hw / W, wq = hw % W;
        float dy = omb[(size_t)(c * 18 + kk * 2 + 0) * HW + hw];
        float dx = omb[(size_t)(c * 18 + kk * 2 + 1) * HW + hw];
        float mv = omb[(size_t)(126 + c * 9 + kk) * HW + hw];
        float m = 1.f / (1.f + __expf(-mv));
        float py = (float)hq + (float)(kk / 3 - 1) + dy;
        float px = (float)wq + (float)(kk % 3 - 1) + dx;
        float y0f = floorf(py), x0f = floorf(px);
        int y0 = (int)y0f, x0 = (int)x0f;
        float wy1 = py - y0f, wx1 = px - x0f;
        float wy0 = 1.f - wy1, wx0 = 1.f - wx1;
        float v00 = 0.f, v01 = 0.f, v10 = 0.f, v11 = 0.f;
        const float* xc = xb + (size_t)c * HW;
        bool yin0 = (y0 >= 0) & (y0 < H);
        bool yin1 = (y0 + 1 >= 0) & (y0 + 1 < H);
        bool xin0 = (x0 >= 0) & (x0 < W);
        bool xin1 = (x0 + 1 >= 0) & (x0 + 1 < W);
        if (yin0) {
            const float* rr = xc + (size_t)y0 * W;
            if (xin0) v00 = rr[x0];
            if (xin1) v01 = rr[x0 + 1];
        }
        if (yin1) {
            const float* rr = xc + (size_t)(y0 + 1) * W;
            if (xin0) v10 = rr[x0];
            if (xin1) v11 = rr[x0 + 1];
        }
        smp[tap * 64 + pxl] =
            (wy0 * wx0 * v00 + wy0 * wx1 * v01 + wy1 * wx0 * v10 + wy1 * wx1 * v11) * m;
    }
    __syncthreads();

    int pxl = tid & 63;
    int g = tid >> 6;
    int gu = __builtin_amdgcn_readfirstlane(g);
    const float* swb = wt2 + gu * 16;
    const float* bsb = bias + gu * 16;
    float acc[16];
#pragma unroll
    for (int o = 0; o < 16; ++o) acc[o] = 0.f;
    for (int tap = 0; tap < 63; ++tap) {
        float s = smp[tap * 64 + pxl];
        const float* sw = swb + tap * 64;
#pragma unroll
        for (int o = 0; o < 16; ++o) acc[o] += s * sw[o];
    }
    int hw = pxbase + pxl;
    size_t obase = (size_t)b * 64 * HW + (size_t)gu * 16 * HW + hw;
#pragma unroll
    for (int o = 0; o < 16; ++o)
        out[obase + (size_t)o * HW] = fmaxf(acc[o] + bsb[o], 0.f);
}

extern "C" void kernel_launch(void* const* d_in, const int* in_sizes, int n_in,
                              void* d_out, int out_size, void* d_ws, size_t ws_size,
                              hipStream_t stream) {
    (void)in_sizes; (void)n_in; (void)out_size; (void)ws_size;
    const float* inputs = (const float*)d_in[0];
    const float* w_in   = (const float*)d_in[1];  const float* b_in   = (const float*)d_in[2];
    const float* w_dn1a = (const float*)d_in[3];  const float* b_dn1a = (const float*)d_in[4];
    const float* w_dn1b = (const float*)d_in[5];  const float* b_dn1b = (const float*)d_in[6];
    const float* w_up1a = (const float*)d_in[7];  const float* b_up1a = (const float*)d_in[8];
    const float* wt_up1 = (const float*)d_in[9];  const float* bt_up1 = (const float*)d_in[10];
    const float* w_dn2a = (const float*)d_in[11]; const float* b_dn2a = (const float*)d_in[12];
    const float* w_dn2b = (const float*)d_in[13]; const float* b_dn2b = (const float*)d_in[14];
    const float* w_up2a = (const float*)d_in[15]; const float* b_up2a = (const float*)d_in[16];
    const float* wt_up2 = (const float*)d_in[17]; const float* bt_up2 = (const float*)d_in[18];
    const float* w_tra  = (const float*)d_in[19]; const float* b_tra  = (const float*)d_in[20];
    const float* w_trb  = (const float*)d_in[21]; const float* b_trb  = (const float*)d_in[22];
    const float* wt_tr  = (const float*)d_in[23]; const float* bt_tr  = (const float*)d_in[24];
    const float* w_out  = (const float*)d_in[25]; const float* b_out  = (const float*)d_in[26];
    const float* w_tf3a = (const float*)d_in[27]; const float* b_tf3a = (const float*)d_in[28];
    const float* w_tf3b = (const float*)d_in[29]; const float* b_tf3b = (const float*)d_in[30];
    const float* w_tf2  = (const float*)d_in[31]; const float* b_tf2  = (const float*)d_in[32];
    const float* w_om   = (const float*)d_in[33]; const float* b_om   = (const float*)d_in[34];
    const float* w_dc   = (const float*)d_in[35]; const float* b_dc   = (const float*)d_in[36];
    float* out = (float*)d_out;

    const int B = 2, nf = 32, H = 160, W = 160;
    const size_t n160 = (size_t)B * nf * 160 * 160;
    const size_t n80  = (size_t)B * nf * 80 * 80;
    const size_t n40  = (size_t)B * nf * 40 * 40;
    const size_t n20  = (size_t)B * nf * 20 * 20;

    float* ws = (float*)d_ws;
    float* F0    = ws;
    float* TMP80 = F0 + n160;
    float* F1    = TMP80 + n80;
    float* TMP40 = F1 + n80;
    float* F2    = TMP40 + n40;
    float* T20A  = F2 + n40;
    float* T20B  = T20A + n20;
    float* T40   = T20B + n20;
    float* T40B  = T40 + n40;
    float* T80   = T40B + n40;
    float* T80B  = T80 + n80;
    float* T160  = T80B + n80;
    float* TF    = T160 + n160;
    float* XA    = TF + n160;                         // 11,757,312 f
    float* OM    = XA;                                // ALIAS (disjoint lifetimes)
    float* WT2   = XA + 11757312;                     // 4,032 f
    unsigned short* WBF   = (unsigned short*)(WT2 + 4032);           // 27,648
    unsigned short* XACL  = WBF + 27648;                             // 11,757,312
    unsigned short* WOMF  = XACL + 11757312;                         // 55,296
    unsigned short* OCL   = WOMF + 55296;                            // 1,679,616
    unsigned short* MCL   = OCL + 1679616;                           // 1,679,616
    unsigned short* TCL   = MCL + 1679616;                           // 1,679,616
    unsigned short* CATCL = TCL + 1679616;                           // 860,672
    unsigned short* WTF2F = CATCL + 860672;                          // 9,216
    unsigned short* WOUTF = WTF2F + 9216;                            // 9,216
    unsigned short* WUP1F = WOUTF + 9216;                            // 18,432

    const int bpc160 = 25;            // ceil(160*40/256)
    const int bpc80_128 = 13;         // ceil(80*20/128)
    const int bpc40_64  = 7;          // ceil(40*10/64)
    const int bpc20_64  = 2;          // ceil(20*5/64)

    // prep (merged) + conv_a (fp32) + transpose to bf16 channel-last
    prep_k<<<nblk(27648 + 4032 + 448 * 644 + 55296 + 9216 + 9216 + 18432), TPB, 0, stream>>>(
        w_tf3b, w_dc, w_om, w_tf2, w_out, w_up1a, WBF, WOMF, WTF2F, WOUTF, WUP1F, WT2, XA);
    conv3da_k<<<B * 32 * 7 * 25, TPB, 0, stream>>>(inputs, w_tf3a, b_tf3a, XA, B, H, W);
    xa2cl_k<<<nblk(2 * 7 * 26244), TPB, 0, stream>>>(XA, XACL);

    // --- 2D U-Net branch ---
    conv2d_c4_k<1, 0, 0><<<B * 8 * bpc160, TPB, 0, stream>>>(inputs, nullptr, w_in, b_in, nullptr, F0, B, 7, 160, 160, nf, 8, bpc160);
    conv2d_s2_t4_k<128><<<B * nf * bpc80_128, 128, 0, stream>>>(F0, w_dn1a, b_dn1a, TMP80, B, nf, 160, 160, nf, bpc80_128);
    conv2d_t4_k<128, 1, 0><<<B * nf * bpc80_128, 128, 0, stream>>>(TMP80, w_dn1b, b_dn1b, nullptr, F1, B, nf, 80, 80, nf, bpc80_128);
    conv2d_s2_t4_k<64><<<B * nf * bpc40_64, 64, 0, stream>>>(F1, w_dn2a, b_dn2a, TMP40, B, nf, 80, 80, nf, bpc40_64);
    conv2d_t4_k<64, 1, 0><<<B * nf * bpc40_64, 64, 0, stream>>>(TMP40, w_dn2b, b_dn2b, nullptr, F2, B, nf, 40, 40, nf, bpc40_64);
    conv2d_s2_t4_k<64><<<B * nf * bpc20_64, 64, 0, stream>>>(F2, w_tra, b_tra, T20A, B, nf, 40, 40, nf, bpc20_64);
    conv2d_t4_k<64, 1, 0><<<B * nf * bpc20_64, 64, 0, stream>>>(T20A, w_trb, b_trb, nullptr, T20B, B, nf, 20, 20, nf, bpc20_64);
    convt2d_t4_k<64><<<B * nf * bpc40_64, 64, 0, stream>>>(T20B, wt_tr, bt_tr, T40, B, nf, 20, 20, bpc40_64);
    conv2d_cat_t4_k<64><<<B * nf * bpc40_64, 64, 0, stream>>>(T40, F2, w_up2a, b_up2a, T40B, B, nf, nf, 40, 40, nf, bpc40_64);
    convt2d_t4_k<128><<<B * nf * bpc80_128, 128, 0, stream>>>(T40B, wt_up2, bt_up2, T80, B, nf, 40, 40, bpc80_128);
    // up1a concat conv via MFMA: cat transform then implicit GEMM
    cat2cl_k<<<nblk(2 * 6724), TPB, 0, stream>>>(T80, F1, CATCL);
    conv_up1a_mfma_k<<<B * 200, TPB, 0, stream>>>(CATCL, WUP1F, b_up1a, T80B, B);
    convt2d_c4_k<<<B * 8 * bpc160, TPB, 0, stream>>>(T80B, wt_up1, bt_up1, T160, B, nf, 80, 80, bpc160);

    // --- conv3d_b + relu + mean (bf16 MFMA) -> F0 ---
    conv3db_mfma_k<<<B * 800, TPB, 0, stream>>>(XACL, WBF, b_tf3b, F0, B, H, W);
    // FUSED = relu(conv_tf2(MEAN) + T160)  [MFMA]
    o2cl_k<<<nblk(2 * 26244), TPB, 0, stream>>>(F0, MCL);
    conv_nf_mfma_k<1, 1><<<B * 800, TPB, 0, stream>>>(MCL, WTF2F, b_tf2, T160, TF, B);

    // --- offset/mask head: w_out MFMA -> F0; o2cl; w_om MFMA ---
    o2cl_k<<<nblk(2 * 26244), TPB, 0, stream>>>(TF, TCL);
    conv_nf_mfma_k<0, 1><<<B * 800, TPB, 0, stream>>>(TCL, WOUTF, b_out, nullptr, F0, B);
    o2cl_k<<<nblk(2 * 26244), TPB, 0, stream>>>(F0, OCL);
    conv_om_mfma_k<<<B * 1600, TPB, 0, stream>>>(OCL, WOMF, b_om, OM, B);

    // --- deformable conv (two-phase) ---
    deform_conv2_k<<<B * (H * W / 64), TPB, 0, stream>>>(inputs, OM, WT2, b_dc, out, B, H, W);
}

// Round 20
// 514.535 us; speedup vs baseline: 1.9167x; 1.0517x over previous
//
#include <hip/hip_runtime.h>
#include <math.h>

// ---------------------------------------------------------------------------
// STDF forward, round 20: conv3d_a fused with relu+bf16+channel-last layout
// (writes XACL directly; fp32 XA buffer and xa2cl_k eliminated — 90MB round
// trip -> 22.5MB write). Everything else identical to round 19 (541us).
// ---------------------------------------------------------------------------

#define TPB 256

static inline int nblk(long long total) { return (int)((total + TPB - 1) / TPB); }

typedef short bf16x8 __attribute__((ext_vector_type(8)));
typedef float f32x4 __attribute__((ext_vector_type(4)));

__device__ __forceinline__ unsigned short f2bf(float f) {
    unsigned int u = __float_as_uint(f);
    unsigned int r = u + 0x7FFFu + ((u >> 16) & 1u);   // RNE
    return (unsigned short)(r >> 16);
}

// ---------------- 3x3 conv2d, stride 1, 4 outputs/thread, block-uniform co --
template <int TB, int RELU, int HAS_RES>
__global__ __launch_bounds__(TB) void conv2d_t4_k(
    const float* __restrict__ in, const float* __restrict__ w,
    const float* __restrict__ bias, const float* __restrict__ res,
    float* __restrict__ out, int B, int Ci, int H, int W, int Co, int BPC) {
    __shared__ float ws_w[32 * 9];
    int co = (blockIdx.x / BPC) % Co;
    int b  = blockIdx.x / (BPC * Co);
    for (int i = threadIdx.x; i < Ci * 9; i += TB)
        ws_w[i] = w[(size_t)co * Ci * 9 + i];
    __syncthreads();
    int nq = W >> 2;
    int r = (blockIdx.x % BPC) * TB + threadIdx.x;
    if (r >= H * nq) return;
    int q = r % nq, ho = r / nq;
    int wb = q * 4;
    float bv = bias[co];
    float a0 = bv, a1 = bv, a2 = bv, a3 = bv;
    const float* ipb = in + (size_t)b * Ci * H * W;
    for (int ci = 0; ci < Ci; ++ci) {
        const float* ip = ipb + (size_t)ci * H * W;
        const float* wc = ws_w + ci * 9;
#pragma unroll
        for (int kh = 0; kh < 3; ++kh) {
            int y = ho - 1 + kh;
            if (y < 0 || y >= H) continue;
            const float* row = ip + (size_t)y * W + wb;
            float4 xv = *(const float4*)row;
            float xm = (wb > 0) ? row[-1] : 0.f;
            float xp = (wb + 4 < W) ? row[4] : 0.f;
            float w0 = wc[kh * 3], w1 = wc[kh * 3 + 1], w2 = wc[kh * 3 + 2];
            a0 += xm   * w0 + xv.x * w1 + xv.y * w2;
            a1 += xv.x * w0 + xv.y * w1 + xv.z * w2;
            a2 += xv.y * w0 + xv.z * w1 + xv.w * w2;
            a3 += xv.z * w0 + xv.w * w1 + xp   * w2;
        }
    }
    size_t o = ((size_t)(b * Co + co) * H + ho) * W + wb;
    if (HAS_RES) {
        float4 rv = *(const float4*)(res + o);
        a0 += rv.x; a1 += rv.y; a2 += rv.z; a3 += rv.w;
    }
    if (RELU) { a0 = fmaxf(a0, 0.f); a1 = fmaxf(a1, 0.f); a2 = fmaxf(a2, 0.f); a3 = fmaxf(a3, 0.f); }
    *(float4*)(out + o) = make_float4(a0, a1, a2, a3);
}

// ------- 3x3 conv2d, stride 1, 4 outputs x 4 co per thread -----------------
template <int RELU, int HAS_RES, int HAS_IN2>
__global__ __launch_bounds__(TPB) void conv2d_c4_k(
    const float* __restrict__ in, const float* __restrict__ in2,
    const float* __restrict__ w, const float* __restrict__ bias,
    const float* __restrict__ res, float* __restrict__ out,
    int B, int Ci, int H, int W, int Co, int COG, int BPC) {
    __shared__ float ws_w[4 * 32 * 9];
    int cog = (blockIdx.x / BPC) % COG;
    int b   = blockIdx.x / (BPC * COG);
    int co0 = cog * 4;
    int nw = Ci * 9;
    for (int i = threadIdx.x; i < 4 * nw; i += TPB) {
        int cr = i / nw; int co = co0 + cr;
        ws_w[i] = (co < Co) ? w[(size_t)co * nw + (i - cr * nw)] : 0.f;
    }
    __syncthreads();
    int nq = W >> 2;
    int r = (blockIdx.x % BPC) * TPB + threadIdx.x;
    if (r >= H * nq) return;
    int q = r % nq, ho = r / nq;
    int wb = q * 4;
    float a[4][4];
#pragma unroll
    for (int cr = 0; cr < 4; ++cr) {
        float bv = (co0 + cr < Co) ? bias[co0 + cr] : 0.f;
        a[cr][0] = bv; a[cr][1] = bv; a[cr][2] = bv; a[cr][3] = bv;
    }
    const float* ipb = in + (size_t)b * Ci * H * W;
    const float* ipb2 = HAS_IN2 ? in2 + (size_t)b * Ci * H * W : nullptr;
    for (int ci = 0; ci < Ci; ++ci) {
        const float* ip = ipb + (size_t)ci * H * W;
        const float* ip2 = HAS_IN2 ? ipb2 + (size_t)ci * H * W : nullptr;
#pragma unroll
        for (int kh = 0; kh < 3; ++kh) {
            int y = ho - 1 + kh;
            if (y < 0 || y >= H) continue;
            const float* row = ip + (size_t)y * W + wb;
            float4 xv = *(const float4*)row;
            float x_[6];
            x_[0] = (wb > 0) ? row[-1] : 0.f;
            x_[5] = (wb + 4 < W) ? row[4] : 0.f;
            if (HAS_IN2) {
                const float* row2 = ip2 + (size_t)y * W + wb;
                float4 x2 = *(const float4*)row2;
                xv.x += x2.x; xv.y += x2.y; xv.z += x2.z; xv.w += x2.w;
                if (wb > 0) x_[0] += row2[-1];
                if (wb + 4 < W) x_[5] += row2[4];
            }
            x_[1] = xv.x; x_[2] = xv.y; x_[3] = xv.z; x_[4] = xv.w;
#pragma unroll
            for (int cr = 0; cr < 4; ++cr) {
                const float* wc = ws_w + cr * nw + ci * 9 + kh * 3;
                float w0 = wc[0], w1 = wc[1], w2 = wc[2];
                a[cr][0] += x_[0] * w0 + x_[1] * w1 + x_[2] * w2;
                a[cr][1] += x_[1] * w0 + x_[2] * w1 + x_[3] * w2;
                a[cr][2] += x_[2] * w0 + x_[3] * w1 + x_[4] * w2;
                a[cr][3] += x_[3] * w0 + x_[4] * w1 + x_[5] * w2;
            }
        }
    }
#pragma unroll
    for (int cr = 0; cr < 4; ++cr) {
        int co = co0 + cr;
        if (co >= Co) break;
        size_t o = ((size_t)(b * Co + co) * H + ho) * W + wb;
        float a0 = a[cr][0], a1 = a[cr][1], a2 = a[cr][2], a3 = a[cr][3];
        if (HAS_RES) {
            float4 rv = *(const float4*)(res + o);
            a0 += rv.x; a1 += rv.y; a2 += rv.z; a3 += rv.w;
        }
        if (RELU) { a0 = fmaxf(a0, 0.f); a1 = fmaxf(a1, 0.f); a2 = fmaxf(a2, 0.f); a3 = fmaxf(a3, 0.f); }
        *(float4*)(out + o) = make_float4(a0, a1, a2, a3);
    }
}

// ------------- 3x3 conv2d over concat of two 32-ch inputs, stride 1, relu ---
template <int TB>
__global__ __launch_bounds__(TB) void conv2d_cat_t4_k(
    const float* __restrict__ in1, const float* __restrict__ in2,
    const float* __restrict__ w, const float* __restrict__ bias,
    float* __restrict__ out, int B, int C1, int C2, int H, int W, int Co, int BPC) {
    __shared__ float ws_w[64 * 9];
    int Ci = C1 + C2;
    int co = (blockIdx.x / BPC) % Co;
    int b  = blockIdx.x / (BPC * Co);
    for (int i = threadIdx.x; i < Ci * 9; i += TB)
        ws_w[i] = w[(size_t)co * Ci * 9 + i];
    __syncthreads();
    int nq = W >> 2;
    int r = (blockIdx.x % BPC) * TB + threadIdx.x;
    if (r >= H * nq) return;
    int q = r % nq, ho = r / nq;
    int wb = q * 4;
    float bv = bias[co];
    float a0 = bv, a1 = bv, a2 = bv, a3 = bv;
    for (int ci = 0; ci < Ci; ++ci) {
        const float* ip = (ci < C1)
            ? in1 + ((size_t)(b * C1 + ci)) * H * W
            : in2 + ((size_t)(b * C2 + (ci - C1))) * H * W;
        const float* wc = ws_w + ci * 9;
#pragma unroll
        for (int kh = 0; kh < 3; ++kh) {
            int y = ho - 1 + kh;
            if (y < 0 || y >= H) continue;
            const float* row = ip + (size_t)y * W + wb;
            float4 xv = *(const float4*)row;
            float xm = (wb > 0) ? row[-1] : 0.f;
            float xp = (wb + 4 < W) ? row[4] : 0.f;
            float w0 = wc[kh * 3], w1 = wc[kh * 3 + 1], w2 = wc[kh * 3 + 2];
            a0 += xm   * w0 + xv.x * w1 + xv.y * w2;
            a1 += xv.x * w0 + xv.y * w1 + xv.z * w2;
            a2 += xv.y * w0 + xv.z * w1 + xv.w * w2;
            a3 += xv.z * w0 + xv.w * w1 + xp   * w2;
        }
    }
    size_t o = ((size_t)(b * Co + co) * H + ho) * W + wb;
    *(float4*)(out + o) = make_float4(fmaxf(a0, 0.f), fmaxf(a1, 0.f), fmaxf(a2, 0.f), fmaxf(a3, 0.f));
}

// ------------- 3x3 conv2d, stride 2, 4 outputs/thread, relu ----------------
template <int TB>
__global__ __launch_bounds__(TB) void conv2d_s2_t4_k(
    const float* __restrict__ in, const float* __restrict__ w,
    const float* __restrict__ bias, float* __restrict__ out,
    int B, int Ci, int Hi, int Wi, int Co, int BPC) {
    __shared__ float ws_w[32 * 9];
    int Ho = Hi >> 1, Wo = Wi >> 1;
    int co = (blockIdx.x / BPC) % Co;
    int b  = blockIdx.x / (BPC * Co);
    for (int i = threadIdx.x; i < Ci * 9; i += TB)
        ws_w[i] = w[(size_t)co * Ci * 9 + i];
    __syncthreads();
    int nq = Wo >> 2;
    int r = (blockIdx.x % BPC) * TB + threadIdx.x;
    if (r >= Ho * nq) return;
    int q = r % nq, ho = r / nq;
    int wb = q * 4;
    float bv = bias[co];
    float a0 = bv, a1 = bv, a2 = bv, a3 = bv;
    const float* ipb = in + (size_t)b * Ci * Hi * Wi;
    for (int ci = 0; ci < Ci; ++ci) {
        const float* ip = ipb + (size_t)ci * Hi * Wi;
        const float* wc = ws_w + ci * 9;
#pragma unroll
        for (int kh = 0; kh < 3; ++kh) {
            int y = 2 * ho - 1 + kh;
            if (y < 0 || y >= Hi) continue;
            const float* row = ip + (size_t)y * Wi;
            float z0 = (2 * wb - 1 >= 0) ? row[2 * wb - 1] : 0.f;
            float4 za = *(const float4*)(row + 2 * wb);
            float4 zb = *(const float4*)(row + 2 * wb + 4);
            float w0 = wc[kh * 3], w1 = wc[kh * 3 + 1], w2 = wc[kh * 3 + 2];
            a0 += z0   * w0 + za.x * w1 + za.y * w2;
            a1 += za.y * w0 + za.z * w1 + za.w * w2;
            a2 += za.w * w0 + zb.x * w1 + zb.y * w2;
            a3 += zb.y * w0 + zb.z * w1 + zb.w * w2;
        }
    }
    size_t o = ((size_t)(b * Co + co) * Ho + ho) * Wo + wb;
    *(float4*)(out + o) = make_float4(fmaxf(a0, 0.f), fmaxf(a1, 0.f), fmaxf(a2, 0.f), fmaxf(a3, 0.f));
}

// ------------- transposed conv 4x4 stride 2, 4 outputs/thread, relu --------
template <int TB>
__global__ __launch_bounds__(TB) void convt2d_t4_k(
    const float* __restrict__ in, const float* __restrict__ wt,
    const float* __restrict__ bias, float* __restrict__ out,
    int B, int C, int Hi, int Wi, int BPC) {
    __shared__ float ws_w[32 * 16];
    int Ho = 2 * Hi, Wo = 2 * Wi;
    int co = (blockIdx.x / BPC) % C;
    int b  = blockIdx.x / (BPC * C);
    for (int i = threadIdx.x; i < C * 16; i += TB) {
        int ci = i >> 4, t = i & 15;
        ws_w[i] = wt[((size_t)ci * C + co) * 16 + t];
    }
    __syncthreads();
    int nq = Wo >> 2;
    int r = (blockIdx.x % BPC) * TB + threadIdx.x;
    if (r >= Ho * nq) return;
    int q = r % nq, ho = r / nq;
    int wb = q * 4;
    int p = ho & 1;
    int iy0 = (ho + p) / 2 - 1;
    int iy1 = iy0 + 1;
    int ix0 = wb / 2 - 1;
    bool vy0 = (iy0 >= 0) && (iy0 < Hi);
    bool vy1 = (iy1 >= 0) && (iy1 < Hi);
    float bv = bias[co];
    float a0 = bv, a1 = bv, a2 = bv, a3 = bv;
    const float* ipb = in + (size_t)b * C * Hi * Wi;
    for (int ci = 0; ci < C; ++ci) {
        const float* ip = ipb + (size_t)ci * Hi * Wi;
        float u0 = 0, u1 = 0, u2 = 0, u3 = 0, v0 = 0, v1 = 0, v2 = 0, v3 = 0;
        if (vy0) {
            const float* rw = ip + (size_t)iy0 * Wi;
            if (ix0 >= 0) u0 = rw[ix0];
            u1 = rw[ix0 + 1]; u2 = rw[ix0 + 2];
            if (ix0 + 3 < Wi) u3 = rw[ix0 + 3];
        }
        if (vy1) {
            const float* rw = ip + (size_t)iy1 * Wi;
            if (ix0 >= 0) v0 = rw[ix0];
            v1 = rw[ix0 + 1]; v2 = rw[ix0 + 2];
            if (ix0 + 3 < Wi) v3 = rw[ix0 + 3];
        }
        const float* wr0 = ws_w + ci * 16 + (3 - p) * 4;
        const float* wr1 = ws_w + ci * 16 + (1 - p) * 4;
        a0 += u0 * wr0[3] + u1 * wr0[1] + v0 * wr1[3] + v1 * wr1[1];
        a1 += u1 * wr0[2] + u2 * wr0[0] + v1 * wr1[2] + v2 * wr1[0];
        a2 += u1 * wr0[3] + u2 * wr0[1] + v1 * wr1[3] + v2 * wr1[1];
        a3 += u2 * wr0[2] + u3 * wr0[0] + v2 * wr1[2] + v3 * wr1[0];
    }
    size_t o = ((size_t)(b * C + co) * Ho + ho) * Wo + wb;
    *(float4*)(out + o) = make_float4(fmaxf(a0, 0.f), fmaxf(a1, 0.f), fmaxf(a2, 0.f), fmaxf(a3, 0.f));
}

// ------------- transposed conv 4x4 stride 2, 4 outputs x 4 co/thread -------
__global__ __launch_bounds__(TPB) void convt2d_c4_k(
    const float* __restrict__ in, const float* __restrict__ wt,
    const float* __restrict__ bias, float* __restrict__ out,
    int B, int C, int Hi, int Wi, int BPC) {
    __shared__ float ws_w[4][32 * 16];
    int Ho = 2 * Hi, Wo = 2 * Wi;
    int cog = (blockIdx.x / BPC) % (C / 4);
    int b   = blockIdx.x / (BPC * (C / 4));
    int co0 = cog * 4;
    for (int i = threadIdx.x; i < 4 * C * 16; i += TPB) {
        int cr = i / (C * 16); int j = i % (C * 16);
        int ci = j >> 4, t = j & 15;
        ws_w[cr][j] = wt[((size_t)ci * C + (co0 + cr)) * 16 + t];
    }
    __syncthreads();
    int nq = Wo >> 2;
    int r = (blockIdx.x % BPC) * TPB + threadIdx.x;
    if (r >= Ho * nq) return;
    int q = r % nq, ho = r / nq;
    int wb = q * 4;
    int p = ho & 1;
    int iy0 = (ho + p) / 2 - 1;
    int iy1 = iy0 + 1;
    int ix0 = wb / 2 - 1;
    bool vy0 = (iy0 >= 0) && (iy0 < Hi);
    bool vy1 = (iy1 >= 0) && (iy1 < Hi);
    float a[4][4];
#pragma unroll
    for (int cr = 0; cr < 4; ++cr) {
        float bv = bias[co0 + cr];
        a[cr][0] = bv; a[cr][1] = bv; a[cr][2] = bv; a[cr][3] = bv;
    }
    const float* ipb = in + (size_t)b * C * Hi * Wi;
    for (int ci = 0; ci < C; ++ci) {
        const float* ip = ipb + (size_t)ci * Hi * Wi;
        float u0 = 0, u1 = 0, u2 = 0, u3 = 0, v0 = 0, v1 = 0, v2 = 0, v3 = 0;
        if (vy0) {
            const float* rw = ip + (size_t)iy0 * Wi;
            if (ix0 >= 0) u0 = rw[ix0];
            u1 = rw[ix0 + 1]; u2 = rw[ix0 + 2];
            if (ix0 + 3 < Wi) u3 = rw[ix0 + 3];
        }
        if (vy1) {
            const float* rw = ip + (size_t)iy1 * Wi;
            if (ix0 >= 0) v0 = rw[ix0];
            v1 = rw[ix0 + 1]; v2 = rw[ix0 + 2];
            if (ix0 + 3 < Wi) v3 = rw[ix0 + 3];
        }
#pragma unroll
        for (int cr = 0; cr < 4; ++cr) {
            const float* wr0 = ws_w[cr] + ci * 16 + (3 - p) * 4;
            const float* wr1 = ws_w[cr] + ci * 16 + (1 - p) * 4;
            a[cr][0] += u0 * wr0[3] + u1 * wr0[1] + v0 * wr1[3] + v1 * wr1[1];
            a[cr][1] += u1 * wr0[2] + u2 * wr0[0] + v1 * wr1[2] + v2 * wr1[0];
            a[cr][2] += u1 * wr0[3] + u2 * wr0[1] + v1 * wr1[3] + v2 * wr1[1];
            a[cr][3] += u2 * wr0[2] + u3 * wr0[0] + v2 * wr1[2] + v3 * wr1[0];
        }
    }
#pragma unroll
    for (int cr = 0; cr < 4; ++cr) {
        size_t o = ((size_t)(b * C + co0 + cr) * Ho + ho) * Wo + wb;
        *(float4*)(out + o) = make_float4(fmaxf(a[cr][0], 0.f), fmaxf(a[cr][1], 0.f),
                                          fmaxf(a[cr][2], 0.f), fmaxf(a[cr][3], 0.f));
    }
}

// ---- merged prep: all B-fragment packs + wdc transpose + XACL border zero --
__global__ void prep_k(const float* __restrict__ wb, const float* __restrict__ wdc,
                       const float* __restrict__ wom, const float* __restrict__ wtf2,
                       const float* __restrict__ wout, const float* __restrict__ wup1a,
                       unsigned short* __restrict__ wbf, unsigned short* __restrict__ womf,
                       unsigned short* __restrict__ wtf2f, unsigned short* __restrict__ woutf,
                       unsigned short* __restrict__ wup1f,
                       float* __restrict__ wt2, unsigned short* __restrict__ xacl) {
    int i = blockIdx.x * TPB + threadIdx.x;
    if (i < 27648) {                          // conv3db B-frags
        int j = i & 7;
        int l = (i >> 3) & 63;
        int coH = (i >> 9) & 1;
        int tap = i >> 10;
        int ci = ((l >> 4) << 3) + j;
        int co = (coH << 4) + (l & 15);
        wbf[i] = f2bf(wb[(size_t)(co * 32 + ci) * 27 + tap]);
        return;
    }
    int i2 = i - 27648;
    if (i2 < 4032) {                          // deform weight transpose
        int o = i2 & 63, ck = i2 >> 6;
        wt2[i2] = wdc[o * 63 + ck];
        return;
    }
    int i3 = i2 - 4032;
    if (i3 < 14 * 644) {                      // XACL border zero (14 bd-planes)
        int pl = i3 / 644, e = i3 % 644;
        int off;
        if (e < 162)      off = e;
        else if (e < 324) off = 161 * 162 + (e - 162);
        else if (e < 484) off = (e - 324 + 1) * 162;
        else              off = (e - 484 + 1) * 162 + 161;
        uint4* d = (uint4*)(xacl + ((size_t)pl * 26244 + off) * 32);
        uint4 z = make_uint4(0, 0, 0, 0);
        d[0] = z; d[1] = z; d[2] = z; d[3] = z;
        return;
    }
    int i4 = i3 - 14 * 644;
    if (i4 < 55296) {                         // w_om B-frags [tap][nt12][l][8]
        int j = i4 & 7;
        int l = (i4 >> 3) & 63;
        int nt = (i4 >> 9) % 12;
        int tap = i4 / 6144;
        int ci = ((l >> 4) << 3) + j;
        int co = nt * 16 + (l & 15);
        womf[i4] = (co < 189) ? f2bf(wom[((size_t)co * 32 + ci) * 9 + tap]) : (unsigned short)0;
        return;
    }
    int i5 = i4 - 55296;
    if (i5 < 9216) {                          // tf2 B-frags [tap][coH][l][8]
        int j = i5 & 7;
        int l = (i5 >> 3) & 63;
        int q = i5 >> 9;
        int coH = q & 1, tap = q >> 1;
        int ci = ((l >> 4) << 3) + j;
        int co = coH * 16 + (l & 15);
        wtf2f[i5] = f2bf(wtf2[((size_t)co * 32 + ci) * 9 + tap]);
        return;
    }
    int i6 = i5 - 9216;
    if (i6 < 9216) {                          // w_out B-frags
        int j = i6 & 7;
        int l = (i6 >> 3) & 63;
        int q = i6 >> 9;
        int coH = q & 1, tap = q >> 1;
        int ci = ((l >> 4) << 3) + j;
        int co = coH * 16 + (l & 15);
        woutf[i6] = f2bf(wout[((size_t)co * 32 + ci) * 9 + tap]);
        return;
    }
    int i7 = i6 - 9216;
    if (i7 >= 18432) return;                  // up1a B-frags [tap][kc][coH][l][8]
    int j = i7 & 7;
    int l = (i7 >> 3) & 63;
    int q = i7 >> 9;
    int coH = q & 1, kc = (q >> 1) & 1, tap = q >> 2;
    int ci = kc * 32 + ((l >> 4) << 3) + j;
    int co = coH * 16 + (l & 15);
    wup1f[i7] = f2bf(wup1a[((size_t)co * 64 + ci) * 9 + tap]);
}

// ---- conv3d_a fused: x (B,7,H,W) -> relu -> bf16 -> XACL channel-last ------
// grid = B*7*160*20; block 256 = 8 x-positions x 32 co (co fastest).
__global__ __launch_bounds__(TPB) void conv3da_cl_k(
    const float* __restrict__ x, const float* __restrict__ wa,
    const float* __restrict__ ba, unsigned short* __restrict__ xacl,
    int B, int H, int W) {
    __shared__ float xin[90];       // [dz3][yy3][xx10]
    __shared__ float wsa[864];      // all 32 co x 27
    int blk = blockIdx.x;
    int xc = blk % 20;
    int y  = (blk / 20) % 160;
    int d  = (blk / 3200) % 7;
    int b  = blk / 22400;
    int tid = threadIdx.x;
    // stage input window + weights
    for (int i = tid; i < 90; i += TPB) {
        int xx = i % 10; int t = i / 10; int yy = t % 3; int dz = t / 3;
        int gd = d - 1 + dz, gy = y - 1 + yy, gx = xc * 8 - 1 + xx;
        float v = 0.f;
        if (gd >= 0 && gd < 7 && gy >= 0 && gy < H && gx >= 0 && gx < W)
            v = x[((size_t)(b * 7 + gd)) * H * W + (size_t)gy * W + gx];
        xin[i] = v;
    }
    for (int i = tid; i < 864; i += TPB) wsa[i] = wa[i];
    __syncthreads();
    int co = tid & 31;
    int xi = tid >> 5;
    float acc = ba[co];
    const float* wc = wsa + co * 27;
#pragma unroll
    for (int dz = 0; dz < 3; ++dz)
#pragma unroll
        for (int yy = 0; yy < 3; ++yy)
#pragma unroll
            for (int kw = 0; kw < 3; ++kw)
                acc += xin[dz * 30 + yy * 10 + xi + kw] * wc[dz * 9 + yy * 3 + kw];
    int gx = xc * 8 + xi;
    size_t o = (((size_t)(b * 7 + d) * 162 + (y + 1)) * 162 + (gx + 1)) * 32 + co;
    xacl[o] = f2bf(fmaxf(acc, 0.f));
}

// ---- 32ch fp32 ch-first 160x160 -> bf16 CL 162x162 padded ------------------
__global__ __launch_bounds__(TPB) void o2cl_k(
    const float* __restrict__ o, unsigned short* __restrict__ ocl) {
    int idx = blockIdx.x * TPB + threadIdx.x;
    if (idx >= 2 * 26244) return;
    int pos = idx % 26244;
    int b = idx / 26244;
    int y = pos / 162, x = pos % 162;
    uint4* dst = (uint4*)(ocl + (size_t)idx * 32);
    if (y == 0 || y == 161 || x == 0 || x == 161) {
        uint4 z = make_uint4(0, 0, 0, 0);
        dst[0] = z; dst[1] = z; dst[2] = z; dst[3] = z;
        return;
    }
    unsigned int pk[16];
    const float* src = o + (size_t)b * 32 * 25600 + (size_t)(y - 1) * 160 + (x - 1);
#pragma unroll
    for (int j = 0; j < 16; ++j) {
        float v0 = src[(size_t)(2 * j) * 25600];
        float v1 = src[(size_t)(2 * j + 1) * 25600];
        pk[j] = (unsigned int)f2bf(v0) | ((unsigned int)f2bf(v1) << 16);
    }
    dst[0] = make_uint4(pk[0], pk[1], pk[2], pk[3]);
    dst[1] = make_uint4(pk[4], pk[5], pk[6], pk[7]);
    dst[2] = make_uint4(pk[8], pk[9], pk[10], pk[11]);
    dst[3] = make_uint4(pk[12], pk[13], pk[14], pk[15]);
}

// ---- concat(T80, F1) fp32 ch-first 80x80 -> bf16 CL [82][82][64] padded ----
__global__ __launch_bounds__(TPB) void cat2cl_k(
    const float* __restrict__ a, const float* __restrict__ c2,
    unsigned short* __restrict__ dst) {
    int idx = blockIdx.x * TPB + threadIdx.x;
    if (idx >= 2 * 6724) return;
    int pos = idx % 6724;
    int b = idx / 6724;
    int y = pos / 82, x = pos % 82;
    uint4* d = (uint4*)(dst + (size_t)idx * 64);
    if (y == 0 || y == 81 || x == 0 || x == 81) {
        uint4 z = make_uint4(0, 0, 0, 0);
#pragma unroll
        for (int k = 0; k < 8; ++k) d[k] = z;
        return;
    }
    size_t off = (size_t)(y - 1) * 80 + (x - 1);
    const float* sa = a + (size_t)b * 32 * 6400 + off;
    const float* sc = c2 + (size_t)b * 32 * 6400 + off;
    unsigned int pk[32];
#pragma unroll
    for (int j = 0; j < 16; ++j) {
        float v0 = sa[(size_t)(2 * j) * 6400];
        float v1 = sa[(size_t)(2 * j + 1) * 6400];
        pk[j] = (unsigned int)f2bf(v0) | ((unsigned int)f2bf(v1) << 16);
    }
#pragma unroll
    for (int j = 0; j < 16; ++j) {
        float v0 = sc[(size_t)(2 * j) * 6400];
        float v1 = sc[(size_t)(2 * j + 1) * 6400];
        pk[16 + j] = (unsigned int)f2bf(v0) | ((unsigned int)f2bf(v1) << 16);
    }
#pragma unroll
    for (int k = 0; k < 8; ++k)
        d[k] = make_uint4(pk[4 * k], pk[4 * k + 1], pk[4 * k + 2], pk[4 * k + 3]);
}

// ---- conv3d_b + relu + mean as bf16 MFMA implicit GEMM (verified r17) ------
__global__ __launch_bounds__(TPB) void conv3db_mfma_k(
    const unsigned short* __restrict__ xacl, const unsigned short* __restrict__ wbf,
    const float* __restrict__ bb, float* __restrict__ out, int B, int H, int W) {
    int blk = blockIdx.x;
    int b = blk / 800;
    int rem = blk % 800;
    int y = rem / 5;
    int xp = rem % 5;
    int tid = threadIdx.x;
    int l = tid & 63;
    int wv = tid >> 6;
    int mt = wv & 1, coH = wv >> 1;
    int x0 = xp * 32 + mt * 16;
    int co = coH * 16 + (l & 15);
    float bv = bb[co];
    f32x4 acc[7];
#pragma unroll
    for (int d = 0; d < 7; ++d) { acc[d][0] = bv; acc[d][1] = bv; acc[d][2] = bv; acc[d][3] = bv; }

    int ubase = (y * 162 + x0 + (l & 15)) * 32 + ((l >> 4) << 3);
    const unsigned short* xb = xacl + (size_t)b * 5878656;
    const unsigned short* wbase = wbf + ((size_t)coH * 64 + l) * 8;

#pragma unroll
    for (int kd = 0; kd < 3; ++kd) {
        for (int j2 = 0; j2 < 9; ++j2) {
            int off2 = (j2 / 3) * 5184 + (j2 % 3) * 32;
            bf16x8 bf = *reinterpret_cast<const bf16x8*>(wbase + (size_t)(kd * 9 + j2) * 1024);
#pragma unroll
            for (int d = 0; d < 7; ++d) {
                int dz = d + kd - 1;
                if (dz < 0 || dz >= 7) continue;
                bf16x8 af = *reinterpret_cast<const bf16x8*>(xb + (size_t)dz * 839808 + ubase + off2);
                acc[d] = __builtin_amdgcn_mfma_f32_16x16x32_bf16(af, bf, acc[d], 0, 0, 0);
            }
        }
    }

    int xo = x0 + ((l >> 4) << 2);
    size_t obase = ((size_t)(b * 32 + co)) * 25600 + (size_t)y * 160 + xo;
#pragma unroll
    for (int r = 0; r < 4; ++r) {
        float s = 0.f;
#pragma unroll
        for (int d = 0; d < 7; ++d) s += fmaxf(acc[d][r], 0.f);
        out[obase + r] = s * (1.f / 7.f);
    }
}

// ---- N=32 K=288 160-level conv as bf16 MFMA (tf2 / w_out) ------------------
template <int HAS_RES, int RELU>
__global__ __launch_bounds__(TPB) void conv_nf_mfma_k(
    const unsigned short* __restrict__ icl, const unsigned short* __restrict__ wf,
    const float* __restrict__ bias, const float* __restrict__ res,
    float* __restrict__ out, int B) {
    int blk = blockIdx.x;
    int b = blk / 800;
    int rem = blk % 800;
    int y = rem / 5;
    int xp = rem % 5;
    int tid = threadIdx.x;
    int l = tid & 63;
    int wv = tid >> 6;
    int mt = wv & 1, coH = wv >> 1;
    int x0 = xp * 32 + mt * 16;
    int co = coH * 16 + (l & 15);
    float bv = bias[co];
    f32x4 acc;
    acc[0] = bv; acc[1] = bv; acc[2] = bv; acc[3] = bv;
    int ubase = (y * 162 + x0 + (l & 15)) * 32 + ((l >> 4) << 3);
    const unsigned short* ib = icl + (size_t)b * 839808;
    const unsigned short* wl = wf + (size_t)l * 8;
#pragma unroll
    for (int tap = 0; tap < 9; ++tap) {
        int off = ((tap / 3) * 162 + (tap % 3)) * 32;
        bf16x8 af = *reinterpret_cast<const bf16x8*>(ib + ubase + off);
        bf16x8 bf = *reinterpret_cast<const bf16x8*>(wl + (size_t)(tap * 2 + coH) * 512);
        acc = __builtin_amdgcn_mfma_f32_16x16x32_bf16(af, bf, acc, 0, 0, 0);
    }
    int xo = x0 + ((l >> 4) << 2);
    size_t obase = ((size_t)(b * 32 + co)) * 25600 + (size_t)y * 160 + xo;
#pragma unroll
    for (int r = 0; r < 4; ++r) {
        float v = acc[r];
        if (HAS_RES) v += res[obase + r];
        if (RELU) v = fmaxf(v, 0.f);
        out[obase + r] = v;
    }
}

// ---- up1a concat conv as bf16 MFMA: M=80x80, N=32, K=576 -------------------
__global__ __launch_bounds__(TPB) void conv_up1a_mfma_k(
    const unsigned short* __restrict__ catcl, const unsigned short* __restrict__ wf,
    const float* __restrict__ bias, float* __restrict__ out, int B) {
    int blk = blockIdx.x;
    int b = blk / 200;
    int rem = blk % 200;
    int tid = threadIdx.x;
    int l = tid & 63;
    int wv = tid >> 6;
    int mtile = rem * 2 + (wv & 1);
    int coH = wv >> 1;
    int y = mtile / 5, x0 = (mtile % 5) * 16;
    int co = coH * 16 + (l & 15);
    float bv = bias[co];
    f32x4 acc;
    acc[0] = bv; acc[1] = bv; acc[2] = bv; acc[3] = bv;
    int ubase = (y * 82 + x0 + (l & 15)) * 64 + ((l >> 4) << 3);
    const unsigned short* cb = catcl + (size_t)b * 430336;
    const unsigned short* wl = wf + (size_t)l * 8;
#pragma unroll
    for (int tap = 0; tap < 9; ++tap) {
        int off = ((tap / 3) * 82 + (tap % 3)) * 64;
#pragma unroll
        for (int kc = 0; kc < 2; ++kc) {
            bf16x8 af = *reinterpret_cast<const bf16x8*>(cb + ubase + off + kc * 32);
            bf16x8 bf = *reinterpret_cast<const bf16x8*>(wl + (size_t)(((tap * 2 + kc) * 2 + coH)) * 512);
            acc = __builtin_amdgcn_mfma_f32_16x16x32_bf16(af, bf, acc, 0, 0, 0);
        }
    }
    int xo = x0 + ((l >> 4) << 2);
    size_t obase = ((size_t)(b * 32 + co)) * 6400 + (size_t)y * 80 + xo;
#pragma unroll
    for (int r = 0; r < 4; ++r)
        out[obase + r] = fmaxf(acc[r], 0.f);
}

// ---- w_om head as bf16 MFMA implicit GEMM (verified r18) -------------------
__global__ __launch_bounds__(TPB) void conv_om_mfma_k(
    const unsigned short* __restrict__ ocl, const unsigned short* __restrict__ womf,
    const float* __restrict__ bias, float* __restrict__ out, int B) {
    int blk = blockIdx.x;
    int b = blk / 1600;
    int rem = blk % 1600;
    int y = rem / 10;
    int xs = rem % 10;
    int tid = threadIdx.x;
    int l = tid & 63;
    int wv = tid >> 6;
    int x0 = xs * 16;
    f32x4 acc[3];
#pragma unroll
    for (int t = 0; t < 3; ++t) {
        int co = (wv * 3 + t) * 16 + (l & 15);
        float bv = (co < 189) ? bias[co] : 0.f;
        acc[t][0] = bv; acc[t][1] = bv; acc[t][2] = bv; acc[t][3] = bv;
    }
    int ubase = (y * 162 + x0 + (l & 15)) * 32 + ((l >> 4) << 3);
    const unsigned short* ob = ocl + (size_t)b * 839808;
    const unsigned short* wl = womf + (size_t)l * 8;
#pragma unroll
    for (int tap = 0; tap < 9; ++tap) {
        int off = ((tap / 3) * 162 + (tap % 3)) * 32;
        bf16x8 af = *reinterpret_cast<const bf16x8*>(ob + ubase + off);
#pragma unroll
        for (int t = 0; t < 3; ++t) {
            int nt = wv * 3 + t;
            bf16x8 bf = *reinterpret_cast<const bf16x8*>(wl + (size_t)(tap * 12 + nt) * 512);
            acc[t] = __builtin_amdgcn_mfma_f32_16x16x32_bf16(af, bf, acc[t], 0, 0, 0);
        }
    }
    int xo = x0 + ((l >> 4) << 2);
#pragma unroll
    for (int t = 0; t < 3; ++t) {
        int co = (wv * 3 + t) * 16 + (l & 15);
        if (co >= 189) continue;
        size_t obase = ((size_t)(b * 189 + co)) * 25600 + (size_t)y * 160 + xo;
#pragma unroll
        for (int r = 0; r < 4; ++r) out[obase + r] = acc[t][r];
    }
}

// ------------- two-phase modulated deformable conv ---------------------------
__global__ __launch_bounds__(TPB) void deform_conv2_k(
    const float* __restrict__ x, const float* __restrict__ om,
    const float* __restrict__ wt2, const float* __restrict__ bias,
    float* __restrict__ out, int B, int H, int W) {
    __shared__ float smp[63 * 64];
    const int HW = H * W;
    int blk = blockIdx.x;
    int b = blk / (HW / 64);
    int pxbase = (blk % (HW / 64)) * 64;
    int tid = threadIdx.x;
    const float* omb = om + (size_t)b * 189 * HW;
    const float* xb = x + (size_t)b * 7 * HW;

#pragma unroll 4
    for (int k = 0; k < 16; ++k) {
        int it = tid + k * 256;
        if (it >= 4032) break;
        int pxl = it & 63;
        int tap = it >> 6;
        int c = tap / 9, kk = tap % 9;
        int hw = pxbase + pxl;
        int hq = hw / W, wq = hw % W;
        float dy = omb[(size_t)(c * 18 + kk * 2 + 0) * HW + hw];
        float dx = omb[(size_t)(c * 18 + kk * 2 + 1) * HW + hw];
        float mv = omb[(size_t)(126 + c * 9 + kk) * HW + hw];
        float m = 1.f / (1.f + __expf(-mv));
        float py = (float)hq + (float)(kk / 3 - 1) + dy;
        float px = (float)wq + (float)(kk % 3 - 1) + dx;
        float y0f = floorf(py), x0f = floorf(px);
        int y0 = (int)y0f, x0 = (int)x0f;
        float wy1 = py - y0f, wx1 = px - x0f;
        float wy0 = 1.f - wy1, wx0 = 1.f - wx1;
        float v00 = 0.f, v01 = 0.f, v10 = 0.f, v11 = 0.f;
        const float* xc = xb + (size_t)c * HW;
        bool yin0 = (y0 >= 0) & (y0 < H);
        bool yin1 = (y0 + 1 >= 0) & (y0 + 1 < H);
        bool xin0 = (x0 >= 0) & (x0 < W);
        bool xin1 = (x0 + 1 >= 0) & (x0 + 1 < W);
        if (yin0) {
            const float* rr = xc + (size_t)y0 * W;
            if (xin0) v00 = rr[x0];
            if (xin1) v01 = rr[x0 + 1];
        }
        if (yin1) {
            const float* rr = xc + (size_t)(y0 + 1) * W;
            if (xin0) v10 = rr[x0];
            if (xin1) v11 = rr[x0 + 1];
        }
        smp[tap * 64 + pxl] =
            (wy0 * wx0 * v00 + wy0 * wx1 * v01 + wy1 * wx0 * v10 + wy1 * wx1 * v11) * m;
    }
    __syncthreads();

    int pxl = tid & 63;
    int g = tid >> 6;
    int gu = __builtin_amdgcn_readfirstlane(g);
    const float* swb = wt2 + gu * 16;
    const float* bsb = bias + gu * 16;
    float acc[16];
#pragma unroll
    for (int o = 0; o < 16; ++o) acc[o] = 0.f;
    for (int tap = 0; tap < 63; ++tap) {
        float s = smp[tap * 64 + pxl];
        const float* sw = swb + tap * 64;
#pragma unroll
        for (int o = 0; o < 16; ++o) acc[o] += s * sw[o];
    }
    int hw = pxbase + pxl;
    size_t obase = (size_t)b * 64 * HW + (size_t)gu * 16 * HW + hw;
#pragma unroll
    for (int o = 0; o < 16; ++o)
        out[obase + (size_t)o * HW] = fmaxf(acc[o] + bsb[o], 0.f);
}

extern "C" void kernel_launch(void* const* d_in, const int* in_sizes, int n_in,
                              void* d_out, int out_size, void* d_ws, size_t ws_size,
                              hipStream_t stream) {
    (void)in_sizes; (void)n_in; (void)out_size; (void)ws_size;
    const float* inputs = (const float*)d_in[0];
    const float* w_in   = (const float*)d_in[1];  const float* b_in   = (const float*)d_in[2];
    const float* w_dn1a = (const float*)d_in[3];  const float* b_dn1a = (const float*)d_in[4];
    const float* w_dn1b = (const float*)d_in[5];  const float* b_dn1b = (const float*)d_in[6];
    const float* w_up1a = (const float*)d_in[7];  const float* b_up1a = (const float*)d_in[8];
    const float* wt_up1 = (const float*)d_in[9];  const float* bt_up1 = (const float*)d_in[10];
    const float* w_dn2a = (const float*)d_in[11]; const float* b_dn2a = (const float*)d_in[12];
    const float* w_dn2b = (const float*)d_in[13]; const float* b_dn2b = (const float*)d_in[14];
    const float* w_up2a = (const float*)d_in[15]; const float* b_up2a = (const float*)d_in[16];
    const float* wt_up2 = (const float*)d_in[17]; const float* bt_up2 = (const float*)d_in[18];
    const float* w_tra  = (const float*)d_in[19]; const float* b_tra  = (const float*)d_in[20];
    const float* w_trb  = (const float*)d_in[21]; const float* b_trb  = (const float*)d_in[22];
    const float* wt_tr  = (const float*)d_in[23]; const float* bt_tr  = (const float*)d_in[24];
    const float* w_out  = (const float*)d_in[25]; const float* b_out  = (const float*)d_in[26];
    const float* w_tf3a = (const float*)d_in[27]; const float* b_tf3a = (const float*)d_in[28];
    const float* w_tf3b = (const float*)d_in[29]; const float* b_tf3b = (const float*)d_in[30];
    const float* w_tf2  = (const float*)d_in[31]; const float* b_tf2  = (const float*)d_in[32];
    const float* w_om   = (const float*)d_in[33]; const float* b_om   = (const float*)d_in[34];
    const float* w_dc   = (const float*)d_in[35]; const float* b_dc   = (const float*)d_in[36];
    float* out = (float*)d_out;

    const int B = 2, nf = 32, H = 160, W = 160;
    const size_t n160 = (size_t)B * nf * 160 * 160;
    const size_t n80  = (size_t)B * nf * 80 * 80;
    const size_t n40  = (size_t)B * nf * 40 * 40;
    const size_t n20  = (size_t)B * nf * 20 * 20;

    float* ws = (float*)d_ws;
    float* F0    = ws;
    float* TMP80 = F0 + n160;
    float* F1    = TMP80 + n80;
    float* TMP40 = F1 + n80;
    float* F2    = TMP40 + n40;
    float* T20A  = F2 + n40;
    float* T20B  = T20A + n20;
    float* T40   = T20B + n20;
    float* T40B  = T40 + n40;
    float* T80   = T40B + n40;
    float* T80B  = T80 + n80;
    float* T160  = T80B + n80;
    float* TF    = T160 + n160;
    float* XAREG = TF + n160;                         // 11,757,312 f region
    float* OM    = XAREG;                             // OM lives here now
    float* WT2   = XAREG + 11757312;                  // 4,032 f
    unsigned short* WBF   = (unsigned short*)(WT2 + 4032);           // 27,648
    unsigned short* XACL  = WBF + 27648;                             // 11,757,312
    unsigned short* WOMF  = XACL + 11757312;                         // 55,296
    unsigned short* OCL   = WOMF + 55296;                            // 1,679,616
    unsigned short* MCL   = OCL + 1679616;                           // 1,679,616
    unsigned short* TCL   = MCL + 1679616;                           // 1,679,616
    unsigned short* CATCL = TCL + 1679616;                           // 860,672
    unsigned short* WTF2F = CATCL + 860672;                          // 9,216
    unsigned short* WOUTF = WTF2F + 9216;                            // 9,216
    unsigned short* WUP1F = WOUTF + 9216;                            // 18,432

    const int bpc160 = 25;
    const int bpc80_128 = 13;
    const int bpc40_64  = 7;
    const int bpc20_64  = 2;

    // prep (merged) + conv_a fused to bf16 channel-last
    prep_k<<<nblk(27648 + 4032 + 14 * 644 + 55296 + 9216 + 9216 + 18432), TPB, 0, stream>>>(
        w_tf3b, w_dc, w_om, w_tf2, w_out, w_up1a, WBF, WOMF, WTF2F, WOUTF, WUP1F, WT2, XACL);
    conv3da_cl_k<<<B * 7 * 160 * 20, TPB, 0, stream>>>(inputs, w_tf3a, b_tf3a, XACL, B, H, W);

    // --- 2D U-Net branch ---
    conv2d_c4_k<1, 0, 0><<<B * 8 * bpc160, TPB, 0, stream>>>(inputs, nullptr, w_in, b_in, nullptr, F0, B, 7, 160, 160, nf, 8, bpc160);
    conv2d_s2_t4_k<128><<<B * nf * bpc80_128, 128, 0, stream>>>(F0, w_dn1a, b_dn1a, TMP80, B, nf, 160, 160, nf, bpc80_128);
    conv2d_t4_k<128, 1, 0><<<B * nf * bpc80_128, 128, 0, stream>>>(TMP80, w_dn1b, b_dn1b, nullptr, F1, B, nf, 80, 80, nf, bpc80_128);
    conv2d_s2_t4_k<64><<<B * nf * bpc40_64, 64, 0, stream>>>(F1, w_dn2a, b_dn2a, TMP40, B, nf, 80, 80, nf, bpc40_64);
    conv2d_t4_k<64, 1, 0><<<B * nf * bpc40_64, 64, 0, stream>>>(TMP40, w_dn2b, b_dn2b, nullptr, F2, B, nf, 40, 40, nf, bpc40_64);
    conv2d_s2_t4_k<64><<<B * nf * bpc20_64, 64, 0, stream>>>(F2, w_tra, b_tra, T20A, B, nf, 40, 40, nf, bpc20_64);
    conv2d_t4_k<64, 1, 0><<<B * nf * bpc20_64, 64, 0, stream>>>(T20A, w_trb, b_trb, nullptr, T20B, B, nf, 20, 20, nf, bpc20_64);
    convt2d_t4_k<64><<<B * nf * bpc40_64, 64, 0, stream>>>(T20B, wt_tr, bt_tr, T40, B, nf, 20, 20, bpc40_64);
    conv2d_cat_t4_k<64><<<B * nf * bpc40_64, 64, 0, stream>>>(T40, F2, w_up2a, b_up2a, T40B, B, nf, nf, 40, 40, nf, bpc40_64);
    convt2d_t4_k<128><<<B * nf * bpc80_128, 128, 0, stream>>>(T40B, wt_up2, bt_up2, T80, B, nf, 40, 40, bpc80_128);
    cat2cl_k<<<nblk(2 * 6724), TPB, 0, stream>>>(T80, F1, CATCL);
    conv_up1a_mfma_k<<<B * 200, TPB, 0, stream>>>(CATCL, WUP1F, b_up1a, T80B, B);
    convt2d_c4_k<<<B * 8 * bpc160, TPB, 0, stream>>>(T80B, wt_up1, bt_up1, T160, B, nf, 80, 80, bpc160);

    // --- conv3d_b + relu + mean (bf16 MFMA) -> F0 ---
    conv3db_mfma_k<<<B * 800, TPB, 0, stream>>>(XACL, WBF, b_tf3b, F0, B, H, W);
    // FUSED = relu(conv_tf2(MEAN) + T160)  [MFMA]
    o2cl_k<<<nblk(2 * 26244), TPB, 0, stream>>>(F0, MCL);
    conv_nf_mfma_k<1, 1><<<B * 800, TPB, 0, stream>>>(MCL, WTF2F, b_tf2, T160, TF, B);

    // --- offset/mask head: w_out MFMA -> F0; o2cl; w_om MFMA ---
    o2cl_k<<<nblk(2 * 26244), TPB, 0, stream>>>(TF, TCL);
    conv_nf_mfma_k<0, 1><<<B * 800, TPB, 0, stream>>>(TCL, WOUTF, b_out, nullptr, F0, B);
    o2cl_k<<<nblk(2 * 26244), TPB, 0, stream>>>(F0, OCL);
    conv_om_mfma_k<<<B * 1600, TPB, 0, stream>>>(OCL, WOMF, b_om, OM, B);

    // --- deformable conv (two-phase) ---
    deform_conv2_k<<<B * (H * W / 64), TPB, 0, stream>>>(inputs, OM, WT2, b_dc, out, B, H, W);
}

// Round 21
// 448.317 us; speedup vs baseline: 2.1998x; 1.1477x over previous
//
#include <hip/hip_runtime.h>
#include <math.h>

// ---------------------------------------------------------------------------
// STDF forward, round 21: (a) conv3da_cl rebuilt row-wise (weights+window
// staged once per 160-px row: 44800 -> 2240 blocks); (b) up2a 40-level concat
// conv -> MFMA (4th template replication, padded-width CL buffer + masked
// epilogue). Rest identical to round 20 (514us verified).
// ---------------------------------------------------------------------------

#define TPB 256

static inline int nblk(long long total) { return (int)((total + TPB - 1) / TPB); }

typedef short bf16x8 __attribute__((ext_vector_type(8)));
typedef float f32x4 __attribute__((ext_vector_type(4)));

__device__ __forceinline__ unsigned short f2bf(float f) {
    unsigned int u = __float_as_uint(f);
    unsigned int r = u + 0x7FFFu + ((u >> 16) & 1u);   // RNE
    return (unsigned short)(r >> 16);
}

// ---------------- 3x3 conv2d, stride 1, 4 outputs/thread, block-uniform co --
template <int TB, int RELU, int HAS_RES>
__global__ __launch_bounds__(TB) void conv2d_t4_k(
    const float* __restrict__ in, const float* __restrict__ w,
    const float* __restrict__ bias, const float* __restrict__ res,
    float* __restrict__ out, int B, int Ci, int H, int W, int Co, int BPC) {
    __shared__ float ws_w[32 * 9];
    int co = (blockIdx.x / BPC) % Co;
    int b  = blockIdx.x / (BPC * Co);
    for (int i = threadIdx.x; i < Ci * 9; i += TB)
        ws_w[i] = w[(size_t)co * Ci * 9 + i];
    __syncthreads();
    int nq = W >> 2;
    int r = (blockIdx.x % BPC) * TB + threadIdx.x;
    if (r >= H * nq) return;
    int q = r % nq, ho = r / nq;
    int wb = q * 4;
    float bv = bias[co];
    float a0 = bv, a1 = bv, a2 = bv, a3 = bv;
    const float* ipb = in + (size_t)b * Ci * H * W;
    for (int ci = 0; ci < Ci; ++ci) {
        const float* ip = ipb + (size_t)ci * H * W;
        const float* wc = ws_w + ci * 9;
#pragma unroll
        for (int kh = 0; kh < 3; ++kh) {
            int y = ho - 1 + kh;
            if (y < 0 || y >= H) continue;
            const float* row = ip + (size_t)y * W + wb;
            float4 xv = *(const float4*)row;
            float xm = (wb > 0) ? row[-1] : 0.f;
            float xp = (wb + 4 < W) ? row[4] : 0.f;
            float w0 = wc[kh * 3], w1 = wc[kh * 3 + 1], w2 = wc[kh * 3 + 2];
            a0 += xm   * w0 + xv.x * w1 + xv.y * w2;
            a1 += xv.x * w0 + xv.y * w1 + xv.z * w2;
            a2 += xv.y * w0 + xv.z * w1 + xv.w * w2;
            a3 += xv.z * w0 + xv.w * w1 + xp   * w2;
        }
    }
    size_t o = ((size_t)(b * Co + co) * H + ho) * W + wb;
    if (HAS_RES) {
        float4 rv = *(const float4*)(res + o);
        a0 += rv.x; a1 += rv.y; a2 += rv.z; a3 += rv.w;
    }
    if (RELU) { a0 = fmaxf(a0, 0.f); a1 = fmaxf(a1, 0.f); a2 = fmaxf(a2, 0.f); a3 = fmaxf(a3, 0.f); }
    *(float4*)(out + o) = make_float4(a0, a1, a2, a3);
}

// ------- 3x3 conv2d, stride 1, 4 outputs x 4 co per thread -----------------
template <int RELU, int HAS_RES, int HAS_IN2>
__global__ __launch_bounds__(TPB) void conv2d_c4_k(
    const float* __restrict__ in, const float* __restrict__ in2,
    const float* __restrict__ w, const float* __restrict__ bias,
    const float* __restrict__ res, float* __restrict__ out,
    int B, int Ci, int H, int W, int Co, int COG, int BPC) {
    __shared__ float ws_w[4 * 32 * 9];
    int cog = (blockIdx.x / BPC) % COG;
    int b   = blockIdx.x / (BPC * COG);
    int co0 = cog * 4;
    int nw = Ci * 9;
    for (int i = threadIdx.x; i < 4 * nw; i += TPB) {
        int cr = i / nw; int co = co0 + cr;
        ws_w[i] = (co < Co) ? w[(size_t)co * nw + (i - cr * nw)] : 0.f;
    }
    __syncthreads();
    int nq = W >> 2;
    int r = (blockIdx.x % BPC) * TPB + threadIdx.x;
    if (r >= H * nq) return;
    int q = r % nq, ho = r / nq;
    int wb = q * 4;
    float a[4][4];
#pragma unroll
    for (int cr = 0; cr < 4; ++cr) {
        float bv = (co0 + cr < Co) ? bias[co0 + cr] : 0.f;
        a[cr][0] = bv; a[cr][1] = bv; a[cr][2] = bv; a[cr][3] = bv;
    }
    const float* ipb = in + (size_t)b * Ci * H * W;
    const float* ipb2 = HAS_IN2 ? in2 + (size_t)b * Ci * H * W : nullptr;
    for (int ci = 0; ci < Ci; ++ci) {
        const float* ip = ipb + (size_t)ci * H * W;
        const float* ip2 = HAS_IN2 ? ipb2 + (size_t)ci * H * W : nullptr;
#pragma unroll
        for (int kh = 0; kh < 3; ++kh) {
            int y = ho - 1 + kh;
            if (y < 0 || y >= H) continue;
            const float* row = ip + (size_t)y * W + wb;
            float4 xv = *(const float4*)row;
            float x_[6];
            x_[0] = (wb > 0) ? row[-1] : 0.f;
            x_[5] = (wb + 4 < W) ? row[4] : 0.f;
            if (HAS_IN2) {
                const float* row2 = ip2 + (size_t)y * W + wb;
                float4 x2 = *(const float4*)row2;
                xv.x += x2.x; xv.y += x2.y; xv.z += x2.z; xv.w += x2.w;
                if (wb > 0) x_[0] += row2[-1];
                if (wb + 4 < W) x_[5] += row2[4];
            }
            x_[1] = xv.x; x_[2] = xv.y; x_[3] = xv.z; x_[4] = xv.w;
#pragma unroll
            for (int cr = 0; cr < 4; ++cr) {
                const float* wc = ws_w + cr * nw + ci * 9 + kh * 3;
                float w0 = wc[0], w1 = wc[1], w2 = wc[2];
                a[cr][0] += x_[0] * w0 + x_[1] * w1 + x_[2] * w2;
                a[cr][1] += x_[1] * w0 + x_[2] * w1 + x_[3] * w2;
                a[cr][2] += x_[2] * w0 + x_[3] * w1 + x_[4] * w2;
                a[cr][3] += x_[3] * w0 + x_[4] * w1 + x_[5] * w2;
            }
        }
    }
#pragma unroll
    for (int cr = 0; cr < 4; ++cr) {
        int co = co0 + cr;
        if (co >= Co) break;
        size_t o = ((size_t)(b * Co + co) * H + ho) * W + wb;
        float a0 = a[cr][0], a1 = a[cr][1], a2 = a[cr][2], a3 = a[cr][3];
        if (HAS_RES) {
            float4 rv = *(const float4*)(res + o);
            a0 += rv.x; a1 += rv.y; a2 += rv.z; a3 += rv.w;
        }
        if (RELU) { a0 = fmaxf(a0, 0.f); a1 = fmaxf(a1, 0.f); a2 = fmaxf(a2, 0.f); a3 = fmaxf(a3, 0.f); }
        *(float4*)(out + o) = make_float4(a0, a1, a2, a3);
    }
}

// ------------- 3x3 conv2d over concat of two 32-ch inputs, stride 1, relu ---
template <int TB>
__global__ __launch_bounds__(TB) void conv2d_cat_t4_k(
    const float* __restrict__ in1, const float* __restrict__ in2,
    const float* __restrict__ w, const float* __restrict__ bias,
    float* __restrict__ out, int B, int C1, int C2, int H, int W, int Co, int BPC) {
    __shared__ float ws_w[64 * 9];
    int Ci = C1 + C2;
    int co = (blockIdx.x / BPC) % Co;
    int b  = blockIdx.x / (BPC * Co);
    for (int i = threadIdx.x; i < Ci * 9; i += TB)
        ws_w[i] = w[(size_t)co * Ci * 9 + i];
    __syncthreads();
    int nq = W >> 2;
    int r = (blockIdx.x % BPC) * TB + threadIdx.x;
    if (r >= H * nq) return;
    int q = r % nq, ho = r / nq;
    int wb = q * 4;
    float bv = bias[co];
    float a0 = bv, a1 = bv, a2 = bv, a3 = bv;
    for (int ci = 0; ci < Ci; ++ci) {
        const float* ip = (ci < C1)
            ? in1 + ((size_t)(b * C1 + ci)) * H * W
            : in2 + ((size_t)(b * C2 + (ci - C1))) * H * W;
        const float* wc = ws_w + ci * 9;
#pragma unroll
        for (int kh = 0; kh < 3; ++kh) {
            int y = ho - 1 + kh;
            if (y < 0 || y >= H) continue;
            const float* row = ip + (size_t)y * W + wb;
            float4 xv = *(const float4*)row;
            float xm = (wb > 0) ? row[-1] : 0.f;
            float xp = (wb + 4 < W) ? row[4] : 0.f;
            float w0 = wc[kh * 3], w1 = wc[kh * 3 + 1], w2 = wc[kh * 3 + 2];
            a0 += xm   * w0 + xv.x * w1 + xv.y * w2;
            a1 += xv.x * w0 + xv.y * w1 + xv.z * w2;
            a2 += xv.y * w0 + xv.z * w1 + xv.w * w2;
            a3 += xv.z * w0 + xv.w * w1 + xp   * w2;
        }
    }
    size_t o = ((size_t)(b * Co + co) * H + ho) * W + wb;
    *(float4*)(out + o) = make_float4(fmaxf(a0, 0.f), fmaxf(a1, 0.f), fmaxf(a2, 0.f), fmaxf(a3, 0.f));
}

// ------------- 3x3 conv2d, stride 2, 4 outputs/thread, relu ----------------
template <int TB>
__global__ __launch_bounds__(TB) void conv2d_s2_t4_k(
    const float* __restrict__ in, const float* __restrict__ w,
    const float* __restrict__ bias, float* __restrict__ out,
    int B, int Ci, int Hi, int Wi, int Co, int BPC) {
    __shared__ float ws_w[32 * 9];
    int Ho = Hi >> 1, Wo = Wi >> 1;
    int co = (blockIdx.x / BPC) % Co;
    int b  = blockIdx.x / (BPC * Co);
    for (int i = threadIdx.x; i < Ci * 9; i += TB)
        ws_w[i] = w[(size_t)co * Ci * 9 + i];
    __syncthreads();
    int nq = Wo >> 2;
    int r = (blockIdx.x % BPC) * TB + threadIdx.x;
    if (r >= Ho * nq) return;
    int q = r % nq, ho = r / nq;
    int wb = q * 4;
    float bv = bias[co];
    float a0 = bv, a1 = bv, a2 = bv, a3 = bv;
    const float* ipb = in + (size_t)b * Ci * Hi * Wi;
    for (int ci = 0; ci < Ci; ++ci) {
        const float* ip = ipb + (size_t)ci * Hi * Wi;
        const float* wc = ws_w + ci * 9;
#pragma unroll
        for (int kh = 0; kh < 3; ++kh) {
            int y = 2 * ho - 1 + kh;
            if (y < 0 || y >= Hi) continue;
            const float* row = ip + (size_t)y * Wi;
            float z0 = (2 * wb - 1 >= 0) ? row[2 * wb - 1] : 0.f;
            float4 za = *(const float4*)(row + 2 * wb);
            float4 zb = *(const float4*)(row + 2 * wb + 4);
            float w0 = wc[kh * 3], w1 = wc[kh * 3 + 1], w2 = wc[kh * 3 + 2];
            a0 += z0   * w0 + za.x * w1 + za.y * w2;
            a1 += za.y * w0 + za.z * w1 + za.w * w2;
            a2 += za.w * w0 + zb.x * w1 + zb.y * w2;
            a3 += zb.y * w0 + zb.z * w1 + zb.w * w2;
        }
    }
    size_t o = ((size_t)(b * Co + co) * Ho + ho) * Wo + wb;
    *(float4*)(out + o) = make_float4(fmaxf(a0, 0.f), fmaxf(a1, 0.f), fmaxf(a2, 0.f), fmaxf(a3, 0.f));
}

// ------------- transposed conv 4x4 stride 2, 4 outputs/thread, relu --------
template <int TB>
__global__ __launch_bounds__(TB) void convt2d_t4_k(
    const float* __restrict__ in, const float* __restrict__ wt,
    const float* __restrict__ bias, float* __restrict__ out,
    int B, int C, int Hi, int Wi, int BPC) {
    __shared__ float ws_w[32 * 16];
    int Ho = 2 * Hi, Wo = 2 * Wi;
    int co = (blockIdx.x / BPC) % C;
    int b  = blockIdx.x / (BPC * C);
    for (int i = threadIdx.x; i < C * 16; i += TB) {
        int ci = i >> 4, t = i & 15;
        ws_w[i] = wt[((size_t)ci * C + co) * 16 + t];
    }
    __syncthreads();
    int nq = Wo >> 2;
    int r = (blockIdx.x % BPC) * TB + threadIdx.x;
    if (r >= Ho * nq) return;
    int q = r % nq, ho = r / nq;
    int wb = q * 4;
    int p = ho & 1;
    int iy0 = (ho + p) / 2 - 1;
    int iy1 = iy0 + 1;
    int ix0 = wb / 2 - 1;
    bool vy0 = (iy0 >= 0) && (iy0 < Hi);
    bool vy1 = (iy1 >= 0) && (iy1 < Hi);
    float bv = bias[co];
    float a0 = bv, a1 = bv, a2 = bv, a3 = bv;
    const float* ipb = in + (size_t)b * C * Hi * Wi;
    for (int ci = 0; ci < C; ++ci) {
        const float* ip = ipb + (size_t)ci * Hi * Wi;
        float u0 = 0, u1 = 0, u2 = 0, u3 = 0, v0 = 0, v1 = 0, v2 = 0, v3 = 0;
        if (vy0) {
            const float* rw = ip + (size_t)iy0 * Wi;
            if (ix0 >= 0) u0 = rw[ix0];
            u1 = rw[ix0 + 1]; u2 = rw[ix0 + 2];
            if (ix0 + 3 < Wi) u3 = rw[ix0 + 3];
        }
        if (vy1) {
            const float* rw = ip + (size_t)iy1 * Wi;
            if (ix0 >= 0) v0 = rw[ix0];
            v1 = rw[ix0 + 1]; v2 = rw[ix0 + 2];
            if (ix0 + 3 < Wi) v3 = rw[ix0 + 3];
        }
        const float* wr0 = ws_w + ci * 16 + (3 - p) * 4;
        const float* wr1 = ws_w + ci * 16 + (1 - p) * 4;
        a0 += u0 * wr0[3] + u1 * wr0[1] + v0 * wr1[3] + v1 * wr1[1];
        a1 += u1 * wr0[2] + u2 * wr0[0] + v1 * wr1[2] + v2 * wr1[0];
        a2 += u1 * wr0[3] + u2 * wr0[1] + v1 * wr1[3] + v2 * wr1[1];
        a3 += u2 * wr0[2] + u3 * wr0[0] + v2 * wr1[2] + v3 * wr1[0];
    }
    size_t o = ((size_t)(b * C + co) * Ho + ho) * Wo + wb;
    *(float4*)(out + o) = make_float4(fmaxf(a0, 0.f), fmaxf(a1, 0.f), fmaxf(a2, 0.f), fmaxf(a3, 0.f));
}

// ------------- transposed conv 4x4 stride 2, 4 outputs x 4 co/thread -------
__global__ __launch_bounds__(TPB) void convt2d_c4_k(
    const float* __restrict__ in, const float* __restrict__ wt,
    const float* __restrict__ bias, float* __restrict__ out,
    int B, int C, int Hi, int Wi, int BPC) {
    __shared__ float ws_w[4][32 * 16];
    int Ho = 2 * Hi, Wo = 2 * Wi;
    int cog = (blockIdx.x / BPC) % (C / 4);
    int b   = blockIdx.x / (BPC * (C / 4));
    int co0 = cog * 4;
    for (int i = threadIdx.x; i < 4 * C * 16; i += TPB) {
        int cr = i / (C * 16); int j = i % (C * 16);
        int ci = j >> 4, t = j & 15;
        ws_w[cr][j] = wt[((size_t)ci * C + (co0 + cr)) * 16 + t];
    }
    __syncthreads();
    int nq = Wo >> 2;
    int r = (blockIdx.x % BPC) * TPB + threadIdx.x;
    if (r >= Ho * nq) return;
    int q = r % nq, ho = r / nq;
    int wb = q * 4;
    int p = ho & 1;
    int iy0 = (ho + p) / 2 - 1;
    int iy1 = iy0 + 1;
    int ix0 = wb / 2 - 1;
    bool vy0 = (iy0 >= 0) && (iy0 < Hi);
    bool vy1 = (iy1 >= 0) && (iy1 < Hi);
    float a[4][4];
#pragma unroll
    for (int cr = 0; cr < 4; ++cr) {
        float bv = bias[co0 + cr];
        a[cr][0] = bv; a[cr][1] = bv; a[cr][2] = bv; a[cr][3] = bv;
    }
    const float* ipb = in + (size_t)b * C * Hi * Wi;
    for (int ci = 0; ci < C; ++ci) {
        const float* ip = ipb + (size_t)ci * Hi * Wi;
        float u0 = 0, u1 = 0, u2 = 0, u3 = 0, v0 = 0, v1 = 0, v2 = 0, v3 = 0;
        if (vy0) {
            const float* rw = ip + (size_t)iy0 * Wi;
            if (ix0 >= 0) u0 = rw[ix0];
            u1 = rw[ix0 + 1]; u2 = rw[ix0 + 2];
            if (ix0 + 3 < Wi) u3 = rw[ix0 + 3];
        }
        if (vy1) {
            const float* rw = ip + (size_t)iy1 * Wi;
            if (ix0 >= 0) v0 = rw[ix0];
            v1 = rw[ix0 + 1]; v2 = rw[ix0 + 2];
            if (ix0 + 3 < Wi) v3 = rw[ix0 + 3];
        }
#pragma unroll
        for (int cr = 0; cr < 4; ++cr) {
            const float* wr0 = ws_w[cr] + ci * 16 + (3 - p) * 4;
            const float* wr1 = ws_w[cr] + ci * 16 + (1 - p) * 4;
            a[cr][0] += u0 * wr0[3] + u1 * wr0[1] + v0 * wr1[3] + v1 * wr1[1];
            a[cr][1] += u1 * wr0[2] + u2 * wr0[0] + v1 * wr1[2] + v2 * wr1[0];
            a[cr][2] += u1 * wr0[3] + u2 * wr0[1] + v1 * wr1[3] + v2 * wr1[1];
            a[cr][3] += u2 * wr0[2] + u3 * wr0[0] + v2 * wr1[2] + v3 * wr1[0];
        }
    }
#pragma unroll
    for (int cr = 0; cr < 4; ++cr) {
        size_t o = ((size_t)(b * C + co0 + cr) * Ho + ho) * Wo + wb;
        *(float4*)(out + o) = make_float4(fmaxf(a[cr][0], 0.f), fmaxf(a[cr][1], 0.f),
                                          fmaxf(a[cr][2], 0.f), fmaxf(a[cr][3], 0.f));
    }
}

// ---- merged prep: all B-fragment packs + wdc transpose + XACL border zero --
__global__ void prep_k(const float* __restrict__ wb, const float* __restrict__ wdc,
                       const float* __restrict__ wom, const float* __restrict__ wtf2,
                       const float* __restrict__ wout, const float* __restrict__ wup1a,
                       const float* __restrict__ wup2a,
                       unsigned short* __restrict__ wbf, unsigned short* __restrict__ womf,
                       unsigned short* __restrict__ wtf2f, unsigned short* __restrict__ woutf,
                       unsigned short* __restrict__ wup1f, unsigned short* __restrict__ wup2f,
                       float* __restrict__ wt2, unsigned short* __restrict__ xacl) {
    int i = blockIdx.x * TPB + threadIdx.x;
    if (i < 27648) {                          // conv3db B-frags
        int j = i & 7;
        int l = (i >> 3) & 63;
        int coH = (i >> 9) & 1;
        int tap = i >> 10;
        int ci = ((l >> 4) << 3) + j;
        int co = (coH << 4) + (l & 15);
        wbf[i] = f2bf(wb[(size_t)(co * 32 + ci) * 27 + tap]);
        return;
    }
    int i2 = i - 27648;
    if (i2 < 4032) {                          // deform weight transpose
        int o = i2 & 63, ck = i2 >> 6;
        wt2[i2] = wdc[o * 63 + ck];
        return;
    }
    int i3 = i2 - 4032;
    if (i3 < 14 * 644) {                      // XACL border zero (14 bd-planes)
        int pl = i3 / 644, e = i3 % 644;
        int off;
        if (e < 162)      off = e;
        else if (e < 324) off = 161 * 162 + (e - 162);
        else if (e < 484) off = (e - 324 + 1) * 162;
        else              off = (e - 484 + 1) * 162 + 161;
        uint4* d = (uint4*)(xacl + ((size_t)pl * 26244 + off) * 32);
        uint4 z = make_uint4(0, 0, 0, 0);
        d[0] = z; d[1] = z; d[2] = z; d[3] = z;
        return;
    }
    int i4 = i3 - 14 * 644;
    if (i4 < 55296) {                         // w_om B-frags [tap][nt12][l][8]
        int j = i4 & 7;
        int l = (i4 >> 3) & 63;
        int nt = (i4 >> 9) % 12;
        int tap = i4 / 6144;
        int ci = ((l >> 4) << 3) + j;
        int co = nt * 16 + (l & 15);
        womf[i4] = (co < 189) ? f2bf(wom[((size_t)co * 32 + ci) * 9 + tap]) : (unsigned short)0;
        return;
    }
    int i5 = i4 - 55296;
    if (i5 < 9216) {                          // tf2 B-frags [tap][coH][l][8]
        int j = i5 & 7;
        int l = (i5 >> 3) & 63;
        int q = i5 >> 9;
        int coH = q & 1, tap = q >> 1;
        int ci = ((l >> 4) << 3) + j;
        int co = coH * 16 + (l & 15);
        wtf2f[i5] = f2bf(wtf2[((size_t)co * 32 + ci) * 9 + tap]);
        return;
    }
    int i6 = i5 - 9216;
    if (i6 < 9216) {                          // w_out B-frags
        int j = i6 & 7;
        int l = (i6 >> 3) & 63;
        int q = i6 >> 9;
        int coH = q & 1, tap = q >> 1;
        int ci = ((l >> 4) << 3) + j;
        int co = coH * 16 + (l & 15);
        woutf[i6] = f2bf(wout[((size_t)co * 32 + ci) * 9 + tap]);
        return;
    }
    int i7 = i6 - 9216;
    if (i7 < 18432) {                         // up1a B-frags [tap][kc][coH][l][8]
        int j = i7 & 7;
        int l = (i7 >> 3) & 63;
        int q = i7 >> 9;
        int coH = q & 1, kc = (q >> 1) & 1, tap = q >> 2;
        int ci = kc * 32 + ((l >> 4) << 3) + j;
        int co = coH * 16 + (l & 15);
        wup1f[i7] = f2bf(wup1a[((size_t)co * 64 + ci) * 9 + tap]);
        return;
    }
    int i8 = i7 - 18432;
    if (i8 >= 18432) return;                  // up2a B-frags, same layout
    int j = i8 & 7;
    int l = (i8 >> 3) & 63;
    int q = i8 >> 9;
    int coH = q & 1, kc = (q >> 1) & 1, tap = q >> 2;
    int ci = kc * 32 + ((l >> 4) << 3) + j;
    int co = coH * 16 + (l & 15);
    wup2f[i8] = f2bf(wup2a[((size_t)co * 64 + ci) * 9 + tap]);
}

// ---- conv3d_a fused v2: row-wise blocks (weights+window staged once) -------
// grid = B*7*160; block 256 = 8 x x 32 co; each thread 20 outputs.
__global__ __launch_bounds__(TPB) void conv3da_cl_k(
    const float* __restrict__ x, const float* __restrict__ wa,
    const float* __restrict__ ba, unsigned short* __restrict__ xacl,
    int B, int H, int W) {
    __shared__ float xin[3 * 3 * 162];   // [dz][yy][padded x]
    __shared__ float wsa[864];
    int blk = blockIdx.x;
    int y  = blk % 160;
    int d  = (blk / 160) % 7;
    int b  = blk / 1120;
    int tid = threadIdx.x;
    for (int i = tid; i < 3 * 3 * 162; i += TPB) {
        int xx = i % 162; int t = i / 162; int yy = t % 3; int dz = t / 3;
        int gd = d - 1 + dz, gy = y - 1 + yy, gx = xx - 1;
        float v = 0.f;
        if (gd >= 0 && gd < 7 && gy >= 0 && gy < H && gx >= 0 && gx < W)
            v = x[((size_t)(b * 7 + gd)) * H * W + (size_t)gy * W + gx];
        xin[i] = v;
    }
    for (int i = tid; i < 864; i += TPB) wsa[i] = wa[i];
    __syncthreads();
    int co = tid & 31;
    int xi0 = tid >> 5;
    float bv = ba[co];
    const float* wc = wsa + co * 27;
    size_t rowbase = (((size_t)(b * 7 + d) * 162 + (y + 1)) * 162 + 1) * 32 + co;
    for (int k = 0; k < 20; ++k) {
        int gx = k * 8 + xi0;
        float acc = bv;
#pragma unroll
        for (int dz = 0; dz < 3; ++dz)
#pragma unroll
            for (int yy = 0; yy < 3; ++yy)
#pragma unroll
                for (int kw = 0; kw < 3; ++kw)
                    acc += xin[dz * 486 + yy * 162 + gx + kw] * wc[dz * 9 + yy * 3 + kw];
        xacl[rowbase + (size_t)gx * 32] = f2bf(fmaxf(acc, 0.f));
    }
}

// ---- 32ch fp32 ch-first 160x160 -> bf16 CL 162x162 padded ------------------
__global__ __launch_bounds__(TPB) void o2cl_k(
    const float* __restrict__ o, unsigned short* __restrict__ ocl) {
    int idx = blockIdx.x * TPB + threadIdx.x;
    if (idx >= 2 * 26244) return;
    int pos = idx % 26244;
    int b = idx / 26244;
    int y = pos / 162, x = pos % 162;
    uint4* dst = (uint4*)(ocl + (size_t)idx * 32);
    if (y == 0 || y == 161 || x == 0 || x == 161) {
        uint4 z = make_uint4(0, 0, 0, 0);
        dst[0] = z; dst[1] = z; dst[2] = z; dst[3] = z;
        return;
    }
    unsigned int pk[16];
    const float* src = o + (size_t)b * 32 * 25600 + (size_t)(y - 1) * 160 + (x - 1);
#pragma unroll
    for (int j = 0; j < 16; ++j) {
        float v0 = src[(size_t)(2 * j) * 25600];
        float v1 = src[(size_t)(2 * j + 1) * 25600];
        pk[j] = (unsigned int)f2bf(v0) | ((unsigned int)f2bf(v1) << 16);
    }
    dst[0] = make_uint4(pk[0], pk[1], pk[2], pk[3]);
    dst[1] = make_uint4(pk[4], pk[5], pk[6], pk[7]);
    dst[2] = make_uint4(pk[8], pk[9], pk[10], pk[11]);
    dst[3] = make_uint4(pk[12], pk[13], pk[14], pk[15]);
}

// ---- concat fp32 ch-first -> bf16 CL padded: generic (PW wide, HxW valid) --
// dst[b][PH][PW][64]; valid data at rows 1..H, cols 1..W; rest zero.
template <int HH, int WW, int PH, int PW>
__global__ __launch_bounds__(TPB) void cat2cl_k(
    const float* __restrict__ a, const float* __restrict__ c2,
    unsigned short* __restrict__ dst) {
    int idx = blockIdx.x * TPB + threadIdx.x;
    if (idx >= 2 * PH * PW) return;
    int pos = idx % (PH * PW);
    int b = idx / (PH * PW);
    int y = pos / PW, x = pos % PW;
    uint4* d = (uint4*)(dst + (size_t)idx * 64);
    if (y == 0 || y > HH || x == 0 || x > WW) {
        uint4 z = make_uint4(0, 0, 0, 0);
#pragma unroll
        for (int k = 0; k < 8; ++k) d[k] = z;
        return;
    }
    size_t off = (size_t)(y - 1) * WW + (x - 1);
    const float* sa = a + (size_t)b * 32 * (HH * WW) + off;
    const float* sc = c2 + (size_t)b * 32 * (HH * WW) + off;
    unsigned int pk[32];
#pragma unroll
    for (int j = 0; j < 16; ++j) {
        float v0 = sa[(size_t)(2 * j) * (HH * WW)];
        float v1 = sa[(size_t)(2 * j + 1) * (HH * WW)];
        pk[j] = (unsigned int)f2bf(v0) | ((unsigned int)f2bf(v1) << 16);
    }
#pragma unroll
    for (int j = 0; j < 16; ++j) {
        float v0 = sc[(size_t)(2 * j) * (HH * WW)];
        float v1 = sc[(size_t)(2 * j + 1) * (HH * WW)];
        pk[16 + j] = (unsigned int)f2bf(v0) | ((unsigned int)f2bf(v1) << 16);
    }
#pragma unroll
    for (int k = 0; k < 8; ++k)
        d[k] = make_uint4(pk[4 * k], pk[4 * k + 1], pk[4 * k + 2], pk[4 * k + 3]);
}

// ---- conv3d_b + relu + mean as bf16 MFMA implicit GEMM (verified r17) ------
__global__ __launch_bounds__(TPB) void conv3db_mfma_k(
    const unsigned short* __restrict__ xacl, const unsigned short* __restrict__ wbf,
    const float* __restrict__ bb, float* __restrict__ out, int B, int H, int W) {
    int blk = blockIdx.x;
    int b = blk / 800;
    int rem = blk % 800;
    int y = rem / 5;
    int xp = rem % 5;
    int tid = threadIdx.x;
    int l = tid & 63;
    int wv = tid >> 6;
    int mt = wv & 1, coH = wv >> 1;
    int x0 = xp * 32 + mt * 16;
    int co = coH * 16 + (l & 15);
    float bv = bb[co];
    f32x4 acc[7];
#pragma unroll
    for (int d = 0; d < 7; ++d) { acc[d][0] = bv; acc[d][1] = bv; acc[d][2] = bv; acc[d][3] = bv; }

    int ubase = (y * 162 + x0 + (l & 15)) * 32 + ((l >> 4) << 3);
    const unsigned short* xb = xacl + (size_t)b * 5878656;
    const unsigned short* wbase = wbf + ((size_t)coH * 64 + l) * 8;

#pragma unroll
    for (int kd = 0; kd < 3; ++kd) {
        for (int j2 = 0; j2 < 9; ++j2) {
            int off2 = (j2 / 3) * 5184 + (j2 % 3) * 32;
            bf16x8 bf = *reinterpret_cast<const bf16x8*>(wbase + (size_t)(kd * 9 + j2) * 1024);
#pragma unroll
            for (int d = 0; d < 7; ++d) {
                int dz = d + kd - 1;
                if (dz < 0 || dz >= 7) continue;
                bf16x8 af = *reinterpret_cast<const bf16x8*>(xb + (size_t)dz * 839808 + ubase + off2);
                acc[d] = __builtin_amdgcn_mfma_f32_16x16x32_bf16(af, bf, acc[d], 0, 0, 0);
            }
        }
    }

    int xo = x0 + ((l >> 4) << 2);
    size_t obase = ((size_t)(b * 32 + co)) * 25600 + (size_t)y * 160 + xo;
#pragma unroll
    for (int r = 0; r < 4; ++r) {
        float s = 0.f;
#pragma unroll
        for (int d = 0; d < 7; ++d) s += fmaxf(acc[d][r], 0.f);
        out[obase + r] = s * (1.f / 7.f);
    }
}

// ---- N=32 K=288 160-level conv as bf16 MFMA (tf2 / w_out) ------------------
template <int HAS_RES, int RELU>
__global__ __launch_bounds__(TPB) void conv_nf_mfma_k(
    const unsigned short* __restrict__ icl, const unsigned short* __restrict__ wf,
    const float* __restrict__ bias, const float* __restrict__ res,
    float* __restrict__ out, int B) {
    int blk = blockIdx.x;
    int b = blk / 800;
    int rem = blk % 800;
    int y = rem / 5;
    int xp = rem % 5;
    int tid = threadIdx.x;
    int l = tid & 63;
    int wv = tid >> 6;
    int mt = wv & 1, coH = wv >> 1;
    int x0 = xp * 32 + mt * 16;
    int co = coH * 16 + (l & 15);
    float bv = bias[co];
    f32x4 acc;
    acc[0] = bv; acc[1] = bv; acc[2] = bv; acc[3] = bv;
    int ubase = (y * 162 + x0 + (l & 15)) * 32 + ((l >> 4) << 3);
    const unsigned short* ib = icl + (size_t)b * 839808;
    const unsigned short* wl = wf + (size_t)l * 8;
#pragma unroll
    for (int tap = 0; tap < 9; ++tap) {
        int off = ((tap / 3) * 162 + (tap % 3)) * 32;
        bf16x8 af = *reinterpret_cast<const bf16x8*>(ib + ubase + off);
        bf16x8 bf = *reinterpret_cast<const bf16x8*>(wl + (size_t)(tap * 2 + coH) * 512);
        acc = __builtin_amdgcn_mfma_f32_16x16x32_bf16(af, bf, acc, 0, 0, 0);
    }
    int xo = x0 + ((l >> 4) << 2);
    size_t obase = ((size_t)(b * 32 + co)) * 25600 + (size_t)y * 160 + xo;
#pragma unroll
    for (int r = 0; r < 4; ++r) {
        float v = acc[r];
        if (HAS_RES) v += res[obase + r];
        if (RELU) v = fmaxf(v, 0.f);
        out[obase + r] = v;
    }
}

// ---- up1a concat conv as bf16 MFMA: M=80x80, N=32, K=576 -------------------
__global__ __launch_bounds__(TPB) void conv_up1a_mfma_k(
    const unsigned short* __restrict__ catcl, const unsigned short* __restrict__ wf,
    const float* __restrict__ bias, float* __restrict__ out, int B) {
    int blk = blockIdx.x;
    int b = blk / 200;
    int rem = blk % 200;
    int tid = threadIdx.x;
    int l = tid & 63;
    int wv = tid >> 6;
    int mtile = rem * 2 + (wv & 1);
    int coH = wv >> 1;
    int y = mtile / 5, x0 = (mtile % 5) * 16;
    int co = coH * 16 + (l & 15);
    float bv = bias[co];
    f32x4 acc;
    acc[0] = bv; acc[1] = bv; acc[2] = bv; acc[3] = bv;
    int ubase = (y * 82 + x0 + (l & 15)) * 64 + ((l >> 4) << 3);
    const unsigned short* cb = catcl + (size_t)b * 430336;
    const unsigned short* wl = wf + (size_t)l * 8;
#pragma unroll
    for (int tap = 0; tap < 9; ++tap) {
        int off = ((tap / 3) * 82 + (tap % 3)) * 64;
#pragma unroll
        for (int kc = 0; kc < 2; ++kc) {
            bf16x8 af = *reinterpret_cast<const bf16x8*>(cb + ubase + off + kc * 32);
            bf16x8 bf = *reinterpret_cast<const bf16x8*>(wl + (size_t)(((tap * 2 + kc) * 2 + coH)) * 512);
            acc = __builtin_amdgcn_mfma_f32_16x16x32_bf16(af, bf, acc, 0, 0, 0);
        }
    }
    int xo = x0 + ((l >> 4) << 2);
    size_t obase = ((size_t)(b * 32 + co)) * 6400 + (size_t)y * 80 + xo;
#pragma unroll
    for (int r = 0; r < 4; ++r)
        out[obase + r] = fmaxf(acc[r], 0.f);
}

// ---- up2a concat conv as bf16 MFMA: M=40x40, N=32, K=576, PW=52 ------------
// grid = B*60; 120 mtiles/b (40 rows x 3 xsegs of 16, masked at x>=40).
__global__ __launch_bounds__(TPB) void conv_up2a_mfma_k(
    const unsigned short* __restrict__ catcl, const unsigned short* __restrict__ wf,
    const float* __restrict__ bias, float* __restrict__ out, int B) {
    const int PW = 52;
    int blk = blockIdx.x;
    int b = blk / 60;
    int rem = blk % 60;
    int tid = threadIdx.x;
    int l = tid & 63;
    int wv = tid >> 6;
    int mtile = rem * 2 + (wv & 1);          // 0..119
    int coH = wv >> 1;
    int y = mtile / 3, x0 = (mtile % 3) * 16;
    int co = coH * 16 + (l & 15);
    float bv = bias[co];
    f32x4 acc;
    acc[0] = bv; acc[1] = bv; acc[2] = bv; acc[3] = bv;
    int ubase = (y * PW + x0 + (l & 15)) * 64 + ((l >> 4) << 3);
    const unsigned short* cb = catcl + (size_t)b * (42 * PW * 64);
    const unsigned short* wl = wf + (size_t)l * 8;
#pragma unroll
    for (int tap = 0; tap < 9; ++tap) {
        int off = ((tap / 3) * PW + (tap % 3)) * 64;
#pragma unroll
        for (int kc = 0; kc < 2; ++kc) {
            bf16x8 af = *reinterpret_cast<const bf16x8*>(cb + ubase + off + kc * 32);
            bf16x8 bf = *reinterpret_cast<const bf16x8*>(wl + (size_t)(((tap * 2 + kc) * 2 + coH)) * 512);
            acc = __builtin_amdgcn_mfma_f32_16x16x32_bf16(af, bf, acc, 0, 0, 0);
        }
    }
    int xo = x0 + ((l >> 4) << 2);
    size_t obase = ((size_t)(b * 32 + co)) * 1600 + (size_t)y * 40;
#pragma unroll
    for (int r = 0; r < 4; ++r) {
        int ox = xo + r;
        if (ox < 40) out[obase + ox] = fmaxf(acc[r], 0.f);
    }
}

// ---- w_om head as bf16 MFMA implicit GEMM (verified r18) -------------------
__global__ __launch_bounds__(TPB) void conv_om_mfma_k(
    const unsigned short* __restrict__ ocl, const unsigned short* __restrict__ womf,
    const float* __restrict__ bias, float* __restrict__ out, int B) {
    int blk = blockIdx.x;
    int b = blk / 1600;
    int rem = blk % 1600;
    int y = rem / 10;
    int xs = rem % 10;
    int tid = threadIdx.x;
    int l = tid & 63;
    int wv = tid >> 6;
    int x0 = xs * 16;
    f32x4 acc[3];
#pragma unroll
    for (int t = 0; t < 3; ++t) {
        int co = (wv * 3 + t) * 16 + (l & 15);
        float bv = (co < 189) ? bias[co] : 0.f;
        acc[t][0] = bv; acc[t][1] = bv; acc[t][2] = bv; acc[t][3] = bv;
    }
    int ubase = (y * 162 + x0 + (l & 15)) * 32 + ((l >> 4) << 3);
    const unsigned short* ob = ocl + (size_t)b * 839808;
    const unsigned short* wl = womf + (size_t)l * 8;
#pragma unroll
    for (int tap = 0; tap < 9; ++tap) {
        int off = ((tap / 3) * 162 + (tap % 3)) * 32;
        bf16x8 af = *reinterpret_cast<const bf16x8*>(ob + ubase + off);
#pragma unroll
        for (int t = 0; t < 3; ++t) {
            int nt = wv * 3 + t;
            bf16x8 bf = *reinterpret_cast<const bf16x8*>(wl + (size_t)(tap * 12 + nt) * 512);
            acc[t] = __builtin_amdgcn_mfma_f32_16x16x32_bf16(af, bf, acc[t], 0, 0, 0);
        }
    }
    int xo = x0 + ((l >> 4) << 2);
#pragma unroll
    for (int t = 0; t < 3; ++t) {
        int co = (wv * 3 + t) * 16 + (l & 15);
        if (co >= 189) continue;
        size_t obase = ((size_t)(b * 189 + co)) * 25600 + (size_t)y * 160 + xo;
#pragma unroll
        for (int r = 0; r < 4; ++r) out[obase + r] = acc[t][r];
    }
}

// ------------- two-phase modulated deformable conv ---------------------------
__global__ __launch_bounds__(TPB) void deform_conv2_k(
    const float* __restrict__ x, const float* __restrict__ om,
    const float* __restrict__ wt2, const float* __restrict__ bias,
    float* __restrict__ out, int B, int H, int W) {
    __shared__ float smp[63 * 64];
    const int HW = H * W;
    int blk = blockIdx.x;
    int b = blk / (HW / 64);
    int pxbase = (blk % (HW / 64)) * 64;
    int tid = threadIdx.x;
    const float* omb = om + (size_t)b * 189 * HW;
    const float* xb = x + (size_t)b * 7 * HW;

#pragma unroll 4
    for (int k = 0; k < 16; ++k) {
        int it = tid + k * 256;
        if (it >= 4032) break;
        int pxl = it & 63;
        int tap = it >> 6;
        int c = tap / 9, kk = tap % 9;
        int hw = pxbase + pxl;
        int hq = hw / W, wq = hw % W;
        float dy = omb[(size_t)(c * 18 + kk * 2 + 0) * HW + hw];
        float dx = omb[(size_t)(c * 18 + kk * 2 + 1) * HW + hw];
        float mv = omb[(size_t)(126 + c * 9 + kk) * HW + hw];
        float m = 1.f / (1.f + __expf(-mv));
        float py = (float)hq + (float)(kk / 3 - 1) + dy;
        float px = (float)wq + (float)(kk % 3 - 1) + dx;
        float y0f = floorf(py), x0f = floorf(px);
        int y0 = (int)y0f, x0 = (int)x0f;
        float wy1 = py - y0f, wx1 = px - x0f;
        float wy0 = 1.f - wy1, wx0 = 1.f - wx1;
        float v00 = 0.f, v01 = 0.f, v10 = 0.f, v11 = 0.f;
        const float* xc = xb + (size_t)c * HW;
        bool yin0 = (y0 >= 0) & (y0 < H);
        bool yin1 = (y0 + 1 >= 0) & (y0 + 1 < H);
        bool xin0 = (x0 >= 0) & (x0 < W);
        bool xin1 = (x0 + 1 >= 0) & (x0 + 1 < W);
        if (yin0) {
            const float* rr = xc + (size_t)y0 * W;
            if (xin0) v00 = rr[x0];
            if (xin1) v01 = rr[x0 + 1];
        }
        if (yin1) {
            const float* rr = xc + (size_t)(y0 + 1) * W;
            if (xin0) v10 = rr[x0];
            if (xin1) v11 = rr[x0 + 1];
        }
        smp[tap * 64 + pxl] =
            (wy0 * wx0 * v00 + wy0 * wx1 * v01 + wy1 * wx0 * v10 + wy1 * wx1 * v11) * m;
    }
    __syncthreads();

    int pxl = tid & 63;
    int g = tid >> 6;
    int gu = __builtin_amdgcn_readfirstlane(g);
    const float* swb = wt2 + gu * 16;
    const float* bsb = bias + gu * 16;
    float acc[16];
#pragma unroll
    for (int o = 0; o < 16; ++o) acc[o] = 0.f;
    for (int tap = 0; tap < 63; ++tap) {
        float s = smp[tap * 64 + pxl];
        const float* sw = swb + tap * 64;
#pragma unroll
        for (int o = 0; o < 16; ++o) acc[o] += s * sw[o];
    }
    int hw = pxbase + pxl;
    size_t obase = (size_t)b * 64 * HW + (size_t)gu * 16 * HW + hw;
#pragma unroll
    for (int o = 0; o < 16; ++o)
        out[obase + (size_t)o * HW] = fmaxf(acc[o] + bsb[o], 0.f);
}

extern "C" void kernel_launch(void* const* d_in, const int* in_sizes, int n_in,
                              void* d_out, int out_size, void* d_ws, size_t ws_size,
                              hipStream_t stream) {
    (void)in_sizes; (void)n_in; (void)out_size; (void)ws_size;
    const float* inputs = (const float*)d_in[0];
    const float* w_in   = (const float*)d_in[1];  const float* b_in   = (const float*)d_in[2];
    const float* w_dn1a = (const float*)d_in[3];  const float* b_dn1a = (const float*)d_in[4];
    const float* w_dn1b = (const float*)d_in[5];  const float* b_dn1b = (const float*)d_in[6];
    const float* w_up1a = (const float*)d_in[7];  const float* b_up1a = (const float*)d_in[8];
    const float* wt_up1 = (const float*)d_in[9];  const float* bt_up1 = (const float*)d_in[10];
    const float* w_dn2a = (const float*)d_in[11]; const float* b_dn2a = (const float*)d_in[12];
    const float* w_dn2b = (const float*)d_in[13]; const float* b_dn2b = (const float*)d_in[14];
    const float* w_up2a = (const float*)d_in[15]; const float* b_up2a = (const float*)d_in[16];
    const float* wt_up2 = (const float*)d_in[17]; const float* bt_up2 = (const float*)d_in[18];
    const float* w_tra  = (const float*)d_in[19]; const float* b_tra  = (const float*)d_in[20];
    const float* w_trb  = (const float*)d_in[21]; const float* b_trb  = (const float*)d_in[22];
    const float* wt_tr  = (const float*)d_in[23]; const float* bt_tr  = (const float*)d_in[24];
    const float* w_out  = (const float*)d_in[25]; const float* b_out  = (const float*)d_in[26];
    const float* w_tf3a = (const float*)d_in[27]; const float* b_tf3a = (const float*)d_in[28];
    const float* w_tf3b = (const float*)d_in[29]; const float* b_tf3b = (const float*)d_in[30];
    const float* w_tf2  = (const float*)d_in[31]; const float* b_tf2  = (const float*)d_in[32];
    const float* w_om   = (const float*)d_in[33]; const float* b_om   = (const float*)d_in[34];
    const float* w_dc   = (const float*)d_in[35]; const float* b_dc   = (const float*)d_in[36];
    float* out = (float*)d_out;

    const int B = 2, nf = 32, H = 160, W = 160;
    const size_t n160 = (size_t)B * nf * 160 * 160;
    const size_t n80  = (size_t)B * nf * 80 * 80;
    const size_t n40  = (size_t)B * nf * 40 * 40;
    const size_t n20  = (size_t)B * nf * 20 * 20;

    float* ws = (float*)d_ws;
    float* F0    = ws;
    float* TMP80 = F0 + n160;
    float* F1    = TMP80 + n80;
    float* TMP40 = F1 + n80;
    float* F2    = TMP40 + n40;
    float* T20A  = F2 + n40;
    float* T20B  = T20A + n20;
    float* T40   = T20B + n20;
    float* T40B  = T40 + n40;
    float* T80   = T40B + n40;
    float* T80B  = T80 + n80;
    float* T160  = T80B + n80;
    float* TF    = T160 + n160;
    float* XAREG = TF + n160;                         // 11,757,312 f region
    float* OM    = XAREG;                             // OM lives here
    float* WT2   = XAREG + 11757312;                  // 4,032 f
    unsigned short* WBF    = (unsigned short*)(WT2 + 4032);          // 27,648
    unsigned short* XACL   = WBF + 27648;                            // 11,757,312
    unsigned short* WOMF   = XACL + 11757312;                        // 55,296
    unsigned short* OCL    = WOMF + 55296;                           // 1,679,616
    unsigned short* MCL    = OCL + 1679616;                          // 1,679,616
    unsigned short* TCL    = MCL + 1679616;                          // 1,679,616
    unsigned short* CATCL  = TCL + 1679616;                          // 860,672
    unsigned short* CATCL2 = CATCL + 860672;                         // 279,552 (2*42*52*64)
    unsigned short* WTF2F  = CATCL2 + 279552;                        // 9,216
    unsigned short* WOUTF  = WTF2F + 9216;                           // 9,216
    unsigned short* WUP1F  = WOUTF + 9216;                           // 18,432
    unsigned short* WUP2F  = WUP1F + 18432;                          // 18,432

    const int bpc160 = 25;
    const int bpc80_128 = 13;
    const int bpc40_64  = 7;
    const int bpc20_64  = 2;

    // prep (merged) + conv_a fused to bf16 channel-last (row-wise v2)
    prep_k<<<nblk(27648 + 4032 + 14 * 644 + 55296 + 9216 + 9216 + 18432 + 18432), TPB, 0, stream>>>(
        w_tf3b, w_dc, w_om, w_tf2, w_out, w_up1a, w_up2a,
        WBF, WOMF, WTF2F, WOUTF, WUP1F, WUP2F, WT2, XACL);
    conv3da_cl_k<<<B * 7 * 160, TPB, 0, stream>>>(inputs, w_tf3a, b_tf3a, XACL, B, H, W);

    // --- 2D U-Net branch ---
    conv2d_c4_k<1, 0, 0><<<B * 8 * bpc160, TPB, 0, stream>>>(inputs, nullptr, w_in, b_in, nullptr, F0, B, 7, 160, 160, nf, 8, bpc160);
    conv2d_s2_t4_k<128><<<B * nf * bpc80_128, 128, 0, stream>>>(F0, w_dn1a, b_dn1a, TMP80, B, nf, 160, 160, nf, bpc80_128);
    conv2d_t4_k<128, 1, 0><<<B * nf * bpc80_128, 128, 0, stream>>>(TMP80, w_dn1b, b_dn1b, nullptr, F1, B, nf, 80, 80, nf, bpc80_128);
    conv2d_s2_t4_k<64><<<B * nf * bpc40_64, 64, 0, stream>>>(F1, w_dn2a, b_dn2a, TMP40, B, nf, 80, 80, nf, bpc40_64);
    conv2d_t4_k<64, 1, 0><<<B * nf * bpc40_64, 64, 0, stream>>>(TMP40, w_dn2b, b_dn2b, nullptr, F2, B, nf, 40, 40, nf, bpc40_64);
    conv2d_s2_t4_k<64><<<B * nf * bpc20_64, 64, 0, stream>>>(F2, w_tra, b_tra, T20A, B, nf, 40, 40, nf, bpc20_64);
    conv2d_t4_k<64, 1, 0><<<B * nf * bpc20_64, 64, 0, stream>>>(T20A, w_trb, b_trb, nullptr, T20B, B, nf, 20, 20, nf, bpc20_64);
    convt2d_t4_k<64><<<B * nf * bpc40_64, 64, 0, stream>>>(T20B, wt_tr, bt_tr, T40, B, nf, 20, 20, bpc40_64);
    // up2a concat conv via MFMA (40-level, padded width 52)
    cat2cl_k<40, 40, 42, 52><<<nblk(2 * 42 * 52), TPB, 0, stream>>>(T40, F2, CATCL2);
    conv_up2a_mfma_k<<<B * 60, TPB, 0, stream>>>(CATCL2, WUP2F, b_up2a, T40B, B);
    convt2d_t4_k<128><<<B * nf * bpc80_128, 128, 0, stream>>>(T40B, wt_up2, bt_up2, T80, B, nf, 40, 40, bpc80_128);
    // up1a concat conv via MFMA
    cat2cl_k<80, 80, 82, 82><<<nblk(2 * 82 * 82), TPB, 0, stream>>>(T80, F1, CATCL);
    conv_up1a_mfma_k<<<B * 200, TPB, 0, stream>>>(CATCL, WUP1F, b_up1a, T80B, B);
    convt2d_c4_k<<<B * 8 * bpc160, TPB, 0, stream>>>(T80B, wt_up1, bt_up1, T160, B, nf, 80, 80, bpc160);

    // --- conv3d_b + relu + mean (bf16 MFMA) -> F0 ---
    conv3db_mfma_k<<<B * 800, TPB, 0, stream>>>(XACL, WBF, b_tf3b, F0, B, H, W);
    // FUSED = relu(conv_tf2(MEAN) + T160)  [MFMA]
    o2cl_k<<<nblk(2 * 26244), TPB, 0, stream>>>(F0, MCL);
    conv_nf_mfma_k<1, 1><<<B * 800, TPB, 0, stream>>>(MCL, WTF2F, b_tf2, T160, TF, B);

    // --- offset/mask head: w_out MFMA -> F0; o2cl; w_om MFMA ---
    o2cl_k<<<nblk(2 * 26244), TPB, 0, stream>>>(TF, TCL);
    conv_nf_mfma_k<0, 1><<<B * 800, TPB, 0, stream>>>(TCL, WOUTF, b_out, nullptr, F0, B);
    o2cl_k<<<nblk(2 * 26244), TPB, 0, stream>>>(F0, OCL);
    conv_om_mfma_k<<<B * 1600, TPB, 0, stream>>>(OCL, WOMF, b_om, OM, B);

    // --- deformable conv (two-phase) ---
    deform_conv2_k<<<B * (H * W / 64), TPB, 0, stream>>>(inputs, OM, WT2, b_dc, out, B, H, W);
}

// Round 22
// 433.192 us; speedup vs baseline: 2.2766x; 1.0349x over previous
//
#include <hip/hip_runtime.h>
#include <math.h>

// ---------------------------------------------------------------------------
// STDF forward, round 22: conv3db_mfma A-load hoisting (j2-outer/dz-inner:
// each A fragment loaded once, feeds up to 3 MFMAs; 171 -> 63 A-loads/wave,
// VGPR down). Everything else identical to round 21 (448us verified).
// ---------------------------------------------------------------------------

#define TPB 256

static inline int nblk(long long total) { return (int)((total + TPB - 1) / TPB); }

typedef short bf16x8 __attribute__((ext_vector_type(8)));
typedef float f32x4 __attribute__((ext_vector_type(4)));

__device__ __forceinline__ unsigned short f2bf(float f) {
    unsigned int u = __float_as_uint(f);
    unsigned int r = u + 0x7FFFu + ((u >> 16) & 1u);   // RNE
    return (unsigned short)(r >> 16);
}

// ---------------- 3x3 conv2d, stride 1, 4 outputs/thread, block-uniform co --
template <int TB, int RELU, int HAS_RES>
__global__ __launch_bounds__(TB) void conv2d_t4_k(
    const float* __restrict__ in, const float* __restrict__ w,
    const float* __restrict__ bias, const float* __restrict__ res,
    float* __restrict__ out, int B, int Ci, int H, int W, int Co, int BPC) {
    __shared__ float ws_w[32 * 9];
    int co = (blockIdx.x / BPC) % Co;
    int b  = blockIdx.x / (BPC * Co);
    for (int i = threadIdx.x; i < Ci * 9; i += TB)
        ws_w[i] = w[(size_t)co * Ci * 9 + i];
    __syncthreads();
    int nq = W >> 2;
    int r = (blockIdx.x % BPC) * TB + threadIdx.x;
    if (r >= H * nq) return;
    int q = r % nq, ho = r / nq;
    int wb = q * 4;
    float bv = bias[co];
    float a0 = bv, a1 = bv, a2 = bv, a3 = bv;
    const float* ipb = in + (size_t)b * Ci * H * W;
    for (int ci = 0; ci < Ci; ++ci) {
        const float* ip = ipb + (size_t)ci * H * W;
        const float* wc = ws_w + ci * 9;
#pragma unroll
        for (int kh = 0; kh < 3; ++kh) {
            int y = ho - 1 + kh;
            if (y < 0 || y >= H) continue;
            const float* row = ip + (size_t)y * W + wb;
            float4 xv = *(const float4*)row;
            float xm = (wb > 0) ? row[-1] : 0.f;
            float xp = (wb + 4 < W) ? row[4] : 0.f;
            float w0 = wc[kh * 3], w1 = wc[kh * 3 + 1], w2 = wc[kh * 3 + 2];
            a0 += xm   * w0 + xv.x * w1 + xv.y * w2;
            a1 += xv.x * w0 + xv.y * w1 + xv.z * w2;
            a2 += xv.y * w0 + xv.z * w1 + xv.w * w2;
            a3 += xv.z * w0 + xv.w * w1 + xp   * w2;
        }
    }
    size_t o = ((size_t)(b * Co + co) * H + ho) * W + wb;
    if (HAS_RES) {
        float4 rv = *(const float4*)(res + o);
        a0 += rv.x; a1 += rv.y; a2 += rv.z; a3 += rv.w;
    }
    if (RELU) { a0 = fmaxf(a0, 0.f); a1 = fmaxf(a1, 0.f); a2 = fmaxf(a2, 0.f); a3 = fmaxf(a3, 0.f); }
    *(float4*)(out + o) = make_float4(a0, a1, a2, a3);
}

// ------- 3x3 conv2d, stride 1, 4 outputs x 4 co per thread -----------------
template <int RELU, int HAS_RES, int HAS_IN2>
__global__ __launch_bounds__(TPB) void conv2d_c4_k(
    const float* __restrict__ in, const float* __restrict__ in2,
    const float* __restrict__ w, const float* __restrict__ bias,
    const float* __restrict__ res, float* __restrict__ out,
    int B, int Ci, int H, int W, int Co, int COG, int BPC) {
    __shared__ float ws_w[4 * 32 * 9];
    int cog = (blockIdx.x / BPC) % COG;
    int b   = blockIdx.x / (BPC * COG);
    int co0 = cog * 4;
    int nw = Ci * 9;
    for (int i = threadIdx.x; i < 4 * nw; i += TPB) {
        int cr = i / nw; int co = co0 + cr;
        ws_w[i] = (co < Co) ? w[(size_t)co * nw + (i - cr * nw)] : 0.f;
    }
    __syncthreads();
    int nq = W >> 2;
    int r = (blockIdx.x % BPC) * TPB + threadIdx.x;
    if (r >= H * nq) return;
    int q = r % nq, ho = r / nq;
    int wb = q * 4;
    float a[4][4];
#pragma unroll
    for (int cr = 0; cr < 4; ++cr) {
        float bv = (co0 + cr < Co) ? bias[co0 + cr] : 0.f;
        a[cr][0] = bv; a[cr][1] = bv; a[cr][2] = bv; a[cr][3] = bv;
    }
    const float* ipb = in + (size_t)b * Ci * H * W;
    const float* ipb2 = HAS_IN2 ? in2 + (size_t)b * Ci * H * W : nullptr;
    for (int ci = 0; ci < Ci; ++ci) {
        const float* ip = ipb + (size_t)ci * H * W;
        const float* ip2 = HAS_IN2 ? ipb2 + (size_t)ci * H * W : nullptr;
#pragma unroll
        for (int kh = 0; kh < 3; ++kh) {
            int y = ho - 1 + kh;
            if (y < 0 || y >= H) continue;
            const float* row = ip + (size_t)y * W + wb;
            float4 xv = *(const float4*)row;
            float x_[6];
            x_[0] = (wb > 0) ? row[-1] : 0.f;
            x_[5] = (wb + 4 < W) ? row[4] : 0.f;
            if (HAS_IN2) {
                const float* row2 = ip2 + (size_t)y * W + wb;
                float4 x2 = *(const float4*)row2;
                xv.x += x2.x; xv.y += x2.y; xv.z += x2.z; xv.w += x2.w;
                if (wb > 0) x_[0] += row2[-1];
                if (wb + 4 < W) x_[5] += row2[4];
            }
            x_[1] = xv.x; x_[2] = xv.y; x_[3] = xv.z; x_[4] = xv.w;
#pragma unroll
            for (int cr = 0; cr < 4; ++cr) {
                const float* wc = ws_w + cr * nw + ci * 9 + kh * 3;
                float w0 = wc[0], w1 = wc[1], w2 = wc[2];
                a[cr][0] += x_[0] * w0 + x_[1] * w1 + x_[2] * w2;
                a[cr][1] += x_[1] * w0 + x_[2] * w1 + x_[3] * w2;
                a[cr][2] += x_[2] * w0 + x_[3] * w1 + x_[4] * w2;
                a[cr][3] += x_[3] * w0 + x_[4] * w1 + x_[5] * w2;
            }
        }
    }
#pragma unroll
    for (int cr = 0; cr < 4; ++cr) {
        int co = co0 + cr;
        if (co >= Co) break;
        size_t o = ((size_t)(b * Co + co) * H + ho) * W + wb;
        float a0 = a[cr][0], a1 = a[cr][1], a2 = a[cr][2], a3 = a[cr][3];
        if (HAS_RES) {
            float4 rv = *(const float4*)(res + o);
            a0 += rv.x; a1 += rv.y; a2 += rv.z; a3 += rv.w;
        }
        if (RELU) { a0 = fmaxf(a0, 0.f); a1 = fmaxf(a1, 0.f); a2 = fmaxf(a2, 0.f); a3 = fmaxf(a3, 0.f); }
        *(float4*)(out + o) = make_float4(a0, a1, a2, a3);
    }
}

// ------------- 3x3 conv2d, stride 2, 4 outputs/thread, relu ----------------
template <int TB>
__global__ __launch_bounds__(TB) void conv2d_s2_t4_k(
    const float* __restrict__ in, const float* __restrict__ w,
    const float* __restrict__ bias, float* __restrict__ out,
    int B, int Ci, int Hi, int Wi, int Co, int BPC) {
    __shared__ float ws_w[32 * 9];
    int Ho = Hi >> 1, Wo = Wi >> 1;
    int co = (blockIdx.x / BPC) % Co;
    int b  = blockIdx.x / (BPC * Co);
    for (int i = threadIdx.x; i < Ci * 9; i += TB)
        ws_w[i] = w[(size_t)co * Ci * 9 + i];
    __syncthreads();
    int nq = Wo >> 2;
    int r = (blockIdx.x % BPC) * TB + threadIdx.x;
    if (r >= Ho * nq) return;
    int q = r % nq, ho = r / nq;
    int wb = q * 4;
    float bv = bias[co];
    float a0 = bv, a1 = bv, a2 = bv, a3 = bv;
    const float* ipb = in + (size_t)b * Ci * Hi * Wi;
    for (int ci = 0; ci < Ci; ++ci) {
        const float* ip = ipb + (size_t)ci * Hi * Wi;
        const float* wc = ws_w + ci * 9;
#pragma unroll
        for (int kh = 0; kh < 3; ++kh) {
            int y = 2 * ho - 1 + kh;
            if (y < 0 || y >= Hi) continue;
            const float* row = ip + (size_t)y * Wi;
            float z0 = (2 * wb - 1 >= 0) ? row[2 * wb - 1] : 0.f;
            float4 za = *(const float4*)(row + 2 * wb);
            float4 zb = *(const float4*)(row + 2 * wb + 4);
            float w0 = wc[kh * 3], w1 = wc[kh * 3 + 1], w2 = wc[kh * 3 + 2];
            a0 += z0   * w0 + za.x * w1 + za.y * w2;
            a1 += za.y * w0 + za.z * w1 + za.w * w2;
            a2 += za.w * w0 + zb.x * w1 + zb.y * w2;
            a3 += zb.y * w0 + zb.z * w1 + zb.w * w2;
        }
    }
    size_t o = ((size_t)(b * Co + co) * Ho + ho) * Wo + wb;
    *(float4*)(out + o) = make_float4(fmaxf(a0, 0.f), fmaxf(a1, 0.f), fmaxf(a2, 0.f), fmaxf(a3, 0.f));
}

// ------------- transposed conv 4x4 stride 2, 4 outputs/thread, relu --------
template <int TB>
__global__ __launch_bounds__(TB) void convt2d_t4_k(
    const float* __restrict__ in, const float* __restrict__ wt,
    const float* __restrict__ bias, float* __restrict__ out,
    int B, int C, int Hi, int Wi, int BPC) {
    __shared__ float ws_w[32 * 16];
    int Ho = 2 * Hi, Wo = 2 * Wi;
    int co = (blockIdx.x / BPC) % C;
    int b  = blockIdx.x / (BPC * C);
    for (int i = threadIdx.x; i < C * 16; i += TB) {
        int ci = i >> 4, t = i & 15;
        ws_w[i] = wt[((size_t)ci * C + co) * 16 + t];
    }
    __syncthreads();
    int nq = Wo >> 2;
    int r = (blockIdx.x % BPC) * TB + threadIdx.x;
    if (r >= Ho * nq) return;
    int q = r % nq, ho = r / nq;
    int wb = q * 4;
    int p = ho & 1;
    int iy0 = (ho + p) / 2 - 1;
    int iy1 = iy0 + 1;
    int ix0 = wb / 2 - 1;
    bool vy0 = (iy0 >= 0) && (iy0 < Hi);
    bool vy1 = (iy1 >= 0) && (iy1 < Hi);
    float bv = bias[co];
    float a0 = bv, a1 = bv, a2 = bv, a3 = bv;
    const float* ipb = in + (size_t)b * C * Hi * Wi;
    for (int ci = 0; ci < C; ++ci) {
        const float* ip = ipb + (size_t)ci * Hi * Wi;
        float u0 = 0, u1 = 0, u2 = 0, u3 = 0, v0 = 0, v1 = 0, v2 = 0, v3 = 0;
        if (vy0) {
            const float* rw = ip + (size_t)iy0 * Wi;
            if (ix0 >= 0) u0 = rw[ix0];
            u1 = rw[ix0 + 1]; u2 = rw[ix0 + 2];
            if (ix0 + 3 < Wi) u3 = rw[ix0 + 3];
        }
        if (vy1) {
            const float* rw = ip + (size_t)iy1 * Wi;
            if (ix0 >= 0) v0 = rw[ix0];
            v1 = rw[ix0 + 1]; v2 = rw[ix0 + 2];
            if (ix0 + 3 < Wi) v3 = rw[ix0 + 3];
        }
        const float* wr0 = ws_w + ci * 16 + (3 - p) * 4;
        const float* wr1 = ws_w + ci * 16 + (1 - p) * 4;
        a0 += u0 * wr0[3] + u1 * wr0[1] + v0 * wr1[3] + v1 * wr1[1];
        a1 += u1 * wr0[2] + u2 * wr0[0] + v1 * wr1[2] + v2 * wr1[0];
        a2 += u1 * wr0[3] + u2 * wr0[1] + v1 * wr1[3] + v2 * wr1[1];
        a3 += u2 * wr0[2] + u3 * wr0[0] + v2 * wr1[2] + v3 * wr1[0];
    }
    size_t o = ((size_t)(b * C + co) * Ho + ho) * Wo + wb;
    *(float4*)(out + o) = make_float4(fmaxf(a0, 0.f), fmaxf(a1, 0.f), fmaxf(a2, 0.f), fmaxf(a3, 0.f));
}

// ------------- transposed conv 4x4 stride 2, 4 outputs x 4 co/thread -------
__global__ __launch_bounds__(TPB) void convt2d_c4_k(
    const float* __restrict__ in, const float* __restrict__ wt,
    const float* __restrict__ bias, float* __restrict__ out,
    int B, int C, int Hi, int Wi, int BPC) {
    __shared__ float ws_w[4][32 * 16];
    int Ho = 2 * Hi, Wo = 2 * Wi;
    int cog = (blockIdx.x / BPC) % (C / 4);
    int b   = blockIdx.x / (BPC * (C / 4));
    int co0 = cog * 4;
    for (int i = threadIdx.x; i < 4 * C * 16; i += TPB) {
        int cr = i / (C * 16); int j = i % (C * 16);
        int ci = j >> 4, t = j & 15;
        ws_w[cr][j] = wt[((size_t)ci * C + (co0 + cr)) * 16 + t];
    }
    __syncthreads();
    int nq = Wo >> 2;
    int r = (blockIdx.x % BPC) * TPB + threadIdx.x;
    if (r >= Ho * nq) return;
    int q = r % nq, ho = r / nq;
    int wb = q * 4;
    int p = ho & 1;
    int iy0 = (ho + p) / 2 - 1;
    int iy1 = iy0 + 1;
    int ix0 = wb / 2 - 1;
    bool vy0 = (iy0 >= 0) && (iy0 < Hi);
    bool vy1 = (iy1 >= 0) && (iy1 < Hi);
    float a[4][4];
#pragma unroll
    for (int cr = 0; cr < 4; ++cr) {
        float bv = bias[co0 + cr];
        a[cr][0] = bv; a[cr][1] = bv; a[cr][2] = bv; a[cr][3] = bv;
    }
    const float* ipb = in + (size_t)b * C * Hi * Wi;
    for (int ci = 0; ci < C; ++ci) {
        const float* ip = ipb + (size_t)ci * Hi * Wi;
        float u0 = 0, u1 = 0, u2 = 0, u3 = 0, v0 = 0, v1 = 0, v2 = 0, v3 = 0;
        if (vy0) {
            const float* rw = ip + (size_t)iy0 * Wi;
            if (ix0 >= 0) u0 = rw[ix0];
            u1 = rw[ix0 + 1]; u2 = rw[ix0 + 2];
            if (ix0 + 3 < Wi) u3 = rw[ix0 + 3];
        }
        if (vy1) {
            const float* rw = ip + (size_t)iy1 * Wi;
            if (ix0 >= 0) v0 = rw[ix0];
            v1 = rw[ix0 + 1]; v2 = rw[ix0 + 2];
            if (ix0 + 3 < Wi) v3 = rw[ix0 + 3];
        }
#pragma unroll
        for (int cr = 0; cr < 4; ++cr) {
            const float* wr0 = ws_w[cr] + ci * 16 + (3 - p) * 4;
            const float* wr1 = ws_w[cr] + ci * 16 + (1 - p) * 4;
            a[cr][0] += u0 * wr0[3] + u1 * wr0[1] + v0 * wr1[3] + v1 * wr1[1];
            a[cr][1] += u1 * wr0[2] + u2 * wr0[0] + v1 * wr1[2] + v2 * wr1[0];
            a[cr][2] += u1 * wr0[3] + u2 * wr0[1] + v1 * wr1[3] + v2 * wr1[1];
            a[cr][3] += u2 * wr0[2] + u3 * wr0[0] + v2 * wr1[2] + v3 * wr1[0];
        }
    }
#pragma unroll
    for (int cr = 0; cr < 4; ++cr) {
        size_t o = ((size_t)(b * C + co0 + cr) * Ho + ho) * Wo + wb;
        *(float4*)(out + o) = make_float4(fmaxf(a[cr][0], 0.f), fmaxf(a[cr][1], 0.f),
                                          fmaxf(a[cr][2], 0.f), fmaxf(a[cr][3], 0.f));
    }
}

// ---- merged prep: all B-fragment packs + wdc transpose + XACL border zero --
__global__ void prep_k(const float* __restrict__ wb, const float* __restrict__ wdc,
                       const float* __restrict__ wom, const float* __restrict__ wtf2,
                       const float* __restrict__ wout, const float* __restrict__ wup1a,
                       const float* __restrict__ wup2a,
                       unsigned short* __restrict__ wbf, unsigned short* __restrict__ womf,
                       unsigned short* __restrict__ wtf2f, unsigned short* __restrict__ woutf,
                       unsigned short* __restrict__ wup1f, unsigned short* __restrict__ wup2f,
                       float* __restrict__ wt2, unsigned short* __restrict__ xacl) {
    int i = blockIdx.x * TPB + threadIdx.x;
    if (i < 27648) {                          // conv3db B-frags
        int j = i & 7;
        int l = (i >> 3) & 63;
        int coH = (i >> 9) & 1;
        int tap = i >> 10;
        int ci = ((l >> 4) << 3) + j;
        int co = (coH << 4) + (l & 15);
        wbf[i] = f2bf(wb[(size_t)(co * 32 + ci) * 27 + tap]);
        return;
    }
    int i2 = i - 27648;
    if (i2 < 4032) {                          // deform weight transpose
        int o = i2 & 63, ck = i2 >> 6;
        wt2[i2] = wdc[o * 63 + ck];
        return;
    }
    int i3 = i2 - 4032;
    if (i3 < 14 * 644) {                      // XACL border zero (14 bd-planes)
        int pl = i3 / 644, e = i3 % 644;
        int off;
        if (e < 162)      off = e;
        else if (e < 324) off = 161 * 162 + (e - 162);
        else if (e < 484) off = (e - 324 + 1) * 162;
        else              off = (e - 484 + 1) * 162 + 161;
        uint4* d = (uint4*)(xacl + ((size_t)pl * 26244 + off) * 32);
        uint4 z = make_uint4(0, 0, 0, 0);
        d[0] = z; d[1] = z; d[2] = z; d[3] = z;
        return;
    }
    int i4 = i3 - 14 * 644;
    if (i4 < 55296) {                         // w_om B-frags [tap][nt12][l][8]
        int j = i4 & 7;
        int l = (i4 >> 3) & 63;
        int nt = (i4 >> 9) % 12;
        int tap = i4 / 6144;
        int ci = ((l >> 4) << 3) + j;
        int co = nt * 16 + (l & 15);
        womf[i4] = (co < 189) ? f2bf(wom[((size_t)co * 32 + ci) * 9 + tap]) : (unsigned short)0;
        return;
    }
    int i5 = i4 - 55296;
    if (i5 < 9216) {                          // tf2 B-frags [tap][coH][l][8]
        int j = i5 & 7;
        int l = (i5 >> 3) & 63;
        int q = i5 >> 9;
        int coH = q & 1, tap = q >> 1;
        int ci = ((l >> 4) << 3) + j;
        int co = coH * 16 + (l & 15);
        wtf2f[i5] = f2bf(wtf2[((size_t)co * 32 + ci) * 9 + tap]);
        return;
    }
    int i6 = i5 - 9216;
    if (i6 < 9216) {                          // w_out B-frags
        int j = i6 & 7;
        int l = (i6 >> 3) & 63;
        int q = i6 >> 9;
        int coH = q & 1, tap = q >> 1;
        int ci = ((l >> 4) << 3) + j;
        int co = coH * 16 + (l & 15);
        woutf[i6] = f2bf(wout[((size_t)co * 32 + ci) * 9 + tap]);
        return;
    }
    int i7 = i6 - 9216;
    if (i7 < 18432) {                         // up1a B-frags [tap][kc][coH][l][8]
        int j = i7 & 7;
        int l = (i7 >> 3) & 63;
        int q = i7 >> 9;
        int coH = q & 1, kc = (q >> 1) & 1, tap = q >> 2;
        int ci = kc * 32 + ((l >> 4) << 3) + j;
        int co = coH * 16 + (l & 15);
        wup1f[i7] = f2bf(wup1a[((size_t)co * 64 + ci) * 9 + tap]);
        return;
    }
    int i8 = i7 - 18432;
    if (i8 >= 18432) return;                  // up2a B-frags, same layout
    int j = i8 & 7;
    int l = (i8 >> 3) & 63;
    int q = i8 >> 9;
    int coH = q & 1, kc = (q >> 1) & 1, tap = q >> 2;
    int ci = kc * 32 + ((l >> 4) << 3) + j;
    int co = coH * 16 + (l & 15);
    wup2f[i8] = f2bf(wup2a[((size_t)co * 64 + ci) * 9 + tap]);
}

// ---- conv3d_a fused v2: row-wise blocks (weights+window staged once) -------
__global__ __launch_bounds__(TPB) void conv3da_cl_k(
    const float* __restrict__ x, const float* __restrict__ wa,
    const float* __restrict__ ba, unsigned short* __restrict__ xacl,
    int B, int H, int W) {
    __shared__ float xin[3 * 3 * 162];
    __shared__ float wsa[864];
    int blk = blockIdx.x;
    int y  = blk % 160;
    int d  = (blk / 160) % 7;
    int b  = blk / 1120;
    int tid = threadIdx.x;
    for (int i = tid; i < 3 * 3 * 162; i += TPB) {
        int xx = i % 162; int t = i / 162; int yy = t % 3; int dz = t / 3;
        int gd = d - 1 + dz, gy = y - 1 + yy, gx = xx - 1;
        float v = 0.f;
        if (gd >= 0 && gd < 7 && gy >= 0 && gy < H && gx >= 0 && gx < W)
            v = x[((size_t)(b * 7 + gd)) * H * W + (size_t)gy * W + gx];
        xin[i] = v;
    }
    for (int i = tid; i < 864; i += TPB) wsa[i] = wa[i];
    __syncthreads();
    int co = tid & 31;
    int xi0 = tid >> 5;
    float bv = ba[co];
    const float* wc = wsa + co * 27;
    size_t rowbase = (((size_t)(b * 7 + d) * 162 + (y + 1)) * 162 + 1) * 32 + co;
    for (int k = 0; k < 20; ++k) {
        int gx = k * 8 + xi0;
        float acc = bv;
#pragma unroll
        for (int dz = 0; dz < 3; ++dz)
#pragma unroll
            for (int yy = 0; yy < 3; ++yy)
#pragma unroll
                for (int kw = 0; kw < 3; ++kw)
                    acc += xin[dz * 486 + yy * 162 + gx + kw] * wc[dz * 9 + yy * 3 + kw];
        xacl[rowbase + (size_t)gx * 32] = f2bf(fmaxf(acc, 0.f));
    }
}

// ---- 32ch fp32 ch-first 160x160 -> bf16 CL 162x162 padded ------------------
__global__ __launch_bounds__(TPB) void o2cl_k(
    const float* __restrict__ o, unsigned short* __restrict__ ocl) {
    int idx = blockIdx.x * TPB + threadIdx.x;
    if (idx >= 2 * 26244) return;
    int pos = idx % 26244;
    int b = idx / 26244;
    int y = pos / 162, x = pos % 162;
    uint4* dst = (uint4*)(ocl + (size_t)idx * 32);
    if (y == 0 || y == 161 || x == 0 || x == 161) {
        uint4 z = make_uint4(0, 0, 0, 0);
        dst[0] = z; dst[1] = z; dst[2] = z; dst[3] = z;
        return;
    }
    unsigned int pk[16];
    const float* src = o + (size_t)b * 32 * 25600 + (size_t)(y - 1) * 160 + (x - 1);
#pragma unroll
    for (int j = 0; j < 16; ++j) {
        float v0 = src[(size_t)(2 * j) * 25600];
        float v1 = src[(size_t)(2 * j + 1) * 25600];
        pk[j] = (unsigned int)f2bf(v0) | ((unsigned int)f2bf(v1) << 16);
    }
    dst[0] = make_uint4(pk[0], pk[1], pk[2], pk[3]);
    dst[1] = make_uint4(pk[4], pk[5], pk[6], pk[7]);
    dst[2] = make_uint4(pk[8], pk[9], pk[10], pk[11]);
    dst[3] = make_uint4(pk[12], pk[13], pk[14], pk[15]);
}

// ---- concat fp32 ch-first -> bf16 CL padded: generic (PW wide, HxW valid) --
template <int HH, int WW, int PH, int PW>
__global__ __launch_bounds__(TPB) void cat2cl_k(
    const float* __restrict__ a, const float* __restrict__ c2,
    unsigned short* __restrict__ dst) {
    int idx = blockIdx.x * TPB + threadIdx.x;
    if (idx >= 2 * PH * PW) return;
    int pos = idx % (PH * PW);
    int b = idx / (PH * PW);
    int y = pos / PW, x = pos % PW;
    uint4* d = (uint4*)(dst + (size_t)idx * 64);
    if (y == 0 || y > HH || x == 0 || x > WW) {
        uint4 z = make_uint4(0, 0, 0, 0);
#pragma unroll
        for (int k = 0; k < 8; ++k) d[k] = z;
        return;
    }
    size_t off = (size_t)(y - 1) * WW + (x - 1);
    const float* sa = a + (size_t)b * 32 * (HH * WW) + off;
    const float* sc = c2 + (size_t)b * 32 * (HH * WW) + off;
    unsigned int pk[32];
#pragma unroll
    for (int j = 0; j < 16; ++j) {
        float v0 = sa[(size_t)(2 * j) * (HH * WW)];
        float v1 = sa[(size_t)(2 * j + 1) * (HH * WW)];
        pk[j] = (unsigned int)f2bf(v0) | ((unsigned int)f2bf(v1) << 16);
    }
#pragma unroll
    for (int j = 0; j < 16; ++j) {
        float v0 = sc[(size_t)(2 * j) * (HH * WW)];
        float v1 = sc[(size_t)(2 * j + 1) * (HH * WW)];
        pk[16 + j] = (unsigned int)f2bf(v0) | ((unsigned int)f2bf(v1) << 16);
    }
#pragma unroll
    for (int k = 0; k < 8; ++k)
        d[k] = make_uint4(pk[4 * k], pk[4 * k + 1], pk[4 * k + 2], pk[4 * k + 3]);
}

// ---- conv3d_b + relu + mean as bf16 MFMA (A-load hoisted, r22) -------------
__global__ __launch_bounds__(TPB) void conv3db_mfma_k(
    const unsigned short* __restrict__ xacl, const unsigned short* __restrict__ wbf,
    const float* __restrict__ bb, float* __restrict__ out, int B, int H, int W) {
    int blk = blockIdx.x;
    int b = blk / 800;
    int rem = blk % 800;
    int y = rem / 5;
    int xp = rem % 5;
    int tid = threadIdx.x;
    int l = tid & 63;
    int wv = tid >> 6;
    int mt = wv & 1, coH = wv >> 1;
    int x0 = xp * 32 + mt * 16;
    int co = coH * 16 + (l & 15);
    float bv = bb[co];
    f32x4 acc[7];
#pragma unroll
    for (int d = 0; d < 7; ++d) { acc[d][0] = bv; acc[d][1] = bv; acc[d][2] = bv; acc[d][3] = bv; }

    int ubase = (y * 162 + x0 + (l & 15)) * 32 + ((l >> 4) << 3);
    const unsigned short* xb = xacl + (size_t)b * 5878656;
    const unsigned short* wbase = wbf + ((size_t)coH * 64 + l) * 8;

    // j2-outer / dz-inner: each A fragment loaded ONCE, feeds up to 3 MFMAs
    // (original mapping: acc[d] uses dz = d + kd - 1, kd = 0,1,2).
    for (int j2 = 0; j2 < 9; ++j2) {
        int off2 = (j2 / 3) * 5184 + (j2 % 3) * 32;
        bf16x8 bf0 = *reinterpret_cast<const bf16x8*>(wbase + (size_t)(0 * 9 + j2) * 1024);
        bf16x8 bf1 = *reinterpret_cast<const bf16x8*>(wbase + (size_t)(1 * 9 + j2) * 1024);
        bf16x8 bf2 = *reinterpret_cast<const bf16x8*>(wbase + (size_t)(2 * 9 + j2) * 1024);
#pragma unroll
        for (int dz = 0; dz < 7; ++dz) {
            bf16x8 af = *reinterpret_cast<const bf16x8*>(xb + (size_t)dz * 839808 + ubase + off2);
            if (dz + 1 < 7) acc[dz + 1] = __builtin_amdgcn_mfma_f32_16x16x32_bf16(af, bf0, acc[dz + 1], 0, 0, 0);
            acc[dz] = __builtin_amdgcn_mfma_f32_16x16x32_bf16(af, bf1, acc[dz], 0, 0, 0);
            if (dz - 1 >= 0) acc[dz - 1] = __builtin_amdgcn_mfma_f32_16x16x32_bf16(af, bf2, acc[dz - 1], 0, 0, 0);
        }
    }

    int xo = x0 + ((l >> 4) << 2);
    size_t obase = ((size_t)(b * 32 + co)) * 25600 + (size_t)y * 160 + xo;
#pragma unroll
    for (int r = 0; r < 4; ++r) {
        float s = 0.f;
#pragma unroll
        for (int d = 0; d < 7; ++d) s += fmaxf(acc[d][r], 0.f);
        out[obase + r] = s * (1.f / 7.f);
    }
}

// ---- N=32 K=288 160-level conv as bf16 MFMA (tf2 / w_out) ------------------
template <int HAS_RES, int RELU>
__global__ __launch_bounds__(TPB) void conv_nf_mfma_k(
    const unsigned short* __restrict__ icl, const unsigned short* __restrict__ wf,
    const float* __restrict__ bias, const float* __restrict__ res,
    float* __restrict__ out, int B) {
    int blk = blockIdx.x;
    int b = blk / 800;
    int rem = blk % 800;
    int y = rem / 5;
    int xp = rem % 5;
    int tid = threadIdx.x;
    int l = tid & 63;
    int wv = tid >> 6;
    int mt = wv & 1, coH = wv >> 1;
    int x0 = xp * 32 + mt * 16;
    int co = coH * 16 + (l & 15);
    float bv = bias[co];
    f32x4 acc;
    acc[0] = bv; acc[1] = bv; acc[2] = bv; acc[3] = bv;
    int ubase = (y * 162 + x0 + (l & 15)) * 32 + ((l >> 4) << 3);
    const unsigned short* ib = icl + (size_t)b * 839808;
    const unsigned short* wl = wf + (size_t)l * 8;
#pragma unroll
    for (int tap = 0; tap < 9; ++tap) {
        int off = ((tap / 3) * 162 + (tap % 3)) * 32;
        bf16x8 af = *reinterpret_cast<const bf16x8*>(ib + ubase + off);
        bf16x8 bf = *reinterpret_cast<const bf16x8*>(wl + (size_t)(tap * 2 + coH) * 512);
        acc = __builtin_amdgcn_mfma_f32_16x16x32_bf16(af, bf, acc, 0, 0, 0);
    }
    int xo = x0 + ((l >> 4) << 2);
    size_t obase = ((size_t)(b * 32 + co)) * 25600 + (size_t)y * 160 + xo;
#pragma unroll
    for (int r = 0; r < 4; ++r) {
        float v = acc[r];
        if (HAS_RES) v += res[obase + r];
        if (RELU) v = fmaxf(v, 0.f);
        out[obase + r] = v;
    }
}

// ---- up1a concat conv as bf16 MFMA: M=80x80, N=32, K=576 -------------------
__global__ __launch_bounds__(TPB) void conv_up1a_mfma_k(
    const unsigned short* __restrict__ catcl, const unsigned short* __restrict__ wf,
    const float* __restrict__ bias, float* __restrict__ out, int B) {
    int blk = blockIdx.x;
    int b = blk / 200;
    int rem = blk % 200;
    int tid = threadIdx.x;
    int l = tid & 63;
    int wv = tid >> 6;
    int mtile = rem * 2 + (wv & 1);
    int coH = wv >> 1;
    int y = mtile / 5, x0 = (mtile % 5) * 16;
    int co = coH * 16 + (l & 15);
    float bv = bias[co];
    f32x4 acc;
    acc[0] = bv; acc[1] = bv; acc[2] = bv; acc[3] = bv;
    int ubase = (y * 82 + x0 + (l & 15)) * 64 + ((l >> 4) << 3);
    const unsigned short* cb = catcl + (size_t)b * 430336;
    const unsigned short* wl = wf + (size_t)l * 8;
#pragma unroll
    for (int tap = 0; tap < 9; ++tap) {
        int off = ((tap / 3) * 82 + (tap % 3)) * 64;
#pragma unroll
        for (int kc = 0; kc < 2; ++kc) {
            bf16x8 af = *reinterpret_cast<const bf16x8*>(cb + ubase + off + kc * 32);
            bf16x8 bf = *reinterpret_cast<const bf16x8*>(wl + (size_t)(((tap * 2 + kc) * 2 + coH)) * 512);
            acc = __builtin_amdgcn_mfma_f32_16x16x32_bf16(af, bf, acc, 0, 0, 0);
        }
    }
    int xo = x0 + ((l >> 4) << 2);
    size_t obase = ((size_t)(b * 32 + co)) * 6400 + (size_t)y * 80 + xo;
#pragma unroll
    for (int r = 0; r < 4; ++r)
        out[obase + r] = fmaxf(acc[r], 0.f);
}

// ---- up2a concat conv as bf16 MFMA: M=40x40, N=32, K=576, PW=52 ------------
__global__ __launch_bounds__(TPB) void conv_up2a_mfma_k(
    const unsigned short* __restrict__ catcl, const unsigned short* __restrict__ wf,
    const float* __restrict__ bias, float* __restrict__ out, int B) {
    const int PW = 52;
    int blk = blockIdx.x;
    int b = blk / 60;
    int rem = blk % 60;
    int tid = threadIdx.x;
    int l = tid & 63;
    int wv = tid >> 6;
    int mtile = rem * 2 + (wv & 1);
    int coH = wv >> 1;
    int y = mtile / 3, x0 = (mtile % 3) * 16;
    int co = coH * 16 + (l & 15);
    float bv = bias[co];
    f32x4 acc;
    acc[0] = bv; acc[1] = bv; acc[2] = bv; acc[3] = bv;
    int ubase = (y * PW + x0 + (l & 15)) * 64 + ((l >> 4) << 3);
    const unsigned short* cb = catcl + (size_t)b * (42 * PW * 64);
    const unsigned short* wl = wf + (size_t)l * 8;
#pragma unroll
    for (int tap = 0; tap < 9; ++tap) {
        int off = ((tap / 3) * PW + (tap % 3)) * 64;
#pragma unroll
        for (int kc = 0; kc < 2; ++kc) {
            bf16x8 af = *reinterpret_cast<const bf16x8*>(cb + ubase + off + kc * 32);
            bf16x8 bf = *reinterpret_cast<const bf16x8*>(wl + (size_t)(((tap * 2 + kc) * 2 + coH)) * 512);
            acc = __builtin_amdgcn_mfma_f32_16x16x32_bf16(af, bf, acc, 0, 0, 0);
        }
    }
    int xo = x0 + ((l >> 4) << 2);
    size_t obase = ((size_t)(b * 32 + co)) * 1600 + (size_t)y * 40;
#pragma unroll
    for (int r = 0; r < 4; ++r) {
        int ox = xo + r;
        if (ox < 40) out[obase + ox] = fmaxf(acc[r], 0.f);
    }
}

// ---- w_om head as bf16 MFMA implicit GEMM (verified r18) -------------------
__global__ __launch_bounds__(TPB) void conv_om_mfma_k(
    const unsigned short* __restrict__ ocl, const unsigned short* __restrict__ womf,
    const float* __restrict__ bias, float* __restrict__ out, int B) {
    int blk = blockIdx.x;
    int b = blk / 1600;
    int rem = blk % 1600;
    int y = rem / 10;
    int xs = rem % 10;
    int tid = threadIdx.x;
    int l = tid & 63;
    int wv = tid >> 6;
    int x0 = xs * 16;
    f32x4 acc[3];
#pragma unroll
    for (int t = 0; t < 3; ++t) {
        int co = (wv * 3 + t) * 16 + (l & 15);
        float bv = (co < 189) ? bias[co] : 0.f;
        acc[t][0] = bv; acc[t][1] = bv; acc[t][2] = bv; acc[t][3] = bv;
    }
    int ubase = (y * 162 + x0 + (l & 15)) * 32 + ((l >> 4) << 3);
    const unsigned short* ob = ocl + (size_t)b * 839808;
    const unsigned short* wl = womf + (size_t)l * 8;
#pragma unroll
    for (int tap = 0; tap < 9; ++tap) {
        int off = ((tap / 3) * 162 + (tap % 3)) * 32;
        bf16x8 af = *reinterpret_cast<const bf16x8*>(ob + ubase + off);
#pragma unroll
        for (int t = 0; t < 3; ++t) {
            int nt = wv * 3 + t;
            bf16x8 bf = *reinterpret_cast<const bf16x8*>(wl + (size_t)(tap * 12 + nt) * 512);
            acc[t] = __builtin_amdgcn_mfma_f32_16x16x32_bf16(af, bf, acc[t], 0, 0, 0);
        }
    }
    int xo = x0 + ((l >> 4) << 2);
#pragma unroll
    for (int t = 0; t < 3; ++t) {
        int co = (wv * 3 + t) * 16 + (l & 15);
        if (co >= 189) continue;
        size_t obase = ((size_t)(b * 189 + co)) * 25600 + (size_t)y * 160 + xo;
#pragma unroll
        for (int r = 0; r < 4; ++r) out[obase + r] = acc[t][r];
    }
}

// ------------- two-phase modulated deformable conv ---------------------------
__global__ __launch_bounds__(TPB) void deform_conv2_k(
    const float* __restrict__ x, const float* __restrict__ om,
    const float* __restrict__ wt2, const float* __restrict__ bias,
    float* __restrict__ out, int B, int H, int W) {
    __shared__ float smp[63 * 64];
    const int HW = H * W;
    int blk = blockIdx.x;
    int b = blk / (HW / 64);
    int pxbase = (blk % (HW / 64)) * 64;
    int tid = threadIdx.x;
    const float* omb = om + (size_t)b * 189 * HW;
    const float* xb = x + (size_t)b * 7 * HW;

#pragma unroll 4
    for (int k = 0; k < 16; ++k) {
        int it = tid + k * 256;
        if (it >= 4032) break;
        int pxl = it & 63;
        int tap = it >> 6;
        int c = tap / 9, kk = tap % 9;
        int hw = pxbase + pxl;
        int hq = hw / W, wq = hw % W;
        float dy = omb[(size_t)(c * 18 + kk * 2 + 0) * HW + hw];
        float dx = omb[(size_t)(c * 18 + kk * 2 + 1) * HW + hw];
        float mv = omb[(size_t)(126 + c * 9 + kk) * HW + hw];
        float m = 1.f / (1.f + __expf(-mv));
        float py = (float)hq + (float)(kk / 3 - 1) + dy;
        float px = (float)wq + (float)(kk % 3 - 1) + dx;
        float y0f = floorf(py), x0f = floorf(px);
        int y0 = (int)y0f, x0 = (int)x0f;
        float wy1 = py - y0f, wx1 = px - x0f;
        float wy0 = 1.f - wy1, wx0 = 1.f - wx1;
        float v00 = 0.f, v01 = 0.f, v10 = 0.f, v11 = 0.f;
        const float* xc = xb + (size_t)c * HW;
        bool yin0 = (y0 >= 0) & (y0 < H);
        bool yin1 = (y0 + 1 >= 0) & (y0 + 1 < H);
        bool xin0 = (x0 >= 0) & (x0 < W);
        bool xin1 = (x0 + 1 >= 0) & (x0 + 1 < W);
        if (yin0) {
            const float* rr = xc + (size_t)y0 * W;
            if (xin0) v00 = rr[x0];
            if (xin1) v01 = rr[x0 + 1];
        }
        if (yin1) {
            const float* rr = xc + (size_t)(y0 + 1) * W;
            if (xin0) v10 = rr[x0];
            if (xin1) v11 = rr[x0 + 1];
        }
        smp[tap * 64 + pxl] =
            (wy0 * wx0 * v00 + wy0 * wx1 * v01 + wy1 * wx0 * v10 + wy1 * wx1 * v11) * m;
    }
    __syncthreads();

    int pxl = tid & 63;
    int g = tid >> 6;
    int gu = __builtin_amdgcn_readfirstlane(g);
    const float* swb = wt2 + gu * 16;
    const float* bsb = bias + gu * 16;
    float acc[16];
#pragma unroll
    for (int o = 0; o < 16; ++o) acc[o] = 0.f;
    for (int tap = 0; tap < 63; ++tap) {
        float s = smp[tap * 64 + pxl];
        const float* sw = swb + tap * 64;
#pragma unroll
        for (int o = 0; o < 16; ++o) acc[o] += s * sw[o];
    }
    int hw = pxbase + pxl;
    size_t obase = (size_t)b * 64 * HW + (size_t)gu * 16 * HW + hw;
#pragma unroll
    for (int o = 0; o < 16; ++o)
        out[obase + (size_t)o * HW] = fmaxf(acc[o] + bsb[o], 0.f);
}

extern "C" void kernel_launch(void* const* d_in, const int* in_sizes, int n_in,
                              void* d_out, int out_size, void* d_ws, size_t ws_size,
                              hipStream_t stream) {
    (void)in_sizes; (void)n_in; (void)out_size; (void)ws_size;
    const float* inputs = (const float*)d_in[0];
    const float* w_in   = (const float*)d_in[1];  const float* b_in   = (const float*)d_in[2];
    const float* w_dn1a = (const float*)d_in[3];  const float* b_dn1a = (const float*)d_in[4];
    const float* w_dn1b = (const float*)d_in[5];  const float* b_dn1b = (const float*)d_in[6];
    const float* w_up1a = (const float*)d_in[7];  const float* b_up1a = (const float*)d_in[8];
    const float* wt_up1 = (const float*)d_in[9];  const float* bt_up1 = (const float*)d_in[10];
    const float* w_dn2a = (const float*)d_in[11]; const float* b_dn2a = (const float*)d_in[12];
    const float* w_dn2b = (const float*)d_in[13]; const float* b_dn2b = (const float*)d_in[14];
    const float* w_up2a = (const float*)d_in[15]; const float* b_up2a = (const float*)d_in[16];
    const float* wt_up2 = (const float*)d_in[17]; const float* bt_up2 = (const float*)d_in[18];
    const float* w_tra  = (const float*)d_in[19]; const float* b_tra  = (const float*)d_in[20];
    const float* w_trb  = (const float*)d_in[21]; const float* b_trb  = (const float*)d_in[22];
    const float* wt_tr  = (const float*)d_in[23]; const float* bt_tr  = (const float*)d_in[24];
    const float* w_out  = (const float*)d_in[25]; const float* b_out  = (const float*)d_in[26];
    const float* w_tf3a = (const float*)d_in[27]; const float* b_tf3a = (const float*)d_in[28];
    const float* w_tf3b = (const float*)d_in[29]; const float* b_tf3b = (const float*)d_in[30];
    const float* w_tf2  = (const float*)d_in[31]; const float* b_tf2  = (const float*)d_in[32];
    const float* w_om   = (const float*)d_in[33]; const float* b_om   = (const float*)d_in[34];
    const float* w_dc   = (const float*)d_in[35]; const float* b_dc   = (const float*)d_in[36];
    float* out = (float*)d_out;

    const int B = 2, nf = 32, H = 160, W = 160;
    const size_t n160 = (size_t)B * nf * 160 * 160;
    const size_t n80  = (size_t)B * nf * 80 * 80;
    const size_t n40  = (size_t)B * nf * 40 * 40;
    const size_t n20  = (size_t)B * nf * 20 * 20;

    float* ws = (float*)d_ws;
    float* F0    = ws;
    float* TMP80 = F0 + n160;
    float* F1    = TMP80 + n80;
    float* TMP40 = F1 + n80;
    float* F2    = TMP40 + n40;
    float* T20A  = F2 + n40;
    float* T20B  = T20A + n20;
    float* T40   = T20B + n20;
    float* T40B  = T40 + n40;
    float* T80   = T40B + n40;
    float* T80B  = T80 + n80;
    float* T160  = T80B + n80;
    float* TF    = T160 + n160;
    float* XAREG = TF + n160;
    float* OM    = XAREG;
    float* WT2   = XAREG + 11757312;
    unsigned short* WBF    = (unsigned short*)(WT2 + 4032);
    unsigned short* XACL   = WBF + 27648;
    unsigned short* WOMF   = XACL + 11757312;
    unsigned short* OCL    = WOMF + 55296;
    unsigned short* MCL    = OCL + 1679616;
    unsigned short* TCL    = MCL + 1679616;
    unsigned short* CATCL  = TCL + 1679616;
    unsigned short* CATCL2 = CATCL + 860672;
    unsigned short* WTF2F  = CATCL2 + 279552;
    unsigned short* WOUTF  = WTF2F + 9216;
    unsigned short* WUP1F  = WOUTF + 9216;
    unsigned short* WUP2F  = WUP1F + 18432;

    const int bpc160 = 25;
    const int bpc80_128 = 13;
    const int bpc40_64  = 7;
    const int bpc20_64  = 2;

    // prep (merged) + conv_a fused to bf16 channel-last (row-wise v2)
    prep_k<<<nblk(27648 + 4032 + 14 * 644 + 55296 + 9216 + 9216 + 18432 + 18432), TPB, 0, stream>>>(
        w_tf3b, w_dc, w_om, w_tf2, w_out, w_up1a, w_up2a,
        WBF, WOMF, WTF2F, WOUTF, WUP1F, WUP2F, WT2, XACL);
    conv3da_cl_k<<<B * 7 * 160, TPB, 0, stream>>>(inputs, w_tf3a, b_tf3a, XACL, B, H, W);

    // --- 2D U-Net branch ---
    conv2d_c4_k<1, 0, 0><<<B * 8 * bpc160, TPB, 0, stream>>>(inputs, nullptr, w_in, b_in, nullptr, F0, B, 7, 160, 160, nf, 8, bpc160);
    conv2d_s2_t4_k<128><<<B * nf * bpc80_128, 128, 0, stream>>>(F0, w_dn1a, b_dn1a, TMP80, B, nf, 160, 160, nf, bpc80_128);
    conv2d_t4_k<128, 1, 0><<<B * nf * bpc80_128, 128, 0, stream>>>(TMP80, w_dn1b, b_dn1b, nullptr, F1, B, nf, 80, 80, nf, bpc80_128);
    conv2d_s2_t4_k<64><<<B * nf * bpc40_64, 64, 0, stream>>>(F1, w_dn2a, b_dn2a, TMP40, B, nf, 80, 80, nf, bpc40_64);
    conv2d_t4_k<64, 1, 0><<<B * nf * bpc40_64, 64, 0, stream>>>(TMP40, w_dn2b, b_dn2b, nullptr, F2, B, nf, 40, 40, nf, bpc40_64);
    conv2d_s2_t4_k<64><<<B * nf * bpc20_64, 64, 0, stream>>>(F2, w_tra, b_tra, T20A, B, nf, 40, 40, nf, bpc20_64);
    conv2d_t4_k<64, 1, 0><<<B * nf * bpc20_64, 64, 0, stream>>>(T20A, w_trb, b_trb, nullptr, T20B, B, nf, 20, 20, nf, bpc20_64);
    convt2d_t4_k<64><<<B * nf * bpc40_64, 64, 0, stream>>>(T20B, wt_tr, bt_tr, T40, B, nf, 20, 20, bpc40_64);
    cat2cl_k<40, 40, 42, 52><<<nblk(2 * 42 * 52), TPB, 0, stream>>>(T40, F2, CATCL2);
    conv_up2a_mfma_k<<<B * 60, TPB, 0, stream>>>(CATCL2, WUP2F, b_up2a, T40B, B);
    convt2d_t4_k<128><<<B * nf * bpc80_128, 128, 0, stream>>>(T40B, wt_up2, bt_up2, T80, B, nf, 40, 40, bpc80_128);
    cat2cl_k<80, 80, 82, 82><<<nblk(2 * 82 * 82), TPB, 0, stream>>>(T80, F1, CATCL);
    conv_up1a_mfma_k<<<B * 200, TPB, 0, stream>>>(CATCL, WUP1F, b_up1a, T80B, B);
    convt2d_c4_k<<<B * 8 * bpc160, TPB, 0, stream>>>(T80B, wt_up1, bt_up1, T160, B, nf, 80, 80, bpc160);

    // --- conv3d_b + relu + mean (bf16 MFMA, hoisted) -> F0 ---
    conv3db_mfma_k<<<B * 800, TPB, 0, stream>>>(XACL, WBF, b_tf3b, F0, B, H, W);
    // FUSED = relu(conv_tf2(MEAN) + T160)  [MFMA]
    o2cl_k<<<nblk(2 * 26244), TPB, 0, stream>>>(F0, MCL);
    conv_nf_mfma_k<1, 1><<<B * 800, TPB, 0, stream>>>(MCL, WTF2F, b_tf2, T160, TF, B);

    // --- offset/mask head: w_out MFMA -> F0; o2cl; w_om MFMA ---
    o2cl_k<<<nblk(2 * 26244), TPB, 0, stream>>>(TF, TCL);
    conv_nf_mfma_k<0, 1><<<B * 800, TPB, 0, stream>>>(TCL, WOUTF, b_out, nullptr, F0, B);
    o2cl_k<<<nblk(2 * 26244), TPB, 0, stream>>>(F0, OCL);
    conv_om_mfma_k<<<B * 1600, TPB, 0, stream>>>(OCL, WOMF, b_om, OM, B);

    // --- deformable conv (two-phase) ---
    deform_conv2_k<<<B * (H * W / 64), TPB, 0, stream>>>(inputs, OM, WT2, b_dc, out, B, H, W);
}

// Round 23
// 419.645 us; speedup vs baseline: 2.3501x; 1.0323x over previous
//
#include <hip/hip_runtime.h>
#include <math.h>

// ---------------------------------------------------------------------------
// STDF forward, round 23: direct-CL epilogues. conv3db/tf2/w_out MFMA kernels
// write their bf16 channel-last buffers (MCL/TCL/OCL) directly; the three
// o2cl passes and fp32 F0/TF round-trips are eliminated (~59MB traffic,
// 3 launches). Borders zeroed once in prep_k. Bit-identical values.
// Everything else identical to round 22 (433us verified).
// ---------------------------------------------------------------------------

#define TPB 256

static inline int nblk(long long total) { return (int)((total + TPB - 1) / TPB); }

typedef short bf16x8 __attribute__((ext_vector_type(8)));
typedef float f32x4 __attribute__((ext_vector_type(4)));

__device__ __forceinline__ unsigned short f2bf(float f) {
    unsigned int u = __float_as_uint(f);
    unsigned int r = u + 0x7FFFu + ((u >> 16) & 1u);   // RNE
    return (unsigned short)(r >> 16);
}

// ---------------- 3x3 conv2d, stride 1, 4 outputs/thread, block-uniform co --
template <int TB, int RELU, int HAS_RES>
__global__ __launch_bounds__(TB) void conv2d_t4_k(
    const float* __restrict__ in, const float* __restrict__ w,
    const float* __restrict__ bias, const float* __restrict__ res,
    float* __restrict__ out, int B, int Ci, int H, int W, int Co, int BPC) {
    __shared__ float ws_w[32 * 9];
    int co = (blockIdx.x / BPC) % Co;
    int b  = blockIdx.x / (BPC * Co);
    for (int i = threadIdx.x; i < Ci * 9; i += TB)
        ws_w[i] = w[(size_t)co * Ci * 9 + i];
    __syncthreads();
    int nq = W >> 2;
    int r = (blockIdx.x % BPC) * TB + threadIdx.x;
    if (r >= H * nq) return;
    int q = r % nq, ho = r / nq;
    int wb = q * 4;
    float bv = bias[co];
    float a0 = bv, a1 = bv, a2 = bv, a3 = bv;
    const float* ipb = in + (size_t)b * Ci * H * W;
    for (int ci = 0; ci < Ci; ++ci) {
        const float* ip = ipb + (size_t)ci * H * W;
        const float* wc = ws_w + ci * 9;
#pragma unroll
        for (int kh = 0; kh < 3; ++kh) {
            int y = ho - 1 + kh;
            if (y < 0 || y >= H) continue;
            const float* row = ip + (size_t)y * W + wb;
            float4 xv = *(const float4*)row;
            float xm = (wb > 0) ? row[-1] : 0.f;
            float xp = (wb + 4 < W) ? row[4] : 0.f;
            float w0 = wc[kh * 3], w1 = wc[kh * 3 + 1], w2 = wc[kh * 3 + 2];
            a0 += xm   * w0 + xv.x * w1 + xv.y * w2;
            a1 += xv.x * w0 + xv.y * w1 + xv.z * w2;
            a2 += xv.y * w0 + xv.z * w1 + xv.w * w2;
            a3 += xv.z * w0 + xv.w * w1 + xp   * w2;
        }
    }
    size_t o = ((size_t)(b * Co + co) * H + ho) * W + wb;
    if (HAS_RES) {
        float4 rv = *(const float4*)(res + o);
        a0 += rv.x; a1 += rv.y; a2 += rv.z; a3 += rv.w;
    }
    if (RELU) { a0 = fmaxf(a0, 0.f); a1 = fmaxf(a1, 0.f); a2 = fmaxf(a2, 0.f); a3 = fmaxf(a3, 0.f); }
    *(float4*)(out + o) = make_float4(a0, a1, a2, a3);
}

// ------- 3x3 conv2d, stride 1, 4 outputs x 4 co per thread -----------------
template <int RELU, int HAS_RES, int HAS_IN2>
__global__ __launch_bounds__(TPB) void conv2d_c4_k(
    const float* __restrict__ in, const float* __restrict__ in2,
    const float* __restrict__ w, const float* __restrict__ bias,
    const float* __restrict__ res, float* __restrict__ out,
    int B, int Ci, int H, int W, int Co, int COG, int BPC) {
    __shared__ float ws_w[4 * 32 * 9];
    int cog = (blockIdx.x / BPC) % COG;
    int b   = blockIdx.x / (BPC * COG);
    int co0 = cog * 4;
    int nw = Ci * 9;
    for (int i = threadIdx.x; i < 4 * nw; i += TPB) {
        int cr = i / nw; int co = co0 + cr;
        ws_w[i] = (co < Co) ? w[(size_t)co * nw + (i - cr * nw)] : 0.f;
    }
    __syncthreads();
    int nq = W >> 2;
    int r = (blockIdx.x % BPC) * TPB + threadIdx.x;
    if (r >= H * nq) return;
    int q = r % nq, ho = r / nq;
    int wb = q * 4;
    float a[4][4];
#pragma unroll
    for (int cr = 0; cr < 4; ++cr) {
        float bv = (co0 + cr < Co) ? bias[co0 + cr] : 0.f;
        a[cr][0] = bv; a[cr][1] = bv; a[cr][2] = bv; a[cr][3] = bv;
    }
    const float* ipb = in + (size_t)b * Ci * H * W;
    const float* ipb2 = HAS_IN2 ? in2 + (size_t)b * Ci * H * W : nullptr;
    for (int ci = 0; ci < Ci; ++ci) {
        const float* ip = ipb + (size_t)ci * H * W;
        const float* ip2 = HAS_IN2 ? ipb2 + (size_t)ci * H * W : nullptr;
#pragma unroll
        for (int kh = 0; kh < 3; ++kh) {
            int y = ho - 1 + kh;
            if (y < 0 || y >= H) continue;
            const float* row = ip + (size_t)y * W + wb;
            float4 xv = *(const float4*)row;
            float x_[6];
            x_[0] = (wb > 0) ? row[-1] : 0.f;
            x_[5] = (wb + 4 < W) ? row[4] : 0.f;
            if (HAS_IN2) {
                const float* row2 = ip2 + (size_t)y * W + wb;
                float4 x2 = *(const float4*)row2;
                xv.x += x2.x; xv.y += x2.y; xv.z += x2.z; xv.w += x2.w;
                if (wb > 0) x_[0] += row2[-1];
                if (wb + 4 < W) x_[5] += row2[4];
            }
            x_[1] = xv.x; x_[2] = xv.y; x_[3] = xv.z; x_[4] = xv.w;
#pragma unroll
            for (int cr = 0; cr < 4; ++cr) {
                const float* wc = ws_w + cr * nw + ci * 9 + kh * 3;
                float w0 = wc[0], w1 = wc[1], w2 = wc[2];
                a[cr][0] += x_[0] * w0 + x_[1] * w1 + x_[2] * w2;
                a[cr][1] += x_[1] * w0 + x_[2] * w1 + x_[3] * w2;
                a[cr][2] += x_[2] * w0 + x_[3] * w1 + x_[4] * w2;
                a[cr][3] += x_[3] * w0 + x_[4] * w1 + x_[5] * w2;
            }
        }
    }
#pragma unroll
    for (int cr = 0; cr < 4; ++cr) {
        int co = co0 + cr;
        if (co >= Co) break;
        size_t o = ((size_t)(b * Co + co) * H + ho) * W + wb;
        float a0 = a[cr][0], a1 = a[cr][1], a2 = a[cr][2], a3 = a[cr][3];
        if (HAS_RES) {
            float4 rv = *(const float4*)(res + o);
            a0 += rv.x; a1 += rv.y; a2 += rv.z; a3 += rv.w;
        }
        if (RELU) { a0 = fmaxf(a0, 0.f); a1 = fmaxf(a1, 0.f); a2 = fmaxf(a2, 0.f); a3 = fmaxf(a3, 0.f); }
        *(float4*)(out + o) = make_float4(a0, a1, a2, a3);
    }
}

// ------------- 3x3 conv2d, stride 2, 4 outputs/thread, relu ----------------
template <int TB>
__global__ __launch_bounds__(TB) void conv2d_s2_t4_k(
    const float* __restrict__ in, const float* __restrict__ w,
    const float* __restrict__ bias, float* __restrict__ out,
    int B, int Ci, int Hi, int Wi, int Co, int BPC) {
    __shared__ float ws_w[32 * 9];
    int Ho = Hi >> 1, Wo = Wi >> 1;
    int co = (blockIdx.x / BPC) % Co;
    int b  = blockIdx.x / (BPC * Co);
    for (int i = threadIdx.x; i < Ci * 9; i += TB)
        ws_w[i] = w[(size_t)co * Ci * 9 + i];
    __syncthreads();
    int nq = Wo >> 2;
    int r = (blockIdx.x % BPC) * TB + threadIdx.x;
    if (r >= Ho * nq) return;
    int q = r % nq, ho = r / nq;
    int wb = q * 4;
    float bv = bias[co];
    float a0 = bv, a1 = bv, a2 = bv, a3 = bv;
    const float* ipb = in + (size_t)b * Ci * Hi * Wi;
    for (int ci = 0; ci < Ci; ++ci) {
        const float* ip = ipb + (size_t)ci * Hi * Wi;
        const float* wc = ws_w + ci * 9;
#pragma unroll
        for (int kh = 0; kh < 3; ++kh) {
            int y = 2 * ho - 1 + kh;
            if (y < 0 || y >= Hi) continue;
            const float* row = ip + (size_t)y * Wi;
            float z0 = (2 * wb - 1 >= 0) ? row[2 * wb - 1] : 0.f;
            float4 za = *(const float4*)(row + 2 * wb);
            float4 zb = *(const float4*)(row + 2 * wb + 4);
            float w0 = wc[kh * 3], w1 = wc[kh * 3 + 1], w2 = wc[kh * 3 + 2];
            a0 += z0   * w0 + za.x * w1 + za.y * w2;
            a1 += za.y * w0 + za.z * w1 + za.w * w2;
            a2 += za.w * w0 + zb.x * w1 + zb.y * w2;
            a3 += zb.y * w0 + zb.z * w1 + zb.w * w2;
        }
    }
    size_t o = ((size_t)(b * Co + co) * Ho + ho) * Wo + wb;
    *(float4*)(out + o) = make_float4(fmaxf(a0, 0.f), fmaxf(a1, 0.f), fmaxf(a2, 0.f), fmaxf(a3, 0.f));
}

// ------------- transposed conv 4x4 stride 2, 4 outputs/thread, relu --------
template <int TB>
__global__ __launch_bounds__(TB) void convt2d_t4_k(
    const float* __restrict__ in, const float* __restrict__ wt,
    const float* __restrict__ bias, float* __restrict__ out,
    int B, int C, int Hi, int Wi, int BPC) {
    __shared__ float ws_w[32 * 16];
    int Ho = 2 * Hi, Wo = 2 * Wi;
    int co = (blockIdx.x / BPC) % C;
    int b  = blockIdx.x / (BPC * C);
    for (int i = threadIdx.x; i < C * 16; i += TB) {
        int ci = i >> 4, t = i & 15;
        ws_w[i] = wt[((size_t)ci * C + co) * 16 + t];
    }
    __syncthreads();
    int nq = Wo >> 2;
    int r = (blockIdx.x % BPC) * TB + threadIdx.x;
    if (r >= Ho * nq) return;
    int q = r % nq, ho = r / nq;
    int wb = q * 4;
    int p = ho & 1;
    int iy0 = (ho + p) / 2 - 1;
    int iy1 = iy0 + 1;
    int ix0 = wb / 2 - 1;
    bool vy0 = (iy0 >= 0) && (iy0 < Hi);
    bool vy1 = (iy1 >= 0) && (iy1 < Hi);
    float bv = bias[co];
    float a0 = bv, a1 = bv, a2 = bv, a3 = bv;
    const float* ipb = in + (size_t)b * C * Hi * Wi;
    for (int ci = 0; ci < C; ++ci) {
        const float* ip = ipb + (size_t)ci * Hi * Wi;
        float u0 = 0, u1 = 0, u2 = 0, u3 = 0, v0 = 0, v1 = 0, v2 = 0, v3 = 0;
        if (vy0) {
            const float* rw = ip + (size_t)iy0 * Wi;
            if (ix0 >= 0) u0 = rw[ix0];
            u1 = rw[ix0 + 1]; u2 = rw[ix0 + 2];
            if (ix0 + 3 < Wi) u3 = rw[ix0 + 3];
        }
        if (vy1) {
            const float* rw = ip + (size_t)iy1 * Wi;
            if (ix0 >= 0) v0 = rw[ix0];
            v1 = rw[ix0 + 1]; v2 = rw[ix0 + 2];
            if (ix0 + 3 < Wi) v3 = rw[ix0 + 3];
        }
        const float* wr0 = ws_w + ci * 16 + (3 - p) * 4;
        const float* wr1 = ws_w + ci * 16 + (1 - p) * 4;
        a0 += u0 * wr0[3] + u1 * wr0[1] + v0 * wr1[3] + v1 * wr1[1];
        a1 += u1 * wr0[2] + u2 * wr0[0] + v1 * wr1[2] + v2 * wr1[0];
        a2 += u1 * wr0[3] + u2 * wr0[1] + v1 * wr1[3] + v2 * wr1[1];
        a3 += u2 * wr0[2] + u3 * wr0[0] + v2 * wr1[2] + v3 * wr1[0];
    }
    size_t o = ((size_t)(b * C + co) * Ho + ho) * Wo + wb;
    *(float4*)(out + o) = make_float4(fmaxf(a0, 0.f), fmaxf(a1, 0.f), fmaxf(a2, 0.f), fmaxf(a3, 0.f));
}

// ------------- transposed conv 4x4 stride 2, 4 outputs x 4 co/thread -------
__global__ __launch_bounds__(TPB) void convt2d_c4_k(
    const float* __restrict__ in, const float* __restrict__ wt,
    const float* __restrict__ bias, float* __restrict__ out,
    int B, int C, int Hi, int Wi, int BPC) {
    __shared__ float ws_w[4][32 * 16];
    int Ho = 2 * Hi, Wo = 2 * Wi;
    int cog = (blockIdx.x / BPC) % (C / 4);
    int b   = blockIdx.x / (BPC * (C / 4));
    int co0 = cog * 4;
    for (int i = threadIdx.x; i < 4 * C * 16; i += TPB) {
        int cr = i / (C * 16); int j = i % (C * 16);
        int ci = j >> 4, t = j & 15;
        ws_w[cr][j] = wt[((size_t)ci * C + (co0 + cr)) * 16 + t];
    }
    __syncthreads();
    int nq = Wo >> 2;
    int r = (blockIdx.x % BPC) * TPB + threadIdx.x;
    if (r >= Ho * nq) return;
    int q = r % nq, ho = r / nq;
    int wb = q * 4;
    int p = ho & 1;
    int iy0 = (ho + p) / 2 - 1;
    int iy1 = iy0 + 1;
    int ix0 = wb / 2 - 1;
    bool vy0 = (iy0 >= 0) && (iy0 < Hi);
    bool vy1 = (iy1 >= 0) && (iy1 < Hi);
    float a[4][4];
#pragma unroll
    for (int cr = 0; cr < 4; ++cr) {
        float bv = bias[co0 + cr];
        a[cr][0] = bv; a[cr][1] = bv; a[cr][2] = bv; a[cr][3] = bv;
    }
    const float* ipb = in + (size_t)b * C * Hi * Wi;
    for (int ci = 0; ci < C; ++ci) {
        const float* ip = ipb + (size_t)ci * Hi * Wi;
        float u0 = 0, u1 = 0, u2 = 0, u3 = 0, v0 = 0, v1 = 0, v2 = 0, v3 = 0;
        if (vy0) {
            const float* rw = ip + (size_t)iy0 * Wi;
            if (ix0 >= 0) u0 = rw[ix0];
            u1 = rw[ix0 + 1]; u2 = rw[ix0 + 2];
            if (ix0 + 3 < Wi) u3 = rw[ix0 + 3];
        }
        if (vy1) {
            const float* rw = ip + (size_t)iy1 * Wi;
            if (ix0 >= 0) v0 = rw[ix0];
            v1 = rw[ix0 + 1]; v2 = rw[ix0 + 2];
            if (ix0 + 3 < Wi) v3 = rw[ix0 + 3];
        }
#pragma unroll
        for (int cr = 0; cr < 4; ++cr) {
            const float* wr0 = ws_w[cr] + ci * 16 + (3 - p) * 4;
            const float* wr1 = ws_w[cr] + ci * 16 + (1 - p) * 4;
            a[cr][0] += u0 * wr0[3] + u1 * wr0[1] + v0 * wr1[3] + v1 * wr1[1];
            a[cr][1] += u1 * wr0[2] + u2 * wr0[0] + v1 * wr1[2] + v2 * wr1[0];
            a[cr][2] += u1 * wr0[3] + u2 * wr0[1] + v1 * wr1[3] + v2 * wr1[1];
            a[cr][3] += u2 * wr0[2] + u3 * wr0[0] + v2 * wr1[2] + v3 * wr1[0];
        }
    }
#pragma unroll
    for (int cr = 0; cr < 4; ++cr) {
        size_t o = ((size_t)(b * C + co0 + cr) * Ho + ho) * Wo + wb;
        *(float4*)(out + o) = make_float4(fmaxf(a[cr][0], 0.f), fmaxf(a[cr][1], 0.f),
                                          fmaxf(a[cr][2], 0.f), fmaxf(a[cr][3], 0.f));
    }
}

// ---- merged prep: B-frag packs + wdc transpose + CL border zero (20 pl) ----
__global__ void prep_k(const float* __restrict__ wb, const float* __restrict__ wdc,
                       const float* __restrict__ wom, const float* __restrict__ wtf2,
                       const float* __restrict__ wout, const float* __restrict__ wup1a,
                       const float* __restrict__ wup2a,
                       unsigned short* __restrict__ wbf, unsigned short* __restrict__ womf,
                       unsigned short* __restrict__ wtf2f, unsigned short* __restrict__ woutf,
                       unsigned short* __restrict__ wup1f, unsigned short* __restrict__ wup2f,
                       float* __restrict__ wt2, unsigned short* __restrict__ xacl,
                       unsigned short* __restrict__ mcl, unsigned short* __restrict__ tcl,
                       unsigned short* __restrict__ ocl) {
    int i = blockIdx.x * TPB + threadIdx.x;
    if (i < 27648) {                          // conv3db B-frags
        int j = i & 7;
        int l = (i >> 3) & 63;
        int coH = (i >> 9) & 1;
        int tap = i >> 10;
        int ci = ((l >> 4) << 3) + j;
        int co = (coH << 4) + (l & 15);
        wbf[i] = f2bf(wb[(size_t)(co * 32 + ci) * 27 + tap]);
        return;
    }
    int i2 = i - 27648;
    if (i2 < 4032) {                          // deform weight transpose
        int o = i2 & 63, ck = i2 >> 6;
        wt2[i2] = wdc[o * 63 + ck];
        return;
    }
    int i3 = i2 - 4032;
    if (i3 < 20 * 644) {                      // CL border zero: XACL(14)+MCL(2)+TCL(2)+OCL(2)
        int pl = i3 / 644, e = i3 % 644;
        int off;
        if (e < 162)      off = e;
        else if (e < 324) off = 161 * 162 + (e - 162);
        else if (e < 484) off = (e - 324 + 1) * 162;
        else              off = (e - 484 + 1) * 162 + 161;
        unsigned short* base;
        int pl2;
        if (pl < 14)      { base = xacl; pl2 = pl; }
        else if (pl < 16) { base = mcl;  pl2 = pl - 14; }
        else if (pl < 18) { base = tcl;  pl2 = pl - 16; }
        else              { base = ocl;  pl2 = pl - 18; }
        uint4* d = (uint4*)(base + ((size_t)pl2 * 26244 + off) * 32);
        uint4 z = make_uint4(0, 0, 0, 0);
        d[0] = z; d[1] = z; d[2] = z; d[3] = z;
        return;
    }
    int i4 = i3 - 20 * 644;
    if (i4 < 55296) {                         // w_om B-frags [tap][nt12][l][8]
        int j = i4 & 7;
        int l = (i4 >> 3) & 63;
        int nt = (i4 >> 9) % 12;
        int tap = i4 / 6144;
        int ci = ((l >> 4) << 3) + j;
        int co = nt * 16 + (l & 15);
        womf[i4] = (co < 189) ? f2bf(wom[((size_t)co * 32 + ci) * 9 + tap]) : (unsigned short)0;
        return;
    }
    int i5 = i4 - 55296;
    if (i5 < 9216) {                          // tf2 B-frags [tap][coH][l][8]
        int j = i5 & 7;
        int l = (i5 >> 3) & 63;
        int q = i5 >> 9;
        int coH = q & 1, tap = q >> 1;
        int ci = ((l >> 4) << 3) + j;
        int co = coH * 16 + (l & 15);
        wtf2f[i5] = f2bf(wtf2[((size_t)co * 32 + ci) * 9 + tap]);
        return;
    }
    int i6 = i5 - 9216;
    if (i6 < 9216) {                          // w_out B-frags
        int j = i6 & 7;
        int l = (i6 >> 3) & 63;
        int q = i6 >> 9;
        int coH = q & 1, tap = q >> 1;
        int ci = ((l >> 4) << 3) + j;
        int co = coH * 16 + (l & 15);
        woutf[i6] = f2bf(wout[((size_t)co * 32 + ci) * 9 + tap]);
        return;
    }
    int i7 = i6 - 9216;
    if (i7 < 18432) {                         // up1a B-frags [tap][kc][coH][l][8]
        int j = i7 & 7;
        int l = (i7 >> 3) & 63;
        int q = i7 >> 9;
        int coH = q & 1, kc = (q >> 1) & 1, tap = q >> 2;
        int ci = kc * 32 + ((l >> 4) << 3) + j;
        int co = coH * 16 + (l & 15);
        wup1f[i7] = f2bf(wup1a[((size_t)co * 64 + ci) * 9 + tap]);
        return;
    }
    int i8 = i7 - 18432;
    if (i8 >= 18432) return;                  // up2a B-frags, same layout
    int j = i8 & 7;
    int l = (i8 >> 3) & 63;
    int q = i8 >> 9;
    int coH = q & 1, kc = (q >> 1) & 1, tap = q >> 2;
    int ci = kc * 32 + ((l >> 4) << 3) + j;
    int co = coH * 16 + (l & 15);
    wup2f[i8] = f2bf(wup2a[((size_t)co * 64 + ci) * 9 + tap]);
}

// ---- conv3d_a fused v2: row-wise blocks (weights+window staged once) -------
__global__ __launch_bounds__(TPB) void conv3da_cl_k(
    const float* __restrict__ x, const float* __restrict__ wa,
    const float* __restrict__ ba, unsigned short* __restrict__ xacl,
    int B, int H, int W) {
    __shared__ float xin[3 * 3 * 162];
    __shared__ float wsa[864];
    int blk = blockIdx.x;
    int y  = blk % 160;
    int d  = (blk / 160) % 7;
    int b  = blk / 1120;
    int tid = threadIdx.x;
    for (int i = tid; i < 3 * 3 * 162; i += TPB) {
        int xx = i % 162; int t = i / 162; int yy = t % 3; int dz = t / 3;
        int gd = d - 1 + dz, gy = y - 1 + yy, gx = xx - 1;
        float v = 0.f;
        if (gd >= 0 && gd < 7 && gy >= 0 && gy < H && gx >= 0 && gx < W)
            v = x[((size_t)(b * 7 + gd)) * H * W + (size_t)gy * W + gx];
        xin[i] = v;
    }
    for (int i = tid; i < 864; i += TPB) wsa[i] = wa[i];
    __syncthreads();
    int co = tid & 31;
    int xi0 = tid >> 5;
    float bv = ba[co];
    const float* wc = wsa + co * 27;
    size_t rowbase = (((size_t)(b * 7 + d) * 162 + (y + 1)) * 162 + 1) * 32 + co;
    for (int k = 0; k < 20; ++k) {
        int gx = k * 8 + xi0;
        float acc = bv;
#pragma unroll
        for (int dz = 0; dz < 3; ++dz)
#pragma unroll
            for (int yy = 0; yy < 3; ++yy)
#pragma unroll
                for (int kw = 0; kw < 3; ++kw)
                    acc += xin[dz * 486 + yy * 162 + gx + kw] * wc[dz * 9 + yy * 3 + kw];
        xacl[rowbase + (size_t)gx * 32] = f2bf(fmaxf(acc, 0.f));
    }
}

// ---- concat fp32 ch-first -> bf16 CL padded: generic (PW wide, HxW valid) --
template <int HH, int WW, int PH, int PW>
__global__ __launch_bounds__(TPB) void cat2cl_k(
    const float* __restrict__ a, const float* __restrict__ c2,
    unsigned short* __restrict__ dst) {
    int idx = blockIdx.x * TPB + threadIdx.x;
    if (idx >= 2 * PH * PW) return;
    int pos = idx % (PH * PW);
    int b = idx / (PH * PW);
    int y = pos / PW, x = pos % PW;
    uint4* d = (uint4*)(dst + (size_t)idx * 64);
    if (y == 0 || y > HH || x == 0 || x > WW) {
        uint4 z = make_uint4(0, 0, 0, 0);
#pragma unroll
        for (int k = 0; k < 8; ++k) d[k] = z;
        return;
    }
    size_t off = (size_t)(y - 1) * WW + (x - 1);
    const float* sa = a + (size_t)b * 32 * (HH * WW) + off;
    const float* sc = c2 + (size_t)b * 32 * (HH * WW) + off;
    unsigned int pk[32];
#pragma unroll
    for (int j = 0; j < 16; ++j) {
        float v0 = sa[(size_t)(2 * j) * (HH * WW)];
        float v1 = sa[(size_t)(2 * j + 1) * (HH * WW)];
        pk[j] = (unsigned int)f2bf(v0) | ((unsigned int)f2bf(v1) << 16);
    }
#pragma unroll
    for (int j = 0; j < 16; ++j) {
        float v0 = sc[(size_t)(2 * j) * (HH * WW)];
        float v1 = sc[(size_t)(2 * j + 1) * (HH * WW)];
        pk[16 + j] = (unsigned int)f2bf(v0) | ((unsigned int)f2bf(v1) << 16);
    }
#pragma unroll
    for (int k = 0; k < 8; ++k)
        d[k] = make_uint4(pk[4 * k], pk[4 * k + 1], pk[4 * k + 2], pk[4 * k + 3]);
}

// ---- conv3d_b + relu + mean as bf16 MFMA; writes MCL (bf16 CL) directly ----
__global__ __launch_bounds__(TPB) void conv3db_mfma_k(
    const unsigned short* __restrict__ xacl, const unsigned short* __restrict__ wbf,
    const float* __restrict__ bb, unsigned short* __restrict__ mcl, int B, int H, int W) {
    int blk = blockIdx.x;
    int b = blk / 800;
    int rem = blk % 800;
    int y = rem / 5;
    int xp = rem % 5;
    int tid = threadIdx.x;
    int l = tid & 63;
    int wv = tid >> 6;
    int mt = wv & 1, coH = wv >> 1;
    int x0 = xp * 32 + mt * 16;
    int co = coH * 16 + (l & 15);
    float bv = bb[co];
    f32x4 acc[7];
#pragma unroll
    for (int d = 0; d < 7; ++d) { acc[d][0] = bv; acc[d][1] = bv; acc[d][2] = bv; acc[d][3] = bv; }

    int ubase = (y * 162 + x0 + (l & 15)) * 32 + ((l >> 4) << 3);
    const unsigned short* xb = xacl + (size_t)b * 5878656;
    const unsigned short* wbase = wbf + ((size_t)coH * 64 + l) * 8;

    // j2-outer / dz-inner: each A fragment loaded ONCE, feeds up to 3 MFMAs
    for (int j2 = 0; j2 < 9; ++j2) {
        int off2 = (j2 / 3) * 5184 + (j2 % 3) * 32;
        bf16x8 bf0 = *reinterpret_cast<const bf16x8*>(wbase + (size_t)(0 * 9 + j2) * 1024);
        bf16x8 bf1 = *reinterpret_cast<const bf16x8*>(wbase + (size_t)(1 * 9 + j2) * 1024);
        bf16x8 bf2 = *reinterpret_cast<const bf16x8*>(wbase + (size_t)(2 * 9 + j2) * 1024);
#pragma unroll
        for (int dz = 0; dz < 7; ++dz) {
            bf16x8 af = *reinterpret_cast<const bf16x8*>(xb + (size_t)dz * 839808 + ubase + off2);
            if (dz + 1 < 7) acc[dz + 1] = __builtin_amdgcn_mfma_f32_16x16x32_bf16(af, bf0, acc[dz + 1], 0, 0, 0);
            acc[dz] = __builtin_amdgcn_mfma_f32_16x16x32_bf16(af, bf1, acc[dz], 0, 0, 0);
            if (dz - 1 >= 0) acc[dz - 1] = __builtin_amdgcn_mfma_f32_16x16x32_bf16(af, bf2, acc[dz - 1], 0, 0, 0);
        }
    }

    int xo = x0 + ((l >> 4) << 2);
    size_t clbase = ((size_t)b * 26244 + (size_t)(y + 1) * 162 + (xo + 1)) * 32 + co;
#pragma unroll
    for (int r = 0; r < 4; ++r) {
        float s = 0.f;
#pragma unroll
        for (int d = 0; d < 7; ++d) s += fmaxf(acc[d][r], 0.f);
        mcl[clbase + (size_t)r * 32] = f2bf(s * (1.f / 7.f));
    }
}

// ---- N=32 K=288 160-level conv, bf16 MFMA, writes bf16 CL directly ---------
template <int HAS_RES, int RELU>
__global__ __launch_bounds__(TPB) void conv_nf_mfma_k(
    const unsigned short* __restrict__ icl, const unsigned short* __restrict__ wf,
    const float* __restrict__ bias, const float* __restrict__ res,
    unsigned short* __restrict__ outcl, int B) {
    int blk = blockIdx.x;
    int b = blk / 800;
    int rem = blk % 800;
    int y = rem / 5;
    int xp = rem % 5;
    int tid = threadIdx.x;
    int l = tid & 63;
    int wv = tid >> 6;
    int mt = wv & 1, coH = wv >> 1;
    int x0 = xp * 32 + mt * 16;
    int co = coH * 16 + (l & 15);
    float bv = bias[co];
    f32x4 acc;
    acc[0] = bv; acc[1] = bv; acc[2] = bv; acc[3] = bv;
    int ubase = (y * 162 + x0 + (l & 15)) * 32 + ((l >> 4) << 3);
    const unsigned short* ib = icl + (size_t)b * 839808;
    const unsigned short* wl = wf + (size_t)l * 8;
#pragma unroll
    for (int tap = 0; tap < 9; ++tap) {
        int off = ((tap / 3) * 162 + (tap % 3)) * 32;
        bf16x8 af = *reinterpret_cast<const bf16x8*>(ib + ubase + off);
        bf16x8 bf = *reinterpret_cast<const bf16x8*>(wl + (size_t)(tap * 2 + coH) * 512);
        acc = __builtin_amdgcn_mfma_f32_16x16x32_bf16(af, bf, acc, 0, 0, 0);
    }
    int xo = x0 + ((l >> 4) << 2);
    size_t obase = ((size_t)(b * 32 + co)) * 25600 + (size_t)y * 160 + xo;  // residual (fp32 ch-first)
    size_t clbase = ((size_t)b * 26244 + (size_t)(y + 1) * 162 + (xo + 1)) * 32 + co;
#pragma unroll
    for (int r = 0; r < 4; ++r) {
        float v = acc[r];
        if (HAS_RES) v += res[obase + r];
        if (RELU) v = fmaxf(v, 0.f);
        outcl[clbase + (size_t)r * 32] = f2bf(v);
    }
}

// ---- up1a concat conv as bf16 MFMA: M=80x80, N=32, K=576 -------------------
__global__ __launch_bounds__(TPB) void conv_up1a_mfma_k(
    const unsigned short* __restrict__ catcl, const unsigned short* __restrict__ wf,
    const float* __restrict__ bias, float* __restrict__ out, int B) {
    int blk = blockIdx.x;
    int b = blk / 200;
    int rem = blk % 200;
    int tid = threadIdx.x;
    int l = tid & 63;
    int wv = tid >> 6;
    int mtile = rem * 2 + (wv & 1);
    int coH = wv >> 1;
    int y = mtile / 5, x0 = (mtile % 5) * 16;
    int co = coH * 16 + (l & 15);
    float bv = bias[co];
    f32x4 acc;
    acc[0] = bv; acc[1] = bv; acc[2] = bv; acc[3] = bv;
    int ubase = (y * 82 + x0 + (l & 15)) * 64 + ((l >> 4) << 3);
    const unsigned short* cb = catcl + (size_t)b * 430336;
    const unsigned short* wl = wf + (size_t)l * 8;
#pragma unroll
    for (int tap = 0; tap < 9; ++tap) {
        int off = ((tap / 3) * 82 + (tap % 3)) * 64;
#pragma unroll
        for (int kc = 0; kc < 2; ++kc) {
            bf16x8 af = *reinterpret_cast<const bf16x8*>(cb + ubase + off + kc * 32);
            bf16x8 bf = *reinterpret_cast<const bf16x8*>(wl + (size_t)(((tap * 2 + kc) * 2 + coH)) * 512);
            acc = __builtin_amdgcn_mfma_f32_16x16x32_bf16(af, bf, acc, 0, 0, 0);
        }
    }
    int xo = x0 + ((l >> 4) << 2);
    size_t obase = ((size_t)(b * 32 + co)) * 6400 + (size_t)y * 80 + xo;
#pragma unroll
    for (int r = 0; r < 4; ++r)
        out[obase + r] = fmaxf(acc[r], 0.f);
}

// ---- up2a concat conv as bf16 MFMA: M=40x40, N=32, K=576, PW=52 ------------
__global__ __launch_bounds__(TPB) void conv_up2a_mfma_k(
    const unsigned short* __restrict__ catcl, const unsigned short* __restrict__ wf,
    const float* __restrict__ bias, float* __restrict__ out, int B) {
    const int PW = 52;
    int blk = blockIdx.x;
    int b = blk / 60;
    int rem = blk % 60;
    int tid = threadIdx.x;
    int l = tid & 63;
    int wv = tid >> 6;
    int mtile = rem * 2 + (wv & 1);
    int coH = wv >> 1;
    int y = mtile / 3, x0 = (mtile % 3) * 16;
    int co = coH * 16 + (l & 15);
    float bv = bias[co];
    f32x4 acc;
    acc[0] = bv; acc[1] = bv; acc[2] = bv; acc[3] = bv;
    int ubase = (y * PW + x0 + (l & 15)) * 64 + ((l >> 4) << 3);
    const unsigned short* cb = catcl + (size_t)b * (42 * PW * 64);
    const unsigned short* wl = wf + (size_t)l * 8;
#pragma unroll
    for (int tap = 0; tap < 9; ++tap) {
        int off = ((tap / 3) * PW + (tap % 3)) * 64;
#pragma unroll
        for (int kc = 0; kc < 2; ++kc) {
            bf16x8 af = *reinterpret_cast<const bf16x8*>(cb + ubase + off + kc * 32);
            bf16x8 bf = *reinterpret_cast<const bf16x8*>(wl + (size_t)(((tap * 2 + kc) * 2 + coH)) * 512);
            acc = __builtin_amdgcn_mfma_f32_16x16x32_bf16(af, bf, acc, 0, 0, 0);
        }
    }
    int xo = x0 + ((l >> 4) << 2);
    size_t obase = ((size_t)(b * 32 + co)) * 1600 + (size_t)y * 40;
#pragma unroll
    for (int r = 0; r < 4; ++r) {
        int ox = xo + r;
        if (ox < 40) out[obase + ox] = fmaxf(acc[r], 0.f);
    }
}

// ---- w_om head as bf16 MFMA implicit GEMM (verified r18) -------------------
__global__ __launch_bounds__(TPB) void conv_om_mfma_k(
    const unsigned short* __restrict__ ocl, const unsigned short* __restrict__ womf,
    const float* __restrict__ bias, float* __restrict__ out, int B) {
    int blk = blockIdx.x;
    int b = blk / 1600;
    int rem = blk % 1600;
    int y = rem / 10;
    int xs = rem % 10;
    int tid = threadIdx.x;
    int l = tid & 63;
    int wv = tid >> 6;
    int x0 = xs * 16;
    f32x4 acc[3];
#pragma unroll
    for (int t = 0; t < 3; ++t) {
        int co = (wv * 3 + t) * 16 + (l & 15);
        float bv = (co < 189) ? bias[co] : 0.f;
        acc[t][0] = bv; acc[t][1] = bv; acc[t][2] = bv; acc[t][3] = bv;
    }
    int ubase = (y * 162 + x0 + (l & 15)) * 32 + ((l >> 4) << 3);
    const unsigned short* ob = ocl + (size_t)b * 839808;
    const unsigned short* wl = womf + (size_t)l * 8;
#pragma unroll
    for (int tap = 0; tap < 9; ++tap) {
        int off = ((tap / 3) * 162 + (tap % 3)) * 32;
        bf16x8 af = *reinterpret_cast<const bf16x8*>(ob + ubase + off);
#pragma unroll
        for (int t = 0; t < 3; ++t) {
            int nt = wv * 3 + t;
            bf16x8 bf = *reinterpret_cast<const bf16x8*>(wl + (size_t)(tap * 12 + nt) * 512);
            acc[t] = __builtin_amdgcn_mfma_f32_16x16x32_bf16(af, bf, acc[t], 0, 0, 0);
        }
    }
    int xo = x0 + ((l >> 4) << 2);
#pragma unroll
    for (int t = 0; t < 3; ++t) {
        int co = (wv * 3 + t) * 16 + (l & 15);
        if (co >= 189) continue;
        size_t obase = ((size_t)(b * 189 + co)) * 25600 + (size_t)y * 160 + xo;
#pragma unroll
        for (int r = 0; r < 4; ++r) out[obase + r] = acc[t][r];
    }
}

// ------------- two-phase modulated deformable conv ---------------------------
__global__ __launch_bounds__(TPB) void deform_conv2_k(
    const float* __restrict__ x, const float* __restrict__ om,
    const float* __restrict__ wt2, const float* __restrict__ bias,
    float* __restrict__ out, int B, int H, int W) {
    __shared__ float smp[63 * 64];
    const int HW = H * W;
    int blk = blockIdx.x;
    int b = blk / (HW / 64);
    int pxbase = (blk % (HW / 64)) * 64;
    int tid = threadIdx.x;
    const float* omb = om + (size_t)b * 189 * HW;
    const float* xb = x + (size_t)b * 7 * HW;

#pragma unroll 4
    for (int k = 0; k < 16; ++k) {
        int it = tid + k * 256;
        if (it >= 4032) break;
        int pxl = it & 63;
        int tap = it >> 6;
        int c = tap / 9, kk = tap % 9;
        int hw = pxbase + pxl;
        int hq = hw / W, wq = hw % W;
        float dy = omb[(size_t)(c * 18 + kk * 2 + 0) * HW + hw];
        float dx = omb[(size_t)(c * 18 + kk * 2 + 1) * HW + hw];
        float mv = omb[(size_t)(126 + c * 9 + kk) * HW + hw];
        float m = 1.f / (1.f + __expf(-mv));
        float py = (float)hq + (float)(kk / 3 - 1) + dy;
        float px = (float)wq + (float)(kk % 3 - 1) + dx;
        float y0f = floorf(py), x0f = floorf(px);
        int y0 = (int)y0f, x0 = (int)x0f;
        float wy1 = py - y0f, wx1 = px - x0f;
        float wy0 = 1.f - wy1, wx0 = 1.f - wx1;
        float v00 = 0.f, v01 = 0.f, v10 = 0.f, v11 = 0.f;
        const float* xc = xb + (size_t)c * HW;
        bool yin0 = (y0 >= 0) & (y0 < H);
        bool yin1 = (y0 + 1 >= 0) & (y0 + 1 < H);
        bool xin0 = (x0 >= 0) & (x0 < W);
        bool xin1 = (x0 + 1 >= 0) & (x0 + 1 < W);
        if (yin0) {
            const float* rr = xc + (size_t)y0 * W;
            if (xin0) v00 = rr[x0];
            if (xin1) v01 = rr[x0 + 1];
        }
        if (yin1) {
            const float* rr = xc + (size_t)(y0 + 1) * W;
            if (xin0) v10 = rr[x0];
            if (xin1) v11 = rr[x0 + 1];
        }
        smp[tap * 64 + pxl] =
            (wy0 * wx0 * v00 + wy0 * wx1 * v01 + wy1 * wx0 * v10 + wy1 * wx1 * v11) * m;
    }
    __syncthreads();

    int pxl = tid & 63;
    int g = tid >> 6;
    int gu = __builtin_amdgcn_readfirstlane(g);
    const float* swb = wt2 + gu * 16;
    const float* bsb = bias + gu * 16;
    float acc[16];
#pragma unroll
    for (int o = 0; o < 16; ++o) acc[o] = 0.f;
    for (int tap = 0; tap < 63; ++tap) {
        float s = smp[tap * 64 + pxl];
        const float* sw = swb + tap * 64;
#pragma unroll
        for (int o = 0; o < 16; ++o) acc[o] += s * sw[o];
    }
    int hw = pxbase + pxl;
    size_t obase = (size_t)b * 64 * HW + (size_t)gu * 16 * HW + hw;
#pragma unroll
    for (int o = 0; o < 16; ++o)
        out[obase + (size_t)o * HW] = fmaxf(acc[o] + bsb[o], 0.f);
}

extern "C" void kernel_launch(void* const* d_in, const int* in_sizes, int n_in,
                              void* d_out, int out_size, void* d_ws, size_t ws_size,
                              hipStream_t stream) {
    (void)in_sizes; (void)n_in; (void)out_size; (void)ws_size;
    const float* inputs = (const float*)d_in[0];
    const float* w_in   = (const float*)d_in[1];  const float* b_in   = (const float*)d_in[2];
    const float* w_dn1a = (const float*)d_in[3];  const float* b_dn1a = (const float*)d_in[4];
    const float* w_dn1b = (const float*)d_in[5];  const float* b_dn1b = (const float*)d_in[6];
    const float* w_up1a = (const float*)d_in[7];  const float* b_up1a = (const float*)d_in[8];
    const float* wt_up1 = (const float*)d_in[9];  const float* bt_up1 = (const float*)d_in[10];
    const float* w_dn2a = (const float*)d_in[11]; const float* b_dn2a = (const float*)d_in[12];
    const float* w_dn2b = (const float*)d_in[13]; const float* b_dn2b = (const float*)d_in[14];
    const float* w_up2a = (const float*)d_in[15]; const float* b_up2a = (const float*)d_in[16];
    const float* wt_up2 = (const float*)d_in[17]; const float* bt_up2 = (const float*)d_in[18];
    const float* w_tra  = (const float*)d_in[19]; const float* b_tra  = (const float*)d_in[20];
    const float* w_trb  = (const float*)d_in[21]; const float* b_trb  = (const float*)d_in[22];
    const float* wt_tr  = (const float*)d_in[23]; const float* bt_tr  = (const float*)d_in[24];
    const float* w_out  = (const float*)d_in[25]; const float* b_out  = (const float*)d_in[26];
    const float* w_tf3a = (const float*)d_in[27]; const float* b_tf3a = (const float*)d_in[28];
    const float* w_tf3b = (const float*)d_in[29]; const float* b_tf3b = (const float*)d_in[30];
    const float* w_tf2  = (const float*)d_in[31]; const float* b_tf2  = (const float*)d_in[32];
    const float* w_om   = (const float*)d_in[33]; const float* b_om   = (const float*)d_in[34];
    const float* w_dc   = (const float*)d_in[35]; const float* b_dc   = (const float*)d_in[36];
    float* out = (float*)d_out;

    const int B = 2, nf = 32, H = 160, W = 160;
    const size_t n160 = (size_t)B * nf * 160 * 160;
    const size_t n80  = (size_t)B * nf * 80 * 80;
    const size_t n40  = (size_t)B * nf * 40 * 40;
    const size_t n20  = (size_t)B * nf * 20 * 20;

    float* ws = (float*)d_ws;
    float* F0    = ws;
    float* TMP80 = F0 + n160;
    float* F1    = TMP80 + n80;
    float* TMP40 = F1 + n80;
    float* F2    = TMP40 + n40;
    float* T20A  = F2 + n40;
    float* T20B  = T20A + n20;
    float* T40   = T20B + n20;
    float* T40B  = T40 + n40;
    float* T80   = T40B + n40;
    float* T80B  = T80 + n80;
    float* T160  = T80B + n80;
    float* TF    = T160 + n160;                       // (unused now; layout kept)
    float* XAREG = TF + n160;
    float* OM    = XAREG;
    float* WT2   = XAREG + 11757312;
    unsigned short* WBF    = (unsigned short*)(WT2 + 4032);
    unsigned short* XACL   = WBF + 27648;
    unsigned short* WOMF   = XACL + 11757312;
    unsigned short* OCL    = WOMF + 55296;
    unsigned short* MCL    = OCL + 1679616;
    unsigned short* TCL    = MCL + 1679616;
    unsigned short* CATCL  = TCL + 1679616;
    unsigned short* CATCL2 = CATCL + 860672;
    unsigned short* WTF2F  = CATCL2 + 279552;
    unsigned short* WOUTF  = WTF2F + 9216;
    unsigned short* WUP1F  = WOUTF + 9216;
    unsigned short* WUP2F  = WUP1F + 18432;

    const int bpc160 = 25;
    const int bpc80_128 = 13;
    const int bpc40_64  = 7;
    const int bpc20_64  = 2;

    // prep (merged: frags + borders for XACL/MCL/TCL/OCL) + conv_a fused
    prep_k<<<nblk(27648 + 4032 + 20 * 644 + 55296 + 9216 + 9216 + 18432 + 18432), TPB, 0, stream>>>(
        w_tf3b, w_dc, w_om, w_tf2, w_out, w_up1a, w_up2a,
        WBF, WOMF, WTF2F, WOUTF, WUP1F, WUP2F, WT2, XACL, MCL, TCL, OCL);
    conv3da_cl_k<<<B * 7 * 160, TPB, 0, stream>>>(inputs, w_tf3a, b_tf3a, XACL, B, H, W);

    // --- 2D U-Net branch ---
    conv2d_c4_k<1, 0, 0><<<B * 8 * bpc160, TPB, 0, stream>>>(inputs, nullptr, w_in, b_in, nullptr, F0, B, 7, 160, 160, nf, 8, bpc160);
    conv2d_s2_t4_k<128><<<B * nf * bpc80_128, 128, 0, stream>>>(F0, w_dn1a, b_dn1a, TMP80, B, nf, 160, 160, nf, bpc80_128);
    conv2d_t4_k<128, 1, 0><<<B * nf * bpc80_128, 128, 0, stream>>>(TMP80, w_dn1b, b_dn1b, nullptr, F1, B, nf, 80, 80, nf, bpc80_128);
    conv2d_s2_t4_k<64><<<B * nf * bpc40_64, 64, 0, stream>>>(F1, w_dn2a, b_dn2a, TMP40, B, nf, 80, 80, nf, bpc40_64);
    conv2d_t4_k<64, 1, 0><<<B * nf * bpc40_64, 64, 0, stream>>>(TMP40, w_dn2b, b_dn2b, nullptr, F2, B, nf, 40, 40, nf, bpc40_64);
    conv2d_s2_t4_k<64><<<B * nf * bpc20_64, 64, 0, stream>>>(F2, w_tra, b_tra, T20A, B, nf, 40, 40, nf, bpc20_64);
    conv2d_t4_k<64, 1, 0><<<B * nf * bpc20_64, 64, 0, stream>>>(T20A, w_trb, b_trb, nullptr, T20B, B, nf, 20, 20, nf, bpc20_64);
    convt2d_t4_k<64><<<B * nf * bpc40_64, 64, 0, stream>>>(T20B, wt_tr, bt_tr, T40, B, nf, 20, 20, bpc40_64);
    cat2cl_k<40, 40, 42, 52><<<nblk(2 * 42 * 52), TPB, 0, stream>>>(T40, F2, CATCL2);
    conv_up2a_mfma_k<<<B * 60, TPB, 0, stream>>>(CATCL2, WUP2F, b_up2a, T40B, B);
    convt2d_t4_k<128><<<B * nf * bpc80_128, 128, 0, stream>>>(T40B, wt_up2, bt_up2, T80, B, nf, 40, 40, bpc80_128);
    cat2cl_k<80, 80, 82, 82><<<nblk(2 * 82 * 82), TPB, 0, stream>>>(T80, F1, CATCL);
    conv_up1a_mfma_k<<<B * 200, TPB, 0, stream>>>(CATCL, WUP1F, b_up1a, T80B, B);
    convt2d_c4_k<<<B * 8 * bpc160, TPB, 0, stream>>>(T80B, wt_up1, bt_up1, T160, B, nf, 80, 80, bpc160);

    // --- conv3d_b + relu + mean (MFMA) -> MCL directly ---
    conv3db_mfma_k<<<B * 800, TPB, 0, stream>>>(XACL, WBF, b_tf3b, MCL, B, H, W);
    // FUSED = relu(conv_tf2(MEAN) + T160) -> TCL directly
    conv_nf_mfma_k<1, 1><<<B * 800, TPB, 0, stream>>>(MCL, WTF2F, b_tf2, T160, TCL, B);
    // w_out conv -> OCL directly
    conv_nf_mfma_k<0, 1><<<B * 800, TPB, 0, stream>>>(TCL, WOUTF, b_out, nullptr, OCL, B);
    // w_om head -> OM (fp32 ch-first, deform consumes)
    conv_om_mfma_k<<<B * 1600, TPB, 0, stream>>>(OCL, WOMF, b_om, OM, B);

    // --- deformable conv (two-phase) ---
    deform_conv2_k<<<B * (H * W / 64), TPB, 0, stream>>>(inputs, OM, WT2, b_dc, out, B, H, W);
}

// Round 24
// 402.180 us; speedup vs baseline: 2.4521x; 1.0434x over previous
//
#include <hip/hip_runtime.h>
#include <math.h>

// ---------------------------------------------------------------------------
// STDF forward, round 24: co-scheduling via block-partitioned fused launches.
// head_k = conv3da_cl || w_in conv || prep (all depend only on inputs/weights);
// mid_k = conv3db_mfma || convt2d_c4(up1) (independent of each other).
// Same-stream kernels can't overlap; fused grids can. Bit-identical values.
// Everything else identical to round 23 (419us verified).
// ---------------------------------------------------------------------------

#define TPB 256

static inline int nblk(long long total) { return (int)((total + TPB - 1) / TPB); }

typedef short bf16x8 __attribute__((ext_vector_type(8)));
typedef float f32x4 __attribute__((ext_vector_type(4)));

__device__ __forceinline__ unsigned short f2bf(float f) {
    unsigned int u = __float_as_uint(f);
    unsigned int r = u + 0x7FFFu + ((u >> 16) & 1u);   // RNE
    return (unsigned short)(r >> 16);
}

// ---------------- 3x3 conv2d, stride 1, 4 outputs/thread, block-uniform co --
template <int TB, int RELU, int HAS_RES>
__global__ __launch_bounds__(TB) void conv2d_t4_k(
    const float* __restrict__ in, const float* __restrict__ w,
    const float* __restrict__ bias, const float* __restrict__ res,
    float* __restrict__ out, int B, int Ci, int H, int W, int Co, int BPC) {
    __shared__ float ws_w[32 * 9];
    int co = (blockIdx.x / BPC) % Co;
    int b  = blockIdx.x / (BPC * Co);
    for (int i = threadIdx.x; i < Ci * 9; i += TB)
        ws_w[i] = w[(size_t)co * Ci * 9 + i];
    __syncthreads();
    int nq = W >> 2;
    int r = (blockIdx.x % BPC) * TB + threadIdx.x;
    if (r >= H * nq) return;
    int q = r % nq, ho = r / nq;
    int wb = q * 4;
    float bv = bias[co];
    float a0 = bv, a1 = bv, a2 = bv, a3 = bv;
    const float* ipb = in + (size_t)b * Ci * H * W;
    for (int ci = 0; ci < Ci; ++ci) {
        const float* ip = ipb + (size_t)ci * H * W;
        const float* wc = ws_w + ci * 9;
#pragma unroll
        for (int kh = 0; kh < 3; ++kh) {
            int y = ho - 1 + kh;
            if (y < 0 || y >= H) continue;
            const float* row = ip + (size_t)y * W + wb;
            float4 xv = *(const float4*)row;
            float xm = (wb > 0) ? row[-1] : 0.f;
            float xp = (wb + 4 < W) ? row[4] : 0.f;
            float w0 = wc[kh * 3], w1 = wc[kh * 3 + 1], w2 = wc[kh * 3 + 2];
            a0 += xm   * w0 + xv.x * w1 + xv.y * w2;
            a1 += xv.x * w0 + xv.y * w1 + xv.z * w2;
            a2 += xv.y * w0 + xv.z * w1 + xv.w * w2;
            a3 += xv.z * w0 + xv.w * w1 + xp   * w2;
        }
    }
    size_t o = ((size_t)(b * Co + co) * H + ho) * W + wb;
    if (HAS_RES) {
        float4 rv = *(const float4*)(res + o);
        a0 += rv.x; a1 += rv.y; a2 += rv.z; a3 += rv.w;
    }
    if (RELU) { a0 = fmaxf(a0, 0.f); a1 = fmaxf(a1, 0.f); a2 = fmaxf(a2, 0.f); a3 = fmaxf(a3, 0.f); }
    *(float4*)(out + o) = make_float4(a0, a1, a2, a3);
}

// ------------- 3x3 conv2d, stride 2, 4 outputs/thread, relu ----------------
template <int TB>
__global__ __launch_bounds__(TB) void conv2d_s2_t4_k(
    const float* __restrict__ in, const float* __restrict__ w,
    const float* __restrict__ bias, float* __restrict__ out,
    int B, int Ci, int Hi, int Wi, int Co, int BPC) {
    __shared__ float ws_w[32 * 9];
    int Ho = Hi >> 1, Wo = Wi >> 1;
    int co = (blockIdx.x / BPC) % Co;
    int b  = blockIdx.x / (BPC * Co);
    for (int i = threadIdx.x; i < Ci * 9; i += TB)
        ws_w[i] = w[(size_t)co * Ci * 9 + i];
    __syncthreads();
    int nq = Wo >> 2;
    int r = (blockIdx.x % BPC) * TB + threadIdx.x;
    if (r >= Ho * nq) return;
    int q = r % nq, ho = r / nq;
    int wb = q * 4;
    float bv = bias[co];
    float a0 = bv, a1 = bv, a2 = bv, a3 = bv;
    const float* ipb = in + (size_t)b * Ci * Hi * Wi;
    for (int ci = 0; ci < Ci; ++ci) {
        const float* ip = ipb + (size_t)ci * Hi * Wi;
        const float* wc = ws_w + ci * 9;
#pragma unroll
        for (int kh = 0; kh < 3; ++kh) {
            int y = 2 * ho - 1 + kh;
            if (y < 0 || y >= Hi) continue;
            const float* row = ip + (size_t)y * Wi;
            float z0 = (2 * wb - 1 >= 0) ? row[2 * wb - 1] : 0.f;
            float4 za = *(const float4*)(row + 2 * wb);
            float4 zb = *(const float4*)(row + 2 * wb + 4);
            float w0 = wc[kh * 3], w1 = wc[kh * 3 + 1], w2 = wc[kh * 3 + 2];
            a0 += z0   * w0 + za.x * w1 + za.y * w2;
            a1 += za.y * w0 + za.z * w1 + za.w * w2;
            a2 += za.w * w0 + zb.x * w1 + zb.y * w2;
            a3 += zb.y * w0 + zb.z * w1 + zb.w * w2;
        }
    }
    size_t o = ((size_t)(b * Co + co) * Ho + ho) * Wo + wb;
    *(float4*)(out + o) = make_float4(fmaxf(a0, 0.f), fmaxf(a1, 0.f), fmaxf(a2, 0.f), fmaxf(a3, 0.f));
}

// ------------- transposed conv 4x4 stride 2, 4 outputs/thread, relu --------
template <int TB>
__global__ __launch_bounds__(TB) void convt2d_t4_k(
    const float* __restrict__ in, const float* __restrict__ wt,
    const float* __restrict__ bias, float* __restrict__ out,
    int B, int C, int Hi, int Wi, int BPC) {
    __shared__ float ws_w[32 * 16];
    int Ho = 2 * Hi, Wo = 2 * Wi;
    int co = (blockIdx.x / BPC) % C;
    int b  = blockIdx.x / (BPC * C);
    for (int i = threadIdx.x; i < C * 16; i += TB) {
        int ci = i >> 4, t = i & 15;
        ws_w[i] = wt[((size_t)ci * C + co) * 16 + t];
    }
    __syncthreads();
    int nq = Wo >> 2;
    int r = (blockIdx.x % BPC) * TB + threadIdx.x;
    if (r >= Ho * nq) return;
    int q = r % nq, ho = r / nq;
    int wb = q * 4;
    int p = ho & 1;
    int iy0 = (ho + p) / 2 - 1;
    int iy1 = iy0 + 1;
    int ix0 = wb / 2 - 1;
    bool vy0 = (iy0 >= 0) && (iy0 < Hi);
    bool vy1 = (iy1 >= 0) && (iy1 < Hi);
    float bv = bias[co];
    float a0 = bv, a1 = bv, a2 = bv, a3 = bv;
    const float* ipb = in + (size_t)b * C * Hi * Wi;
    for (int ci = 0; ci < C; ++ci) {
        const float* ip = ipb + (size_t)ci * Hi * Wi;
        float u0 = 0, u1 = 0, u2 = 0, u3 = 0, v0 = 0, v1 = 0, v2 = 0, v3 = 0;
        if (vy0) {
            const float* rw = ip + (size_t)iy0 * Wi;
            if (ix0 >= 0) u0 = rw[ix0];
            u1 = rw[ix0 + 1]; u2 = rw[ix0 + 2];
            if (ix0 + 3 < Wi) u3 = rw[ix0 + 3];
        }
        if (vy1) {
            const float* rw = ip + (size_t)iy1 * Wi;
            if (ix0 >= 0) v0 = rw[ix0];
            v1 = rw[ix0 + 1]; v2 = rw[ix0 + 2];
            if (ix0 + 3 < Wi) v3 = rw[ix0 + 3];
        }
        const float* wr0 = ws_w + ci * 16 + (3 - p) * 4;
        const float* wr1 = ws_w + ci * 16 + (1 - p) * 4;
        a0 += u0 * wr0[3] + u1 * wr0[1] + v0 * wr1[3] + v1 * wr1[1];
        a1 += u1 * wr0[2] + u2 * wr0[0] + v1 * wr1[2] + v2 * wr1[0];
        a2 += u1 * wr0[3] + u2 * wr0[1] + v1 * wr1[3] + v2 * wr1[1];
        a3 += u2 * wr0[2] + u3 * wr0[0] + v2 * wr1[2] + v3 * wr1[0];
    }
    size_t o = ((size_t)(b * C + co) * Ho + ho) * Wo + wb;
    *(float4*)(out + o) = make_float4(fmaxf(a0, 0.f), fmaxf(a1, 0.f), fmaxf(a2, 0.f), fmaxf(a3, 0.f));
}

// ======================= device bodies for fused launches ===================

// ---- prep body: B-frag packs + wdc transpose + CL border zero (20 planes) --
__device__ __forceinline__ void prep_body(
    int i, const float* __restrict__ wb, const float* __restrict__ wdc,
    const float* __restrict__ wom, const float* __restrict__ wtf2,
    const float* __restrict__ wout, const float* __restrict__ wup1a,
    const float* __restrict__ wup2a,
    unsigned short* __restrict__ wbf, unsigned short* __restrict__ womf,
    unsigned short* __restrict__ wtf2f, unsigned short* __restrict__ woutf,
    unsigned short* __restrict__ wup1f, unsigned short* __restrict__ wup2f,
    float* __restrict__ wt2, unsigned short* __restrict__ xacl,
    unsigned short* __restrict__ mcl, unsigned short* __restrict__ tcl,
    unsigned short* __restrict__ ocl) {
    if (i < 27648) {                          // conv3db B-frags
        int j = i & 7;
        int l = (i >> 3) & 63;
        int coH = (i >> 9) & 1;
        int tap = i >> 10;
        int ci = ((l >> 4) << 3) + j;
        int co = (coH << 4) + (l & 15);
        wbf[i] = f2bf(wb[(size_t)(co * 32 + ci) * 27 + tap]);
        return;
    }
    int i2 = i - 27648;
    if (i2 < 4032) {                          // deform weight transpose
        int o = i2 & 63, ck = i2 >> 6;
        wt2[i2] = wdc[o * 63 + ck];
        return;
    }
    int i3 = i2 - 4032;
    if (i3 < 20 * 644) {                      // borders: XACL(14)+MCL(2)+TCL(2)+OCL(2)
        int pl = i3 / 644, e = i3 % 644;
        int off;
        if (e < 162)      off = e;
        else if (e < 324) off = 161 * 162 + (e - 162);
        else if (e < 484) off = (e - 324 + 1) * 162;
        else              off = (e - 484 + 1) * 162 + 161;
        unsigned short* base;
        int pl2;
        if (pl < 14)      { base = xacl; pl2 = pl; }
        else if (pl < 16) { base = mcl;  pl2 = pl - 14; }
        else if (pl < 18) { base = tcl;  pl2 = pl - 16; }
        else              { base = ocl;  pl2 = pl - 18; }
        uint4* d = (uint4*)(base + ((size_t)pl2 * 26244 + off) * 32);
        uint4 z = make_uint4(0, 0, 0, 0);
        d[0] = z; d[1] = z; d[2] = z; d[3] = z;
        return;
    }
    int i4 = i3 - 20 * 644;
    if (i4 < 55296) {                         // w_om B-frags
        int j = i4 & 7;
        int l = (i4 >> 3) & 63;
        int nt = (i4 >> 9) % 12;
        int tap = i4 / 6144;
        int ci = ((l >> 4) << 3) + j;
        int co = nt * 16 + (l & 15);
        womf[i4] = (co < 189) ? f2bf(wom[((size_t)co * 32 + ci) * 9 + tap]) : (unsigned short)0;
        return;
    }
    int i5 = i4 - 55296;
    if (i5 < 9216) {                          // tf2 B-frags
        int j = i5 & 7;
        int l = (i5 >> 3) & 63;
        int q = i5 >> 9;
        int coH = q & 1, tap = q >> 1;
        int ci = ((l >> 4) << 3) + j;
        int co = coH * 16 + (l & 15);
        wtf2f[i5] = f2bf(wtf2[((size_t)co * 32 + ci) * 9 + tap]);
        return;
    }
    int i6 = i5 - 9216;
    if (i6 < 9216) {                          // w_out B-frags
        int j = i6 & 7;
        int l = (i6 >> 3) & 63;
        int q = i6 >> 9;
        int coH = q & 1, tap = q >> 1;
        int ci = ((l >> 4) << 3) + j;
        int co = coH * 16 + (l & 15);
        woutf[i6] = f2bf(wout[((size_t)co * 32 + ci) * 9 + tap]);
        return;
    }
    int i7 = i6 - 9216;
    if (i7 < 18432) {                         // up1a B-frags
        int j = i7 & 7;
        int l = (i7 >> 3) & 63;
        int q = i7 >> 9;
        int coH = q & 1, kc = (q >> 1) & 1, tap = q >> 2;
        int ci = kc * 32 + ((l >> 4) << 3) + j;
        int co = coH * 16 + (l & 15);
        wup1f[i7] = f2bf(wup1a[((size_t)co * 64 + ci) * 9 + tap]);
        return;
    }
    int i8 = i7 - 18432;
    if (i8 >= 18432) return;                  // up2a B-frags
    int j = i8 & 7;
    int l = (i8 >> 3) & 63;
    int q = i8 >> 9;
    int coH = q & 1, kc = (q >> 1) & 1, tap = q >> 2;
    int ci = kc * 32 + ((l >> 4) << 3) + j;
    int co = coH * 16 + (l & 15);
    wup2f[i8] = f2bf(wup2a[((size_t)co * 64 + ci) * 9 + tap]);
}

// ---- conv3d_a body: row-wise, writes XACL bf16 CL ---------------------------
__device__ __forceinline__ void conv3da_body(
    int blk, int tid, float* __restrict__ xin /*1458*/, float* __restrict__ wsa /*864*/,
    const float* __restrict__ x, const float* __restrict__ wa,
    const float* __restrict__ ba, unsigned short* __restrict__ xacl,
    int B, int H, int W) {
    int y  = blk % 160;
    int d  = (blk / 160) % 7;
    int b  = blk / 1120;
    for (int i = tid; i < 3 * 3 * 162; i += TPB) {
        int xx = i % 162; int t = i / 162; int yy = t % 3; int dz = t / 3;
        int gd = d - 1 + dz, gy = y - 1 + yy, gx = xx - 1;
        float v = 0.f;
        if (gd >= 0 && gd < 7 && gy >= 0 && gy < H && gx >= 0 && gx < W)
            v = x[((size_t)(b * 7 + gd)) * H * W + (size_t)gy * W + gx];
        xin[i] = v;
    }
    for (int i = tid; i < 864; i += TPB) wsa[i] = wa[i];
    __syncthreads();
    int co = tid & 31;
    int xi0 = tid >> 5;
    float bv = ba[co];
    const float* wc = wsa + co * 27;
    size_t rowbase = (((size_t)(b * 7 + d) * 162 + (y + 1)) * 162 + 1) * 32 + co;
    for (int k = 0; k < 20; ++k) {
        int gx = k * 8 + xi0;
        float acc = bv;
#pragma unroll
        for (int dz = 0; dz < 3; ++dz)
#pragma unroll
            for (int yy = 0; yy < 3; ++yy)
#pragma unroll
                for (int kw = 0; kw < 3; ++kw)
                    acc += xin[dz * 486 + yy * 162 + gx + kw] * wc[dz * 9 + yy * 3 + kw];
        xacl[rowbase + (size_t)gx * 32] = f2bf(fmaxf(acc, 0.f));
    }
}

// ---- w_in conv body: Ci=7 -> 32, 160x160, 4x4 per thread, relu -------------
__device__ __forceinline__ void win_body(
    int blk, int tid, float* __restrict__ ws_w /*252*/,
    const float* __restrict__ in, const float* __restrict__ w,
    const float* __restrict__ bias, float* __restrict__ out) {
    const int Ci = 7, H = 160, W = 160, Co = 32, COG = 8, BPC = 25;
    int cog = (blk / BPC) % COG;
    int b   = blk / (BPC * COG);
    int co0 = cog * 4;
    int nw = Ci * 9;
    for (int i = tid; i < 4 * nw; i += TPB) {
        int cr = i / nw; int co = co0 + cr;
        ws_w[i] = (co < Co) ? w[(size_t)co * nw + (i - cr * nw)] : 0.f;
    }
    __syncthreads();
    int nq = W >> 2;
    int r = (blk % BPC) * TPB + tid;
    if (r >= H * nq) return;
    int q = r % nq, ho = r / nq;
    int wb = q * 4;
    float a[4][4];
#pragma unroll
    for (int cr = 0; cr < 4; ++cr) {
        float bv = (co0 + cr < Co) ? bias[co0 + cr] : 0.f;
        a[cr][0] = bv; a[cr][1] = bv; a[cr][2] = bv; a[cr][3] = bv;
    }
    const float* ipb = in + (size_t)b * Ci * H * W;
    for (int ci = 0; ci < Ci; ++ci) {
        const float* ip = ipb + (size_t)ci * H * W;
#pragma unroll
        for (int kh = 0; kh < 3; ++kh) {
            int y = ho - 1 + kh;
            if (y < 0 || y >= H) continue;
            const float* row = ip + (size_t)y * W + wb;
            float4 xv = *(const float4*)row;
            float x_[6];
            x_[0] = (wb > 0) ? row[-1] : 0.f;
            x_[5] = (wb + 4 < W) ? row[4] : 0.f;
            x_[1] = xv.x; x_[2] = xv.y; x_[3] = xv.z; x_[4] = xv.w;
#pragma unroll
            for (int cr = 0; cr < 4; ++cr) {
                const float* wc = ws_w + cr * nw + ci * 9 + kh * 3;
                float w0 = wc[0], w1 = wc[1], w2 = wc[2];
                a[cr][0] += x_[0] * w0 + x_[1] * w1 + x_[2] * w2;
                a[cr][1] += x_[1] * w0 + x_[2] * w1 + x_[3] * w2;
                a[cr][2] += x_[2] * w0 + x_[3] * w1 + x_[4] * w2;
                a[cr][3] += x_[3] * w0 + x_[4] * w1 + x_[5] * w2;
            }
        }
    }
#pragma unroll
    for (int cr = 0; cr < 4; ++cr) {
        size_t o = ((size_t)(b * Co + co0 + cr) * H + ho) * W + wb;
        *(float4*)(out + o) = make_float4(fmaxf(a[cr][0], 0.f), fmaxf(a[cr][1], 0.f),
                                          fmaxf(a[cr][2], 0.f), fmaxf(a[cr][3], 0.f));
    }
}

// ---- fused head: conv3da_cl || w_in conv || prep ---------------------------
__global__ __launch_bounds__(TPB) void head_k(
    const float* __restrict__ x, const float* __restrict__ wa, const float* __restrict__ ba,
    unsigned short* __restrict__ xacl,
    const float* __restrict__ w_in, const float* __restrict__ b_in, float* __restrict__ F0,
    const float* __restrict__ wb, const float* __restrict__ wdc,
    const float* __restrict__ wom, const float* __restrict__ wtf2,
    const float* __restrict__ wout, const float* __restrict__ wup1a,
    const float* __restrict__ wup2a,
    unsigned short* __restrict__ wbf, unsigned short* __restrict__ womf,
    unsigned short* __restrict__ wtf2f, unsigned short* __restrict__ woutf,
    unsigned short* __restrict__ wup1f, unsigned short* __restrict__ wup2f,
    float* __restrict__ wt2,
    unsigned short* __restrict__ mcl, unsigned short* __restrict__ tcl,
    unsigned short* __restrict__ ocl, int B, int H, int W) {
    __shared__ float smem[2322];
    int blk = blockIdx.x;
    int tid = threadIdx.x;
    if (blk < 2240) {
        conv3da_body(blk, tid, smem, smem + 1458, x, wa, ba, xacl, B, H, W);
        return;
    }
    blk -= 2240;
    if (blk < 400) {
        win_body(blk, tid, smem, x, w_in, b_in, F0);
        return;
    }
    blk -= 400;
    prep_body(blk * TPB + tid, wb, wdc, wom, wtf2, wout, wup1a, wup2a,
              wbf, womf, wtf2f, woutf, wup1f, wup2f, wt2, xacl, mcl, tcl, ocl);
}

// ---- conv3d_b body (A-load hoisted), writes MCL bf16 CL ---------------------
__device__ __forceinline__ void conv3db_body(
    int blk, int tid, const unsigned short* __restrict__ xacl,
    const unsigned short* __restrict__ wbf, const float* __restrict__ bb,
    unsigned short* __restrict__ mcl) {
    int b = blk / 800;
    int rem = blk % 800;
    int y = rem / 5;
    int xp = rem % 5;
    int l = tid & 63;
    int wv = tid >> 6;
    int mt = wv & 1, coH = wv >> 1;
    int x0 = xp * 32 + mt * 16;
    int co = coH * 16 + (l & 15);
    float bv = bb[co];
    f32x4 acc[7];
#pragma unroll
    for (int d = 0; d < 7; ++d) { acc[d][0] = bv; acc[d][1] = bv; acc[d][2] = bv; acc[d][3] = bv; }

    int ubase = (y * 162 + x0 + (l & 15)) * 32 + ((l >> 4) << 3);
    const unsigned short* xb = xacl + (size_t)b * 5878656;
    const unsigned short* wbase = wbf + ((size_t)coH * 64 + l) * 8;

    for (int j2 = 0; j2 < 9; ++j2) {
        int off2 = (j2 / 3) * 5184 + (j2 % 3) * 32;
        bf16x8 bf0 = *reinterpret_cast<const bf16x8*>(wbase + (size_t)(0 * 9 + j2) * 1024);
        bf16x8 bf1 = *reinterpret_cast<const bf16x8*>(wbase + (size_t)(1 * 9 + j2) * 1024);
        bf16x8 bf2 = *reinterpret_cast<const bf16x8*>(wbase + (size_t)(2 * 9 + j2) * 1024);
#pragma unroll
        for (int dz = 0; dz < 7; ++dz) {
            bf16x8 af = *reinterpret_cast<const bf16x8*>(xb + (size_t)dz * 839808 + ubase + off2);
            if (dz + 1 < 7) acc[dz + 1] = __builtin_amdgcn_mfma_f32_16x16x32_bf16(af, bf0, acc[dz + 1], 0, 0, 0);
            acc[dz] = __builtin_amdgcn_mfma_f32_16x16x32_bf16(af, bf1, acc[dz], 0, 0, 0);
            if (dz - 1 >= 0) acc[dz - 1] = __builtin_amdgcn_mfma_f32_16x16x32_bf16(af, bf2, acc[dz - 1], 0, 0, 0);
        }
    }

    int xo = x0 + ((l >> 4) << 2);
    size_t clbase = ((size_t)b * 26244 + (size_t)(y + 1) * 162 + (xo + 1)) * 32 + co;
#pragma unroll
    for (int r = 0; r < 4; ++r) {
        float s = 0.f;
#pragma unroll
        for (int d = 0; d < 7; ++d) s += fmaxf(acc[d][r], 0.f);
        mcl[clbase + (size_t)r * 32] = f2bf(s * (1.f / 7.f));
    }
}

// ---- convt2d_c4 body (up1: 80->160, 4 co per thread) ------------------------
__device__ __forceinline__ void convtc4_body(
    int blk, int tid, float* __restrict__ ws /*2048 floats*/,
    const float* __restrict__ in, const float* __restrict__ wt,
    const float* __restrict__ bias, float* __restrict__ out) {
    const int C = 32, Hi = 80, Wi = 80, BPC = 25;
    int Ho = 2 * Hi, Wo = 2 * Wi;
    int cog = (blk / BPC) % (C / 4);
    int b   = blk / (BPC * (C / 4));
    int co0 = cog * 4;
    for (int i = tid; i < 4 * C * 16; i += TPB) {
        int cr = i / (C * 16); int j = i % (C * 16);
        int ci = j >> 4, t = j & 15;
        ws[cr * 512 + j] = wt[((size_t)ci * C + (co0 + cr)) * 16 + t];
    }
    __syncthreads();
    int nq = Wo >> 2;
    int r = (blk % BPC) * TPB + tid;
    if (r >= Ho * nq) return;
    int q = r % nq, ho = r / nq;
    int wb = q * 4;
    int p = ho & 1;
    int iy0 = (ho + p) / 2 - 1;
    int iy1 = iy0 + 1;
    int ix0 = wb / 2 - 1;
    bool vy0 = (iy0 >= 0) && (iy0 < Hi);
    bool vy1 = (iy1 >= 0) && (iy1 < Hi);
    float a[4][4];
#pragma unroll
    for (int cr = 0; cr < 4; ++cr) {
        float bv = bias[co0 + cr];
        a[cr][0] = bv; a[cr][1] = bv; a[cr][2] = bv; a[cr][3] = bv;
    }
    const float* ipb = in + (size_t)b * C * Hi * Wi;
    for (int ci = 0; ci < C; ++ci) {
        const float* ip = ipb + (size_t)ci * Hi * Wi;
        float u0 = 0, u1 = 0, u2 = 0, u3 = 0, v0 = 0, v1 = 0, v2 = 0, v3 = 0;
        if (vy0) {
            const float* rw = ip + (size_t)iy0 * Wi;
            if (ix0 >= 0) u0 = rw[ix0];
            u1 = rw[ix0 + 1]; u2 = rw[ix0 + 2];
            if (ix0 + 3 < Wi) u3 = rw[ix0 + 3];
        }
        if (vy1) {
            const float* rw = ip + (size_t)iy1 * Wi;
            if (ix0 >= 0) v0 = rw[ix0];
            v1 = rw[ix0 + 1]; v2 = rw[ix0 + 2];
            if (ix0 + 3 < Wi) v3 = rw[ix0 + 3];
        }
#pragma unroll
        for (int cr = 0; cr < 4; ++cr) {
            const float* wr0 = ws + cr * 512 + ci * 16 + (3 - p) * 4;
            const float* wr1 = ws + cr * 512 + ci * 16 + (1 - p) * 4;
            a[cr][0] += u0 * wr0[3] + u1 * wr0[1] + v0 * wr1[3] + v1 * wr1[1];
            a[cr][1] += u1 * wr0[2] + u2 * wr0[0] + v1 * wr1[2] + v2 * wr1[0];
            a[cr][2] += u1 * wr0[3] + u2 * wr0[1] + v1 * wr1[3] + v2 * wr1[1];
            a[cr][3] += u2 * wr0[2] + u3 * wr0[0] + v2 * wr1[2] + v3 * wr1[0];
        }
    }
#pragma unroll
    for (int cr = 0; cr < 4; ++cr) {
        size_t o = ((size_t)(b * C + co0 + cr) * Ho + ho) * Wo + wb;
        *(float4*)(out + o) = make_float4(fmaxf(a[cr][0], 0.f), fmaxf(a[cr][1], 0.f),
                                          fmaxf(a[cr][2], 0.f), fmaxf(a[cr][3], 0.f));
    }
}

// ---- fused mid: conv3db_mfma || convt2d_c4(up1) -----------------------------
__global__ __launch_bounds__(TPB) void mid_k(
    const unsigned short* __restrict__ xacl, const unsigned short* __restrict__ wbf,
    const float* __restrict__ bb, unsigned short* __restrict__ mcl,
    const float* __restrict__ t80b, const float* __restrict__ wt_up1,
    const float* __restrict__ bt_up1, float* __restrict__ t160, int B) {
    __shared__ float smem[2048];
    int blk = blockIdx.x;
    int tid = threadIdx.x;
    if (blk < B * 800) {
        conv3db_body(blk, tid, xacl, wbf, bb, mcl);
        return;
    }
    blk -= B * 800;
    convtc4_body(blk, tid, smem, t80b, wt_up1, bt_up1, t160);
}

// ---- concat fp32 ch-first -> bf16 CL padded: generic (PW wide, HxW valid) --
template <int HH, int WW, int PH, int PW>
__global__ __launch_bounds__(TPB) void cat2cl_k(
    const float* __restrict__ a, const float* __restrict__ c2,
    unsigned short* __restrict__ dst) {
    int idx = blockIdx.x * TPB + threadIdx.x;
    if (idx >= 2 * PH * PW) return;
    int pos = idx % (PH * PW);
    int b = idx / (PH * PW);
    int y = pos / PW, x = pos % PW;
    uint4* d = (uint4*)(dst + (size_t)idx * 64);
    if (y == 0 || y > HH || x == 0 || x > WW) {
        uint4 z = make_uint4(0, 0, 0, 0);
#pragma unroll
        for (int k = 0; k < 8; ++k) d[k] = z;
        return;
    }
    size_t off = (size_t)(y - 1) * WW + (x - 1);
    const float* sa = a + (size_t)b * 32 * (HH * WW) + off;
    const float* sc = c2 + (size_t)b * 32 * (HH * WW) + off;
    unsigned int pk[32];
#pragma unroll
    for (int j = 0; j < 16; ++j) {
        float v0 = sa[(size_t)(2 * j) * (HH * WW)];
        float v1 = sa[(size_t)(2 * j + 1) * (HH * WW)];
        pk[j] = (unsigned int)f2bf(v0) | ((unsigned int)f2bf(v1) << 16);
    }
#pragma unroll
    for (int j = 0; j < 16; ++j) {
        float v0 = sc[(size_t)(2 * j) * (HH * WW)];
        float v1 = sc[(size_t)(2 * j + 1) * (HH * WW)];
        pk[16 + j] = (unsigned int)f2bf(v0) | ((unsigned int)f2bf(v1) << 16);
    }
#pragma unroll
    for (int k = 0; k < 8; ++k)
        d[k] = make_uint4(pk[4 * k], pk[4 * k + 1], pk[4 * k + 2], pk[4 * k + 3]);
}

// ---- N=32 K=288 160-level conv, bf16 MFMA, writes bf16 CL directly ---------
template <int HAS_RES, int RELU>
__global__ __launch_bounds__(TPB) void conv_nf_mfma_k(
    const unsigned short* __restrict__ icl, const unsigned short* __restrict__ wf,
    const float* __restrict__ bias, const float* __restrict__ res,
    unsigned short* __restrict__ outcl, int B) {
    int blk = blockIdx.x;
    int b = blk / 800;
    int rem = blk % 800;
    int y = rem / 5;
    int xp = rem % 5;
    int tid = threadIdx.x;
    int l = tid & 63;
    int wv = tid >> 6;
    int mt = wv & 1, coH = wv >> 1;
    int x0 = xp * 32 + mt * 16;
    int co = coH * 16 + (l & 15);
    float bv = bias[co];
    f32x4 acc;
    acc[0] = bv; acc[1] = bv; acc[2] = bv; acc[3] = bv;
    int ubase = (y * 162 + x0 + (l & 15)) * 32 + ((l >> 4) << 3);
    const unsigned short* ib = icl + (size_t)b * 839808;
    const unsigned short* wl = wf + (size_t)l * 8;
#pragma unroll
    for (int tap = 0; tap < 9; ++tap) {
        int off = ((tap / 3) * 162 + (tap % 3)) * 32;
        bf16x8 af = *reinterpret_cast<const bf16x8*>(ib + ubase + off);
        bf16x8 bf = *reinterpret_cast<const bf16x8*>(wl + (size_t)(tap * 2 + coH) * 512);
        acc = __builtin_amdgcn_mfma_f32_16x16x32_bf16(af, bf, acc, 0, 0, 0);
    }
    int xo = x0 + ((l >> 4) << 2);
    size_t obase = ((size_t)(b * 32 + co)) * 25600 + (size_t)y * 160 + xo;  // residual (fp32 ch-first)
    size_t clbase = ((size_t)b * 26244 + (size_t)(y + 1) * 162 + (xo + 1)) * 32 + co;
#pragma unroll
    for (int r = 0; r < 4; ++r) {
        float v = acc[r];
        if (HAS_RES) v += res[obase + r];
        if (RELU) v = fmaxf(v, 0.f);
        outcl[clbase + (size_t)r * 32] = f2bf(v);
    }
}

// ---- up1a concat conv as bf16 MFMA: M=80x80, N=32, K=576 -------------------
__global__ __launch_bounds__(TPB) void conv_up1a_mfma_k(
    const unsigned short* __restrict__ catcl, const unsigned short* __restrict__ wf,
    const float* __restrict__ bias, float* __restrict__ out, int B) {
    int blk = blockIdx.x;
    int b = blk / 200;
    int rem = blk % 200;
    int tid = threadIdx.x;
    int l = tid & 63;
    int wv = tid >> 6;
    int mtile = rem * 2 + (wv & 1);
    int coH = wv >> 1;
    int y = mtile / 5, x0 = (mtile % 5) * 16;
    int co = coH * 16 + (l & 15);
    float bv = bias[co];
    f32x4 acc;
    acc[0] = bv; acc[1] = bv; acc[2] = bv; acc[3] = bv;
    int ubase = (y * 82 + x0 + (l & 15)) * 64 + ((l >> 4) << 3);
    const unsigned short* cb = catcl + (size_t)b * 430336;
    const unsigned short* wl = wf + (size_t)l * 8;
#pragma unroll
    for (int tap = 0; tap < 9; ++tap) {
        int off = ((tap / 3) * 82 + (tap % 3)) * 64;
#pragma unroll
        for (int kc = 0; kc < 2; ++kc) {
            bf16x8 af = *reinterpret_cast<const bf16x8*>(cb + ubase + off + kc * 32);
            bf16x8 bf = *reinterpret_cast<const bf16x8*>(wl + (size_t)(((tap * 2 + kc) * 2 + coH)) * 512);
            acc = __builtin_amdgcn_mfma_f32_16x16x32_bf16(af, bf, acc, 0, 0, 0);
        }
    }
    int xo = x0 + ((l >> 4) << 2);
    size_t obase = ((size_t)(b * 32 + co)) * 6400 + (size_t)y * 80 + xo;
#pragma unroll
    for (int r = 0; r < 4; ++r)
        out[obase + r] = fmaxf(acc[r], 0.f);
}

// ---- up2a concat conv as bf16 MFMA: M=40x40, N=32, K=576, PW=52 ------------
__global__ __launch_bounds__(TPB) void conv_up2a_mfma_k(
    const unsigned short* __restrict__ catcl, const unsigned short* __restrict__ wf,
    const float* __restrict__ bias, float* __restrict__ out, int B) {
    const int PW = 52;
    int blk = blockIdx.x;
    int b = blk / 60;
    int rem = blk % 60;
    int tid = threadIdx.x;
    int l = tid & 63;
    int wv = tid >> 6;
    int mtile = rem * 2 + (wv & 1);
    int coH = wv >> 1;
    int y = mtile / 3, x0 = (mtile % 3) * 16;
    int co = coH * 16 + (l & 15);
    float bv = bias[co];
    f32x4 acc;
    acc[0] = bv; acc[1] = bv; acc[2] = bv; acc[3] = bv;
    int ubase = (y * PW + x0 + (l & 15)) * 64 + ((l >> 4) << 3);
    const unsigned short* cb = catcl + (size_t)b * (42 * PW * 64);
    const unsigned short* wl = wf + (size_t)l * 8;
#pragma unroll
    for (int tap = 0; tap < 9; ++tap) {
        int off = ((tap / 3) * PW + (tap % 3)) * 64;
#pragma unroll
        for (int kc = 0; kc < 2; ++kc) {
            bf16x8 af = *reinterpret_cast<const bf16x8*>(cb + ubase + off + kc * 32);
            bf16x8 bf = *reinterpret_cast<const bf16x8*>(wl + (size_t)(((tap * 2 + kc) * 2 + coH)) * 512);
            acc = __builtin_amdgcn_mfma_f32_16x16x32_bf16(af, bf, acc, 0, 0, 0);
        }
    }
    int xo = x0 + ((l >> 4) << 2);
    size_t obase = ((size_t)(b * 32 + co)) * 1600 + (size_t)y * 40;
#pragma unroll
    for (int r = 0; r < 4; ++r) {
        int ox = xo + r;
        if (ox < 40) out[obase + ox] = fmaxf(acc[r], 0.f);
    }
}

// ---- w_om head as bf16 MFMA implicit GEMM (verified r18) -------------------
__global__ __launch_bounds__(TPB) void conv_om_mfma_k(
    const unsigned short* __restrict__ ocl, const unsigned short* __restrict__ womf,
    const float* __restrict__ bias, float* __restrict__ out, int B) {
    int blk = blockIdx.x;
    int b = blk / 1600;
    int rem = blk % 1600;
    int y = rem / 10;
    int xs = rem % 10;
    int tid = threadIdx.x;
    int l = tid & 63;
    int wv = tid >> 6;
    int x0 = xs * 16;
    f32x4 acc[3];
#pragma unroll
    for (int t = 0; t < 3; ++t) {
        int co = (wv * 3 + t) * 16 + (l & 15);
        float bv = (co < 189) ? bias[co] : 0.f;
        acc[t][0] = bv; acc[t][1] = bv; acc[t][2] = bv; acc[t][3] = bv;
    }
    int ubase = (y * 162 + x0 + (l & 15)) * 32 + ((l >> 4) << 3);
    const unsigned short* ob = ocl + (size_t)b * 839808;
    const unsigned short* wl = womf + (size_t)l * 8;
#pragma unroll
    for (int tap = 0; tap < 9; ++tap) {
        int off = ((tap / 3) * 162 + (tap % 3)) * 32;
        bf16x8 af = *reinterpret_cast<const bf16x8*>(ob + ubase + off);
#pragma unroll
        for (int t = 0; t < 3; ++t) {
            int nt = wv * 3 + t;
            bf16x8 bf = *reinterpret_cast<const bf16x8*>(wl + (size_t)(tap * 12 + nt) * 512);
            acc[t] = __builtin_amdgcn_mfma_f32_16x16x32_bf16(af, bf, acc[t], 0, 0, 0);
        }
    }
    int xo = x0 + ((l >> 4) << 2);
#pragma unroll
    for (int t = 0; t < 3; ++t) {
        int co = (wv * 3 + t) * 16 + (l & 15);
        if (co >= 189) continue;
        size_t obase = ((size_t)(b * 189 + co)) * 25600 + (size_t)y * 160 + xo;
#pragma unroll
        for (int r = 0; r < 4; ++r) out[obase + r] = acc[t][r];
    }
}

// ------------- two-phase modulated deformable conv ---------------------------
__global__ __launch_bounds__(TPB) void deform_conv2_k(
    const float* __restrict__ x, const float* __restrict__ om,
    const float* __restrict__ wt2, const float* __restrict__ bias,
    float* __restrict__ out, int B, int H, int W) {
    __shared__ float smp[63 * 64];
    const int HW = H * W;
    int blk = blockIdx.x;
    int b = blk / (HW / 64);
    int pxbase = (blk % (HW / 64)) * 64;
    int tid = threadIdx.x;
    const float* omb = om + (size_t)b * 189 * HW;
    const float* xb = x + (size_t)b * 7 * HW;

#pragma unroll 4
    for (int k = 0; k < 16; ++k) {
        int it = tid + k * 256;
        if (it >= 4032) break;
        int pxl = it & 63;
        int tap = it >> 6;
        int c = tap / 9, kk = tap % 9;
        int hw = pxbase + pxl;
        int hq = hw / W, wq = hw % W;
        float dy = omb[(size_t)(c * 18 + kk * 2 + 0) * HW + hw];
        float dx = omb[(size_t)(c * 18 + kk * 2 + 1) * HW + hw];
        float mv = omb[(size_t)(126 + c * 9 + kk) * HW + hw];
        float m = 1.f / (1.f + __expf(-mv));
        float py = (float)hq + (float)(kk / 3 - 1) + dy;
        float px = (float)wq + (float)(kk % 3 - 1) + dx;
        float y0f = floorf(py), x0f = floorf(px);
        int y0 = (int)y0f, x0 = (int)x0f;
        float wy1 = py - y0f, wx1 = px - x0f;
        float wy0 = 1.f - wy1, wx0 = 1.f - wx1;
        float v00 = 0.f, v01 = 0.f, v10 = 0.f, v11 = 0.f;
        const float* xc = xb + (size_t)c * HW;
        bool yin0 = (y0 >= 0) & (y0 < H);
        bool yin1 = (y0 + 1 >= 0) & (y0 + 1 < H);
        bool xin0 = (x0 >= 0) & (x0 < W);
        bool xin1 = (x0 + 1 >= 0) & (x0 + 1 < W);
        if (yin0) {
            const float* rr = xc + (size_t)y0 * W;
            if (xin0) v00 = rr[x0];
            if (xin1) v01 = rr[x0 + 1];
        }
        if (yin1) {
            const float* rr = xc + (size_t)(y0 + 1) * W;
            if (xin0) v10 = rr[x0];
            if (xin1) v11 = rr[x0 + 1];
        }
        smp[tap * 64 + pxl] =
            (wy0 * wx0 * v00 + wy0 * wx1 * v01 + wy1 * wx0 * v10 + wy1 * wx1 * v11) * m;
    }
    __syncthreads();

    int pxl = tid & 63;
    int g = tid >> 6;
    int gu = __builtin_amdgcn_readfirstlane(g);
    const float* swb = wt2 + gu * 16;
    const float* bsb = bias + gu * 16;
    float acc[16];
#pragma unroll
    for (int o = 0; o < 16; ++o) acc[o] = 0.f;
    for (int tap = 0; tap < 63; ++tap) {
        float s = smp[tap * 64 + pxl];
        const float* sw = swb + tap * 64;
#pragma unroll
        for (int o = 0; o < 16; ++o) acc[o] += s * sw[o];
    }
    int hw = pxbase + pxl;
    size_t obase = (size_t)b * 64 * HW + (size_t)gu * 16 * HW + hw;
#pragma unroll
    for (int o = 0; o < 16; ++o)
        out[obase + (size_t)o * HW] = fmaxf(acc[o] + bsb[o], 0.f);
}

extern "C" void kernel_launch(void* const* d_in, const int* in_sizes, int n_in,
                              void* d_out, int out_size, void* d_ws, size_t ws_size,
                              hipStream_t stream) {
    (void)in_sizes; (void)n_in; (void)out_size; (void)ws_size;
    const float* inputs = (const float*)d_in[0];
    const float* w_in   = (const float*)d_in[1];  const float* b_in   = (const float*)d_in[2];
    const float* w_dn1a = (const float*)d_in[3];  const float* b_dn1a = (const float*)d_in[4];
    const float* w_dn1b = (const float*)d_in[5];  const float* b_dn1b = (const float*)d_in[6];
    const float* w_up1a = (const float*)d_in[7];  const float* b_up1a = (const float*)d_in[8];
    const float* wt_up1 = (const float*)d_in[9];  const float* bt_up1 = (const float*)d_in[10];
    const float* w_dn2a = (const float*)d_in[11]; const float* b_dn2a = (const float*)d_in[12];
    const float* w_dn2b = (const float*)d_in[13]; const float* b_dn2b = (const float*)d_in[14];
    const float* w_up2a = (const float*)d_in[15]; const float* b_up2a = (const float*)d_in[16];
    const float* wt_up2 = (const float*)d_in[17]; const float* bt_up2 = (const float*)d_in[18];
    const float* w_tra  = (const float*)d_in[19]; const float* b_tra  = (const float*)d_in[20];
    const float* w_trb  = (const float*)d_in[21]; const float* b_trb  = (const float*)d_in[22];
    const float* wt_tr  = (const float*)d_in[23]; const float* bt_tr  = (const float*)d_in[24];
    const float* w_out  = (const float*)d_in[25]; const float* b_out  = (const float*)d_in[26];
    const float* w_tf3a = (const float*)d_in[27]; const float* b_tf3a = (const float*)d_in[28];
    const float* w_tf3b = (const float*)d_in[29]; const float* b_tf3b = (const float*)d_in[30];
    const float* w_tf2  = (const float*)d_in[31]; const float* b_tf2  = (const float*)d_in[32];
    const float* w_om   = (const float*)d_in[33]; const float* b_om   = (const float*)d_in[34];
    const float* w_dc   = (const float*)d_in[35]; const float* b_dc   = (const float*)d_in[36];
    float* out = (float*)d_out;

    const int B = 2, nf = 32, H = 160, W = 160;
    const size_t n160 = (size_t)B * nf * 160 * 160;
    const size_t n80  = (size_t)B * nf * 80 * 80;
    const size_t n40  = (size_t)B * nf * 40 * 40;
    const size_t n20  = (size_t)B * nf * 20 * 20;

    float* ws = (float*)d_ws;
    float* F0    = ws;
    float* TMP80 = F0 + n160;
    float* F1    = TMP80 + n80;
    float* TMP40 = F1 + n80;
    float* F2    = TMP40 + n40;
    float* T20A  = F2 + n40;
    float* T20B  = T20A + n20;
    float* T40   = T20B + n20;
    float* T40B  = T40 + n40;
    float* T80   = T40B + n40;
    float* T80B  = T80 + n80;
    float* T160  = T80B + n80;
    float* TF    = T160 + n160;                       // layout kept
    float* XAREG = TF + n160;
    float* OM    = XAREG;
    float* WT2   = XAREG + 11757312;
    unsigned short* WBF    = (unsigned short*)(WT2 + 4032);
    unsigned short* XACL   = WBF + 27648;
    unsigned short* WOMF   = XACL + 11757312;
    unsigned short* OCL    = WOMF + 55296;
    unsigned short* MCL    = OCL + 1679616;
    unsigned short* TCL    = MCL + 1679616;
    unsigned short* CATCL  = TCL + 1679616;
    unsigned short* CATCL2 = CATCL + 860672;
    unsigned short* WTF2F  = CATCL2 + 279552;
    unsigned short* WOUTF  = WTF2F + 9216;
    unsigned short* WUP1F  = WOUTF + 9216;
    unsigned short* WUP2F  = WUP1F + 18432;

    const int bpc80_128 = 13;
    const int bpc40_64  = 7;
    const int bpc20_64  = 2;

    // fused head: conv3da_cl (2240) || w_in conv (400) || prep (607)
    const int PREP_NB = nblk(27648 + 4032 + 20 * 644 + 55296 + 9216 + 9216 + 18432 + 18432);
    head_k<<<2240 + 400 + PREP_NB, TPB, 0, stream>>>(
        inputs, w_tf3a, b_tf3a, XACL, w_in, b_in, F0,
        w_tf3b, w_dc, w_om, w_tf2, w_out, w_up1a, w_up2a,
        WBF, WOMF, WTF2F, WOUTF, WUP1F, WUP2F, WT2, MCL, TCL, OCL, B, H, W);

    // --- 2D U-Net branch ---
    conv2d_s2_t4_k<128><<<B * nf * bpc80_128, 128, 0, stream>>>(F0, w_dn1a, b_dn1a, TMP80, B, nf, 160, 160, nf, bpc80_128);
    conv2d_t4_k<128, 1, 0><<<B * nf * bpc80_128, 128, 0, stream>>>(TMP80, w_dn1b, b_dn1b, nullptr, F1, B, nf, 80, 80, nf, bpc80_128);
    conv2d_s2_t4_k<64><<<B * nf * bpc40_64, 64, 0, stream>>>(F1, w_dn2a, b_dn2a, TMP40, B, nf, 80, 80, nf, bpc40_64);
    conv2d_t4_k<64, 1, 0><<<B * nf * bpc40_64, 64, 0, stream>>>(TMP40, w_dn2b, b_dn2b, nullptr, F2, B, nf, 40, 40, nf, bpc40_64);
    conv2d_s2_t4_k<64><<<B * nf * bpc20_64, 64, 0, stream>>>(F2, w_tra, b_tra, T20A, B, nf, 40, 40, nf, bpc20_64);
    conv2d_t4_k<64, 1, 0><<<B * nf * bpc20_64, 64, 0, stream>>>(T20A, w_trb, b_trb, nullptr, T20B, B, nf, 20, 20, nf, bpc20_64);
    convt2d_t4_k<64><<<B * nf * bpc40_64, 64, 0, stream>>>(T20B, wt_tr, bt_tr, T40, B, nf, 20, 20, bpc40_64);
    cat2cl_k<40, 40, 42, 52><<<nblk(2 * 42 * 52), TPB, 0, stream>>>(T40, F2, CATCL2);
    conv_up2a_mfma_k<<<B * 60, TPB, 0, stream>>>(CATCL2, WUP2F, b_up2a, T40B, B);
    convt2d_t4_k<128><<<B * nf * bpc80_128, 128, 0, stream>>>(T40B, wt_up2, bt_up2, T80, B, nf, 40, 40, bpc80_128);
    cat2cl_k<80, 80, 82, 82><<<nblk(2 * 82 * 82), TPB, 0, stream>>>(T80, F1, CATCL);
    conv_up1a_mfma_k<<<B * 200, TPB, 0, stream>>>(CATCL, WUP1F, b_up1a, T80B, B);

    // fused mid: conv3db_mfma (1600) || convt2d_c4 up1 (400)
    mid_k<<<B * 800 + 400, TPB, 0, stream>>>(XACL, WBF, b_tf3b, MCL, T80B, wt_up1, bt_up1, T160, B);

    // FUSED = relu(conv_tf2(MEAN) + T160) -> TCL directly
    conv_nf_mfma_k<1, 1><<<B * 800, TPB, 0, stream>>>(MCL, WTF2F, b_tf2, T160, TCL, B);
    // w_out conv -> OCL directly
    conv_nf_mfma_k<0, 1><<<B * 800, TPB, 0, stream>>>(TCL, WOUTF, b_out, nullptr, OCL, B);
    // w_om head -> OM (fp32 ch-first, deform consumes)
    conv_om_mfma_k<<<B * 1600, TPB, 0, stream>>>(OCL, WOMF, b_om, OM, B);

    // --- deformable conv (two-phase) ---
    deform_conv2_k<<<B * (H * W / 64), TPB, 0, stream>>>(inputs, OM, WT2, b_dc, out, B, H, W);
}